// Round 2
// baseline (5036.660 us; speedup 1.0000x reference)
//
#include <hip/hip_runtime.h>
#include <math.h>

#define Hh 8
#define Bb 16
#define Nn 512
#define Dd 512
#define VDd 64
#define FFHh 2048
#define NPICKk 256
#define NORMF 0.125f

// swizzled 64x64 fp32 tile index: row r (0..63), float4-group g (0..15)
// addr = r*64 + ((g ^ ((r>>2)&15))<<2)  -> 16B aligned, <=2-way banks on hot reads
#define TIX(r, g) (((r) << 6) + ((((g) ^ (((r) >> 2) & 15))) << 2))

// ---------- transpose (H,D,VD) -> (D, H*VD) ----------
__global__ __launch_bounds__(256) void transpose_hw(const float* __restrict__ W,
                                                    float* __restrict__ WT) {
    int i = blockIdx.x * 256 + threadIdx.x;   // over D*H*VD = 262144
    int d = i >> 9;
    int c = i & 511;
    int h = c >> 6;
    int k = c & 63;
    WT[i] = W[h * (Dd * VDd) + d * VDd + k];
}

// ---------- generic fp32 GEMM, 64x64 tile, 256 threads, fused epilogue ----------
__global__ __launch_bounds__(256) void gemm_f32(
    const float* __restrict__ A, const float* __restrict__ B1,
    const float* __restrict__ B2, float* __restrict__ C,
    int M, int Nc, int K,
    const float* __restrict__ bias, const float* __restrict__ res,
    const float* __restrict__ alpha, int do_relu, int do_split)
{
    __shared__ __align__(16) float As[16 * 68];   // [k][r], stride 68
    __shared__ __align__(16) float Bs[16 * 64];   // [k][c]
    int tid = threadIdx.x;
    int r0 = blockIdx.y * 64;
    int c0 = blockIdx.x * 64;
    const float* B = (do_split && ((r0 & (Nn - 1)) >= NPICKk)) ? B2 : B1;
    int tx = tid & 15, ty = tid >> 4;
    float acc[4][4] = {};
    int ar = tid >> 2, ak = (tid & 3) * 4;
    int br = tid >> 4, bc = (tid & 15) * 4;
    const float* Aload = A + (size_t)(r0 + ar) * K + ak;
    const float* Bload = B + (size_t)br * Nc + c0 + bc;

    for (int kk = 0; kk < K; kk += 16) {
        float4 a4 = *(const float4*)(Aload + kk);
        float4 b4 = *(const float4*)(Bload + (size_t)kk * Nc);
        __syncthreads();
        As[(ak + 0) * 68 + ar] = a4.x;
        As[(ak + 1) * 68 + ar] = a4.y;
        As[(ak + 2) * 68 + ar] = a4.z;
        As[(ak + 3) * 68 + ar] = a4.w;
        *(float4*)&Bs[br * 64 + bc] = b4;
        __syncthreads();
#pragma unroll
        for (int k = 0; k < 16; ++k) {
            float4 av = *(const float4*)&As[k * 68 + ty * 4];
            float4 bv = *(const float4*)&Bs[k * 64 + tx * 4];
            acc[0][0] += av.x * bv.x; acc[0][1] += av.x * bv.y;
            acc[0][2] += av.x * bv.z; acc[0][3] += av.x * bv.w;
            acc[1][0] += av.y * bv.x; acc[1][1] += av.y * bv.y;
            acc[1][2] += av.y * bv.z; acc[1][3] += av.y * bv.w;
            acc[2][0] += av.z * bv.x; acc[2][1] += av.z * bv.y;
            acc[2][2] += av.z * bv.z; acc[2][3] += av.z * bv.w;
            acc[3][0] += av.w * bv.x; acc[3][1] += av.w * bv.y;
            acc[3][2] += av.w * bv.z; acc[3][3] += av.w * bv.w;
        }
    }

    float alp = alpha ? alpha[0] : 1.0f;
    int c = c0 + tx * 4;
    float4 bv4 = make_float4(0.f, 0.f, 0.f, 0.f);
    if (bias) bv4 = *(const float4*)(bias + c);
#pragma unroll
    for (int i = 0; i < 4; ++i) {
        int r = r0 + ty * 4 + i;
        float4 o;
        o.x = acc[i][0] + bv4.x; o.y = acc[i][1] + bv4.y;
        o.z = acc[i][2] + bv4.z; o.w = acc[i][3] + bv4.w;
        if (do_relu) {
            o.x = fmaxf(o.x, 0.f); o.y = fmaxf(o.y, 0.f);
            o.z = fmaxf(o.z, 0.f); o.w = fmaxf(o.w, 0.f);
        }
        o.x *= alp; o.y *= alp; o.z *= alp; o.w *= alp;
        if (res) {
            float4 r4 = *(const float4*)(res + (size_t)r * Nc + c);
            o.x += r4.x; o.y += r4.y; o.z += r4.z; o.w += r4.w;
        }
        *(float4*)(C + (size_t)r * Nc + c) = o;
    }
}

// ---------- HA diagonal scores: Sd[b,n,h] = NORM * QD[b,n,h,:] . K[b,dix,h,:] ----------
__global__ __launch_bounds__(256) void diag_dot(const float* __restrict__ QD,
                                                const float* __restrict__ K,
                                                float* __restrict__ Sdg) {
    int i = blockIdx.x * 256 + threadIdx.x;     // over B*N*H = 65536
    int h = i & 7, n = (i >> 3) & 511, b = i >> 12;
    int dix = (n < NPICKk) ? n + NPICKk : n - NPICKk;
    const float* q = QD + ((size_t)(b * Nn + n) * Hh + h) * VDd;
    const float* k = K + ((size_t)(b * Nn + dix) * Hh + h) * VDd;
    float s = 0.f;
#pragma unroll
    for (int d = 0; d < 64; d += 4) {
        float4 a = *(const float4*)(q + d);
        float4 c = *(const float4*)(k + d);
        s += a.x * c.x + a.y * c.y + a.z * c.z + a.w * c.w;
    }
    Sdg[i] = s * NORMF;
}

// ---------- register-blocked flash attention, 64-row Q tile / block ----------
// Layouts: Q/K/V/QA/QB/Out all (B,N,H,VD). HA: score = {exp(Q.K)+exp(QX.K)} per col,
// QX = QA for cols<256 (tiles 0..3) else QB; plus diag term Sd at col dix -> S[r][r] of tile td.
template <int HA>
__global__ __launch_bounds__(256) void attn2(
    const float* __restrict__ Qm, const float* __restrict__ Km,
    const float* __restrict__ Vm, const float* __restrict__ QAm,
    const float* __restrict__ QBm, const float* __restrict__ Sdg,
    float* __restrict__ Out)
{
    __shared__ __align__(16) float Qs[64 * 64];
    __shared__ __align__(16) float Ks[64 * 64];   // doubles as P buffer
    __shared__ __align__(16) float Vs[64 * 64];
    __shared__ __align__(16) float Qx[HA ? 64 * 64 : 4];
    __shared__ float sdl[64];

    const int tid = threadIdx.x;
    const int tx = tid & 15, ty = tid >> 4;
    const int b = blockIdx.z, h = blockIdx.y;
    const int n0 = blockIdx.x * 64;
    const int srow = tid >> 2, sg0 = (tid & 3) * 4;   // staging: row, first float4-group

    const size_t qbase = ((size_t)(b * Nn + n0 + srow) * Hh + h) * VDd + sg0 * 4;

    {   // stage Q (and QA, sdl), scaled by NORMF
        float4 r[4];
#pragma unroll
        for (int q = 0; q < 4; ++q) r[q] = *(const float4*)(Qm + qbase + 4 * q);
#pragma unroll
        for (int q = 0; q < 4; ++q) {
            float4 v = r[q];
            v.x *= NORMF; v.y *= NORMF; v.z *= NORMF; v.w *= NORMF;
            *(float4*)&Qs[TIX(srow, sg0 + q)] = v;
        }
        if (HA) {
#pragma unroll
            for (int q = 0; q < 4; ++q) r[q] = *(const float4*)(QAm + qbase + 4 * q);
#pragma unroll
            for (int q = 0; q < 4; ++q) {
                float4 v = r[q];
                v.x *= NORMF; v.y *= NORMF; v.z *= NORMF; v.w *= NORMF;
                *(float4*)&Qx[TIX(srow, sg0 + q)] = v;
            }
            if (tid < 64) sdl[tid] = Sdg[(size_t)(b * Nn + n0 + tid) * Hh + h];
        }
    }

    const int td = (n0 < NPICKk) ? ((n0 + NPICKk) >> 6) : ((n0 - NPICKk) >> 6);

    float M[4], L[4], O[4][4];
#pragma unroll
    for (int i = 0; i < 4; ++i) {
        M[i] = -INFINITY; L[i] = 0.f;
#pragma unroll
        for (int j = 0; j < 4; ++j) O[i][j] = 0.f;
    }

    for (int t = 0; t < 8; ++t) {
        // issue global loads for this tile (regs only, pre-barrier)
        float4 kr[4], vr[4], xr[4];
        const size_t gkv = ((size_t)(b * Nn + t * 64 + srow) * Hh + h) * VDd + sg0 * 4;
#pragma unroll
        for (int q = 0; q < 4; ++q) {
            kr[q] = *(const float4*)(Km + gkv + 4 * q);
            vr[q] = *(const float4*)(Vm + gkv + 4 * q);
        }
        if (HA && t == 4) {
#pragma unroll
            for (int q = 0; q < 4; ++q) xr[q] = *(const float4*)(QBm + qbase + 4 * q);
        }
        __syncthreads();   // prior tile's PV reads of Ks(P)/Vs complete
#pragma unroll
        for (int q = 0; q < 4; ++q) {
            *(float4*)&Ks[TIX(srow, sg0 + q)] = kr[q];
            *(float4*)&Vs[TIX(srow, sg0 + q)] = vr[q];
        }
        if (HA && t == 4) {
#pragma unroll
            for (int q = 0; q < 4; ++q) {
                float4 v = xr[q];
                v.x *= NORMF; v.y *= NORMF; v.z *= NORMF; v.w *= NORMF;
                *(float4*)&Qx[TIX(srow, sg0 + q)] = v;
            }
        }
        __syncthreads();   // staging visible

        // ---- scores: S = Qs @ Ks^T (and sX = Qx @ Ks^T) ----
        float s1[4][4], sX[4][4];
#pragma unroll
        for (int i = 0; i < 4; ++i)
#pragma unroll
            for (int j = 0; j < 4; ++j) { s1[i][j] = 0.f; sX[i][j] = 0.f; }

#pragma unroll
        for (int kg = 0; kg < 16; ++kg) {
            float4 kvv[4], qvv[4], xvv[4];
#pragma unroll
            for (int j = 0; j < 4; ++j) kvv[j] = *(const float4*)&Ks[TIX(4 * tx + j, kg)];
#pragma unroll
            for (int i = 0; i < 4; ++i) qvv[i] = *(const float4*)&Qs[TIX(4 * ty + i, kg)];
            if (HA) {
#pragma unroll
                for (int i = 0; i < 4; ++i) xvv[i] = *(const float4*)&Qx[TIX(4 * ty + i, kg)];
            }
#pragma unroll
            for (int i = 0; i < 4; ++i)
#pragma unroll
                for (int j = 0; j < 4; ++j) {
                    s1[i][j] += qvv[i].x * kvv[j].x + qvv[i].y * kvv[j].y
                              + qvv[i].z * kvv[j].z + qvv[i].w * kvv[j].w;
                    if (HA)
                        sX[i][j] += xvv[i].x * kvv[j].x + xvv[i].y * kvv[j].y
                                  + xvv[i].z * kvv[j].z + xvv[i].w * kvv[j].w;
                }
        }

        const bool dt = HA && (t == td) && (tx == ty);

        // ---- online softmax (rows span 16 contiguous lanes -> shfl width 16) ----
#pragma unroll
        for (int i = 0; i < 4; ++i) {
            float m = s1[i][0];
#pragma unroll
            for (int j = 1; j < 4; ++j) m = fmaxf(m, s1[i][j]);
            if (HA) {
#pragma unroll
                for (int j = 0; j < 4; ++j) m = fmaxf(m, sX[i][j]);
            }
            if (dt) m = fmaxf(m, sdl[4 * ty + i]);
#pragma unroll
            for (int o = 8; o >= 1; o >>= 1) m = fmaxf(m, __shfl_xor(m, o, 16));
            float mn = fmaxf(M[i], m);
            float sc = __expf(M[i] - mn);
            M[i] = mn; L[i] *= sc;
#pragma unroll
            for (int j = 0; j < 4; ++j) O[i][j] *= sc;
            float r = 0.f;
#pragma unroll
            for (int j = 0; j < 4; ++j) {
                float p = __expf(s1[i][j] - mn);
                if (HA) p += __expf(sX[i][j] - mn);
                if (dt && j == i) p += __expf(sdl[4 * ty + i] - mn);
                s1[i][j] = p;
                r += p;
            }
#pragma unroll
            for (int o = 8; o >= 1; o >>= 1) r += __shfl_xor(r, o, 16);
            L[i] += r;
        }
        __syncthreads();   // all Ks score reads done before P overwrite

#pragma unroll
        for (int i = 0; i < 4; ++i) {
            float4 p4 = make_float4(s1[i][0], s1[i][1], s1[i][2], s1[i][3]);
            *(float4*)&Ks[TIX(4 * ty + i, tx)] = p4;   // P[r][c], c-group = tx
        }
        __syncthreads();   // P visible

        // ---- O += P @ V ----
#pragma unroll
        for (int mg = 0; mg < 16; ++mg) {
            float4 pv[4];
#pragma unroll
            for (int i = 0; i < 4; ++i) pv[i] = *(const float4*)&Ks[TIX(4 * ty + i, mg)];
#pragma unroll
            for (int mm = 0; mm < 4; ++mm) {
                float4 vv = *(const float4*)&Vs[TIX(4 * mg + mm, tx)];
#pragma unroll
                for (int i = 0; i < 4; ++i) {
                    float p = (mm == 0) ? pv[i].x : (mm == 1) ? pv[i].y
                             : (mm == 2) ? pv[i].z : pv[i].w;
                    O[i][0] += p * vv.x; O[i][1] += p * vv.y;
                    O[i][2] += p * vv.z; O[i][3] += p * vv.w;
                }
            }
        }
    }

#pragma unroll
    for (int i = 0; i < 4; ++i) {
        float inv = 1.0f / L[i];
        float4 o = make_float4(O[i][0] * inv, O[i][1] * inv, O[i][2] * inv, O[i][3] * inv);
        *(float4*)(Out + ((size_t)(b * Nn + n0 + 4 * ty + i) * Hh + h) * VDd + 4 * tx) = o;
    }
}

extern "C" void kernel_launch(void* const* d_in, const int* in_sizes, int n_in,
                              void* d_out, int out_size, void* d_ws, size_t ws_size,
                              hipStream_t stream)
{
    const float* x = (const float*)d_in[0];

    int dictOrder = (in_sizes[18] != 512);
    const float* comb_w  = (const float*)d_in[17];
    const float* comb2_w = (const float*)d_in[dictOrder ? 18 : 19];
    const float* comb3_w = (const float*)d_in[dictOrder ? 19 : 21];
    const float* comb_b  = (const float*)d_in[dictOrder ? 20 : 18];
    const float* comb2_b = (const float*)d_in[dictOrder ? 21 : 20];
    const float* comb3_b = (const float*)d_in[22];
    const float* alpha1 = (const float*)d_in[23];
    const float* alpha2 = (const float*)d_in[24];
    const float* alpha3 = (const float*)d_in[25];
    const float* ff1_w1 = (const float*)d_in[26];
    const float* ff1_b1 = (const float*)d_in[27];
    const float* ff1_w2 = (const float*)d_in[28];
    const float* ff1_b2 = (const float*)d_in[29];
    const float* ffa1   = (const float*)d_in[30];
    const float* ff2_w1 = (const float*)d_in[31];
    const float* ff2_b1 = (const float*)d_in[32];
    const float* ff2_w2 = (const float*)d_in[33];
    const float* ff2_b2 = (const float*)d_in[34];
    const float* ffa2   = (const float*)d_in[35];
    const float* ff3_w1 = (const float*)d_in[36];
    const float* ff3_b1 = (const float*)d_in[37];
    const float* ff3_w2 = (const float*)d_in[38];
    const float* ff3_b2 = (const float*)d_in[39];
    const float* ffa3   = (const float*)d_in[40];
    const float* Wq_w   = (const float*)d_in[10];
    const float* Wk_w   = (const float*)d_in[11];
    const float* Wv_w   = (const float*)d_in[12];
    const float* Wq2p_w = (const float*)d_in[13];
    const float* Wq2d_w = (const float*)d_in[14];
    const float* Wk2_w  = (const float*)d_in[15];
    const float* Wv2_w  = (const float*)d_in[16];

    // Workspace layout (floats)
    float* WT = (float*)d_ws;
    const size_t WSZ = 512 * 512;
    const size_t SB = (size_t)Bb * Nn * 512;
    float* bufQ  = WT + 9 * WSZ;
    float* bufK  = bufQ + SB;
    float* bufV  = bufK + SB;
    float* bufQA = bufV + SB;
    float* bufQB = bufQA + SB;
    float* bufQD = bufQB + SB;
    float* bufHA = bufQD + SB;
    float* tmp   = bufQ;        // FF hidden aliases bufQ.. (dead then)
    float* Sd    = WT;          // diag scores (B*N*H) alias WT: WT dead after projections
    float* cur   = (float*)d_out;

    dim3 tb(256);

    // 1. transpose the 9 per-head weights: WT0..WT8 = Wq,Wk,Wv,W1..W6
    for (int i = 0; i < 9; ++i)
        hipLaunchKernelGGL(transpose_hw, dim3(1024), tb, 0, stream,
                           (const float*)d_in[1 + i], WT + i * WSZ);

    auto gemm = [&](const float* A, const float* B1v, const float* B2v, float* Cv,
                    int M, int Ncc, int Kc, const float* bias, const float* res,
                    const float* alp, int relu, int split) {
        hipLaunchKernelGGL(gemm_f32, dim3(Ncc / 64, M / 64), tb, 0, stream,
                           A, B1v, B2v, Cv, M, Ncc, Kc, bias, res, alp, relu, split);
    };
    const int TOK = Bb * Nn;  // 8192

    // 2. HA projections
    gemm(x, WT + 0 * WSZ, WT + 0 * WSZ, bufQ,  TOK, 512, 512, nullptr, nullptr, nullptr, 0, 0);
    gemm(x, WT + 1 * WSZ, WT + 1 * WSZ, bufK,  TOK, 512, 512, nullptr, nullptr, nullptr, 0, 0);
    gemm(x, WT + 2 * WSZ, WT + 2 * WSZ, bufV,  TOK, 512, 512, nullptr, nullptr, nullptr, 0, 0);
    gemm(x, WT + 4 * WSZ, WT + 8 * WSZ, bufQA, TOK, 512, 512, nullptr, nullptr, nullptr, 0, 1); // W2/W6
    gemm(x, WT + 5 * WSZ, WT + 7 * WSZ, bufQB, TOK, 512, 512, nullptr, nullptr, nullptr, 0, 1); // W3/W5
    gemm(x, WT + 3 * WSZ, WT + 6 * WSZ, bufQD, TOK, 512, 512, nullptr, nullptr, nullptr, 0, 1); // W1/W4

    // 3. HA diag scores, then fused attention -> bufHA
    hipLaunchKernelGGL(diag_dot, dim3(Bb * Nn * Hh / 256), tb, 0, stream, bufQD, bufK, Sd);
    hipLaunchKernelGGL((attn2<1>), dim3(Nn / 64, Hh, Bb), tb, 0, stream,
                       bufQ, bufK, bufV, bufQA, bufQB, Sd, bufHA);

    // 4. cur = x + alpha3*(ha @ comb3_w + comb3_b)
    gemm(bufHA, comb3_w, comb3_w, cur, TOK, 512, 512, comb3_b, x, alpha3, 0, 0);

    // 5. FF3
    gemm(cur, ff3_w1, ff3_w1, tmp, TOK, 2048, 512, ff3_b1, nullptr, nullptr, 1, 0);
    gemm(tmp, ff3_w2, ff3_w2, cur, TOK, 512, 2048, ff3_b2, cur, ffa3, 0, 0);

    // 6. MHA1
    gemm(cur, Wq_w, Wq_w, bufQ, TOK, 512, 512, nullptr, nullptr, nullptr, 0, 0);
    gemm(cur, Wk_w, Wk_w, bufK, TOK, 512, 512, nullptr, nullptr, nullptr, 0, 0);
    gemm(cur, Wv_w, Wv_w, bufV, TOK, 512, 512, nullptr, nullptr, nullptr, 0, 0);
    hipLaunchKernelGGL((attn2<0>), dim3(Nn / 64, Hh, Bb), tb, 0, stream,
                       bufQ, bufK, bufV, nullptr, nullptr, nullptr, bufHA);
    gemm(bufHA, comb_w, comb_w, cur, TOK, 512, 512, comb_b, cur, alpha1, 0, 0);

    // 7. FF1
    gemm(cur, ff1_w1, ff1_w1, tmp, TOK, 2048, 512, ff1_b1, nullptr, nullptr, 1, 0);
    gemm(tmp, ff1_w2, ff1_w2, cur, TOK, 512, 2048, ff1_b2, cur, ffa1, 0, 0);

    // 8. MHA2
    gemm(cur, Wq2p_w, Wq2d_w, bufQ, TOK, 512, 512, nullptr, nullptr, nullptr, 0, 1);
    gemm(cur, Wk2_w, Wk2_w, bufK, TOK, 512, 512, nullptr, nullptr, nullptr, 0, 0);
    gemm(cur, Wv2_w, Wv2_w, bufV, TOK, 512, 512, nullptr, nullptr, nullptr, 0, 0);
    hipLaunchKernelGGL((attn2<0>), dim3(Nn / 64, Hh, Bb), tb, 0, stream,
                       bufQ, bufK, bufV, nullptr, nullptr, nullptr, bufHA);
    gemm(bufHA, comb2_w, comb2_w, cur, TOK, 512, 512, comb2_b, cur, alpha2, 0, 0);

    // 9. FF2 -> final output in cur == d_out
    gemm(cur, ff2_w1, ff2_w1, tmp, TOK, 2048, 512, ff2_b1, nullptr, nullptr, 1, 0);
    gemm(tmp, ff2_w2, ff2_w2, cur, TOK, 512, 2048, ff2_b2, cur, ffa2, 0, 0);
}

// Round 3
// 2742.937 us; speedup vs baseline: 1.8362x; 1.8362x over previous
//
#include <hip/hip_runtime.h>
#include <math.h>

#define Hh 8
#define Bb 16
#define Nn 512
#define Dd 512
#define VDd 64
#define NPICKk 256
#define NORMF 0.125f

typedef unsigned short ushortT;
typedef __bf16 bf16x8 __attribute__((ext_vector_type(8)));
typedef float f32x4 __attribute__((ext_vector_type(4)));

__device__ inline ushortT f2bf(float f) {
    union { float f; unsigned int u; } v; v.f = f;
    unsigned int r = v.u + 0x7FFFu + ((v.u >> 16) & 1u);
    return (ushortT)(r >> 16);
}
__device__ inline float bf2f(ushortT u) {
    union { unsigned int u; float f; } v; v.u = ((unsigned int)u) << 16;
    return v.f;
}
// async global->LDS, 16B per lane; LDS dest = wave-uniform base + lane*16
__device__ inline void gload16(const void* gptr, void* ldsptr) {
    auto g = reinterpret_cast<const __attribute__((address_space(1))) unsigned int*>(
        reinterpret_cast<uintptr_t>(gptr));
    auto l = reinterpret_cast<__attribute__((address_space(3))) unsigned int*>(
        reinterpret_cast<uintptr_t>(ldsptr));
    __builtin_amdgcn_global_load_lds(g, l, 16, 0, 0);
}

// swizzled fp32 64x64 tile: row r, logical float4-group g -> float index
#define SW(r, g) (((r) << 6) + ((((g) ^ (((r) >> 2) & 15))) << 2))

// ---------- fp32 -> bf16 elementwise (x) ----------
__global__ __launch_bounds__(256) void castx(const float* __restrict__ in,
                                             ushortT* __restrict__ out) {
    int i = blockIdx.x * 256 + threadIdx.x;
    float4 v = *(const float4*)&in[(size_t)i * 4];
    ushort4 o; o.x = f2bf(v.x); o.y = f2bf(v.y); o.z = f2bf(v.z); o.w = f2bf(v.w);
    *(ushort4*)&out[(size_t)i * 4] = o;
}

// ---------- transpose + cast: out[c][r] = in[r][c], bf16 out ----------
__global__ __launch_bounds__(256) void tcast(const float* __restrict__ in,
                                             ushortT* __restrict__ out,
                                             int in_ld, int out_ld,
                                             long in_zstride, long out_zoff) {
    __shared__ float T[64][65];
    in += (size_t)blockIdx.z * in_zstride;
    out += (size_t)blockIdx.z * out_zoff;
    int r0 = blockIdx.y * 64, c0 = blockIdx.x * 64;
    int tr = threadIdx.x >> 4, tc4 = (threadIdx.x & 15) * 4;
#pragma unroll
    for (int p = 0; p < 4; ++p) {
        float4 v = *(const float4*)&in[(size_t)(r0 + tr + p * 16) * in_ld + c0 + tc4];
        T[tr + p * 16][tc4 + 0] = v.x; T[tr + p * 16][tc4 + 1] = v.y;
        T[tr + p * 16][tc4 + 2] = v.z; T[tr + p * 16][tc4 + 3] = v.w;
    }
    __syncthreads();
#pragma unroll
    for (int p = 0; p < 4; ++p) {
        int orow = c0 + tr + p * 16;
        int ocol = r0 + tc4;
        ushort4 o;
        o.x = f2bf(T[tc4 + 0][tr + p * 16]);
        o.y = f2bf(T[tc4 + 1][tr + p * 16]);
        o.z = f2bf(T[tc4 + 2][tr + p * 16]);
        o.w = f2bf(T[tc4 + 3][tr + p * 16]);
        *(ushort4*)&out[(size_t)orow * out_ld + ocol] = o;
    }
}

// ---------- bf16 MFMA GEMM: C = epilogue(A @ B^T) ----------
// A: M x K bf16 row-major. B1/B2: N x K bf16 (pre-transposed). 128x128 tile, BK=64,
// 4 waves (2x2 of 64x64), global_load_lds staging, linear LDS (m97 structure).
__global__ __launch_bounds__(256) void gemm_bf(
    const ushortT* __restrict__ A, const ushortT* __restrict__ B1,
    const ushortT* __restrict__ B2, float* __restrict__ outF,
    ushortT* __restrict__ outB, int M, int N, int K,
    const float* __restrict__ bias, const float* __restrict__ res,
    const float* __restrict__ alpha, int do_relu, int do_split)
{
    __shared__ __align__(16) ushortT As[128 * 64];
    __shared__ __align__(16) ushortT Bs[128 * 64];
    const int tid = threadIdx.x;
    const int wid = tid >> 6, lane = tid & 63;
    const int wm = wid >> 1, wn = wid & 1;
    const int r0 = blockIdx.y * 128, c0 = blockIdx.x * 128;
    const ushortT* Bt = (do_split && ((r0 & (Nn - 1)) >= NPICKk)) ? B2 : B1;
    const int srow = lane >> 3, g = lane & 7;

    f32x4 acc[4][4] = {};

    for (int kt = 0; kt < K; kt += 64) {
        __syncthreads();
#pragma unroll
        for (int i = 0; i < 4; ++i) {
            int off = wid * 4096 + i * 1024;
            int row = wid * 32 + i * 8 + srow;
            gload16(A + (size_t)(r0 + row) * K + kt + g * 8,
                    (char*)As + off + lane * 16);
            gload16(Bt + (size_t)(c0 + row) * K + kt + g * 8,
                    (char*)Bs + off + lane * 16);
        }
        asm volatile("s_waitcnt vmcnt(0)" ::: "memory");
        __syncthreads();
#pragma unroll
        for (int kk = 0; kk < 2; ++kk) {
            bf16x8 af[4], bfv[4];
#pragma unroll
            for (int mi = 0; mi < 4; ++mi)
                af[mi] = *(const bf16x8*)&As[(wm * 64 + mi * 16 + (lane & 15)) * 64
                                             + kk * 32 + (lane >> 4) * 8];
#pragma unroll
            for (int ni = 0; ni < 4; ++ni)
                bfv[ni] = *(const bf16x8*)&Bs[(wn * 64 + ni * 16 + (lane & 15)) * 64
                                              + kk * 32 + (lane >> 4) * 8];
#pragma unroll
            for (int mi = 0; mi < 4; ++mi)
#pragma unroll
                for (int ni = 0; ni < 4; ++ni)
                    acc[mi][ni] = __builtin_amdgcn_mfma_f32_16x16x32_bf16(
                        af[mi], bfv[ni], acc[mi][ni], 0, 0, 0);
        }
    }

    const float alp = alpha ? alpha[0] : 1.0f;
#pragma unroll
    for (int ni = 0; ni < 4; ++ni) {
        int col = c0 + wn * 64 + ni * 16 + (lane & 15);
        float bv = bias ? bias[col] : 0.f;
#pragma unroll
        for (int mi = 0; mi < 4; ++mi) {
            f32x4 a = acc[mi][ni];
#pragma unroll
            for (int r = 0; r < 4; ++r) {
                int row = r0 + wm * 64 + mi * 16 + (lane >> 4) * 4 + r;
                float v = a[r] + bv;
                if (do_relu) v = fmaxf(v, 0.f);
                v *= alp;
                size_t idx = (size_t)row * N + col;
                if (res) v += res[idx];
                if (outF) outF[idx] = v;
                if (outB) outB[idx] = f2bf(v);
            }
        }
    }
}

// ---------- HA diagonal scores (QD in bf16) ----------
__global__ __launch_bounds__(256) void diag_dot_b(const ushortT* __restrict__ QD,
                                                  const float* __restrict__ K,
                                                  float* __restrict__ Sdg) {
    int i = blockIdx.x * 256 + threadIdx.x;     // B*N*H = 65536
    int h = i & 7, n = (i >> 3) & 511, b = i >> 12;
    int dix = (n < NPICKk) ? n + NPICKk : n - NPICKk;
    const ushortT* q = QD + ((size_t)(b * Nn + n) * Hh + h) * VDd;
    const float* k = K + ((size_t)(b * Nn + dix) * Hh + h) * VDd;
    float s = 0.f;
#pragma unroll
    for (int d = 0; d < 64; d += 4) {
        ushort4 a = *(const ushort4*)(q + d);
        float4 c = *(const float4*)(k + d);
        s += bf2f(a.x) * c.x + bf2f(a.y) * c.y + bf2f(a.z) * c.z + bf2f(a.w) * c.w;
    }
    Sdg[i] = s * NORMF;
}

// ---------- flash attention, fp32, global_load_lds staging + pre-swizzled source ----------
// Q/K/V/QA/QB: (B,N,H,VD) fp32. Out: bf16 (B,N,H,VD).
template <int HA>
__global__ __launch_bounds__(256) void attn3(
    const float* __restrict__ Qm, const float* __restrict__ Km,
    const float* __restrict__ Vm, const float* __restrict__ QAm,
    const float* __restrict__ QBm, const float* __restrict__ Sdg,
    ushortT* __restrict__ Out)
{
    __shared__ __align__(16) float Qs[64 * 64];
    __shared__ __align__(16) float Ks[64 * 64];   // doubles as P buffer
    __shared__ __align__(16) float Vs[64 * 64];
    __shared__ __align__(16) float Qx[HA ? 64 * 64 : 16];
    __shared__ float sdl[64];

    const int tid = threadIdx.x;
    const int wid = tid >> 6, lane = tid & 63;
    const int tx = tid & 15, ty = tid >> 4;
    const int b = blockIdx.z, h = blockIdx.y, n0 = blockIdx.x * 64;

    // staging geometry: per wave 4 issues of 1KB; off = byte offset in 16KB tile
    const int soff = wid * 4096 + lane * 16;

    // stage Q (+QA) via DMA; swizzle applied on the GLOBAL source group
#pragma unroll
    for (int i = 0; i < 4; ++i) {
        int off = soff + i * 1024;
        int row = off >> 8, gg = (off >> 4) & 15;
        int gs = gg ^ ((row >> 2) & 15);
        size_t gidx = (((size_t)(b * Nn + n0 + row) * Hh + h) << 6) + gs * 4;
        gload16(Qm + gidx, (char*)Qs + off);
        if (HA) gload16(QAm + gidx, (char*)Qx + off);
    }
    if (HA && tid < 64) sdl[tid] = Sdg[((size_t)(b * Nn + n0 + tid)) * Hh + h];
    const int td = (n0 < NPICKk) ? ((n0 + NPICKk) >> 6) : ((n0 - NPICKk) >> 6);

    float M[4], L[4], O[4][4];
#pragma unroll
    for (int i = 0; i < 4; ++i) {
        M[i] = -INFINITY; L[i] = 0.f;
#pragma unroll
        for (int j = 0; j < 4; ++j) O[i][j] = 0.f;
    }

    for (int t = 0; t < 8; ++t) {
        __syncthreads();   // prior-iter LDS reads done
#pragma unroll
        for (int i = 0; i < 4; ++i) {
            int off = soff + i * 1024;
            int row = off >> 8, gg = (off >> 4) & 15;
            int gs = gg ^ ((row >> 2) & 15);
            size_t gidx = (((size_t)(b * Nn + t * 64 + row) * Hh + h) << 6) + gs * 4;
            gload16(Km + gidx, (char*)Ks + off);
            gload16(Vm + gidx, (char*)Vs + off);
            if (HA && t == 4) {
                size_t qidx = (((size_t)(b * Nn + n0 + row) * Hh + h) << 6) + gs * 4;
                gload16(QBm + qidx, (char*)Qx + off);
            }
        }
        asm volatile("s_waitcnt vmcnt(0)" ::: "memory");
        __syncthreads();   // staged data visible

        // ---- scores ----
        float s1[4][4], sX[4][4];
#pragma unroll
        for (int i = 0; i < 4; ++i)
#pragma unroll
            for (int j = 0; j < 4; ++j) { s1[i][j] = 0.f; sX[i][j] = 0.f; }

#pragma unroll
        for (int kg = 0; kg < 16; ++kg) {
            float4 kv[4], qv[4], xv[4];
#pragma unroll
            for (int j = 0; j < 4; ++j) kv[j] = *(const float4*)&Ks[SW(4 * tx + j, kg)];
#pragma unroll
            for (int i = 0; i < 4; ++i) qv[i] = *(const float4*)&Qs[SW(4 * ty + i, kg)];
            if (HA) {
#pragma unroll
                for (int i = 0; i < 4; ++i) xv[i] = *(const float4*)&Qx[SW(4 * ty + i, kg)];
            }
#pragma unroll
            for (int i = 0; i < 4; ++i)
#pragma unroll
                for (int j = 0; j < 4; ++j) {
                    s1[i][j] += qv[i].x * kv[j].x + qv[i].y * kv[j].y
                              + qv[i].z * kv[j].z + qv[i].w * kv[j].w;
                    if (HA)
                        sX[i][j] += xv[i].x * kv[j].x + xv[i].y * kv[j].y
                                  + xv[i].z * kv[j].z + xv[i].w * kv[j].w;
                }
        }
#pragma unroll
        for (int i = 0; i < 4; ++i)
#pragma unroll
            for (int j = 0; j < 4; ++j) { s1[i][j] *= NORMF; sX[i][j] *= NORMF; }

        const bool dt = HA && (t == td) && (tx == ty);

        // ---- online softmax (row = 16 lanes) ----
#pragma unroll
        for (int i = 0; i < 4; ++i) {
            float m = s1[i][0];
#pragma unroll
            for (int j = 1; j < 4; ++j) m = fmaxf(m, s1[i][j]);
            if (HA) {
#pragma unroll
                for (int j = 0; j < 4; ++j) m = fmaxf(m, sX[i][j]);
            }
            if (dt) m = fmaxf(m, sdl[4 * ty + i]);
#pragma unroll
            for (int o = 8; o >= 1; o >>= 1) m = fmaxf(m, __shfl_xor(m, o, 16));
            float mn = fmaxf(M[i], m);
            float sc = __expf(M[i] - mn);
            M[i] = mn; L[i] *= sc;
#pragma unroll
            for (int j = 0; j < 4; ++j) O[i][j] *= sc;
            float r = 0.f;
#pragma unroll
            for (int j = 0; j < 4; ++j) {
                float p = __expf(s1[i][j] - mn);
                if (HA) p += __expf(sX[i][j] - mn);
                if (dt && j == i) p += __expf(sdl[4 * ty + i] - mn);
                s1[i][j] = p;
                r += p;
            }
#pragma unroll
            for (int o = 8; o >= 1; o >>= 1) r += __shfl_xor(r, o, 16);
            L[i] += r;
        }
        __syncthreads();   // score reads of Ks done

#pragma unroll
        for (int i = 0; i < 4; ++i)
            *(float4*)&Ks[SW(4 * ty + i, tx)] =
                make_float4(s1[i][0], s1[i][1], s1[i][2], s1[i][3]);
        __syncthreads();   // P visible

        // ---- O += P @ V ----
#pragma unroll
        for (int mg = 0; mg < 16; ++mg) {
            float4 pv[4];
#pragma unroll
            for (int i = 0; i < 4; ++i) pv[i] = *(const float4*)&Ks[SW(4 * ty + i, mg)];
#pragma unroll
            for (int mm = 0; mm < 4; ++mm) {
                float4 vv = *(const float4*)&Vs[SW(4 * mg + mm, tx)];
#pragma unroll
                for (int i = 0; i < 4; ++i) {
                    float p = (mm == 0) ? pv[i].x : (mm == 1) ? pv[i].y
                             : (mm == 2) ? pv[i].z : pv[i].w;
                    O[i][0] += p * vv.x; O[i][1] += p * vv.y;
                    O[i][2] += p * vv.z; O[i][3] += p * vv.w;
                }
            }
        }
    }

#pragma unroll
    for (int i = 0; i < 4; ++i) {
        float inv = 1.0f / L[i];
        ushort4 o;
        o.x = f2bf(O[i][0] * inv); o.y = f2bf(O[i][1] * inv);
        o.z = f2bf(O[i][2] * inv); o.w = f2bf(O[i][3] * inv);
        *(ushort4*)&Out[(((size_t)(b * Nn + n0 + 4 * ty + i) * Hh + h) << 6) + 4 * tx] = o;
    }
}

extern "C" void kernel_launch(void* const* d_in, const int* in_sizes, int n_in,
                              void* d_out, int out_size, void* d_ws, size_t ws_size,
                              hipStream_t stream)
{
    const float* x = (const float*)d_in[0];

    int dictOrder = (in_sizes[18] != 512);
    const float* comb_w  = (const float*)d_in[17];
    const float* comb2_w = (const float*)d_in[dictOrder ? 18 : 19];
    const float* comb3_w = (const float*)d_in[dictOrder ? 19 : 21];
    const float* comb_b  = (const float*)d_in[dictOrder ? 20 : 18];
    const float* comb2_b = (const float*)d_in[dictOrder ? 21 : 20];
    const float* comb3_b = (const float*)d_in[22];
    const float* alpha1 = (const float*)d_in[23];
    const float* alpha2 = (const float*)d_in[24];
    const float* alpha3 = (const float*)d_in[25];
    const float* ff1_w1 = (const float*)d_in[26];
    const float* ff1_b1 = (const float*)d_in[27];
    const float* ff1_w2 = (const float*)d_in[28];
    const float* ff1_b2 = (const float*)d_in[29];
    const float* ffa1   = (const float*)d_in[30];
    const float* ff2_w1 = (const float*)d_in[31];
    const float* ff2_b1 = (const float*)d_in[32];
    const float* ff2_w2 = (const float*)d_in[33];
    const float* ff2_b2 = (const float*)d_in[34];
    const float* ffa2   = (const float*)d_in[35];
    const float* ff3_w1 = (const float*)d_in[36];
    const float* ff3_b1 = (const float*)d_in[37];
    const float* ff3_w2 = (const float*)d_in[38];
    const float* ff3_b2 = (const float*)d_in[39];
    const float* ffa3   = (const float*)d_in[40];

    // ---- workspace layout (bytes) ----
    char* W = (char*)d_ws;
    ushortT* wbHead = (ushortT*)(W + 0);           // 9 x (512x512)
    ushortT* wbMha  = (ushortT*)(W + 4718592);     // 7 x (512x512)
    ushortT* wbComb = (ushortT*)(W + 8388608);     // 3 x (512x512)
    ushortT* wbFf1  = (ushortT*)(W + 9961472);     // 3 x (2048x512)
    ushortT* wbFf2  = (ushortT*)(W + 16252928);    // 3 x (512x2048)
    ushortT* xbf    = (ushortT*)(W + 22544384);    // 8192x512 bf16; later bufHA
    float*   Sd     = (float*)  (W + 30932992);    // 65536 f32
    float*   bufQ   = (float*)  (W + 31195136);    // 8192x512 f32 each
    float*   bufK   = (float*)  (W + 47972352);
    float*   bufV   = (float*)  (W + 64749568);
    float*   bufQA  = (float*)  (W + 81526784);
    float*   bufQB  = (float*)  (W + 98304000);
    ushortT* bufQDb = (ushortT*)(W + 115081216);   // 8192x512 bf16; later curb
    ushortT* hidden = (ushortT*)(W + 81526784);    // 8192x2048 bf16, aliases QA+QB
    ushortT* bufHA  = xbf;                         // attn out bf16, aliases xbf
    ushortT* curb   = bufQDb;                      // bf16 shadow of residual stream
    float*   cur    = (float*)d_out;

    dim3 tb(256);
    const int TOK = Bb * Nn;  // 8192
    const size_t WS = 512 * 512;       // elems per square weight
    const size_t WF = 2048 * 512;      // elems per FF weight

    // 1. casts / transposes
    hipLaunchKernelGGL(castx, dim3(TOK * 512 / 1024), tb, 0, stream, x, xbf);
    for (int i = 0; i < 9; ++i)   // per-head weights (H,D,VD) -> (H*VD, D)
        hipLaunchKernelGGL(tcast, dim3(1, 8, 8), tb, 0, stream,
                           (const float*)d_in[1 + i], wbHead + i * WS,
                           64, 512, (long)(512 * 64), (long)(64 * 512));
    for (int i = 0; i < 7; ++i)   // mha weights (512,512) -> T
        hipLaunchKernelGGL(tcast, dim3(8, 8, 1), tb, 0, stream,
                           (const float*)d_in[10 + i], wbMha + i * WS, 512, 512, 0L, 0L);
    const float* combs[3] = { comb_w, comb2_w, comb3_w };
    for (int i = 0; i < 3; ++i)
        hipLaunchKernelGGL(tcast, dim3(8, 8, 1), tb, 0, stream,
                           combs[i], wbComb + i * WS, 512, 512, 0L, 0L);
    const float* ffw1[3] = { ff1_w1, ff2_w1, ff3_w1 };
    const float* ffw2[3] = { ff1_w2, ff2_w2, ff3_w2 };
    for (int i = 0; i < 3; ++i) {
        hipLaunchKernelGGL(tcast, dim3(32, 8, 1), tb, 0, stream,
                           ffw1[i], wbFf1 + i * WF, 2048, 512, 0L, 0L);
        hipLaunchKernelGGL(tcast, dim3(8, 32, 1), tb, 0, stream,
                           ffw2[i], wbFf2 + i * WF, 512, 2048, 0L, 0L);
    }

    auto gemm = [&](const ushortT* A, const ushortT* B1v, const ushortT* B2v,
                    float* oF, ushortT* oB, int M, int Ncc, int Kc,
                    const float* bias, const float* res, const float* alp,
                    int relu, int split) {
        hipLaunchKernelGGL(gemm_bf, dim3(Ncc / 128, M / 128), tb, 0, stream,
                           A, B1v, B2v, oF, oB, M, Ncc, Kc, bias, res, alp, relu, split);
    };

    // 2. HA projections (A = x_bf)
    gemm(xbf, wbHead + 0 * WS, wbHead + 0 * WS, bufQ,  nullptr, TOK, 512, 512, nullptr, nullptr, nullptr, 0, 0);
    gemm(xbf, wbHead + 1 * WS, wbHead + 1 * WS, bufK,  nullptr, TOK, 512, 512, nullptr, nullptr, nullptr, 0, 0);
    gemm(xbf, wbHead + 2 * WS, wbHead + 2 * WS, bufV,  nullptr, TOK, 512, 512, nullptr, nullptr, nullptr, 0, 0);
    gemm(xbf, wbHead + 4 * WS, wbHead + 8 * WS, bufQA, nullptr, TOK, 512, 512, nullptr, nullptr, nullptr, 0, 1); // W2/W6
    gemm(xbf, wbHead + 5 * WS, wbHead + 7 * WS, bufQB, nullptr, TOK, 512, 512, nullptr, nullptr, nullptr, 0, 1); // W3/W5
    gemm(xbf, wbHead + 3 * WS, wbHead + 6 * WS, nullptr, bufQDb, TOK, 512, 512, nullptr, nullptr, nullptr, 0, 1); // W1/W4

    // 3. HA attention
    hipLaunchKernelGGL(diag_dot_b, dim3(Bb * Nn * Hh / 256), tb, 0, stream, bufQDb, bufK, Sd);
    hipLaunchKernelGGL((attn3<1>), dim3(Nn / 64, Hh, Bb), tb, 0, stream,
                       bufQ, bufK, bufV, bufQA, bufQB, Sd, bufHA);

    // 4. cur = x + alpha3*(ha @ comb3 + b3);  FF3
    gemm(bufHA, wbComb + 2 * WS, wbComb + 2 * WS, cur, curb, TOK, 512, 512, comb3_b, x, alpha3, 0, 0);
    gemm(curb, wbFf1 + 2 * WF, wbFf1 + 2 * WF, nullptr, hidden, TOK, 2048, 512, ff3_b1, nullptr, nullptr, 1, 0);
    gemm(hidden, wbFf2 + 2 * WF, wbFf2 + 2 * WF, cur, curb, TOK, 512, 2048, ff3_b2, cur, ffa3, 0, 0);

    // 5. MHA1
    gemm(curb, wbMha + 0 * WS, wbMha + 0 * WS, bufQ, nullptr, TOK, 512, 512, nullptr, nullptr, nullptr, 0, 0);
    gemm(curb, wbMha + 1 * WS, wbMha + 1 * WS, bufK, nullptr, TOK, 512, 512, nullptr, nullptr, nullptr, 0, 0);
    gemm(curb, wbMha + 2 * WS, wbMha + 2 * WS, bufV, nullptr, TOK, 512, 512, nullptr, nullptr, nullptr, 0, 0);
    hipLaunchKernelGGL((attn3<0>), dim3(Nn / 64, Hh, Bb), tb, 0, stream,
                       bufQ, bufK, bufV, nullptr, nullptr, nullptr, bufHA);
    gemm(bufHA, wbComb + 0 * WS, wbComb + 0 * WS, cur, curb, TOK, 512, 512, comb_b, cur, alpha1, 0, 0);
    gemm(curb, wbFf1 + 0 * WF, wbFf1 + 0 * WF, nullptr, hidden, TOK, 2048, 512, ff1_b1, nullptr, nullptr, 1, 0);
    gemm(hidden, wbFf2 + 0 * WF, wbFf2 + 0 * WF, cur, curb, TOK, 512, 2048, ff1_b2, cur, ffa1, 0, 0);

    // 6. MHA2 (split Q: Wq2p / Wq2d)
    gemm(curb, wbMha + 3 * WS, wbMha + 4 * WS, bufQ, nullptr, TOK, 512, 512, nullptr, nullptr, nullptr, 0, 1);
    gemm(curb, wbMha + 5 * WS, wbMha + 5 * WS, bufK, nullptr, TOK, 512, 512, nullptr, nullptr, nullptr, 0, 0);
    gemm(curb, wbMha + 6 * WS, wbMha + 6 * WS, bufV, nullptr, TOK, 512, 512, nullptr, nullptr, nullptr, 0, 0);
    hipLaunchKernelGGL((attn3<0>), dim3(Nn / 64, Hh, Bb), tb, 0, stream,
                       bufQ, bufK, bufV, nullptr, nullptr, nullptr, bufHA);
    gemm(bufHA, wbComb + 1 * WS, wbComb + 1 * WS, cur, curb, TOK, 512, 512, comb2_b, cur, alpha2, 0, 0);
    gemm(curb, wbFf1 + 1 * WF, wbFf1 + 1 * WF, nullptr, hidden, TOK, 2048, 512, ff2_b1, nullptr, nullptr, 1, 0);
    gemm(hidden, wbFf2 + 1 * WF, wbFf2 + 1 * WF, cur, nullptr, TOK, 512, 2048, ff2_b2, cur, ffa2, 0, 0);
}

// Round 4
// 814.730 us; speedup vs baseline: 6.1820x; 3.3667x over previous
//
#include <hip/hip_runtime.h>
#include <math.h>

#define Hh 8
#define Bb 16
#define Nn 512
#define Dd 512
#define VDd 64
#define NPICKk 256
#define NORMF 0.125f

typedef unsigned short ushortT;
typedef __bf16 bf16x8 __attribute__((ext_vector_type(8)));
typedef float f32x4 __attribute__((ext_vector_type(4)));

__device__ inline ushortT f2bf(float f) {
    union { float f; unsigned int u; } v; v.f = f;
    unsigned int r = v.u + 0x7FFFu + ((v.u >> 16) & 1u);
    return (ushortT)(r >> 16);
}
__device__ inline float bf2f(ushortT u) {
    union { unsigned int u; float f; } v; v.u = ((unsigned int)u) << 16;
    return v.f;
}
// async global->LDS, 16B per lane; LDS dest = wave-uniform base + lane*16
__device__ inline void gload16(const void* gptr, void* ldsptr) {
    auto g = reinterpret_cast<const __attribute__((address_space(1))) unsigned int*>(
        reinterpret_cast<uintptr_t>(gptr));
    auto l = reinterpret_cast<__attribute__((address_space(3))) unsigned int*>(
        reinterpret_cast<uintptr_t>(ldsptr));
    __builtin_amdgcn_global_load_lds(g, l, 16, 0, 0);
}

// swizzled bf16 64x64 tile: row r, logical 16B-group g (0..7) -> ushort index
#define LIX(r, g) (((r) << 6) + ((((g) ^ ((r) & 7))) << 3))

// ---------- fp32 -> bf16 elementwise (x) ----------
__global__ __launch_bounds__(256) void castx(const float* __restrict__ in,
                                             ushortT* __restrict__ out) {
    int i = blockIdx.x * 256 + threadIdx.x;
    float4 v = *(const float4*)&in[(size_t)i * 4];
    ushort4 o; o.x = f2bf(v.x); o.y = f2bf(v.y); o.z = f2bf(v.z); o.w = f2bf(v.w);
    *(ushort4*)&out[(size_t)i * 4] = o;
}

// ---------- transpose + cast: out[c][r] = in[r][c], bf16 out ----------
__global__ __launch_bounds__(256) void tcast(const float* __restrict__ in,
                                             ushortT* __restrict__ out,
                                             int in_ld, int out_ld,
                                             long in_zstride, long out_zoff) {
    __shared__ float T[64][65];
    in += (size_t)blockIdx.z * in_zstride;
    out += (size_t)blockIdx.z * out_zoff;
    int r0 = blockIdx.y * 64, c0 = blockIdx.x * 64;
    int tr = threadIdx.x >> 4, tc4 = (threadIdx.x & 15) * 4;
#pragma unroll
    for (int p = 0; p < 4; ++p) {
        float4 v = *(const float4*)&in[(size_t)(r0 + tr + p * 16) * in_ld + c0 + tc4];
        T[tr + p * 16][tc4 + 0] = v.x; T[tr + p * 16][tc4 + 1] = v.y;
        T[tr + p * 16][tc4 + 2] = v.z; T[tr + p * 16][tc4 + 3] = v.w;
    }
    __syncthreads();
#pragma unroll
    for (int p = 0; p < 4; ++p) {
        int orow = c0 + tr + p * 16;
        int ocol = r0 + tc4;
        ushort4 o;
        o.x = f2bf(T[tc4 + 0][tr + p * 16]);
        o.y = f2bf(T[tc4 + 1][tr + p * 16]);
        o.z = f2bf(T[tc4 + 2][tr + p * 16]);
        o.w = f2bf(T[tc4 + 3][tr + p * 16]);
        *(ushort4*)&out[(size_t)orow * out_ld + ocol] = o;
    }
}

// ---------- bf16 MFMA GEMM: C = epilogue(A @ B^T) ----------
__global__ __launch_bounds__(256) void gemm_bf(
    const ushortT* __restrict__ A, const ushortT* __restrict__ B1,
    const ushortT* __restrict__ B2, float* __restrict__ outF,
    ushortT* __restrict__ outB, int M, int N, int K,
    const float* __restrict__ bias, const float* __restrict__ res,
    const float* __restrict__ alpha, int do_relu, int do_split, int vt)
{
    __shared__ __align__(16) ushortT As[128 * 64];
    __shared__ __align__(16) ushortT Bs[128 * 64];
    const int tid = threadIdx.x;
    const int wid = tid >> 6, lane = tid & 63;
    const int wm = wid >> 1, wn = wid & 1;
    const int r0 = blockIdx.y * 128, c0 = blockIdx.x * 128;
    const ushortT* Bt = (do_split && ((r0 & (Nn - 1)) >= NPICKk)) ? B2 : B1;
    const int srow = lane >> 3, g = lane & 7;

    f32x4 acc[4][4] = {};

    for (int kt = 0; kt < K; kt += 64) {
        __syncthreads();
#pragma unroll
        for (int i = 0; i < 4; ++i) {
            int off = wid * 4096 + i * 1024;
            int row = wid * 32 + i * 8 + srow;
            gload16(A + (size_t)(r0 + row) * K + kt + g * 8,
                    (char*)As + off + lane * 16);
            gload16(Bt + (size_t)(c0 + row) * K + kt + g * 8,
                    (char*)Bs + off + lane * 16);
        }
        asm volatile("s_waitcnt vmcnt(0)" ::: "memory");
        __syncthreads();
#pragma unroll
        for (int kk = 0; kk < 2; ++kk) {
            bf16x8 af[4], bfv[4];
#pragma unroll
            for (int mi = 0; mi < 4; ++mi)
                af[mi] = *(const bf16x8*)&As[(wm * 64 + mi * 16 + (lane & 15)) * 64
                                             + kk * 32 + (lane >> 4) * 8];
#pragma unroll
            for (int ni = 0; ni < 4; ++ni)
                bfv[ni] = *(const bf16x8*)&Bs[(wn * 64 + ni * 16 + (lane & 15)) * 64
                                              + kk * 32 + (lane >> 4) * 8];
#pragma unroll
            for (int mi = 0; mi < 4; ++mi)
#pragma unroll
                for (int ni = 0; ni < 4; ++ni)
                    acc[mi][ni] = __builtin_amdgcn_mfma_f32_16x16x32_bf16(
                        af[mi], bfv[ni], acc[mi][ni], 0, 0, 0);
        }
    }

    const float alp = alpha ? alpha[0] : 1.0f;
#pragma unroll
    for (int ni = 0; ni < 4; ++ni) {
        int col = c0 + wn * 64 + ni * 16 + (lane & 15);
        float bv = bias ? bias[col] : 0.f;
#pragma unroll
        for (int mi = 0; mi < 4; ++mi) {
            f32x4 a = acc[mi][ni];
#pragma unroll
            for (int r = 0; r < 4; ++r) {
                int row = r0 + wm * 64 + mi * 16 + (lane >> 4) * 4 + r;
                float v = a[r] + bv;
                if (do_relu) v = fmaxf(v, 0.f);
                v *= alp;
                size_t idx = (size_t)row * N + col;
                if (res) v += res[idx];
                if (outF) outF[idx] = v;
                if (outB) {
                    size_t bidx = idx;
                    if (vt)   // Vt[((b*8+h)*64+v)][n] layout, N==512
                        bidx = ((((size_t)(row >> 9) * Hh + (col >> 6)) * 64
                                 + (col & 63)) << 9) + (row & 511);
                    outB[bidx] = f2bf(v);
                }
            }
        }
    }
}

// ---------- HA diagonal scores (bf16 in) ----------
__global__ __launch_bounds__(256) void diag_dot_bb(const ushortT* __restrict__ QD,
                                                   const ushortT* __restrict__ K,
                                                   float* __restrict__ Sdg) {
    int i = blockIdx.x * 256 + threadIdx.x;     // B*N*H = 65536
    int h = i & 7, n = (i >> 3) & 511, b = i >> 12;
    int dix = (n < NPICKk) ? n + NPICKk : n - NPICKk;
    const ushortT* q = QD + (((size_t)(b * Nn + n) * Hh + h) << 6);
    const ushortT* k = K + (((size_t)(b * Nn + dix) * Hh + h) << 6);
    float s = 0.f;
#pragma unroll
    for (int d = 0; d < 64; d += 4) {
        ushort4 a = *(const ushort4*)(q + d);
        ushort4 c = *(const ushort4*)(k + d);
        s += bf2f(a.x) * bf2f(c.x) + bf2f(a.y) * bf2f(c.y)
           + bf2f(a.z) * bf2f(c.z) + bf2f(a.w) * bf2f(c.w);
    }
    Sdg[i] = s * NORMF;
}

// ---------- MFMA flash attention ----------
// Q/K/QA/QB: (b,n,h,d) bf16. Vt: ((b*8+h)*64+v, n) bf16. Out: (b,n,h,v) bf16.
// Block: 64 Q-rows x one (b,h); 4 waves, each owns 16-row strip.
template <int HA>
__global__ __launch_bounds__(256) void attn4(
    const ushortT* __restrict__ Qm, const ushortT* __restrict__ Km,
    const ushortT* __restrict__ Vtm, const ushortT* __restrict__ QAm,
    const ushortT* __restrict__ QBm, const float* __restrict__ Sdg,
    ushortT* __restrict__ Out)
{
    __shared__ __align__(16) ushortT Qs[64 * 64];
    __shared__ __align__(16) ushortT Ks[64 * 64];
    __shared__ __align__(16) ushortT Vs[64 * 64];   // Vt tile: [v][m]
    __shared__ __align__(16) ushortT Ps[64 * 64];
    __shared__ __align__(16) ushortT Qxs[HA ? 64 * 64 : 8];
    __shared__ float sdl[64];

    const int tid = threadIdx.x, wid = tid >> 6, lane = tid & 63;
    const int l15 = lane & 15, l4 = lane >> 4;
    const int b = blockIdx.z, h = blockIdx.y, n0 = blockIdx.x * 64;

    // stage Q (+QA) via DMA, pre-swizzled global source
#pragma unroll
    for (int i = 0; i < 2; ++i) {
        int off = wid * 2048 + i * 1024 + lane * 16;
        int row = off >> 7, gs = (off >> 4) & 7;
        int sg = gs ^ (row & 7);
        size_t gidx = (((size_t)(b * Nn + n0 + row) * Hh + h) << 6) + sg * 8;
        gload16(Qm + gidx, (char*)Qs + off);
        if (HA) gload16(QAm + gidx, (char*)Qxs + off);
    }
    if (HA && tid < 64) sdl[tid] = Sdg[((size_t)(b * Nn + n0 + tid)) * Hh + h];
    const int td = (n0 < NPICKk) ? ((n0 + NPICKk) >> 6) : ((n0 - NPICKk) >> 6);

    float M[4], L[4];
    f32x4 Oa[4] = {};
#pragma unroll
    for (int r = 0; r < 4; ++r) { M[r] = -INFINITY; L[r] = 0.f; }

    for (int t = 0; t < 8; ++t) {
        __syncthreads();   // prior-iter LDS reads complete
#pragma unroll
        for (int i = 0; i < 2; ++i) {
            int off = wid * 2048 + i * 1024 + lane * 16;
            int row = off >> 7, gs = (off >> 4) & 7;
            int sg = gs ^ (row & 7);
            gload16(Km + (((size_t)(b * Nn + t * 64 + row) * Hh + h) << 6) + sg * 8,
                    (char*)Ks + off);
            gload16(Vtm + (((size_t)(b * Hh + h) * 64 + row) << 9) + t * 64 + sg * 8,
                    (char*)Vs + off);
            if (HA && t == 4)
                gload16(QBm + (((size_t)(b * Nn + n0 + row) * Hh + h) << 6) + sg * 8,
                        (char*)Qxs + off);
        }
        asm volatile("s_waitcnt vmcnt(0)" ::: "memory");
        __syncthreads();   // staged data visible

        // ---- S = Q K^T via MFMA ----
        f32x4 s1[4] = {}, sX[4] = {};
#pragma unroll
        for (int kk = 0; kk < 2; ++kk) {
            int g0 = kk * 4 + l4;
            bf16x8 aq = *(const bf16x8*)&Qs[LIX(wid * 16 + l15, g0)];
            bf16x8 ax;
            if (HA) ax = *(const bf16x8*)&Qxs[LIX(wid * 16 + l15, g0)];
#pragma unroll
            for (int ni = 0; ni < 4; ++ni) {
                bf16x8 bk = *(const bf16x8*)&Ks[LIX(ni * 16 + l15, g0)];
                s1[ni] = __builtin_amdgcn_mfma_f32_16x16x32_bf16(aq, bk, s1[ni], 0, 0, 0);
                if (HA)
                    sX[ni] = __builtin_amdgcn_mfma_f32_16x16x32_bf16(ax, bk, sX[ni], 0, 0, 0);
            }
        }

        float p1[4][4], pX[4][4];
#pragma unroll
        for (int ni = 0; ni < 4; ++ni)
#pragma unroll
            for (int r = 0; r < 4; ++r) {
                p1[ni][r] = s1[ni][r] * NORMF;
                if (HA) pX[ni][r] = sX[ni][r] * NORMF;
            }

        const bool dt = HA && (t == td);

        // ---- online softmax; rows rw = wid*16 + l4*4 + r, spread over 16 lanes ----
#pragma unroll
        for (int r = 0; r < 4; ++r) {
            int rw = wid * 16 + l4 * 4 + r;
            float m = p1[0][r];
#pragma unroll
            for (int ni = 1; ni < 4; ++ni) m = fmaxf(m, p1[ni][r]);
            if (HA) {
#pragma unroll
                for (int ni = 0; ni < 4; ++ni) m = fmaxf(m, pX[ni][r]);
            }
            if (dt) m = fmaxf(m, sdl[rw]);
#pragma unroll
            for (int o = 8; o >= 1; o >>= 1) m = fmaxf(m, __shfl_xor(m, o, 16));
            float mn = fmaxf(M[r], m);
            float sc = __expf(M[r] - mn);
            M[r] = mn; L[r] *= sc;
#pragma unroll
            for (int ni = 0; ni < 4; ++ni) Oa[ni][r] *= sc;
            float rs = 0.f;
#pragma unroll
            for (int ni = 0; ni < 4; ++ni) {
                float p = __expf(p1[ni][r] - mn);
                if (HA) p += __expf(pX[ni][r] - mn);
                if (dt && ni == wid && l15 == l4 * 4 + r) p += __expf(sdl[rw] - mn);
                p1[ni][r] = p;
                rs += p;
            }
#pragma unroll
            for (int o = 8; o >= 1; o >>= 1) rs += __shfl_xor(rs, o, 16);
            L[r] += rs;
        }

        // ---- write P (bf16, swizzled) ----
#pragma unroll
        for (int ni = 0; ni < 4; ++ni)
#pragma unroll
            for (int r = 0; r < 4; ++r) {
                int prow = wid * 16 + l4 * 4 + r;
                int col = ni * 16 + l15;
                Ps[(prow << 6) + ((((col >> 3) ^ (prow & 7))) << 3) + (col & 7)] =
                    f2bf(p1[ni][r]);
            }
        __syncthreads();   // P visible

        // ---- O += P @ V (B = Vt tile, col v, contiguous m) ----
#pragma unroll
        for (int kk = 0; kk < 2; ++kk) {
            int g0 = kk * 4 + l4;
            bf16x8 ap = *(const bf16x8*)&Ps[LIX(wid * 16 + l15, g0)];
#pragma unroll
            for (int ni = 0; ni < 4; ++ni) {
                bf16x8 bv = *(const bf16x8*)&Vs[LIX(ni * 16 + l15, g0)];
                Oa[ni] = __builtin_amdgcn_mfma_f32_16x16x32_bf16(ap, bv, Oa[ni], 0, 0, 0);
            }
        }
    }

#pragma unroll
    for (int r = 0; r < 4; ++r) {
        float inv = 1.0f / L[r];
        size_t obase = (((size_t)(b * Nn + n0 + wid * 16 + l4 * 4 + r) * Hh + h) << 6);
#pragma unroll
        for (int ni = 0; ni < 4; ++ni)
            Out[obase + ni * 16 + l15] = f2bf(Oa[ni][r] * inv);
    }
}

extern "C" void kernel_launch(void* const* d_in, const int* in_sizes, int n_in,
                              void* d_out, int out_size, void* d_ws, size_t ws_size,
                              hipStream_t stream)
{
    const float* x = (const float*)d_in[0];

    int dictOrder = (in_sizes[18] != 512);
    const float* comb_w  = (const float*)d_in[17];
    const float* comb2_w = (const float*)d_in[dictOrder ? 18 : 19];
    const float* comb3_w = (const float*)d_in[dictOrder ? 19 : 21];
    const float* comb_b  = (const float*)d_in[dictOrder ? 20 : 18];
    const float* comb2_b = (const float*)d_in[dictOrder ? 21 : 20];
    const float* comb3_b = (const float*)d_in[22];
    const float* alpha1 = (const float*)d_in[23];
    const float* alpha2 = (const float*)d_in[24];
    const float* alpha3 = (const float*)d_in[25];
    const float* ff1_w1 = (const float*)d_in[26];
    const float* ff1_b1 = (const float*)d_in[27];
    const float* ff1_w2 = (const float*)d_in[28];
    const float* ff1_b2 = (const float*)d_in[29];
    const float* ffa1   = (const float*)d_in[30];
    const float* ff2_w1 = (const float*)d_in[31];
    const float* ff2_b1 = (const float*)d_in[32];
    const float* ff2_w2 = (const float*)d_in[33];
    const float* ff2_b2 = (const float*)d_in[34];
    const float* ffa2   = (const float*)d_in[35];
    const float* ff3_w1 = (const float*)d_in[36];
    const float* ff3_b1 = (const float*)d_in[37];
    const float* ff3_w2 = (const float*)d_in[38];
    const float* ff3_b2 = (const float*)d_in[39];
    const float* ffa3   = (const float*)d_in[40];

    // ---- workspace layout (bytes) ----
    char* W = (char*)d_ws;
    ushortT* wbHead = (ushortT*)(W + 0);           // 9 x 512x512 bf16
    ushortT* wbMha  = (ushortT*)(W + 4718592);     // 7 x
    ushortT* wbComb = (ushortT*)(W + 8388608);     // 3 x
    ushortT* wbFf1  = (ushortT*)(W + 9961472);     // 3 x 2048x512
    ushortT* wbFf2  = (ushortT*)(W + 16252928);    // 3 x 512x2048
    ushortT* xbf    = (ushortT*)(W + 22544384);    // 8192x512 bf16; later bufHA
    float*   Sd     = (float*)  (W + 30932992);    // 65536 f32
    ushortT* bufQ   = (ushortT*)(W + 31195136);    // 8192x512 bf16 each
    ushortT* bufK   = (ushortT*)(W + 39583744);
    ushortT* bufVt  = (ushortT*)(W + 47972352);
    ushortT* bufQA  = (ushortT*)(W + 56360960);
    ushortT* bufQB  = (ushortT*)(W + 64749568);
    ushortT* bufQD  = (ushortT*)(W + 73138176);
    ushortT* hidden = (ushortT*)(W + 81526784);    // 8192x2048 bf16
    ushortT* curb   = (ushortT*)(W + 115081216);   // bf16 shadow of residual
    ushortT* bufHA  = xbf;                         // attn out, aliases xbf
    float*   cur    = (float*)d_out;

    dim3 tb(256);
    const int TOK = Bb * Nn;  // 8192
    const size_t WS = 512 * 512;
    const size_t WF = 2048 * 512;

    // 1. casts / transposes
    hipLaunchKernelGGL(castx, dim3(TOK * 512 / 1024), tb, 0, stream, x, xbf);
    for (int i = 0; i < 9; ++i)
        hipLaunchKernelGGL(tcast, dim3(1, 8, 8), tb, 0, stream,
                           (const float*)d_in[1 + i], wbHead + i * WS,
                           64, 512, (long)(512 * 64), (long)(64 * 512));
    for (int i = 0; i < 7; ++i)
        hipLaunchKernelGGL(tcast, dim3(8, 8, 1), tb, 0, stream,
                           (const float*)d_in[10 + i], wbMha + i * WS, 512, 512, 0L, 0L);
    const float* combs[3] = { comb_w, comb2_w, comb3_w };
    for (int i = 0; i < 3; ++i)
        hipLaunchKernelGGL(tcast, dim3(8, 8, 1), tb, 0, stream,
                           combs[i], wbComb + i * WS, 512, 512, 0L, 0L);
    const float* ffw1[3] = { ff1_w1, ff2_w1, ff3_w1 };
    const float* ffw2[3] = { ff1_w2, ff2_w2, ff3_w2 };
    for (int i = 0; i < 3; ++i) {
        hipLaunchKernelGGL(tcast, dim3(32, 8, 1), tb, 0, stream,
                           ffw1[i], wbFf1 + i * WF, 2048, 512, 0L, 0L);
        hipLaunchKernelGGL(tcast, dim3(8, 32, 1), tb, 0, stream,
                           ffw2[i], wbFf2 + i * WF, 512, 2048, 0L, 0L);
    }

    auto gemm = [&](const ushortT* A, const ushortT* B1v, const ushortT* B2v,
                    float* oF, ushortT* oB, int M, int Ncc, int Kc,
                    const float* bias, const float* res, const float* alp,
                    int relu, int split, int vt) {
        hipLaunchKernelGGL(gemm_bf, dim3(Ncc / 128, M / 128), tb, 0, stream,
                           A, B1v, B2v, oF, oB, M, Ncc, Kc, bias, res, alp, relu, split, vt);
    };

    // 2. HA projections -> bf16 attention operands
    gemm(xbf, wbHead + 0 * WS, wbHead + 0 * WS, nullptr, bufQ,  TOK, 512, 512, nullptr, nullptr, nullptr, 0, 0, 0);
    gemm(xbf, wbHead + 1 * WS, wbHead + 1 * WS, nullptr, bufK,  TOK, 512, 512, nullptr, nullptr, nullptr, 0, 0, 0);
    gemm(xbf, wbHead + 2 * WS, wbHead + 2 * WS, nullptr, bufVt, TOK, 512, 512, nullptr, nullptr, nullptr, 0, 0, 1);
    gemm(xbf, wbHead + 4 * WS, wbHead + 8 * WS, nullptr, bufQA, TOK, 512, 512, nullptr, nullptr, nullptr, 0, 1, 0); // W2/W6
    gemm(xbf, wbHead + 5 * WS, wbHead + 7 * WS, nullptr, bufQB, TOK, 512, 512, nullptr, nullptr, nullptr, 0, 1, 0); // W3/W5
    gemm(xbf, wbHead + 3 * WS, wbHead + 6 * WS, nullptr, bufQD, TOK, 512, 512, nullptr, nullptr, nullptr, 0, 1, 0); // W1/W4

    // 3. HA attention
    hipLaunchKernelGGL(diag_dot_bb, dim3(Bb * Nn * Hh / 256), tb, 0, stream, bufQD, bufK, Sd);
    hipLaunchKernelGGL((attn4<1>), dim3(Nn / 64, Hh, Bb), tb, 0, stream,
                       bufQ, bufK, bufVt, bufQA, bufQB, Sd, bufHA);

    // 4. cur = x + alpha3*(ha @ comb3 + b3);  FF3
    gemm(bufHA, wbComb + 2 * WS, wbComb + 2 * WS, cur, curb, TOK, 512, 512, comb3_b, x, alpha3, 0, 0, 0);
    gemm(curb, wbFf1 + 2 * WF, wbFf1 + 2 * WF, nullptr, hidden, TOK, 2048, 512, ff3_b1, nullptr, nullptr, 1, 0, 0);
    gemm(hidden, wbFf2 + 2 * WF, wbFf2 + 2 * WF, cur, curb, TOK, 512, 2048, ff3_b2, cur, ffa3, 0, 0, 0);

    // 5. MHA1
    gemm(curb, wbMha + 0 * WS, wbMha + 0 * WS, nullptr, bufQ,  TOK, 512, 512, nullptr, nullptr, nullptr, 0, 0, 0);
    gemm(curb, wbMha + 1 * WS, wbMha + 1 * WS, nullptr, bufK,  TOK, 512, 512, nullptr, nullptr, nullptr, 0, 0, 0);
    gemm(curb, wbMha + 2 * WS, wbMha + 2 * WS, nullptr, bufVt, TOK, 512, 512, nullptr, nullptr, nullptr, 0, 0, 1);
    hipLaunchKernelGGL((attn4<0>), dim3(Nn / 64, Hh, Bb), tb, 0, stream,
                       bufQ, bufK, bufVt, nullptr, nullptr, nullptr, bufHA);
    gemm(bufHA, wbComb + 0 * WS, wbComb + 0 * WS, cur, curb, TOK, 512, 512, comb_b, cur, alpha1, 0, 0, 0);
    gemm(curb, wbFf1 + 0 * WF, wbFf1 + 0 * WF, nullptr, hidden, TOK, 2048, 512, ff1_b1, nullptr, nullptr, 1, 0, 0);
    gemm(hidden, wbFf2 + 0 * WF, wbFf2 + 0 * WF, cur, curb, TOK, 512, 2048, ff1_b2, cur, ffa1, 0, 0, 0);

    // 6. MHA2 (split Q: Wq2p / Wq2d)
    gemm(curb, wbMha + 3 * WS, wbMha + 4 * WS, nullptr, bufQ,  TOK, 512, 512, nullptr, nullptr, nullptr, 0, 1, 0);
    gemm(curb, wbMha + 5 * WS, wbMha + 5 * WS, nullptr, bufK,  TOK, 512, 512, nullptr, nullptr, nullptr, 0, 0, 0);
    gemm(curb, wbMha + 6 * WS, wbMha + 6 * WS, nullptr, bufVt, TOK, 512, 512, nullptr, nullptr, nullptr, 0, 0, 1);
    hipLaunchKernelGGL((attn4<0>), dim3(Nn / 64, Hh, Bb), tb, 0, stream,
                       bufQ, bufK, bufVt, nullptr, nullptr, nullptr, bufHA);
    gemm(bufHA, wbComb + 1 * WS, wbComb + 1 * WS, cur, curb, TOK, 512, 512, comb2_b, cur, alpha2, 0, 0, 0);
    gemm(curb, wbFf1 + 1 * WF, wbFf1 + 1 * WF, nullptr, hidden, TOK, 2048, 512, ff2_b1, nullptr, nullptr, 1, 0, 0);
    gemm(hidden, wbFf2 + 1 * WF, wbFf2 + 1 * WF, cur, nullptr, TOK, 512, 2048, ff2_b2, cur, ffa2, 0, 0, 0);
}

// Round 6
// 651.259 us; speedup vs baseline: 7.7337x; 1.2510x over previous
//
#include <hip/hip_runtime.h>
#include <math.h>

#define Hh 8
#define Bb 16
#define Nn 512
#define Dd 512
#define VDd 64
#define NPICKk 256
#define NORMF 0.125f

typedef unsigned short ushortT;
typedef __bf16 bf16x8 __attribute__((ext_vector_type(8)));
typedef float f32x4 __attribute__((ext_vector_type(4)));

struct PtrsB { const ushortT* p[12]; };   // B per (col-range, row-half)
struct PtrsD { ushortT* p[6]; };          // routed bf16 dests per col-range
struct Ptrs9 { const float* p[9]; };
struct Ptrs10 { const float* p[10]; };
struct Ptrs6 { const float* p[6]; };

__device__ inline ushortT f2bf(float f) {
    union { float f; unsigned int u; } v; v.f = f;
    unsigned int r = v.u + 0x7FFFu + ((v.u >> 16) & 1u);
    return (ushortT)(r >> 16);
}
__device__ inline float bf2f(ushortT u) {
    union { unsigned int u; float f; } v; v.u = ((unsigned int)u) << 16;
    return v.f;
}
__device__ inline void gload16(const void* gptr, void* ldsptr) {
    auto g = reinterpret_cast<const __attribute__((address_space(1))) unsigned int*>(
        reinterpret_cast<uintptr_t>(gptr));
    auto l = reinterpret_cast<__attribute__((address_space(3))) unsigned int*>(
        reinterpret_cast<uintptr_t>(ldsptr));
    __builtin_amdgcn_global_load_lds(g, l, 16, 0, 0);
}

// swizzled bf16 64-col tile: row r, 16B-group g (0..7) -> ushort index
#define LIX(r, g) (((r) << 6) + ((((g) ^ ((r) & 7))) << 3))

// ---------- fp32 -> bf16 elementwise ----------
__global__ __launch_bounds__(256) void castx(const float* __restrict__ in,
                                             ushortT* __restrict__ out) {
    int i = blockIdx.x * 256 + threadIdx.x;
    float4 v = *(const float4*)&in[(size_t)i * 4];
    ushort4 o; o.x = f2bf(v.x); o.y = f2bf(v.y); o.z = f2bf(v.z); o.w = f2bf(v.w);
    *(ushort4*)&out[(size_t)i * 4] = o;
}

// ---------- transpose+cast body: out[c][r] = in[r][c] ----------
__device__ inline void tbody(const float* __restrict__ in, ushortT* __restrict__ out,
                             int in_ld, int out_ld, int r0, int c0) {
    __shared__ float T[64][65];
    int tr = threadIdx.x >> 4, tc4 = (threadIdx.x & 15) * 4;
#pragma unroll
    for (int p = 0; p < 4; ++p) {
        float4 v = *(const float4*)&in[(size_t)(r0 + tr + p * 16) * in_ld + c0 + tc4];
        T[tr + p * 16][tc4 + 0] = v.x; T[tr + p * 16][tc4 + 1] = v.y;
        T[tr + p * 16][tc4 + 2] = v.z; T[tr + p * 16][tc4 + 3] = v.w;
    }
    __syncthreads();
#pragma unroll
    for (int p = 0; p < 4; ++p) {
        int orow = c0 + tr + p * 16;
        int ocol = r0 + tc4;
        ushort4 o;
        o.x = f2bf(T[tc4 + 0][tr + p * 16]);
        o.y = f2bf(T[tc4 + 1][tr + p * 16]);
        o.z = f2bf(T[tc4 + 2][tr + p * 16]);
        o.w = f2bf(T[tc4 + 3][tr + p * 16]);
        *(ushort4*)&out[(size_t)orow * out_ld + ocol] = o;
    }
}

// 9 head weights (H,D,VD): per z = w*8+h, transpose (512x64) slice -> rows h*64.. of (512,512)
__global__ __launch_bounds__(256) void thead(Ptrs9 s, ushortT* __restrict__ dst) {
    int w = blockIdx.z >> 3, h = blockIdx.z & 7;
    tbody(s.p[w] + (size_t)h * 512 * 64,
          dst + (size_t)w * 262144 + (size_t)h * 64 * 512,
          64, 512, blockIdx.y * 64, 0);
}
// 10 square (512,512) weights -> T
__global__ __launch_bounds__(256) void tsq(Ptrs10 s, ushortT* __restrict__ dst) {
    tbody(s.p[blockIdx.z], dst + (size_t)blockIdx.z * 262144,
          512, 512, blockIdx.y * 64, blockIdx.x * 64);
}
// 6 FF weights: z<3: (512,2048)->T(2048,512); z>=3: (2048,512)->T(512,2048)
__global__ __launch_bounds__(256) void tff(Ptrs6 s, ushortT* __restrict__ dst) {
    int z = blockIdx.z;
    if (z < 3) { if (blockIdx.y >= 8 || blockIdx.x >= 32) return; }
    else       { if (blockIdx.y >= 32 || blockIdx.x >= 8) return; }
    int in_ld = (z < 3) ? 2048 : 512;
    int out_ld = (z < 3) ? 512 : 2048;
    tbody(s.p[z], dst + (size_t)z * 1048576, in_ld, out_ld,
          blockIdx.y * 64, blockIdx.x * 64);
}

// ---------- bf16 MFMA GEMM with T2 swizzle + T1 XCD swizzle ----------
// C = epilogue(A @ B^T). B selected per (col-range c0>>9, row-half); each routed-range
// B is 512 x K, so its row index is (c0 & 511) + row in routed mode.
__global__ __launch_bounds__(256) void gemm_bf(
    PtrsB Bp, PtrsD Db, const ushortT* __restrict__ A, float* __restrict__ outF,
    int M, int N, int K, const float* __restrict__ bias,
    const float* __restrict__ res, const float* __restrict__ alpha,
    int do_relu, int nroute, int vtmask)
{
    __shared__ __align__(16) ushortT As[128 * 64];
    __shared__ __align__(16) ushortT Bs[128 * 64];
    const int tid = threadIdx.x;
    const int wid = tid >> 6, lane = tid & 63;
    const int wm = wid >> 1, wn = wid & 1;
    const int l15 = lane & 15, l4 = lane >> 4;

    // T1: bijective XCD-chunked block swizzle (nwg % 8 == 0 for all our grids)
    int bid = blockIdx.y * gridDim.x + blockIdx.x;
    int nwg = gridDim.x * gridDim.y;
    int q = nwg >> 3;
    int swz = (bid & 7) * q + (bid >> 3);
    int bx = swz % gridDim.x, by = swz / gridDim.x;

    const int r0 = by * 128, c0 = bx * 128;
    const int half = ((r0 & (Nn - 1)) >= NPICKk) ? 1 : 0;
    const ushortT* Bt = Bp.p[((c0 >> 9) << 1) | half];
    const int cB = nroute ? (c0 & 511) : c0;   // FIX: B row base within 512-row range

    f32x4 acc[4][4] = {};

    for (int kt = 0; kt < K; kt += 64) {
        __syncthreads();
#pragma unroll
        for (int i = 0; i < 4; ++i) {
            int off = wid * 4096 + i * 1024 + lane * 16;   // byte offset in 16KB tile
            int row = off >> 7, gs = (off >> 4) & 7;
            int sg = gs ^ (row & 7);                       // pre-swizzled global group
            gload16(A + (size_t)(r0 + row) * K + kt + sg * 8, (char*)As + off);
            gload16(Bt + (size_t)(cB + row) * K + kt + sg * 8, (char*)Bs + off);
        }
        asm volatile("s_waitcnt vmcnt(0)" ::: "memory");
        __syncthreads();
#pragma unroll
        for (int kk = 0; kk < 2; ++kk) {
            int g0 = kk * 4 + l4;
            bf16x8 af[4], bfv[4];
#pragma unroll
            for (int mi = 0; mi < 4; ++mi)
                af[mi] = *(const bf16x8*)&As[LIX(wm * 64 + mi * 16 + l15, g0)];
#pragma unroll
            for (int ni = 0; ni < 4; ++ni)
                bfv[ni] = *(const bf16x8*)&Bs[LIX(wn * 64 + ni * 16 + l15, g0)];
#pragma unroll
            for (int mi = 0; mi < 4; ++mi)
#pragma unroll
                for (int ni = 0; ni < 4; ++ni)
                    acc[mi][ni] = __builtin_amdgcn_mfma_f32_16x16x32_bf16(
                        af[mi], bfv[ni], acc[mi][ni], 0, 0, 0);
        }
    }

    if (nroute) {
#pragma unroll
        for (int ni = 0; ni < 4; ++ni) {
            int col = c0 + wn * 64 + ni * 16 + l15;
            int range = col >> 9, cc = col & 511;
            ushortT* d = Db.p[range];
            bool vt = (vtmask >> range) & 1;
#pragma unroll
            for (int mi = 0; mi < 4; ++mi) {
                f32x4 a = acc[mi][ni];
#pragma unroll
                for (int r = 0; r < 4; ++r) {
                    int row = r0 + wm * 64 + mi * 16 + l4 * 4 + r;
                    size_t idx;
                    if (vt)
                        idx = ((((size_t)(row >> 9) * Hh + (cc >> 6)) * 64
                                + (cc & 63)) << 9) + (row & 511);
                    else
                        idx = ((size_t)row << 9) + cc;
                    d[idx] = f2bf(a[r]);
                }
            }
        }
    } else {
        const float alp = alpha ? alpha[0] : 1.0f;
        ushortT* outB = Db.p[0];
#pragma unroll
        for (int ni = 0; ni < 4; ++ni) {
            int col = c0 + wn * 64 + ni * 16 + l15;
            float bv = bias ? bias[col] : 0.f;
#pragma unroll
            for (int mi = 0; mi < 4; ++mi) {
                f32x4 a = acc[mi][ni];
#pragma unroll
                for (int r = 0; r < 4; ++r) {
                    int row = r0 + wm * 64 + mi * 16 + l4 * 4 + r;
                    float v = a[r] + bv;
                    if (do_relu) v = fmaxf(v, 0.f);
                    v *= alp;
                    size_t idx = (size_t)row * N + col;
                    if (res) v += res[idx];
                    if (outF) outF[idx] = v;
                    if (outB) outB[idx] = f2bf(v);
                }
            }
        }
    }
}

// ---------- HA diagonal scores ----------
__global__ __launch_bounds__(256) void diag_dot_bb(const ushortT* __restrict__ QD,
                                                   const ushortT* __restrict__ K,
                                                   float* __restrict__ Sdg) {
    int i = blockIdx.x * 256 + threadIdx.x;     // B*N*H = 65536
    int h = i & 7, n = (i >> 3) & 511, b = i >> 12;
    int dix = (n < NPICKk) ? n + NPICKk : n - NPICKk;
    const ushortT* q = QD + (((size_t)(b * Nn + n) * Hh + h) << 6);
    const ushortT* k = K + (((size_t)(b * Nn + dix) * Hh + h) << 6);
    float s = 0.f;
#pragma unroll
    for (int d = 0; d < 64; d += 4) {
        ushort4 a = *(const ushort4*)(q + d);
        ushort4 c = *(const ushort4*)(k + d);
        s += bf2f(a.x) * bf2f(c.x) + bf2f(a.y) * bf2f(c.y)
           + bf2f(a.z) * bf2f(c.z) + bf2f(a.w) * bf2f(c.w);
    }
    Sdg[i] = s * NORMF;
}

// ---------- MFMA flash attention ----------
template <int HA>
__global__ __launch_bounds__(256) void attn4(
    const ushortT* __restrict__ Qm, const ushortT* __restrict__ Km,
    const ushortT* __restrict__ Vtm, const ushortT* __restrict__ QAm,
    const ushortT* __restrict__ QBm, const float* __restrict__ Sdg,
    ushortT* __restrict__ Out)
{
    __shared__ __align__(16) ushortT Qs[64 * 64];
    __shared__ __align__(16) ushortT Ks[64 * 64];
    __shared__ __align__(16) ushortT Vs[64 * 64];
    __shared__ __align__(16) ushortT Ps[64 * 64];
    __shared__ __align__(16) ushortT Qxs[HA ? 64 * 64 : 8];
    __shared__ float sdl[64];

    const int tid = threadIdx.x, wid = tid >> 6, lane = tid & 63;
    const int l15 = lane & 15, l4 = lane >> 4;
    const int b = blockIdx.z, h = blockIdx.y, n0 = blockIdx.x * 64;

#pragma unroll
    for (int i = 0; i < 2; ++i) {
        int off = wid * 2048 + i * 1024 + lane * 16;
        int row = off >> 7, gs = (off >> 4) & 7;
        int sg = gs ^ (row & 7);
        size_t gidx = (((size_t)(b * Nn + n0 + row) * Hh + h) << 6) + sg * 8;
        gload16(Qm + gidx, (char*)Qs + off);
        if (HA) gload16(QAm + gidx, (char*)Qxs + off);
    }
    if (HA && tid < 64) sdl[tid] = Sdg[((size_t)(b * Nn + n0 + tid)) * Hh + h];
    const int td = (n0 < NPICKk) ? ((n0 + NPICKk) >> 6) : ((n0 - NPICKk) >> 6);

    float M[4], L[4];
    f32x4 Oa[4] = {};
#pragma unroll
    for (int r = 0; r < 4; ++r) { M[r] = -INFINITY; L[r] = 0.f; }

    for (int t = 0; t < 8; ++t) {
        __syncthreads();
#pragma unroll
        for (int i = 0; i < 2; ++i) {
            int off = wid * 2048 + i * 1024 + lane * 16;
            int row = off >> 7, gs = (off >> 4) & 7;
            int sg = gs ^ (row & 7);
            gload16(Km + (((size_t)(b * Nn + t * 64 + row) * Hh + h) << 6) + sg * 8,
                    (char*)Ks + off);
            gload16(Vtm + (((size_t)(b * Hh + h) * 64 + row) << 9) + t * 64 + sg * 8,
                    (char*)Vs + off);
            if (HA && t == 4)
                gload16(QBm + (((size_t)(b * Nn + n0 + row) * Hh + h) << 6) + sg * 8,
                        (char*)Qxs + off);
        }
        asm volatile("s_waitcnt vmcnt(0)" ::: "memory");
        __syncthreads();

        f32x4 s1[4] = {}, sX[4] = {};
#pragma unroll
        for (int kk = 0; kk < 2; ++kk) {
            int g0 = kk * 4 + l4;
            bf16x8 aq = *(const bf16x8*)&Qs[LIX(wid * 16 + l15, g0)];
            bf16x8 ax;
            if (HA) ax = *(const bf16x8*)&Qxs[LIX(wid * 16 + l15, g0)];
#pragma unroll
            for (int ni = 0; ni < 4; ++ni) {
                bf16x8 bk = *(const bf16x8*)&Ks[LIX(ni * 16 + l15, g0)];
                s1[ni] = __builtin_amdgcn_mfma_f32_16x16x32_bf16(aq, bk, s1[ni], 0, 0, 0);
                if (HA)
                    sX[ni] = __builtin_amdgcn_mfma_f32_16x16x32_bf16(ax, bk, sX[ni], 0, 0, 0);
            }
        }

        float p1[4][4], pX[4][4];
#pragma unroll
        for (int ni = 0; ni < 4; ++ni)
#pragma unroll
            for (int r = 0; r < 4; ++r) {
                p1[ni][r] = s1[ni][r] * NORMF;
                if (HA) pX[ni][r] = sX[ni][r] * NORMF;
            }

        const bool dt = HA && (t == td);

#pragma unroll
        for (int r = 0; r < 4; ++r) {
            int rw = wid * 16 + l4 * 4 + r;
            float m = p1[0][r];
#pragma unroll
            for (int ni = 1; ni < 4; ++ni) m = fmaxf(m, p1[ni][r]);
            if (HA) {
#pragma unroll
                for (int ni = 0; ni < 4; ++ni) m = fmaxf(m, pX[ni][r]);
            }
            if (dt) m = fmaxf(m, sdl[rw]);
#pragma unroll
            for (int o = 8; o >= 1; o >>= 1) m = fmaxf(m, __shfl_xor(m, o, 16));
            float mn = fmaxf(M[r], m);
            float sc = __expf(M[r] - mn);
            M[r] = mn; L[r] *= sc;
#pragma unroll
            for (int ni = 0; ni < 4; ++ni) Oa[ni][r] *= sc;
            float rs = 0.f;
#pragma unroll
            for (int ni = 0; ni < 4; ++ni) {
                float p = __expf(p1[ni][r] - mn);
                if (HA) p += __expf(pX[ni][r] - mn);
                if (dt && ni == wid && l15 == l4 * 4 + r) p += __expf(sdl[rw] - mn);
                p1[ni][r] = p;
                rs += p;
            }
#pragma unroll
            for (int o = 8; o >= 1; o >>= 1) rs += __shfl_xor(rs, o, 16);
            L[r] += rs;
        }

#pragma unroll
        for (int ni = 0; ni < 4; ++ni)
#pragma unroll
            for (int r = 0; r < 4; ++r) {
                int prow = wid * 16 + l4 * 4 + r;
                int col = ni * 16 + l15;
                Ps[(prow << 6) + ((((col >> 3) ^ (prow & 7))) << 3) + (col & 7)] =
                    f2bf(p1[ni][r]);
            }
        __syncthreads();

#pragma unroll
        for (int kk = 0; kk < 2; ++kk) {
            int g0 = kk * 4 + l4;
            bf16x8 ap = *(const bf16x8*)&Ps[LIX(wid * 16 + l15, g0)];
#pragma unroll
            for (int ni = 0; ni < 4; ++ni) {
                bf16x8 bv = *(const bf16x8*)&Vs[LIX(ni * 16 + l15, g0)];
                Oa[ni] = __builtin_amdgcn_mfma_f32_16x16x32_bf16(ap, bv, Oa[ni], 0, 0, 0);
            }
        }
    }

#pragma unroll
    for (int r = 0; r < 4; ++r) {
        float inv = 1.0f / L[r];
        size_t obase = (((size_t)(b * Nn + n0 + wid * 16 + l4 * 4 + r) * Hh + h) << 6);
#pragma unroll
        for (int ni = 0; ni < 4; ++ni)
            Out[obase + ni * 16 + l15] = f2bf(Oa[ni][r] * inv);
    }
}

extern "C" void kernel_launch(void* const* d_in, const int* in_sizes, int n_in,
                              void* d_out, int out_size, void* d_ws, size_t ws_size,
                              hipStream_t stream)
{
    const float* x = (const float*)d_in[0];

    int dictOrder = (in_sizes[18] != 512);
    const float* comb_w  = (const float*)d_in[17];
    const float* comb2_w = (const float*)d_in[dictOrder ? 18 : 19];
    const float* comb3_w = (const float*)d_in[dictOrder ? 19 : 21];
    const float* comb_b  = (const float*)d_in[dictOrder ? 20 : 18];
    const float* comb2_b = (const float*)d_in[dictOrder ? 21 : 20];
    const float* comb3_b = (const float*)d_in[22];
    const float* alpha1 = (const float*)d_in[23];
    const float* alpha2 = (const float*)d_in[24];
    const float* alpha3 = (const float*)d_in[25];
    const float* ff1_w1 = (const float*)d_in[26];
    const float* ff1_b1 = (const float*)d_in[27];
    const float* ff1_w2 = (const float*)d_in[28];
    const float* ff1_b2 = (const float*)d_in[29];
    const float* ffa1   = (const float*)d_in[30];
    const float* ff2_w1 = (const float*)d_in[31];
    const float* ff2_b1 = (const float*)d_in[32];
    const float* ff2_w2 = (const float*)d_in[33];
    const float* ff2_b2 = (const float*)d_in[34];
    const float* ffa2   = (const float*)d_in[35];
    const float* ff3_w1 = (const float*)d_in[36];
    const float* ff3_b1 = (const float*)d_in[37];
    const float* ff3_w2 = (const float*)d_in[38];
    const float* ff3_b2 = (const float*)d_in[39];
    const float* ffa3   = (const float*)d_in[40];

    // ---- workspace layout (bytes) ----
    char* W = (char*)d_ws;
    ushortT* wbHead = (ushortT*)(W + 0);           // 9 x 512x512 bf16
    ushortT* wbMha  = (ushortT*)(W + 4718592);     // 7 x  (contiguous with comb)
    ushortT* wbComb = (ushortT*)(W + 8388608);     // 3 x
    ushortT* wbFf1  = (ushortT*)(W + 9961472);     // 3 x 2048x512  (contiguous w/ Ff2)
    ushortT* wbFf2  = (ushortT*)(W + 16252928);    // 3 x 512x2048
    ushortT* xbf    = (ushortT*)(W + 22544384);    // 8192x512 bf16; later bufHA
    float*   Sd     = (float*)  (W + 30932992);    // 65536 f32
    ushortT* bufQ   = (ushortT*)(W + 31195136);    // 8192x512 bf16 each
    ushortT* bufK   = (ushortT*)(W + 39583744);
    ushortT* bufVt  = (ushortT*)(W + 47972352);
    ushortT* bufQA  = (ushortT*)(W + 56360960);
    ushortT* bufQB  = (ushortT*)(W + 64749568);
    ushortT* bufQD  = (ushortT*)(W + 73138176);
    ushortT* hidden = (ushortT*)(W + 81526784);    // 8192x2048 bf16
    ushortT* curb   = (ushortT*)(W + 115081216);   // bf16 shadow of residual
    ushortT* bufHA  = xbf;
    float*   cur    = (float*)d_out;

    dim3 tb(256);
    const int TOK = Bb * Nn;  // 8192
    const size_t WS = 512 * 512;
    const size_t WF = 2048 * 512;

    // 1. casts / transposes (batched)
    hipLaunchKernelGGL(castx, dim3(TOK * 512 / 1024), tb, 0, stream, x, xbf);
    {
        Ptrs9 s; for (int i = 0; i < 9; ++i) s.p[i] = (const float*)d_in[1 + i];
        hipLaunchKernelGGL(thead, dim3(1, 8, 72), tb, 0, stream, s, wbHead);
    }
    {
        Ptrs10 s;
        for (int i = 0; i < 7; ++i) s.p[i] = (const float*)d_in[10 + i];
        s.p[7] = comb_w; s.p[8] = comb2_w; s.p[9] = comb3_w;
        hipLaunchKernelGGL(tsq, dim3(8, 8, 10), tb, 0, stream, s, wbMha);
    }
    {
        Ptrs6 s;
        s.p[0] = ff1_w1; s.p[1] = ff2_w1; s.p[2] = ff3_w1;
        s.p[3] = ff1_w2; s.p[4] = ff2_w2; s.p[5] = ff3_w2;
        hipLaunchKernelGGL(tff, dim3(32, 32, 6), tb, 0, stream, s, wbFf1);
    }

    auto gemm = [&](PtrsB Bp, PtrsD Db, const ushortT* A, float* oF,
                    int M, int Ncc, int Kc, const float* bias, const float* res,
                    const float* alp, int relu, int nroute, int vtmask) {
        hipLaunchKernelGGL(gemm_bf, dim3(Ncc / 128, M / 128), tb, 0, stream,
                           Bp, Db, A, oF, M, Ncc, Kc, bias, res, alp, relu, nroute, vtmask);
    };
    auto uni = [&](const ushortT* w) { PtrsB b; for (int i = 0; i < 12; ++i) b.p[i] = w; return b; };
    auto d1 = [&](ushortT* d) { PtrsD dd = {}; dd.p[0] = d; return dd; };

    // 2. HA projections: ONE fused GEMM, N=3072
    {
        PtrsB b;
        b.p[0] = b.p[1] = wbHead + 0 * WS;           // Q
        b.p[2] = b.p[3] = wbHead + 1 * WS;           // K
        b.p[4] = b.p[5] = wbHead + 2 * WS;           // V (vt)
        b.p[6] = wbHead + 4 * WS; b.p[7] = wbHead + 8 * WS;   // QA: W2 / W6
        b.p[8] = wbHead + 5 * WS; b.p[9] = wbHead + 7 * WS;   // QB: W3 / W5
        b.p[10] = wbHead + 3 * WS; b.p[11] = wbHead + 6 * WS; // QD: W1 / W4
        PtrsD d; d.p[0] = bufQ; d.p[1] = bufK; d.p[2] = bufVt;
        d.p[3] = bufQA; d.p[4] = bufQB; d.p[5] = bufQD;
        gemm(b, d, xbf, nullptr, TOK, 3072, 512, nullptr, nullptr, nullptr, 0, 6, 4);
    }

    // 3. HA attention
    hipLaunchKernelGGL(diag_dot_bb, dim3(Bb * Nn * Hh / 256), tb, 0, stream, bufQD, bufK, Sd);
    hipLaunchKernelGGL((attn4<1>), dim3(Nn / 64, Hh, Bb), tb, 0, stream,
                       bufQ, bufK, bufVt, bufQA, bufQB, Sd, bufHA);

    // 4. comb3 + FF3
    gemm(uni(wbComb + 2 * WS), d1(curb), bufHA, cur, TOK, 512, 512, comb3_b, x, alpha3, 0, 0, 0);
    gemm(uni(wbFf1 + 2 * WF), d1(hidden), curb, nullptr, TOK, 2048, 512, ff3_b1, nullptr, nullptr, 1, 0, 0);
    gemm(uni(wbFf2 + 2 * WF), d1(curb), hidden, cur, TOK, 512, 2048, ff3_b2, cur, ffa3, 0, 0, 0);

    // 5. MHA1: fused QKV projection, N=1536
    {
        PtrsB b;
        b.p[0] = b.p[1] = wbMha + 0 * WS;
        b.p[2] = b.p[3] = wbMha + 1 * WS;
        b.p[4] = b.p[5] = wbMha + 2 * WS;
        PtrsD d = {}; d.p[0] = bufQ; d.p[1] = bufK; d.p[2] = bufVt;
        gemm(b, d, curb, nullptr, TOK, 1536, 512, nullptr, nullptr, nullptr, 0, 3, 4);
    }
    hipLaunchKernelGGL((attn4<0>), dim3(Nn / 64, Hh, Bb), tb, 0, stream,
                       bufQ, bufK, bufVt, nullptr, nullptr, nullptr, bufHA);
    gemm(uni(wbComb + 0 * WS), d1(curb), bufHA, cur, TOK, 512, 512, comb_b, cur, alpha1, 0, 0, 0);
    gemm(uni(wbFf1 + 0 * WF), d1(hidden), curb, nullptr, TOK, 2048, 512, ff1_b1, nullptr, nullptr, 1, 0, 0);
    gemm(uni(wbFf2 + 0 * WF), d1(curb), hidden, cur, TOK, 512, 2048, ff1_b2, cur, ffa1, 0, 0, 0);

    // 6. MHA2: fused projection with split Q (Wq2p/Wq2d), N=1536
    {
        PtrsB b;
        b.p[0] = wbMha + 3 * WS; b.p[1] = wbMha + 4 * WS;
        b.p[2] = b.p[3] = wbMha + 5 * WS;
        b.p[4] = b.p[5] = wbMha + 6 * WS;
        PtrsD d = {}; d.p[0] = bufQ; d.p[1] = bufK; d.p[2] = bufVt;
        gemm(b, d, curb, nullptr, TOK, 1536, 512, nullptr, nullptr, nullptr, 0, 3, 4);
    }
    hipLaunchKernelGGL((attn4<0>), dim3(Nn / 64, Hh, Bb), tb, 0, stream,
                       bufQ, bufK, bufVt, nullptr, nullptr, nullptr, bufHA);
    gemm(uni(wbComb + 1 * WS), d1(curb), bufHA, cur, TOK, 512, 512, comb2_b, cur, alpha2, 0, 0, 0);
    gemm(uni(wbFf1 + 1 * WF), d1(hidden), curb, nullptr, TOK, 2048, 512, ff2_b1, nullptr, nullptr, 1, 0, 0);
    {
        PtrsD d = {};
        gemm(uni(wbFf2 + 1 * WF), d, hidden, cur, TOK, 512, 2048, ff2_b2, cur, ffa2, 0, 0, 0);
    }
}

// Round 7
// 578.978 us; speedup vs baseline: 8.6992x; 1.1248x over previous
//
#include <hip/hip_runtime.h>
#include <math.h>

#define Hh 8
#define Bb 16
#define Nn 512
#define Dd 512
#define VDd 64
#define NPICKk 256
#define NORMF 0.125f

typedef unsigned short ushortT;
typedef __bf16 bf16x8 __attribute__((ext_vector_type(8)));
typedef float f32x4 __attribute__((ext_vector_type(4)));

struct PtrsB { const ushortT* p[12]; };   // B per (col-range, row-half)
struct PtrsD { ushortT* p[6]; };          // routed bf16 dests per col-range
struct Ptrs9 { const float* p[9]; };
struct Ptrs10 { const float* p[10]; };
struct Ptrs6 { const float* p[6]; };

__device__ inline ushortT f2bf(float f) {
    union { float f; unsigned int u; } v; v.f = f;
    unsigned int r = v.u + 0x7FFFu + ((v.u >> 16) & 1u);
    return (ushortT)(r >> 16);
}
__device__ inline float bf2f(ushortT u) {
    union { unsigned int u; float f; } v; v.u = ((unsigned int)u) << 16;
    return v.f;
}
__device__ inline void gload16(const void* gptr, void* ldsptr) {
    auto g = reinterpret_cast<const __attribute__((address_space(1))) unsigned int*>(
        reinterpret_cast<uintptr_t>(gptr));
    auto l = reinterpret_cast<__attribute__((address_space(3))) unsigned int*>(
        reinterpret_cast<uintptr_t>(ldsptr));
    __builtin_amdgcn_global_load_lds(g, l, 16, 0, 0);
}

// swizzled bf16 64-col tile: row r, 16B-group g (0..7) -> ushort index
#define LIX(r, g) (((r) << 6) + ((((g) ^ ((r) & 7))) << 3))

// ---------- fp32 -> bf16 elementwise ----------
__global__ __launch_bounds__(256) void castx(const float* __restrict__ in,
                                             ushortT* __restrict__ out) {
    int i = blockIdx.x * 256 + threadIdx.x;
    float4 v = *(const float4*)&in[(size_t)i * 4];
    ushort4 o; o.x = f2bf(v.x); o.y = f2bf(v.y); o.z = f2bf(v.z); o.w = f2bf(v.w);
    *(ushort4*)&out[(size_t)i * 4] = o;
}

// ---------- transpose+cast body: out[c][r] = in[r][c] ----------
__device__ inline void tbody(const float* __restrict__ in, ushortT* __restrict__ out,
                             int in_ld, int out_ld, int r0, int c0) {
    __shared__ float T[64][65];
    int tr = threadIdx.x >> 4, tc4 = (threadIdx.x & 15) * 4;
#pragma unroll
    for (int p = 0; p < 4; ++p) {
        float4 v = *(const float4*)&in[(size_t)(r0 + tr + p * 16) * in_ld + c0 + tc4];
        T[tr + p * 16][tc4 + 0] = v.x; T[tr + p * 16][tc4 + 1] = v.y;
        T[tr + p * 16][tc4 + 2] = v.z; T[tr + p * 16][tc4 + 3] = v.w;
    }
    __syncthreads();
#pragma unroll
    for (int p = 0; p < 4; ++p) {
        int orow = c0 + tr + p * 16;
        int ocol = r0 + tc4;
        ushort4 o;
        o.x = f2bf(T[tc4 + 0][tr + p * 16]);
        o.y = f2bf(T[tc4 + 1][tr + p * 16]);
        o.z = f2bf(T[tc4 + 2][tr + p * 16]);
        o.w = f2bf(T[tc4 + 3][tr + p * 16]);
        *(ushort4*)&out[(size_t)orow * out_ld + ocol] = o;
    }
}

__global__ __launch_bounds__(256) void thead(Ptrs9 s, ushortT* __restrict__ dst) {
    int w = blockIdx.z >> 3, h = blockIdx.z & 7;
    tbody(s.p[w] + (size_t)h * 512 * 64,
          dst + (size_t)w * 262144 + (size_t)h * 64 * 512,
          64, 512, blockIdx.y * 64, 0);
}
__global__ __launch_bounds__(256) void tsq(Ptrs10 s, ushortT* __restrict__ dst) {
    tbody(s.p[blockIdx.z], dst + (size_t)blockIdx.z * 262144,
          512, 512, blockIdx.y * 64, blockIdx.x * 64);
}
__global__ __launch_bounds__(256) void tff(Ptrs6 s, ushortT* __restrict__ dst) {
    int z = blockIdx.z;
    if (z < 3) { if (blockIdx.y >= 8 || blockIdx.x >= 32) return; }
    else       { if (blockIdx.y >= 32 || blockIdx.x >= 8) return; }
    int in_ld = (z < 3) ? 2048 : 512;
    int out_ld = (z < 3) ? 512 : 2048;
    tbody(s.p[z], dst + (size_t)z * 1048576, in_ld, out_ld,
          blockIdx.y * 64, blockIdx.x * 64);
}

// ---------- bf16 MFMA GEMM, swapped-operand (C^T fragment) epilogue ----------
// acc[mi][ni] = mfma(B_frag, A_frag, .): lane holds row m = ..+l15 (fixed),
// 4 consecutive cols n = ..+l4*4+r  -> vectorized float4/ushort4 stores.
__global__ __launch_bounds__(256) void gemm_bf(
    PtrsB Bp, PtrsD Db, const ushortT* __restrict__ A, float* __restrict__ outF,
    int M, int N, int K, const float* __restrict__ bias,
    const float* __restrict__ res, const float* __restrict__ alpha,
    int do_relu, int nroute, int vtmask)
{
    __shared__ __align__(16) ushortT As[128 * 64];
    __shared__ __align__(16) ushortT Bs[128 * 64];
    const int tid = threadIdx.x;
    const int wid = tid >> 6, lane = tid & 63;
    const int wm = wid >> 1, wn = wid & 1;
    const int l15 = lane & 15, l4 = lane >> 4;

    // T1: bijective XCD-chunked block swizzle (nwg % 8 == 0 for all our grids)
    int bid = blockIdx.y * gridDim.x + blockIdx.x;
    int nwg = gridDim.x * gridDim.y;
    int q = nwg >> 3;
    int swz = (bid & 7) * q + (bid >> 3);
    int bx = swz % gridDim.x, by = swz / gridDim.x;

    const int r0 = by * 128, c0 = bx * 128;
    const int half = ((r0 & (Nn - 1)) >= NPICKk) ? 1 : 0;
    const ushortT* Bt = Bp.p[((c0 >> 9) << 1) | half];
    const int cB = nroute ? (c0 & 511) : c0;   // B row base within 512-row range

    // staging geometry (hoisted): per i, row = wid*32+i*8+(lane>>3), sg = (lane&7)^(row&7)
    const ushortT* aSrc[4];
    const ushortT* bSrc[4];
    char* ldsA[4];
    char* ldsB[4];
#pragma unroll
    for (int i = 0; i < 4; ++i) {
        int off = wid * 4096 + i * 1024 + lane * 16;
        int row = off >> 7;
        int sg = ((off >> 4) & 7) ^ (row & 7);
        aSrc[i] = A + (size_t)(r0 + row) * K + sg * 8;
        bSrc[i] = Bt + (size_t)(cB + row) * K + sg * 8;
        ldsA[i] = (char*)As + off;
        ldsB[i] = (char*)Bs + off;
    }

    f32x4 acc[4][4] = {};

    for (int kt = 0; kt < K; kt += 64) {
        __syncthreads();
#pragma unroll
        for (int i = 0; i < 4; ++i) {
            gload16(aSrc[i] + kt, ldsA[i]);
            gload16(bSrc[i] + kt, ldsB[i]);
        }
        asm volatile("s_waitcnt vmcnt(0)" ::: "memory");
        __syncthreads();
#pragma unroll
        for (int kk = 0; kk < 2; ++kk) {
            int g0 = kk * 4 + l4;
            bf16x8 af[4], bfv[4];
#pragma unroll
            for (int mi = 0; mi < 4; ++mi)
                af[mi] = *(const bf16x8*)&As[LIX(wm * 64 + mi * 16 + l15, g0)];
#pragma unroll
            for (int ni = 0; ni < 4; ++ni)
                bfv[ni] = *(const bf16x8*)&Bs[LIX(wn * 64 + ni * 16 + l15, g0)];
#pragma unroll
            for (int mi = 0; mi < 4; ++mi)
#pragma unroll
                for (int ni = 0; ni < 4; ++ni)
                    acc[mi][ni] = __builtin_amdgcn_mfma_f32_16x16x32_bf16(
                        bfv[ni], af[mi], acc[mi][ni], 0, 0, 0);   // SWAPPED -> C^T frag
        }
    }

    if (nroute) {
#pragma unroll
        for (int mi = 0; mi < 4; ++mi) {
            int row = r0 + wm * 64 + mi * 16 + l15;
#pragma unroll
            for (int ni = 0; ni < 4; ++ni) {
                int col = c0 + wn * 64 + ni * 16 + l4 * 4;
                int range = col >> 9, cc = col & 511;
                ushortT* d = Db.p[range];
                f32x4 a = acc[mi][ni];
                if ((vtmask >> range) & 1) {
                    // Vt[((b*8+h)*64+v)][tok]: v varies per r -> scalar stores
                    size_t vb = ((size_t)(row >> 9) * Hh + (cc >> 6)) * 64 + (cc & 63);
                    int tok = row & 511;
#pragma unroll
                    for (int r = 0; r < 4; ++r)
                        d[((vb + r) << 9) + tok] = f2bf(a[r]);
                } else {
                    ushort4 o;
                    o.x = f2bf(a[0]); o.y = f2bf(a[1]);
                    o.z = f2bf(a[2]); o.w = f2bf(a[3]);
                    *(ushort4*)&d[((size_t)row << 9) + cc] = o;
                }
            }
        }
    } else {
        const float alp = alpha ? alpha[0] : 1.0f;
        ushortT* outB = Db.p[0];
#pragma unroll
        for (int mi = 0; mi < 4; ++mi) {
            int row = r0 + wm * 64 + mi * 16 + l15;
#pragma unroll
            for (int ni = 0; ni < 4; ++ni) {
                int colb = c0 + wn * 64 + ni * 16 + l4 * 4;
                f32x4 a = acc[mi][ni];
                if (bias) {
                    float4 b4 = *(const float4*)&bias[colb];
                    a[0] += b4.x; a[1] += b4.y; a[2] += b4.z; a[3] += b4.w;
                }
                if (do_relu) {
#pragma unroll
                    for (int r = 0; r < 4; ++r) a[r] = fmaxf(a[r], 0.f);
                }
#pragma unroll
                for (int r = 0; r < 4; ++r) a[r] *= alp;
                size_t idx = (size_t)row * N + colb;
                if (res) {
                    float4 r4 = *(const float4*)&res[idx];
                    a[0] += r4.x; a[1] += r4.y; a[2] += r4.z; a[3] += r4.w;
                }
                if (outF)
                    *(float4*)&outF[idx] = make_float4(a[0], a[1], a[2], a[3]);
                if (outB) {
                    ushort4 o;
                    o.x = f2bf(a[0]); o.y = f2bf(a[1]);
                    o.z = f2bf(a[2]); o.w = f2bf(a[3]);
                    *(ushort4*)&outB[idx] = o;
                }
            }
        }
    }
}

// ---------- HA diagonal scores ----------
__global__ __launch_bounds__(256) void diag_dot_bb(const ushortT* __restrict__ QD,
                                                   const ushortT* __restrict__ K,
                                                   float* __restrict__ Sdg) {
    int i = blockIdx.x * 256 + threadIdx.x;     // B*N*H = 65536
    int h = i & 7, n = (i >> 3) & 511, b = i >> 12;
    int dix = (n < NPICKk) ? n + NPICKk : n - NPICKk;
    const ushortT* q = QD + (((size_t)(b * Nn + n) * Hh + h) << 6);
    const ushortT* k = K + (((size_t)(b * Nn + dix) * Hh + h) << 6);
    float s = 0.f;
#pragma unroll
    for (int d = 0; d < 64; d += 4) {
        ushort4 a = *(const ushort4*)(q + d);
        ushort4 c = *(const ushort4*)(k + d);
        s += bf2f(a.x) * bf2f(c.x) + bf2f(a.y) * bf2f(c.y)
           + bf2f(a.z) * bf2f(c.z) + bf2f(a.w) * bf2f(c.w);
    }
    Sdg[i] = s * NORMF;
}

// ---------- MFMA flash attention (unchanged, verified) ----------
template <int HA>
__global__ __launch_bounds__(256) void attn4(
    const ushortT* __restrict__ Qm, const ushortT* __restrict__ Km,
    const ushortT* __restrict__ Vtm, const ushortT* __restrict__ QAm,
    const ushortT* __restrict__ QBm, const float* __restrict__ Sdg,
    ushortT* __restrict__ Out)
{
    __shared__ __align__(16) ushortT Qs[64 * 64];
    __shared__ __align__(16) ushortT Ks[64 * 64];
    __shared__ __align__(16) ushortT Vs[64 * 64];
    __shared__ __align__(16) ushortT Ps[64 * 64];
    __shared__ __align__(16) ushortT Qxs[HA ? 64 * 64 : 8];
    __shared__ float sdl[64];

    const int tid = threadIdx.x, wid = tid >> 6, lane = tid & 63;
    const int l15 = lane & 15, l4 = lane >> 4;
    const int b = blockIdx.z, h = blockIdx.y, n0 = blockIdx.x * 64;

#pragma unroll
    for (int i = 0; i < 2; ++i) {
        int off = wid * 2048 + i * 1024 + lane * 16;
        int row = off >> 7, gs = (off >> 4) & 7;
        int sg = gs ^ (row & 7);
        size_t gidx = (((size_t)(b * Nn + n0 + row) * Hh + h) << 6) + sg * 8;
        gload16(Qm + gidx, (char*)Qs + off);
        if (HA) gload16(QAm + gidx, (char*)Qxs + off);
    }
    if (HA && tid < 64) sdl[tid] = Sdg[((size_t)(b * Nn + n0 + tid)) * Hh + h];
    const int td = (n0 < NPICKk) ? ((n0 + NPICKk) >> 6) : ((n0 - NPICKk) >> 6);

    float M[4], L[4];
    f32x4 Oa[4] = {};
#pragma unroll
    for (int r = 0; r < 4; ++r) { M[r] = -INFINITY; L[r] = 0.f; }

    for (int t = 0; t < 8; ++t) {
        __syncthreads();
#pragma unroll
        for (int i = 0; i < 2; ++i) {
            int off = wid * 2048 + i * 1024 + lane * 16;
            int row = off >> 7, gs = (off >> 4) & 7;
            int sg = gs ^ (row & 7);
            gload16(Km + (((size_t)(b * Nn + t * 64 + row) * Hh + h) << 6) + sg * 8,
                    (char*)Ks + off);
            gload16(Vtm + (((size_t)(b * Hh + h) * 64 + row) << 9) + t * 64 + sg * 8,
                    (char*)Vs + off);
            if (HA && t == 4)
                gload16(QBm + (((size_t)(b * Nn + n0 + row) * Hh + h) << 6) + sg * 8,
                        (char*)Qxs + off);
        }
        asm volatile("s_waitcnt vmcnt(0)" ::: "memory");
        __syncthreads();

        f32x4 s1[4] = {}, sX[4] = {};
#pragma unroll
        for (int kk = 0; kk < 2; ++kk) {
            int g0 = kk * 4 + l4;
            bf16x8 aq = *(const bf16x8*)&Qs[LIX(wid * 16 + l15, g0)];
            bf16x8 ax;
            if (HA) ax = *(const bf16x8*)&Qxs[LIX(wid * 16 + l15, g0)];
#pragma unroll
            for (int ni = 0; ni < 4; ++ni) {
                bf16x8 bk = *(const bf16x8*)&Ks[LIX(ni * 16 + l15, g0)];
                s1[ni] = __builtin_amdgcn_mfma_f32_16x16x32_bf16(aq, bk, s1[ni], 0, 0, 0);
                if (HA)
                    sX[ni] = __builtin_amdgcn_mfma_f32_16x16x32_bf16(ax, bk, sX[ni], 0, 0, 0);
            }
        }

        float p1[4][4], pX[4][4];
#pragma unroll
        for (int ni = 0; ni < 4; ++ni)
#pragma unroll
            for (int r = 0; r < 4; ++r) {
                p1[ni][r] = s1[ni][r] * NORMF;
                if (HA) pX[ni][r] = sX[ni][r] * NORMF;
            }

        const bool dt = HA && (t == td);

#pragma unroll
        for (int r = 0; r < 4; ++r) {
            int rw = wid * 16 + l4 * 4 + r;
            float m = p1[0][r];
#pragma unroll
            for (int ni = 1; ni < 4; ++ni) m = fmaxf(m, p1[ni][r]);
            if (HA) {
#pragma unroll
                for (int ni = 0; ni < 4; ++ni) m = fmaxf(m, pX[ni][r]);
            }
            if (dt) m = fmaxf(m, sdl[rw]);
#pragma unroll
            for (int o = 8; o >= 1; o >>= 1) m = fmaxf(m, __shfl_xor(m, o, 16));
            float mn = fmaxf(M[r], m);
            float sc = __expf(M[r] - mn);
            M[r] = mn; L[r] *= sc;
#pragma unroll
            for (int ni = 0; ni < 4; ++ni) Oa[ni][r] *= sc;
            float rs = 0.f;
#pragma unroll
            for (int ni = 0; ni < 4; ++ni) {
                float p = __expf(p1[ni][r] - mn);
                if (HA) p += __expf(pX[ni][r] - mn);
                if (dt && ni == wid && l15 == l4 * 4 + r) p += __expf(sdl[rw] - mn);
                p1[ni][r] = p;
                rs += p;
            }
#pragma unroll
            for (int o = 8; o >= 1; o >>= 1) rs += __shfl_xor(rs, o, 16);
            L[r] += rs;
        }

#pragma unroll
        for (int ni = 0; ni < 4; ++ni)
#pragma unroll
            for (int r = 0; r < 4; ++r) {
                int prow = wid * 16 + l4 * 4 + r;
                int col = ni * 16 + l15;
                Ps[(prow << 6) + ((((col >> 3) ^ (prow & 7))) << 3) + (col & 7)] =
                    f2bf(p1[ni][r]);
            }
        __syncthreads();

#pragma unroll
        for (int kk = 0; kk < 2; ++kk) {
            int g0 = kk * 4 + l4;
            bf16x8 ap = *(const bf16x8*)&Ps[LIX(wid * 16 + l15, g0)];
#pragma unroll
            for (int ni = 0; ni < 4; ++ni) {
                bf16x8 bv = *(const bf16x8*)&Vs[LIX(ni * 16 + l15, g0)];
                Oa[ni] = __builtin_amdgcn_mfma_f32_16x16x32_bf16(ap, bv, Oa[ni], 0, 0, 0);
            }
        }
    }

#pragma unroll
    for (int r = 0; r < 4; ++r) {
        float inv = 1.0f / L[r];
        size_t obase = (((size_t)(b * Nn + n0 + wid * 16 + l4 * 4 + r) * Hh + h) << 6);
#pragma unroll
        for (int ni = 0; ni < 4; ++ni)
            Out[obase + ni * 16 + l15] = f2bf(Oa[ni][r] * inv);
    }
}

extern "C" void kernel_launch(void* const* d_in, const int* in_sizes, int n_in,
                              void* d_out, int out_size, void* d_ws, size_t ws_size,
                              hipStream_t stream)
{
    const float* x = (const float*)d_in[0];

    int dictOrder = (in_sizes[18] != 512);
    const float* comb_w  = (const float*)d_in[17];
    const float* comb2_w = (const float*)d_in[dictOrder ? 18 : 19];
    const float* comb3_w = (const float*)d_in[dictOrder ? 19 : 21];
    const float* comb_b  = (const float*)d_in[dictOrder ? 20 : 18];
    const float* comb2_b = (const float*)d_in[dictOrder ? 21 : 20];
    const float* comb3_b = (const float*)d_in[22];
    const float* alpha1 = (const float*)d_in[23];
    const float* alpha2 = (const float*)d_in[24];
    const float* alpha3 = (const float*)d_in[25];
    const float* ff1_w1 = (const float*)d_in[26];
    const float* ff1_b1 = (const float*)d_in[27];
    const float* ff1_w2 = (const float*)d_in[28];
    const float* ff1_b2 = (const float*)d_in[29];
    const float* ffa1   = (const float*)d_in[30];
    const float* ff2_w1 = (const float*)d_in[31];
    const float* ff2_b1 = (const float*)d_in[32];
    const float* ff2_w2 = (const float*)d_in[33];
    const float* ff2_b2 = (const float*)d_in[34];
    const float* ffa2   = (const float*)d_in[35];
    const float* ff3_w1 = (const float*)d_in[36];
    const float* ff3_b1 = (const float*)d_in[37];
    const float* ff3_w2 = (const float*)d_in[38];
    const float* ff3_b2 = (const float*)d_in[39];
    const float* ffa3   = (const float*)d_in[40];

    // ---- workspace layout (bytes) ----
    char* W = (char*)d_ws;
    ushortT* wbHead = (ushortT*)(W + 0);           // 9 x 512x512 bf16
    ushortT* wbMha  = (ushortT*)(W + 4718592);     // 7 x
    ushortT* wbComb = (ushortT*)(W + 8388608);     // 3 x
    ushortT* wbFf1  = (ushortT*)(W + 9961472);     // 3 x 2048x512
    ushortT* wbFf2  = (ushortT*)(W + 16252928);    // 3 x 512x2048
    ushortT* xbf    = (ushortT*)(W + 22544384);    // 8192x512 bf16; later bufHA
    float*   Sd     = (float*)  (W + 30932992);    // 65536 f32
    ushortT* bufQ   = (ushortT*)(W + 31195136);    // 8192x512 bf16 each
    ushortT* bufK   = (ushortT*)(W + 39583744);
    ushortT* bufVt  = (ushortT*)(W + 47972352);
    ushortT* bufQA  = (ushortT*)(W + 56360960);
    ushortT* bufQB  = (ushortT*)(W + 64749568);
    ushortT* bufQD  = (ushortT*)(W + 73138176);
    ushortT* hidden = (ushortT*)(W + 81526784);    // 8192x2048 bf16
    ushortT* curb   = (ushortT*)(W + 115081216);   // bf16 shadow of residual
    ushortT* bufHA  = xbf;
    float*   cur    = (float*)d_out;

    dim3 tb(256);
    const int TOK = Bb * Nn;  // 8192
    const size_t WS = 512 * 512;
    const size_t WF = 2048 * 512;

    // 1. casts / transposes (batched)
    hipLaunchKernelGGL(castx, dim3(TOK * 512 / 1024), tb, 0, stream, x, xbf);
    {
        Ptrs9 s; for (int i = 0; i < 9; ++i) s.p[i] = (const float*)d_in[1 + i];
        hipLaunchKernelGGL(thead, dim3(1, 8, 72), tb, 0, stream, s, wbHead);
    }
    {
        Ptrs10 s;
        for (int i = 0; i < 7; ++i) s.p[i] = (const float*)d_in[10 + i];
        s.p[7] = comb_w; s.p[8] = comb2_w; s.p[9] = comb3_w;
        hipLaunchKernelGGL(tsq, dim3(8, 8, 10), tb, 0, stream, s, wbMha);
    }
    {
        Ptrs6 s;
        s.p[0] = ff1_w1; s.p[1] = ff2_w1; s.p[2] = ff3_w1;
        s.p[3] = ff1_w2; s.p[4] = ff2_w2; s.p[5] = ff3_w2;
        hipLaunchKernelGGL(tff, dim3(32, 32, 6), tb, 0, stream, s, wbFf1);
    }

    auto gemm = [&](PtrsB Bp, PtrsD Db, const ushortT* A, float* oF,
                    int M, int Ncc, int Kc, const float* bias, const float* res,
                    const float* alp, int relu, int nroute, int vtmask) {
        hipLaunchKernelGGL(gemm_bf, dim3(Ncc / 128, M / 128), tb, 0, stream,
                           Bp, Db, A, oF, M, Ncc, Kc, bias, res, alp, relu, nroute, vtmask);
    };
    auto uni = [&](const ushortT* w) { PtrsB b; for (int i = 0; i < 12; ++i) b.p[i] = w; return b; };
    auto d1 = [&](ushortT* d) { PtrsD dd = {}; dd.p[0] = d; return dd; };

    // 2. HA projections: ONE fused GEMM, N=3072
    {
        PtrsB b;
        b.p[0] = b.p[1] = wbHead + 0 * WS;           // Q
        b.p[2] = b.p[3] = wbHead + 1 * WS;           // K
        b.p[4] = b.p[5] = wbHead + 2 * WS;           // V (vt)
        b.p[6] = wbHead + 4 * WS; b.p[7] = wbHead + 8 * WS;   // QA: W2 / W6
        b.p[8] = wbHead + 5 * WS; b.p[9] = wbHead + 7 * WS;   // QB: W3 / W5
        b.p[10] = wbHead + 3 * WS; b.p[11] = wbHead + 6 * WS; // QD: W1 / W4
        PtrsD d; d.p[0] = bufQ; d.p[1] = bufK; d.p[2] = bufVt;
        d.p[3] = bufQA; d.p[4] = bufQB; d.p[5] = bufQD;
        gemm(b, d, xbf, nullptr, TOK, 3072, 512, nullptr, nullptr, nullptr, 0, 6, 4);
    }

    // 3. HA attention
    hipLaunchKernelGGL(diag_dot_bb, dim3(Bb * Nn * Hh / 256), tb, 0, stream, bufQD, bufK, Sd);
    hipLaunchKernelGGL((attn4<1>), dim3(Nn / 64, Hh, Bb), tb, 0, stream,
                       bufQ, bufK, bufVt, bufQA, bufQB, Sd, bufHA);

    // 4. comb3 + FF3
    gemm(uni(wbComb + 2 * WS), d1(curb), bufHA, cur, TOK, 512, 512, comb3_b, x, alpha3, 0, 0, 0);
    gemm(uni(wbFf1 + 2 * WF), d1(hidden), curb, nullptr, TOK, 2048, 512, ff3_b1, nullptr, nullptr, 1, 0, 0);
    gemm(uni(wbFf2 + 2 * WF), d1(curb), hidden, cur, TOK, 512, 2048, ff3_b2, cur, ffa3, 0, 0, 0);

    // 5. MHA1: fused QKV projection, N=1536
    {
        PtrsB b;
        b.p[0] = b.p[1] = wbMha + 0 * WS;
        b.p[2] = b.p[3] = wbMha + 1 * WS;
        b.p[4] = b.p[5] = wbMha + 2 * WS;
        PtrsD d = {}; d.p[0] = bufQ; d.p[1] = bufK; d.p[2] = bufVt;
        gemm(b, d, curb, nullptr, TOK, 1536, 512, nullptr, nullptr, nullptr, 0, 3, 4);
    }
    hipLaunchKernelGGL((attn4<0>), dim3(Nn / 64, Hh, Bb), tb, 0, stream,
                       bufQ, bufK, bufVt, nullptr, nullptr, nullptr, bufHA);
    gemm(uni(wbComb + 0 * WS), d1(curb), bufHA, cur, TOK, 512, 512, comb_b, cur, alpha1, 0, 0, 0);
    gemm(uni(wbFf1 + 0 * WF), d1(hidden), curb, nullptr, TOK, 2048, 512, ff1_b1, nullptr, nullptr, 1, 0, 0);
    gemm(uni(wbFf2 + 0 * WF), d1(curb), hidden, cur, TOK, 512, 2048, ff1_b2, cur, ffa1, 0, 0, 0);

    // 6. MHA2: fused projection with split Q (Wq2p/Wq2d), N=1536
    {
        PtrsB b;
        b.p[0] = wbMha + 3 * WS; b.p[1] = wbMha + 4 * WS;
        b.p[2] = b.p[3] = wbMha + 5 * WS;
        b.p[4] = b.p[5] = wbMha + 6 * WS;
        PtrsD d = {}; d.p[0] = bufQ; d.p[1] = bufK; d.p[2] = bufVt;
        gemm(b, d, curb, nullptr, TOK, 1536, 512, nullptr, nullptr, nullptr, 0, 3, 4);
    }
    hipLaunchKernelGGL((attn4<0>), dim3(Nn / 64, Hh, Bb), tb, 0, stream,
                       bufQ, bufK, bufVt, nullptr, nullptr, nullptr, bufHA);
    gemm(uni(wbComb + 1 * WS), d1(curb), bufHA, cur, TOK, 512, 512, comb2_b, cur, alpha2, 0, 0, 0);
    gemm(uni(wbFf1 + 1 * WF), d1(hidden), curb, nullptr, TOK, 2048, 512, ff2_b1, nullptr, nullptr, 1, 0, 0);
    {
        PtrsD d = {};
        gemm(uni(wbFf2 + 1 * WF), d, hidden, cur, TOK, 512, 2048, ff2_b2, cur, ffa2, 0, 0, 0);
    }
}

// Round 8
// 546.585 us; speedup vs baseline: 9.2148x; 1.0593x over previous
//
#include <hip/hip_runtime.h>
#include <math.h>

#define Hh 8
#define Bb 16
#define Nn 512
#define Dd 512
#define VDd 64
#define NPICKk 256
#define NORMF 0.125f

typedef unsigned short ushortT;
typedef __bf16 bf16x8 __attribute__((ext_vector_type(8)));
typedef float f32x4 __attribute__((ext_vector_type(4)));

struct PtrsB { const ushortT* p[12]; };   // B per (col-range, row-half)
struct PtrsD { ushortT* p[6]; };          // routed bf16 dests per col-range
struct Ptrs9 { const float* p[9]; };
struct Ptrs10 { const float* p[10]; };
struct Ptrs6 { const float* p[6]; };

__device__ inline ushortT f2bf(float f) {
    union { float f; unsigned int u; } v; v.f = f;
    unsigned int r = v.u + 0x7FFFu + ((v.u >> 16) & 1u);
    return (ushortT)(r >> 16);
}
__device__ inline float bf2f(ushortT u) {
    union { unsigned int u; float f; } v; v.u = ((unsigned int)u) << 16;
    return v.f;
}
__device__ inline void gload16(const void* gptr, void* ldsptr) {
    auto g = reinterpret_cast<const __attribute__((address_space(1))) unsigned int*>(
        reinterpret_cast<uintptr_t>(gptr));
    auto l = reinterpret_cast<__attribute__((address_space(3))) unsigned int*>(
        reinterpret_cast<uintptr_t>(ldsptr));
    __builtin_amdgcn_global_load_lds(g, l, 16, 0, 0);
}

// swizzled bf16 tile indices (ushort units)
#define LIX(r, g) (((r) << 6) + ((((g) ^ ((r) & 7))) << 3))      // 64-col tile, 8 groups
#define PIX(r, g) (((r) << 7) + ((((g) ^ ((r) & 15))) << 3))     // 128-col tile, 16 groups

// ---------- fp32 -> bf16 elementwise ----------
__global__ __launch_bounds__(256) void castx(const float* __restrict__ in,
                                             ushortT* __restrict__ out) {
    int i = blockIdx.x * 256 + threadIdx.x;
    float4 v = *(const float4*)&in[(size_t)i * 4];
    ushort4 o; o.x = f2bf(v.x); o.y = f2bf(v.y); o.z = f2bf(v.z); o.w = f2bf(v.w);
    *(ushort4*)&out[(size_t)i * 4] = o;
}

// ---------- transpose+cast body ----------
__device__ inline void tbody(const float* __restrict__ in, ushortT* __restrict__ out,
                             int in_ld, int out_ld, int r0, int c0) {
    __shared__ float T[64][65];
    int tr = threadIdx.x >> 4, tc4 = (threadIdx.x & 15) * 4;
#pragma unroll
    for (int p = 0; p < 4; ++p) {
        float4 v = *(const float4*)&in[(size_t)(r0 + tr + p * 16) * in_ld + c0 + tc4];
        T[tr + p * 16][tc4 + 0] = v.x; T[tr + p * 16][tc4 + 1] = v.y;
        T[tr + p * 16][tc4 + 2] = v.z; T[tr + p * 16][tc4 + 3] = v.w;
    }
    __syncthreads();
#pragma unroll
    for (int p = 0; p < 4; ++p) {
        int orow = c0 + tr + p * 16;
        int ocol = r0 + tc4;
        ushort4 o;
        o.x = f2bf(T[tc4 + 0][tr + p * 16]);
        o.y = f2bf(T[tc4 + 1][tr + p * 16]);
        o.z = f2bf(T[tc4 + 2][tr + p * 16]);
        o.w = f2bf(T[tc4 + 3][tr + p * 16]);
        *(ushort4*)&out[(size_t)orow * out_ld + ocol] = o;
    }
}

__global__ __launch_bounds__(256) void thead(Ptrs9 s, ushortT* __restrict__ dst) {
    int w = blockIdx.z >> 3, h = blockIdx.z & 7;
    tbody(s.p[w] + (size_t)h * 512 * 64,
          dst + (size_t)w * 262144 + (size_t)h * 64 * 512,
          64, 512, blockIdx.y * 64, 0);
}
__global__ __launch_bounds__(256) void tsq(Ptrs10 s, ushortT* __restrict__ dst) {
    tbody(s.p[blockIdx.z], dst + (size_t)blockIdx.z * 262144,
          512, 512, blockIdx.y * 64, blockIdx.x * 64);
}
__global__ __launch_bounds__(256) void tff(Ptrs6 s, ushortT* __restrict__ dst) {
    int z = blockIdx.z;
    if (z < 3) { if (blockIdx.y >= 8 || blockIdx.x >= 32) return; }
    else       { if (blockIdx.y >= 32 || blockIdx.x >= 8) return; }
    int in_ld = (z < 3) ? 2048 : 512;
    int out_ld = (z < 3) ? 512 : 2048;
    tbody(s.p[z], dst + (size_t)z * 1048576, in_ld, out_ld,
          blockIdx.y * 64, blockIdx.x * 64);
}

// ---------- 128x128 bf16 MFMA GEMM (routed / standard epilogues) ----------
__global__ __launch_bounds__(256) void gemm_bf(
    PtrsB Bp, PtrsD Db, const ushortT* __restrict__ A, float* __restrict__ outF,
    int M, int N, int K, const float* __restrict__ bias,
    const float* __restrict__ res, const float* __restrict__ alpha,
    int do_relu, int nroute, int vtmask, int scmask)
{
    __shared__ __align__(16) ushortT As[128 * 64];
    __shared__ __align__(16) ushortT Bs[128 * 64];
    const int tid = threadIdx.x;
    const int wid = tid >> 6, lane = tid & 63;
    const int wm = wid >> 1, wn = wid & 1;
    const int l15 = lane & 15, l4 = lane >> 4;

    int bid = blockIdx.y * gridDim.x + blockIdx.x;
    int nwg = gridDim.x * gridDim.y;
    int q = nwg >> 3;
    int swz = (bid & 7) * q + (bid >> 3);
    int bx = swz % gridDim.x, by = swz / gridDim.x;

    const int r0 = by * 128, c0 = bx * 128;
    const int half = ((r0 & (Nn - 1)) >= NPICKk) ? 1 : 0;
    const ushortT* Bt = Bp.p[((c0 >> 9) << 1) | half];
    const int cB = nroute ? (c0 & 511) : c0;

    const ushortT* aSrc[4];
    const ushortT* bSrc[4];
    char* ldsA[4];
    char* ldsB[4];
#pragma unroll
    for (int i = 0; i < 4; ++i) {
        int off = wid * 4096 + i * 1024 + lane * 16;
        int row = off >> 7;
        int sg = ((off >> 4) & 7) ^ (row & 7);
        aSrc[i] = A + (size_t)(r0 + row) * K + sg * 8;
        bSrc[i] = Bt + (size_t)(cB + row) * K + sg * 8;
        ldsA[i] = (char*)As + off;
        ldsB[i] = (char*)Bs + off;
    }

    f32x4 acc[4][4] = {};

    for (int kt = 0; kt < K; kt += 64) {
        __syncthreads();
#pragma unroll
        for (int i = 0; i < 4; ++i) {
            gload16(aSrc[i] + kt, ldsA[i]);
            gload16(bSrc[i] + kt, ldsB[i]);
        }
        asm volatile("s_waitcnt vmcnt(0)" ::: "memory");
        __syncthreads();
#pragma unroll
        for (int kk = 0; kk < 2; ++kk) {
            int g0 = kk * 4 + l4;
            bf16x8 af[4], bfv[4];
#pragma unroll
            for (int mi = 0; mi < 4; ++mi)
                af[mi] = *(const bf16x8*)&As[LIX(wm * 64 + mi * 16 + l15, g0)];
#pragma unroll
            for (int ni = 0; ni < 4; ++ni)
                bfv[ni] = *(const bf16x8*)&Bs[LIX(wn * 64 + ni * 16 + l15, g0)];
#pragma unroll
            for (int mi = 0; mi < 4; ++mi)
#pragma unroll
                for (int ni = 0; ni < 4; ++ni)
                    acc[mi][ni] = __builtin_amdgcn_mfma_f32_16x16x32_bf16(
                        bfv[ni], af[mi], acc[mi][ni], 0, 0, 0);   // C^T fragment
        }
    }

    if (nroute) {
#pragma unroll
        for (int mi = 0; mi < 4; ++mi) {
            int row = r0 + wm * 64 + mi * 16 + l15;
#pragma unroll
            for (int ni = 0; ni < 4; ++ni) {
                int col = c0 + wn * 64 + ni * 16 + l4 * 4;
                int range = col >> 9, cc = col & 511;
                ushortT* d = Db.p[range];
                f32x4 a = acc[mi][ni];
                if ((scmask >> range) & 1) {
                    a[0] *= NORMF; a[1] *= NORMF; a[2] *= NORMF; a[3] *= NORMF;
                }
                if ((vtmask >> range) & 1) {
                    size_t vb = ((size_t)(row >> 9) * Hh + (cc >> 6)) * 64 + (cc & 63);
                    int tok = row & 511;
#pragma unroll
                    for (int r = 0; r < 4; ++r)
                        d[((vb + r) << 9) + tok] = f2bf(a[r]);
                } else {
                    ushort4 o;
                    o.x = f2bf(a[0]); o.y = f2bf(a[1]);
                    o.z = f2bf(a[2]); o.w = f2bf(a[3]);
                    *(ushort4*)&d[((size_t)row << 9) + cc] = o;
                }
            }
        }
    } else {
        const float alp = alpha ? alpha[0] : 1.0f;
        ushortT* outB = Db.p[0];
#pragma unroll
        for (int mi = 0; mi < 4; ++mi) {
            int row = r0 + wm * 64 + mi * 16 + l15;
#pragma unroll
            for (int ni = 0; ni < 4; ++ni) {
                int colb = c0 + wn * 64 + ni * 16 + l4 * 4;
                f32x4 a = acc[mi][ni];
                if (bias) {
                    float4 b4 = *(const float4*)&bias[colb];
                    a[0] += b4.x; a[1] += b4.y; a[2] += b4.z; a[3] += b4.w;
                }
                if (do_relu) {
#pragma unroll
                    for (int r = 0; r < 4; ++r) a[r] = fmaxf(a[r], 0.f);
                }
#pragma unroll
                for (int r = 0; r < 4; ++r) a[r] *= alp;
                size_t idx = (size_t)row * N + colb;
                if (res) {
                    float4 r4 = *(const float4*)&res[idx];
                    a[0] += r4.x; a[1] += r4.y; a[2] += r4.z; a[3] += r4.w;
                }
                if (outF)
                    *(float4*)&outF[idx] = make_float4(a[0], a[1], a[2], a[3]);
                if (outB) {
                    ushort4 o;
                    o.x = f2bf(a[0]); o.y = f2bf(a[1]);
                    o.z = f2bf(a[2]); o.w = f2bf(a[3]);
                    *(ushort4*)&outB[idx] = o;
                }
            }
        }
    }
}

// ---------- 64x128 bf16 MFMA GEMM (for N=512 outputs: 2 blocks/CU) ----------
__global__ __launch_bounds__(256) void gemm64(
    const ushortT* __restrict__ Bw, const ushortT* __restrict__ A,
    float* __restrict__ outF, ushortT* __restrict__ outB,
    int M, int N, int K, const float* __restrict__ bias,
    const float* __restrict__ res, const float* __restrict__ alpha, int do_relu)
{
    __shared__ __align__(16) ushortT As[64 * 64];    // 8 KB
    __shared__ __align__(16) ushortT Bs[128 * 64];   // 16 KB
    const int tid = threadIdx.x;
    const int wid = tid >> 6, lane = tid & 63;
    const int wm = wid >> 1, wn = wid & 1;
    const int l15 = lane & 15, l4 = lane >> 4;

    int bid = blockIdx.y * gridDim.x + blockIdx.x;
    int nwg = gridDim.x * gridDim.y;
    int q = nwg >> 3;
    int swz = (bid & 7) * q + (bid >> 3);
    int bx = swz % gridDim.x, by = swz / gridDim.x;
    const int r0 = by * 64, c0 = bx * 128;

    const ushortT* aSrc[2];
    char* ldsA[2];
#pragma unroll
    for (int i = 0; i < 2; ++i) {
        int off = wid * 2048 + i * 1024 + lane * 16;
        int row = off >> 7;
        int sg = ((off >> 4) & 7) ^ (row & 7);
        aSrc[i] = A + (size_t)(r0 + row) * K + sg * 8;
        ldsA[i] = (char*)As + off;
    }
    const ushortT* bSrc[4];
    char* ldsB[4];
#pragma unroll
    for (int i = 0; i < 4; ++i) {
        int off = wid * 4096 + i * 1024 + lane * 16;
        int row = off >> 7;
        int sg = ((off >> 4) & 7) ^ (row & 7);
        bSrc[i] = Bw + (size_t)(c0 + row) * K + sg * 8;
        ldsB[i] = (char*)Bs + off;
    }

    f32x4 acc[2][4] = {};

    for (int kt = 0; kt < K; kt += 64) {
        __syncthreads();
#pragma unroll
        for (int i = 0; i < 2; ++i) gload16(aSrc[i] + kt, ldsA[i]);
#pragma unroll
        for (int i = 0; i < 4; ++i) gload16(bSrc[i] + kt, ldsB[i]);
        asm volatile("s_waitcnt vmcnt(0)" ::: "memory");
        __syncthreads();
#pragma unroll
        for (int kk = 0; kk < 2; ++kk) {
            int g0 = kk * 4 + l4;
            bf16x8 af[2], bfv[4];
#pragma unroll
            for (int mi = 0; mi < 2; ++mi)
                af[mi] = *(const bf16x8*)&As[LIX(wm * 32 + mi * 16 + l15, g0)];
#pragma unroll
            for (int ni = 0; ni < 4; ++ni)
                bfv[ni] = *(const bf16x8*)&Bs[LIX(wn * 64 + ni * 16 + l15, g0)];
#pragma unroll
            for (int mi = 0; mi < 2; ++mi)
#pragma unroll
                for (int ni = 0; ni < 4; ++ni)
                    acc[mi][ni] = __builtin_amdgcn_mfma_f32_16x16x32_bf16(
                        bfv[ni], af[mi], acc[mi][ni], 0, 0, 0);
        }
    }

    const float alp = alpha ? alpha[0] : 1.0f;
#pragma unroll
    for (int mi = 0; mi < 2; ++mi) {
        int row = r0 + wm * 32 + mi * 16 + l15;
#pragma unroll
        for (int ni = 0; ni < 4; ++ni) {
            int colb = c0 + wn * 64 + ni * 16 + l4 * 4;
            f32x4 a = acc[mi][ni];
            if (bias) {
                float4 b4 = *(const float4*)&bias[colb];
                a[0] += b4.x; a[1] += b4.y; a[2] += b4.z; a[3] += b4.w;
            }
            if (do_relu) {
#pragma unroll
                for (int r = 0; r < 4; ++r) a[r] = fmaxf(a[r], 0.f);
            }
#pragma unroll
            for (int r = 0; r < 4; ++r) a[r] *= alp;
            size_t idx = (size_t)row * N + colb;
            if (res) {
                float4 r4 = *(const float4*)&res[idx];
                a[0] += r4.x; a[1] += r4.y; a[2] += r4.z; a[3] += r4.w;
            }
            if (outF)
                *(float4*)&outF[idx] = make_float4(a[0], a[1], a[2], a[3]);
            if (outB) {
                ushort4 o;
                o.x = f2bf(a[0]); o.y = f2bf(a[1]);
                o.z = f2bf(a[2]); o.w = f2bf(a[3]);
                *(ushort4*)&outB[idx] = o;
            }
        }
    }
}

// ---------- HA diagonal scores (QD pre-scaled by NORM) ----------
__global__ __launch_bounds__(256) void diag_dot_bb(const ushortT* __restrict__ QD,
                                                   const ushortT* __restrict__ K,
                                                   float* __restrict__ Sdg) {
    int i = blockIdx.x * 256 + threadIdx.x;
    int h = i & 7, n = (i >> 3) & 511, b = i >> 12;
    int dix = (n < NPICKk) ? n + NPICKk : n - NPICKk;
    const ushortT* q = QD + (((size_t)(b * Nn + n) * Hh + h) << 6);
    const ushortT* k = K + (((size_t)(b * Nn + dix) * Hh + h) << 6);
    float s = 0.f;
#pragma unroll
    for (int d = 0; d < 64; d += 4) {
        ushort4 a = *(const ushort4*)(q + d);
        ushort4 c = *(const ushort4*)(k + d);
        s += bf2f(a.x) * bf2f(c.x) + bf2f(a.y) * bf2f(c.y)
           + bf2f(a.z) * bf2f(c.z) + bf2f(a.w) * bf2f(c.w);
    }
    Sdg[i] = s;
}

// ---------- MFMA flash attention, KVBLK=128, pre-scaled Q ----------
template <int HA>
__global__ __launch_bounds__(256) void attn5(
    const ushortT* __restrict__ Qm, const ushortT* __restrict__ Km,
    const ushortT* __restrict__ Vtm, const ushortT* __restrict__ QAm,
    const ushortT* __restrict__ QBm, const float* __restrict__ Sdg,
    ushortT* __restrict__ Out)
{
    __shared__ __align__(16) ushortT Qs[64 * 64];            // 8 KB
    __shared__ __align__(16) ushortT Ks[128 * 64];           // 16 KB  [k][d]
    __shared__ __align__(16) ushortT Vs[64 * 128];           // 16 KB  [v][k]
    __shared__ __align__(16) ushortT Ps[64 * 128];           // 16 KB  [q][k]
    __shared__ __align__(16) ushortT Qxs[HA ? 2 * 64 * 64 : 8];
    __shared__ float sdl[64];

    const int tid = threadIdx.x, wid = tid >> 6, lane = tid & 63;
    const int l15 = lane & 15, l4 = lane >> 4;
    const int b = blockIdx.z, h = blockIdx.y, n0 = blockIdx.x * 64;
    const int bh = b * Hh + h;

    // stage Q (+QA into Qxs[0])
#pragma unroll
    for (int i = 0; i < 2; ++i) {
        int off = wid * 2048 + i * 1024 + lane * 16;
        int row = off >> 7, sg = ((off >> 4) & 7) ^ (row & 7);
        size_t gidx = (((size_t)(b * Nn + n0 + row) * Hh + h) << 6) + sg * 8;
        gload16(Qm + gidx, (char*)Qs + off);
        if (HA) gload16(QAm + gidx, (char*)Qxs + off);
    }
    if (HA && tid < 64) sdl[tid] = Sdg[((size_t)(b * Nn + n0 + tid)) * Hh + h];

    const int dn = (n0 < NPICKk) ? n0 + NPICKk : n0 - NPICKk;
    const int td = dn >> 7;
    const int dcw = ((dn & 127) >> 4) + wid;

    // staging bases (t-stride: K = 128*Hh*VDd elems, V = 128 elems)
    const ushortT* kSrc[4]; char* kDst[4];
    const ushortT* vSrc[4]; char* vDst[4];
#pragma unroll
    for (int i = 0; i < 4; ++i) {
        int off = wid * 4096 + i * 1024 + lane * 16;
        int krow = off >> 7, ksg = ((off >> 4) & 7) ^ (krow & 7);
        kSrc[i] = Km + (((size_t)(b * Nn + krow) * Hh + h) << 6) + ksg * 8;
        kDst[i] = (char*)Ks + off;
        int vrow = off >> 8, vsg = ((off >> 4) & 15) ^ (vrow & 15);
        vSrc[i] = Vtm + (((size_t)(bh * 64 + vrow)) << 9) + vsg * 8;
        vDst[i] = (char*)Vs + off;
    }

    float M[4], L[4];
    f32x4 Oa[4] = {};
#pragma unroll
    for (int r = 0; r < 4; ++r) { M[r] = -INFINITY; L[r] = 0.f; }

    for (int t = 0; t < 4; ++t) {
        __syncthreads();
#pragma unroll
        for (int i = 0; i < 4; ++i) {
            gload16(kSrc[i] + (size_t)t * (128 * Hh * VDd), kDst[i]);
            gload16(vSrc[i] + t * 128, vDst[i]);
        }
        if (HA && t == 0) {
#pragma unroll
            for (int i = 0; i < 2; ++i) {
                int off = wid * 2048 + i * 1024 + lane * 16;
                int row = off >> 7, sg = ((off >> 4) & 7) ^ (row & 7);
                gload16(QBm + (((size_t)(b * Nn + n0 + row) * Hh + h) << 6) + sg * 8,
                        (char*)Qxs + 8192 + off);
            }
        }
        asm volatile("s_waitcnt vmcnt(0)" ::: "memory");
        __syncthreads();

        // ---- S = Q K^T (scores for 128 cols) ----
        const ushortT* qx = (HA && t >= 2) ? (Qxs + 4096) : Qxs;
        __builtin_amdgcn_s_setprio(1);
        f32x4 s1[8] = {}, sX[8] = {};
#pragma unroll
        for (int kk = 0; kk < 2; ++kk) {
            int g0 = kk * 4 + l4;
            bf16x8 aq = *(const bf16x8*)&Qs[LIX(wid * 16 + l15, g0)];
            bf16x8 ax;
            if (HA) ax = *(const bf16x8*)&qx[LIX(wid * 16 + l15, g0)];
#pragma unroll
            for (int nj = 0; nj < 8; ++nj) {
                bf16x8 bk = *(const bf16x8*)&Ks[LIX(nj * 16 + l15, g0)];
                s1[nj] = __builtin_amdgcn_mfma_f32_16x16x32_bf16(aq, bk, s1[nj], 0, 0, 0);
                if (HA)
                    sX[nj] = __builtin_amdgcn_mfma_f32_16x16x32_bf16(ax, bk, sX[nj], 0, 0, 0);
            }
        }
        __builtin_amdgcn_s_setprio(0);

        const bool dt = HA && (t == td);

        // ---- online softmax ----
#pragma unroll
        for (int r = 0; r < 4; ++r) {
            int rw = wid * 16 + l4 * 4 + r;
            float m = s1[0][r];
#pragma unroll
            for (int nj = 1; nj < 8; ++nj) m = fmaxf(m, s1[nj][r]);
            if (HA) {
#pragma unroll
                for (int nj = 0; nj < 8; ++nj) m = fmaxf(m, sX[nj][r]);
            }
            if (dt) m = fmaxf(m, sdl[rw]);
#pragma unroll
            for (int o = 8; o >= 1; o >>= 1) m = fmaxf(m, __shfl_xor(m, o, 16));
            float mn = fmaxf(M[r], m);
            float sc = __expf(M[r] - mn);
            M[r] = mn; L[r] *= sc;
#pragma unroll
            for (int ni = 0; ni < 4; ++ni) Oa[ni][r] *= sc;
            float rs = 0.f;
#pragma unroll
            for (int nj = 0; nj < 8; ++nj) {
                float p = __expf(s1[nj][r] - mn);
                if (HA) p += __expf(sX[nj][r] - mn);
                if (dt && nj == dcw && l15 == l4 * 4 + r) p += __expf(sdl[rw] - mn);
                s1[nj][r] = p;
                rs += p;
            }
#pragma unroll
            for (int o = 8; o >= 1; o >>= 1) rs += __shfl_xor(rs, o, 16);
            L[r] += rs;
        }

        // ---- write P (bf16, swizzled [64][128]) ----
#pragma unroll
        for (int nj = 0; nj < 8; ++nj)
#pragma unroll
            for (int r = 0; r < 4; ++r) {
                int prow = wid * 16 + l4 * 4 + r;
                int col = nj * 16 + l15;
                Ps[(prow << 7) + ((((col >> 3) ^ (prow & 15))) << 3) + (col & 7)] =
                    f2bf(s1[nj][r]);
            }
        __syncthreads();

        // ---- O += P @ V ----
        __builtin_amdgcn_s_setprio(1);
#pragma unroll
        for (int kk = 0; kk < 4; ++kk) {
            int g0 = kk * 4 + l4;
            bf16x8 ap = *(const bf16x8*)&Ps[PIX(wid * 16 + l15, g0)];
#pragma unroll
            for (int ni = 0; ni < 4; ++ni) {
                bf16x8 bv = *(const bf16x8*)&Vs[PIX(ni * 16 + l15, g0)];
                Oa[ni] = __builtin_amdgcn_mfma_f32_16x16x32_bf16(ap, bv, Oa[ni], 0, 0, 0);
            }
        }
        __builtin_amdgcn_s_setprio(0);
    }

#pragma unroll
    for (int r = 0; r < 4; ++r) {
        float inv = 1.0f / L[r];
        size_t obase = (((size_t)(b * Nn + n0 + wid * 16 + l4 * 4 + r) * Hh + h) << 6);
#pragma unroll
        for (int ni = 0; ni < 4; ++ni)
            Out[obase + ni * 16 + l15] = f2bf(Oa[ni][r] * inv);
    }
}

extern "C" void kernel_launch(void* const* d_in, const int* in_sizes, int n_in,
                              void* d_out, int out_size, void* d_ws, size_t ws_size,
                              hipStream_t stream)
{
    const float* x = (const float*)d_in[0];

    int dictOrder = (in_sizes[18] != 512);
    const float* comb_w  = (const float*)d_in[17];
    const float* comb2_w = (const float*)d_in[dictOrder ? 18 : 19];
    const float* comb3_w = (const float*)d_in[dictOrder ? 19 : 21];
    const float* comb_b  = (const float*)d_in[dictOrder ? 20 : 18];
    const float* comb2_b = (const float*)d_in[dictOrder ? 21 : 20];
    const float* comb3_b = (const float*)d_in[22];
    const float* alpha1 = (const float*)d_in[23];
    const float* alpha2 = (const float*)d_in[24];
    const float* alpha3 = (const float*)d_in[25];
    const float* ff1_w1 = (const float*)d_in[26];
    const float* ff1_b1 = (const float*)d_in[27];
    const float* ff1_w2 = (const float*)d_in[28];
    const float* ff1_b2 = (const float*)d_in[29];
    const float* ffa1   = (const float*)d_in[30];
    const float* ff2_w1 = (const float*)d_in[31];
    const float* ff2_b1 = (const float*)d_in[32];
    const float* ff2_w2 = (const float*)d_in[33];
    const float* ff2_b2 = (const float*)d_in[34];
    const float* ffa2   = (const float*)d_in[35];
    const float* ff3_w1 = (const float*)d_in[36];
    const float* ff3_b1 = (const float*)d_in[37];
    const float* ff3_w2 = (const float*)d_in[38];
    const float* ff3_b2 = (const float*)d_in[39];
    const float* ffa3   = (const float*)d_in[40];

    // ---- workspace layout (bytes) ----
    char* W = (char*)d_ws;
    ushortT* wbHead = (ushortT*)(W + 0);           // 9 x 512x512 bf16
    ushortT* wbMha  = (ushortT*)(W + 4718592);     // 7 x
    ushortT* wbComb = (ushortT*)(W + 8388608);     // 3 x
    ushortT* wbFf1  = (ushortT*)(W + 9961472);     // 3 x 2048x512
    ushortT* wbFf2  = (ushortT*)(W + 16252928);    // 3 x 512x2048
    ushortT* xbf    = (ushortT*)(W + 22544384);    // 8192x512 bf16; later bufHA
    float*   Sd     = (float*)  (W + 30932992);    // 65536 f32
    ushortT* bufQ   = (ushortT*)(W + 31195136);    // 8192x512 bf16 each
    ushortT* bufK   = (ushortT*)(W + 39583744);
    ushortT* bufVt  = (ushortT*)(W + 47972352);
    ushortT* bufQA  = (ushortT*)(W + 56360960);
    ushortT* bufQB  = (ushortT*)(W + 64749568);
    ushortT* bufQD  = (ushortT*)(W + 73138176);
    ushortT* hidden = (ushortT*)(W + 81526784);    // 8192x2048 bf16
    ushortT* curb   = (ushortT*)(W + 115081216);   // bf16 shadow of residual
    ushortT* bufHA  = xbf;
    float*   cur    = (float*)d_out;

    dim3 tb(256);
    const int TOK = Bb * Nn;  // 8192
    const size_t WS = 512 * 512;
    const size_t WF = 2048 * 512;

    // 1. casts / transposes (batched)
    hipLaunchKernelGGL(castx, dim3(TOK * 512 / 1024), tb, 0, stream, x, xbf);
    {
        Ptrs9 s; for (int i = 0; i < 9; ++i) s.p[i] = (const float*)d_in[1 + i];
        hipLaunchKernelGGL(thead, dim3(1, 8, 72), tb, 0, stream, s, wbHead);
    }
    {
        Ptrs10 s;
        for (int i = 0; i < 7; ++i) s.p[i] = (const float*)d_in[10 + i];
        s.p[7] = comb_w; s.p[8] = comb2_w; s.p[9] = comb3_w;
        hipLaunchKernelGGL(tsq, dim3(8, 8, 10), tb, 0, stream, s, wbMha);
    }
    {
        Ptrs6 s;
        s.p[0] = ff1_w1; s.p[1] = ff2_w1; s.p[2] = ff3_w1;
        s.p[3] = ff1_w2; s.p[4] = ff2_w2; s.p[5] = ff3_w2;
        hipLaunchKernelGGL(tff, dim3(32, 32, 6), tb, 0, stream, s, wbFf1);
    }

    auto gemm = [&](PtrsB Bp, PtrsD Db, const ushortT* A, float* oF,
                    int M, int Ncc, int Kc, const float* bias, const float* res,
                    const float* alp, int relu, int nroute, int vtmask, int scmask) {
        hipLaunchKernelGGL(gemm_bf, dim3(Ncc / 128, M / 128), tb, 0, stream,
                           Bp, Db, A, oF, M, Ncc, Kc, bias, res, alp, relu, nroute,
                           vtmask, scmask);
    };
    auto g64 = [&](const ushortT* Bw, const ushortT* A, float* oF, ushortT* oB,
                   int M, int Ncc, int Kc, const float* bias, const float* res,
                   const float* alp, int relu) {
        hipLaunchKernelGGL(gemm64, dim3(Ncc / 128, M / 64), tb, 0, stream,
                           Bw, A, oF, oB, M, Ncc, Kc, bias, res, alp, relu);
    };
    auto uni = [&](const ushortT* w) { PtrsB b; for (int i = 0; i < 12; ++i) b.p[i] = w; return b; };
    auto d1 = [&](ushortT* d) { PtrsD dd = {}; dd.p[0] = d; return dd; };

    // 2. HA projections: ONE fused GEMM, N=3072; Q/QA/QB/QD pre-scaled by NORM
    {
        PtrsB b;
        b.p[0] = b.p[1] = wbHead + 0 * WS;           // Q
        b.p[2] = b.p[3] = wbHead + 1 * WS;           // K
        b.p[4] = b.p[5] = wbHead + 2 * WS;           // V (vt)
        b.p[6] = wbHead + 4 * WS; b.p[7] = wbHead + 8 * WS;   // QA: W2 / W6
        b.p[8] = wbHead + 5 * WS; b.p[9] = wbHead + 7 * WS;   // QB: W3 / W5
        b.p[10] = wbHead + 3 * WS; b.p[11] = wbHead + 6 * WS; // QD: W1 / W4
        PtrsD d; d.p[0] = bufQ; d.p[1] = bufK; d.p[2] = bufVt;
        d.p[3] = bufQA; d.p[4] = bufQB; d.p[5] = bufQD;
        gemm(b, d, xbf, nullptr, TOK, 3072, 512, nullptr, nullptr, nullptr, 0, 6, 4, 57);
    }

    // 3. HA attention
    hipLaunchKernelGGL(diag_dot_bb, dim3(Bb * Nn * Hh / 256), tb, 0, stream, bufQD, bufK, Sd);
    hipLaunchKernelGGL((attn5<1>), dim3(Nn / 64, Hh, Bb), tb, 0, stream,
                       bufQ, bufK, bufVt, bufQA, bufQB, Sd, bufHA);

    // 4. comb3 + FF3
    g64(wbComb + 2 * WS, bufHA, cur, curb, TOK, 512, 512, comb3_b, x, alpha3, 0);
    gemm(uni(wbFf1 + 2 * WF), d1(hidden), curb, nullptr, TOK, 2048, 512, ff3_b1, nullptr, nullptr, 1, 0, 0, 0);
    g64(wbFf2 + 2 * WF, hidden, cur, curb, TOK, 512, 2048, ff3_b2, cur, ffa3, 0);

    // 5. MHA1: fused QKV projection (Q pre-scaled), N=1536
    {
        PtrsB b;
        b.p[0] = b.p[1] = wbMha + 0 * WS;
        b.p[2] = b.p[3] = wbMha + 1 * WS;
        b.p[4] = b.p[5] = wbMha + 2 * WS;
        PtrsD d = {}; d.p[0] = bufQ; d.p[1] = bufK; d.p[2] = bufVt;
        gemm(b, d, curb, nullptr, TOK, 1536, 512, nullptr, nullptr, nullptr, 0, 3, 4, 1);
    }
    hipLaunchKernelGGL((attn5<0>), dim3(Nn / 64, Hh, Bb), tb, 0, stream,
                       bufQ, bufK, bufVt, nullptr, nullptr, nullptr, bufHA);
    g64(wbComb + 0 * WS, bufHA, cur, curb, TOK, 512, 512, comb_b, cur, alpha1, 0);
    gemm(uni(wbFf1 + 0 * WF), d1(hidden), curb, nullptr, TOK, 2048, 512, ff1_b1, nullptr, nullptr, 1, 0, 0, 0);
    g64(wbFf2 + 0 * WF, hidden, cur, curb, TOK, 512, 2048, ff1_b2, cur, ffa1, 0);

    // 6. MHA2: fused projection with split Q (Wq2p/Wq2d), N=1536
    {
        PtrsB b;
        b.p[0] = wbMha + 3 * WS; b.p[1] = wbMha + 4 * WS;
        b.p[2] = b.p[3] = wbMha + 5 * WS;
        b.p[4] = b.p[5] = wbMha + 6 * WS;
        PtrsD d = {}; d.p[0] = bufQ; d.p[1] = bufK; d.p[2] = bufVt;
        gemm(b, d, curb, nullptr, TOK, 1536, 512, nullptr, nullptr, nullptr, 0, 3, 4, 1);
    }
    hipLaunchKernelGGL((attn5<0>), dim3(Nn / 64, Hh, Bb), tb, 0, stream,
                       bufQ, bufK, bufVt, nullptr, nullptr, nullptr, bufHA);
    g64(wbComb + 1 * WS, bufHA, cur, curb, TOK, 512, 512, comb2_b, cur, alpha2, 0);
    gemm(uni(wbFf1 + 1 * WF), d1(hidden), curb, nullptr, TOK, 2048, 512, ff2_b1, nullptr, nullptr, 1, 0, 0, 0);
    g64(wbFf2 + 1 * WF, hidden, cur, nullptr, TOK, 512, 2048, ff2_b2, cur, ffa2, 0);
}

// Round 9
// 528.849 us; speedup vs baseline: 9.5238x; 1.0335x over previous
//
#include <hip/hip_runtime.h>
#include <math.h>

#define Hh 8
#define Bb 16
#define Nn 512
#define Dd 512
#define VDd 64
#define NPICKk 256
#define NORMF 0.125f

typedef unsigned short ushortT;
typedef __bf16 bf16x8 __attribute__((ext_vector_type(8)));
typedef float f32x4 __attribute__((ext_vector_type(4)));

struct PtrsB { const ushortT* p[12]; };   // B per (col-range, row-half)
struct PtrsD { ushortT* p[6]; };          // routed bf16 dests per col-range
struct Ptrs9 { const float* p[9]; };
struct Ptrs10 { const float* p[10]; };
struct Ptrs6 { const float* p[6]; };

__device__ inline ushortT f2bf(float f) {
    union { float f; unsigned int u; } v; v.f = f;
    unsigned int r = v.u + 0x7FFFu + ((v.u >> 16) & 1u);
    return (ushortT)(r >> 16);
}
__device__ inline float bf2f(ushortT u) {
    union { unsigned int u; float f; } v; v.u = ((unsigned int)u) << 16;
    return v.f;
}
__device__ inline void gload16(const void* gptr, void* ldsptr) {
    auto g = reinterpret_cast<const __attribute__((address_space(1))) unsigned int*>(
        reinterpret_cast<uintptr_t>(gptr));
    auto l = reinterpret_cast<__attribute__((address_space(3))) unsigned int*>(
        reinterpret_cast<uintptr_t>(ldsptr));
    __builtin_amdgcn_global_load_lds(g, l, 16, 0, 0);
}

// swizzled bf16 64-col tile: row r, 16B-group g (0..7) -> ushort index
#define LIX(r, g) (((r) << 6) + ((((g) ^ ((r) & 7))) << 3))

// ---------- fp32 -> bf16 elementwise ----------
__global__ __launch_bounds__(256) void castx(const float* __restrict__ in,
                                             ushortT* __restrict__ out) {
    int i = blockIdx.x * 256 + threadIdx.x;
    float4 v = *(const float4*)&in[(size_t)i * 4];
    ushort4 o; o.x = f2bf(v.x); o.y = f2bf(v.y); o.z = f2bf(v.z); o.w = f2bf(v.w);
    *(ushort4*)&out[(size_t)i * 4] = o;
}

// ---------- transpose+cast body ----------
__device__ inline void tbody(const float* __restrict__ in, ushortT* __restrict__ out,
                             int in_ld, int out_ld, int r0, int c0) {
    __shared__ float T[64][65];
    int tr = threadIdx.x >> 4, tc4 = (threadIdx.x & 15) * 4;
#pragma unroll
    for (int p = 0; p < 4; ++p) {
        float4 v = *(const float4*)&in[(size_t)(r0 + tr + p * 16) * in_ld + c0 + tc4];
        T[tr + p * 16][tc4 + 0] = v.x; T[tr + p * 16][tc4 + 1] = v.y;
        T[tr + p * 16][tc4 + 2] = v.z; T[tr + p * 16][tc4 + 3] = v.w;
    }
    __syncthreads();
#pragma unroll
    for (int p = 0; p < 4; ++p) {
        int orow = c0 + tr + p * 16;
        int ocol = r0 + tc4;
        ushort4 o;
        o.x = f2bf(T[tc4 + 0][tr + p * 16]);
        o.y = f2bf(T[tc4 + 1][tr + p * 16]);
        o.z = f2bf(T[tc4 + 2][tr + p * 16]);
        o.w = f2bf(T[tc4 + 3][tr + p * 16]);
        *(ushort4*)&out[(size_t)orow * out_ld + ocol] = o;
    }
}

__global__ __launch_bounds__(256) void thead(Ptrs9 s, ushortT* __restrict__ dst) {
    int w = blockIdx.z >> 3, h = blockIdx.z & 7;
    tbody(s.p[w] + (size_t)h * 512 * 64,
          dst + (size_t)w * 262144 + (size_t)h * 64 * 512,
          64, 512, blockIdx.y * 64, 0);
}
__global__ __launch_bounds__(256) void tsq(Ptrs10 s, ushortT* __restrict__ dst) {
    tbody(s.p[blockIdx.z], dst + (size_t)blockIdx.z * 262144,
          512, 512, blockIdx.y * 64, blockIdx.x * 64);
}
__global__ __launch_bounds__(256) void tff(Ptrs6 s, ushortT* __restrict__ dst) {
    int z = blockIdx.z;
    if (z < 3) { if (blockIdx.y >= 8 || blockIdx.x >= 32) return; }
    else       { if (blockIdx.y >= 32 || blockIdx.x >= 8) return; }
    int in_ld = (z < 3) ? 2048 : 512;
    int out_ld = (z < 3) ? 512 : 2048;
    tbody(s.p[z], dst + (size_t)z * 1048576, in_ld, out_ld,
          blockIdx.y * 64, blockIdx.x * 64);
}

// ---------- 128x128 bf16 MFMA GEMM (routed / standard epilogues) ----------
__global__ __launch_bounds__(256) void gemm_bf(
    PtrsB Bp, PtrsD Db, const ushortT* __restrict__ A, float* __restrict__ outF,
    int M, int N, int K, const float* __restrict__ bias,
    const float* __restrict__ res, const float* __restrict__ alpha,
    int do_relu, int nroute, int vtmask, int scmask)
{
    __shared__ __align__(16) ushortT As[128 * 64];
    __shared__ __align__(16) ushortT Bs[128 * 64];
    const int tid = threadIdx.x;
    const int wid = tid >> 6, lane = tid & 63;
    const int wm = wid >> 1, wn = wid & 1;
    const int l15 = lane & 15, l4 = lane >> 4;

    int bid = blockIdx.y * gridDim.x + blockIdx.x;
    int nwg = gridDim.x * gridDim.y;
    int q = nwg >> 3;
    int swz = (bid & 7) * q + (bid >> 3);
    int bx = swz % gridDim.x, by = swz / gridDim.x;

    const int r0 = by * 128, c0 = bx * 128;
    const int half = ((r0 & (Nn - 1)) >= NPICKk) ? 1 : 0;
    const ushortT* Bt = Bp.p[((c0 >> 9) << 1) | half];
    const int cB = nroute ? (c0 & 511) : c0;

    const ushortT* aSrc[4];
    const ushortT* bSrc[4];
    char* ldsA[4];
    char* ldsB[4];
#pragma unroll
    for (int i = 0; i < 4; ++i) {
        int off = wid * 4096 + i * 1024 + lane * 16;
        int row = off >> 7;
        int sg = ((off >> 4) & 7) ^ (row & 7);
        aSrc[i] = A + (size_t)(r0 + row) * K + sg * 8;
        bSrc[i] = Bt + (size_t)(cB + row) * K + sg * 8;
        ldsA[i] = (char*)As + off;
        ldsB[i] = (char*)Bs + off;
    }

    f32x4 acc[4][4] = {};

    for (int kt = 0; kt < K; kt += 64) {
        __syncthreads();
#pragma unroll
        for (int i = 0; i < 4; ++i) {
            gload16(aSrc[i] + kt, ldsA[i]);
            gload16(bSrc[i] + kt, ldsB[i]);
        }
        asm volatile("s_waitcnt vmcnt(0)" ::: "memory");
        __syncthreads();
#pragma unroll
        for (int kk = 0; kk < 2; ++kk) {
            int g0 = kk * 4 + l4;
            bf16x8 af[4], bfv[4];
#pragma unroll
            for (int mi = 0; mi < 4; ++mi)
                af[mi] = *(const bf16x8*)&As[LIX(wm * 64 + mi * 16 + l15, g0)];
#pragma unroll
            for (int ni = 0; ni < 4; ++ni)
                bfv[ni] = *(const bf16x8*)&Bs[LIX(wn * 64 + ni * 16 + l15, g0)];
#pragma unroll
            for (int mi = 0; mi < 4; ++mi)
#pragma unroll
                for (int ni = 0; ni < 4; ++ni)
                    acc[mi][ni] = __builtin_amdgcn_mfma_f32_16x16x32_bf16(
                        bfv[ni], af[mi], acc[mi][ni], 0, 0, 0);   // C^T fragment
        }
    }

    if (nroute) {
#pragma unroll
        for (int mi = 0; mi < 4; ++mi) {
            int row = r0 + wm * 64 + mi * 16 + l15;
#pragma unroll
            for (int ni = 0; ni < 4; ++ni) {
                int col = c0 + wn * 64 + ni * 16 + l4 * 4;
                int range = col >> 9, cc = col & 511;
                ushortT* d = Db.p[range];
                f32x4 a = acc[mi][ni];
                if ((scmask >> range) & 1) {
                    a[0] *= NORMF; a[1] *= NORMF; a[2] *= NORMF; a[3] *= NORMF;
                }
                if ((vtmask >> range) & 1) {
                    size_t vb = ((size_t)(row >> 9) * Hh + (cc >> 6)) * 64 + (cc & 63);
                    int tok = row & 511;
#pragma unroll
                    for (int r = 0; r < 4; ++r)
                        d[((vb + r) << 9) + tok] = f2bf(a[r]);
                } else {
                    ushort4 o;
                    o.x = f2bf(a[0]); o.y = f2bf(a[1]);
                    o.z = f2bf(a[2]); o.w = f2bf(a[3]);
                    *(ushort4*)&d[((size_t)row << 9) + cc] = o;
                }
            }
        }
    } else {
        const float alp = alpha ? alpha[0] : 1.0f;
        ushortT* outB = Db.p[0];
#pragma unroll
        for (int mi = 0; mi < 4; ++mi) {
            int row = r0 + wm * 64 + mi * 16 + l15;
#pragma unroll
            for (int ni = 0; ni < 4; ++ni) {
                int colb = c0 + wn * 64 + ni * 16 + l4 * 4;
                f32x4 a = acc[mi][ni];
                if (bias) {
                    float4 b4 = *(const float4*)&bias[colb];
                    a[0] += b4.x; a[1] += b4.y; a[2] += b4.z; a[3] += b4.w;
                }
                if (do_relu) {
#pragma unroll
                    for (int r = 0; r < 4; ++r) a[r] = fmaxf(a[r], 0.f);
                }
#pragma unroll
                for (int r = 0; r < 4; ++r) a[r] *= alp;
                size_t idx = (size_t)row * N + colb;
                if (res) {
                    float4 r4 = *(const float4*)&res[idx];
                    a[0] += r4.x; a[1] += r4.y; a[2] += r4.z; a[3] += r4.w;
                }
                if (outF)
                    *(float4*)&outF[idx] = make_float4(a[0], a[1], a[2], a[3]);
                if (outB) {
                    ushort4 o;
                    o.x = f2bf(a[0]); o.y = f2bf(a[1]);
                    o.z = f2bf(a[2]); o.w = f2bf(a[3]);
                    *(ushort4*)&outB[idx] = o;
                }
            }
        }
    }
}

// ---------- 64x128 bf16 MFMA GEMM (for N=512 outputs: higher occupancy) ----------
__global__ __launch_bounds__(256) void gemm64(
    const ushortT* __restrict__ Bw, const ushortT* __restrict__ A,
    float* __restrict__ outF, ushortT* __restrict__ outB,
    int M, int N, int K, const float* __restrict__ bias,
    const float* __restrict__ res, const float* __restrict__ alpha, int do_relu)
{
    __shared__ __align__(16) ushortT As[64 * 64];    // 8 KB
    __shared__ __align__(16) ushortT Bs[128 * 64];   // 16 KB
    const int tid = threadIdx.x;
    const int wid = tid >> 6, lane = tid & 63;
    const int wm = wid >> 1, wn = wid & 1;
    const int l15 = lane & 15, l4 = lane >> 4;

    int bid = blockIdx.y * gridDim.x + blockIdx.x;
    int nwg = gridDim.x * gridDim.y;
    int q = nwg >> 3;
    int swz = (bid & 7) * q + (bid >> 3);
    int bx = swz % gridDim.x, by = swz / gridDim.x;
    const int r0 = by * 64, c0 = bx * 128;

    const ushortT* aSrc[2];
    char* ldsA[2];
#pragma unroll
    for (int i = 0; i < 2; ++i) {
        int off = wid * 2048 + i * 1024 + lane * 16;
        int row = off >> 7;
        int sg = ((off >> 4) & 7) ^ (row & 7);
        aSrc[i] = A + (size_t)(r0 + row) * K + sg * 8;
        ldsA[i] = (char*)As + off;
    }
    const ushortT* bSrc[4];
    char* ldsB[4];
#pragma unroll
    for (int i = 0; i < 4; ++i) {
        int off = wid * 4096 + i * 1024 + lane * 16;
        int row = off >> 7;
        int sg = ((off >> 4) & 7) ^ (row & 7);
        bSrc[i] = Bw + (size_t)(c0 + row) * K + sg * 8;
        ldsB[i] = (char*)Bs + off;
    }

    f32x4 acc[2][4] = {};

    for (int kt = 0; kt < K; kt += 64) {
        __syncthreads();
#pragma unroll
        for (int i = 0; i < 2; ++i) gload16(aSrc[i] + kt, ldsA[i]);
#pragma unroll
        for (int i = 0; i < 4; ++i) gload16(bSrc[i] + kt, ldsB[i]);
        asm volatile("s_waitcnt vmcnt(0)" ::: "memory");
        __syncthreads();
#pragma unroll
        for (int kk = 0; kk < 2; ++kk) {
            int g0 = kk * 4 + l4;
            bf16x8 af[2], bfv[4];
#pragma unroll
            for (int mi = 0; mi < 2; ++mi)
                af[mi] = *(const bf16x8*)&As[LIX(wm * 32 + mi * 16 + l15, g0)];
#pragma unroll
            for (int ni = 0; ni < 4; ++ni)
                bfv[ni] = *(const bf16x8*)&Bs[LIX(wn * 64 + ni * 16 + l15, g0)];
#pragma unroll
            for (int mi = 0; mi < 2; ++mi)
#pragma unroll
                for (int ni = 0; ni < 4; ++ni)
                    acc[mi][ni] = __builtin_amdgcn_mfma_f32_16x16x32_bf16(
                        bfv[ni], af[mi], acc[mi][ni], 0, 0, 0);
        }
    }

    const float alp = alpha ? alpha[0] : 1.0f;
#pragma unroll
    for (int mi = 0; mi < 2; ++mi) {
        int row = r0 + wm * 32 + mi * 16 + l15;
#pragma unroll
        for (int ni = 0; ni < 4; ++ni) {
            int colb = c0 + wn * 64 + ni * 16 + l4 * 4;
            f32x4 a = acc[mi][ni];
            if (bias) {
                float4 b4 = *(const float4*)&bias[colb];
                a[0] += b4.x; a[1] += b4.y; a[2] += b4.z; a[3] += b4.w;
            }
            if (do_relu) {
#pragma unroll
                for (int r = 0; r < 4; ++r) a[r] = fmaxf(a[r], 0.f);
            }
#pragma unroll
            for (int r = 0; r < 4; ++r) a[r] *= alp;
            size_t idx = (size_t)row * N + colb;
            if (res) {
                float4 r4 = *(const float4*)&res[idx];
                a[0] += r4.x; a[1] += r4.y; a[2] += r4.z; a[3] += r4.w;
            }
            if (outF)
                *(float4*)&outF[idx] = make_float4(a[0], a[1], a[2], a[3]);
            if (outB) {
                ushort4 o;
                o.x = f2bf(a[0]); o.y = f2bf(a[1]);
                o.z = f2bf(a[2]); o.w = f2bf(a[3]);
                *(ushort4*)&outB[idx] = o;
            }
        }
    }
}

// ---------- HA diagonal scores (QD pre-scaled by NORM) ----------
__global__ __launch_bounds__(256) void diag_dot_bb(const ushortT* __restrict__ QD,
                                                   const ushortT* __restrict__ K,
                                                   float* __restrict__ Sdg) {
    int i = blockIdx.x * 256 + threadIdx.x;
    int h = i & 7, n = (i >> 3) & 511, b = i >> 12;
    int dix = (n < NPICKk) ? n + NPICKk : n - NPICKk;
    const ushortT* q = QD + (((size_t)(b * Nn + n) * Hh + h) << 6);
    const ushortT* k = K + (((size_t)(b * Nn + dix) * Hh + h) << 6);
    float s = 0.f;
#pragma unroll
    for (int d = 0; d < 64; d += 4) {
        ushort4 a = *(const ushort4*)(q + d);
        ushort4 c = *(const ushort4*)(k + d);
        s += bf2f(a.x) * bf2f(c.x) + bf2f(a.y) * bf2f(c.y)
           + bf2f(a.z) * bf2f(c.z) + bf2f(a.w) * bf2f(c.w);
    }
    Sdg[i] = s;
}

// ---------- MFMA flash attention, KVBLK=64, P aliases Ks (high occupancy) ----------
template <int HA>
__global__ __launch_bounds__(256) void attn6(
    const ushortT* __restrict__ Qm, const ushortT* __restrict__ Km,
    const ushortT* __restrict__ Vtm, const ushortT* __restrict__ QAm,
    const ushortT* __restrict__ QBm, const float* __restrict__ Sdg,
    ushortT* __restrict__ Out)
{
    __shared__ __align__(16) ushortT Qs[64 * 64];            // 8 KB
    __shared__ __align__(16) ushortT Ks[64 * 64];            // 8 KB, reused as P
    __shared__ __align__(16) ushortT Vs[64 * 64];            // 8 KB
    __shared__ __align__(16) ushortT Qxs[HA ? 64 * 64 : 8];  // 8 KB (HA)
    __shared__ float sdl[64];

    const int tid = threadIdx.x, wid = tid >> 6, lane = tid & 63;
    const int l15 = lane & 15, l4 = lane >> 4;
    const int b = blockIdx.z, h = blockIdx.y, n0 = blockIdx.x * 64;
    const int bh = b * Hh + h;

    // stage Q (+QA) via DMA, pre-swizzled source; Q pre-scaled by NORM upstream
#pragma unroll
    for (int i = 0; i < 2; ++i) {
        int off = wid * 2048 + i * 1024 + lane * 16;
        int row = off >> 7, sg = ((off >> 4) & 7) ^ (row & 7);
        size_t gidx = (((size_t)(b * Nn + n0 + row) * Hh + h) << 6) + sg * 8;
        gload16(Qm + gidx, (char*)Qs + off);
        if (HA) gload16(QAm + gidx, (char*)Qxs + off);
    }
    if (HA && tid < 64) sdl[tid] = Sdg[((size_t)(b * Nn + n0 + tid)) * Hh + h];
    const int td = (n0 < NPICKk) ? ((n0 + NPICKk) >> 6) : ((n0 - NPICKk) >> 6);

    // staging bases
    const ushortT* kSrc[2]; char* kDst[2];
    const ushortT* vSrc[2]; char* vDst[2];
#pragma unroll
    for (int i = 0; i < 2; ++i) {
        int off = wid * 2048 + i * 1024 + lane * 16;
        int row = off >> 7, sg = ((off >> 4) & 7) ^ (row & 7);
        kSrc[i] = Km + (((size_t)(b * Nn + row) * Hh + h) << 6) + sg * 8;
        kDst[i] = (char*)Ks + off;
        vSrc[i] = Vtm + (((size_t)(bh * 64 + row)) << 9) + sg * 8;
        vDst[i] = (char*)Vs + off;
    }

    float M[4], L[4];
    f32x4 Oa[4] = {};
#pragma unroll
    for (int r = 0; r < 4; ++r) { M[r] = -INFINITY; L[r] = 0.f; }

    for (int t = 0; t < 8; ++t) {
        __syncthreads();   // prior-iter PV reads of Ks(P)/Vs complete
#pragma unroll
        for (int i = 0; i < 2; ++i) {
            gload16(kSrc[i] + (size_t)t * (64 * Hh * VDd), kDst[i]);
            gload16(vSrc[i] + t * 64, vDst[i]);
        }
        if (HA && t == 4) {
#pragma unroll
            for (int i = 0; i < 2; ++i) {
                int off = wid * 2048 + i * 1024 + lane * 16;
                int row = off >> 7, sg = ((off >> 4) & 7) ^ (row & 7);
                gload16(QBm + (((size_t)(b * Nn + n0 + row) * Hh + h) << 6) + sg * 8,
                        (char*)Qxs + off);
            }
        }
        asm volatile("s_waitcnt vmcnt(0)" ::: "memory");
        __syncthreads();   // staged data visible

        // ---- S = Q K^T via MFMA ----
        __builtin_amdgcn_s_setprio(1);
        f32x4 s1[4] = {}, sX[4] = {};
#pragma unroll
        for (int kk = 0; kk < 2; ++kk) {
            int g0 = kk * 4 + l4;
            bf16x8 aq = *(const bf16x8*)&Qs[LIX(wid * 16 + l15, g0)];
            bf16x8 ax;
            if (HA) ax = *(const bf16x8*)&Qxs[LIX(wid * 16 + l15, g0)];
#pragma unroll
            for (int ni = 0; ni < 4; ++ni) {
                bf16x8 bk = *(const bf16x8*)&Ks[LIX(ni * 16 + l15, g0)];
                s1[ni] = __builtin_amdgcn_mfma_f32_16x16x32_bf16(aq, bk, s1[ni], 0, 0, 0);
                if (HA)
                    sX[ni] = __builtin_amdgcn_mfma_f32_16x16x32_bf16(ax, bk, sX[ni], 0, 0, 0);
            }
        }
        __builtin_amdgcn_s_setprio(0);

        const bool dt = HA && (t == td);

        // ---- online softmax (rows spread over 16 lanes) ----
#pragma unroll
        for (int r = 0; r < 4; ++r) {
            int rw = wid * 16 + l4 * 4 + r;
            float m = s1[0][r];
#pragma unroll
            for (int ni = 1; ni < 4; ++ni) m = fmaxf(m, s1[ni][r]);
            if (HA) {
#pragma unroll
                for (int ni = 0; ni < 4; ++ni) m = fmaxf(m, sX[ni][r]);
            }
            if (dt) m = fmaxf(m, sdl[rw]);
#pragma unroll
            for (int o = 8; o >= 1; o >>= 1) m = fmaxf(m, __shfl_xor(m, o, 16));
            float mn = fmaxf(M[r], m);
            float sc = __expf(M[r] - mn);
            M[r] = mn; L[r] *= sc;
#pragma unroll
            for (int ni = 0; ni < 4; ++ni) Oa[ni][r] *= sc;
            float rs = 0.f;
#pragma unroll
            for (int ni = 0; ni < 4; ++ni) {
                float p = __expf(s1[ni][r] - mn);
                if (HA) p += __expf(sX[ni][r] - mn);
                if (dt && ni == wid && l15 == l4 * 4 + r) p += __expf(sdl[rw] - mn);
                s1[ni][r] = p;
                rs += p;
            }
#pragma unroll
            for (int o = 8; o >= 1; o >>= 1) rs += __shfl_xor(rs, o, 16);
            L[r] += rs;
        }
        __syncthreads();   // all waves done reading Ks before P overwrite

        // ---- write P into Ks (bf16, swizzled) ----
#pragma unroll
        for (int ni = 0; ni < 4; ++ni)
#pragma unroll
            for (int r = 0; r < 4; ++r) {
                int prow = wid * 16 + l4 * 4 + r;
                int col = ni * 16 + l15;
                Ks[(prow << 6) + ((((col >> 3) ^ (prow & 7))) << 3) + (col & 7)] =
                    f2bf(s1[ni][r]);
            }
        __syncthreads();   // P visible

        // ---- O += P @ V ----
        __builtin_amdgcn_s_setprio(1);
#pragma unroll
        for (int kk = 0; kk < 2; ++kk) {
            int g0 = kk * 4 + l4;
            bf16x8 ap = *(const bf16x8*)&Ks[LIX(wid * 16 + l15, g0)];
#pragma unroll
            for (int ni = 0; ni < 4; ++ni) {
                bf16x8 bv = *(const bf16x8*)&Vs[LIX(ni * 16 + l15, g0)];
                Oa[ni] = __builtin_amdgcn_mfma_f32_16x16x32_bf16(ap, bv, Oa[ni], 0, 0, 0);
            }
        }
        __builtin_amdgcn_s_setprio(0);
    }

#pragma unroll
    for (int r = 0; r < 4; ++r) {
        float inv = 1.0f / L[r];
        size_t obase = (((size_t)(b * Nn + n0 + wid * 16 + l4 * 4 + r) * Hh + h) << 6);
#pragma unroll
        for (int ni = 0; ni < 4; ++ni)
            Out[obase + ni * 16 + l15] = f2bf(Oa[ni][r] * inv);
    }
}

extern "C" void kernel_launch(void* const* d_in, const int* in_sizes, int n_in,
                              void* d_out, int out_size, void* d_ws, size_t ws_size,
                              hipStream_t stream)
{
    const float* x = (const float*)d_in[0];

    int dictOrder = (in_sizes[18] != 512);
    const float* comb_w  = (const float*)d_in[17];
    const float* comb2_w = (const float*)d_in[dictOrder ? 18 : 19];
    const float* comb3_w = (const float*)d_in[dictOrder ? 19 : 21];
    const float* comb_b  = (const float*)d_in[dictOrder ? 20 : 18];
    const float* comb2_b = (const float*)d_in[dictOrder ? 21 : 20];
    const float* comb3_b = (const float*)d_in[22];
    const float* alpha1 = (const float*)d_in[23];
    const float* alpha2 = (const float*)d_in[24];
    const float* alpha3 = (const float*)d_in[25];
    const float* ff1_w1 = (const float*)d_in[26];
    const float* ff1_b1 = (const float*)d_in[27];
    const float* ff1_w2 = (const float*)d_in[28];
    const float* ff1_b2 = (const float*)d_in[29];
    const float* ffa1   = (const float*)d_in[30];
    const float* ff2_w1 = (const float*)d_in[31];
    const float* ff2_b1 = (const float*)d_in[32];
    const float* ff2_w2 = (const float*)d_in[33];
    const float* ff2_b2 = (const float*)d_in[34];
    const float* ffa2   = (const float*)d_in[35];
    const float* ff3_w1 = (const float*)d_in[36];
    const float* ff3_b1 = (const float*)d_in[37];
    const float* ff3_w2 = (const float*)d_in[38];
    const float* ff3_b2 = (const float*)d_in[39];
    const float* ffa3   = (const float*)d_in[40];

    // ---- workspace layout (bytes) ----
    char* W = (char*)d_ws;
    ushortT* wbHead = (ushortT*)(W + 0);           // 9 x 512x512 bf16
    ushortT* wbMha  = (ushortT*)(W + 4718592);     // 7 x
    ushortT* wbComb = (ushortT*)(W + 8388608);     // 3 x
    ushortT* wbFf1  = (ushortT*)(W + 9961472);     // 3 x 2048x512
    ushortT* wbFf2  = (ushortT*)(W + 16252928);    // 3 x 512x2048
    ushortT* xbf    = (ushortT*)(W + 22544384);    // 8192x512 bf16; later bufHA
    float*   Sd     = (float*)  (W + 30932992);    // 65536 f32
    ushortT* bufQ   = (ushortT*)(W + 31195136);    // 8192x512 bf16 each
    ushortT* bufK   = (ushortT*)(W + 39583744);
    ushortT* bufVt  = (ushortT*)(W + 47972352);
    ushortT* bufQA  = (ushortT*)(W + 56360960);
    ushortT* bufQB  = (ushortT*)(W + 64749568);
    ushortT* bufQD  = (ushortT*)(W + 73138176);
    ushortT* hidden = (ushortT*)(W + 81526784);    // 8192x2048 bf16
    ushortT* curb   = (ushortT*)(W + 115081216);   // bf16 shadow of residual
    ushortT* bufHA  = xbf;
    float*   cur    = (float*)d_out;

    dim3 tb(256);
    const int TOK = Bb * Nn;  // 8192
    const size_t WS = 512 * 512;
    const size_t WF = 2048 * 512;

    // 1. casts / transposes (batched)
    hipLaunchKernelGGL(castx, dim3(TOK * 512 / 1024), tb, 0, stream, x, xbf);
    {
        Ptrs9 s; for (int i = 0; i < 9; ++i) s.p[i] = (const float*)d_in[1 + i];
        hipLaunchKernelGGL(thead, dim3(1, 8, 72), tb, 0, stream, s, wbHead);
    }
    {
        Ptrs10 s;
        for (int i = 0; i < 7; ++i) s.p[i] = (const float*)d_in[10 + i];
        s.p[7] = comb_w; s.p[8] = comb2_w; s.p[9] = comb3_w;
        hipLaunchKernelGGL(tsq, dim3(8, 8, 10), tb, 0, stream, s, wbMha);
    }
    {
        Ptrs6 s;
        s.p[0] = ff1_w1; s.p[1] = ff2_w1; s.p[2] = ff3_w1;
        s.p[3] = ff1_w2; s.p[4] = ff2_w2; s.p[5] = ff3_w2;
        hipLaunchKernelGGL(tff, dim3(32, 32, 6), tb, 0, stream, s, wbFf1);
    }

    auto gemm = [&](PtrsB Bp, PtrsD Db, const ushortT* A, float* oF,
                    int M, int Ncc, int Kc, const float* bias, const float* res,
                    const float* alp, int relu, int nroute, int vtmask, int scmask) {
        hipLaunchKernelGGL(gemm_bf, dim3(Ncc / 128, M / 128), tb, 0, stream,
                           Bp, Db, A, oF, M, Ncc, Kc, bias, res, alp, relu, nroute,
                           vtmask, scmask);
    };
    auto g64 = [&](const ushortT* Bw, const ushortT* A, float* oF, ushortT* oB,
                   int M, int Ncc, int Kc, const float* bias, const float* res,
                   const float* alp, int relu) {
        hipLaunchKernelGGL(gemm64, dim3(Ncc / 128, M / 64), tb, 0, stream,
                           Bw, A, oF, oB, M, Ncc, Kc, bias, res, alp, relu);
    };
    auto uni = [&](const ushortT* w) { PtrsB b; for (int i = 0; i < 12; ++i) b.p[i] = w; return b; };
    auto d1 = [&](ushortT* d) { PtrsD dd = {}; dd.p[0] = d; return dd; };

    // 2. HA projections: ONE fused GEMM, N=3072; Q/QA/QB/QD pre-scaled (scmask=57)
    {
        PtrsB b;
        b.p[0] = b.p[1] = wbHead + 0 * WS;           // Q
        b.p[2] = b.p[3] = wbHead + 1 * WS;           // K
        b.p[4] = b.p[5] = wbHead + 2 * WS;           // V (vt)
        b.p[6] = wbHead + 4 * WS; b.p[7] = wbHead + 8 * WS;   // QA: W2 / W6
        b.p[8] = wbHead + 5 * WS; b.p[9] = wbHead + 7 * WS;   // QB: W3 / W5
        b.p[10] = wbHead + 3 * WS; b.p[11] = wbHead + 6 * WS; // QD: W1 / W4
        PtrsD d; d.p[0] = bufQ; d.p[1] = bufK; d.p[2] = bufVt;
        d.p[3] = bufQA; d.p[4] = bufQB; d.p[5] = bufQD;
        gemm(b, d, xbf, nullptr, TOK, 3072, 512, nullptr, nullptr, nullptr, 0, 6, 4, 57);
    }

    // 3. HA attention
    hipLaunchKernelGGL(diag_dot_bb, dim3(Bb * Nn * Hh / 256), tb, 0, stream, bufQD, bufK, Sd);
    hipLaunchKernelGGL((attn6<1>), dim3(Nn / 64, Hh, Bb), tb, 0, stream,
                       bufQ, bufK, bufVt, bufQA, bufQB, Sd, bufHA);

    // 4. comb3 + FF3
    g64(wbComb + 2 * WS, bufHA, cur, curb, TOK, 512, 512, comb3_b, x, alpha3, 0);
    gemm(uni(wbFf1 + 2 * WF), d1(hidden), curb, nullptr, TOK, 2048, 512, ff3_b1, nullptr, nullptr, 1, 0, 0, 0);
    g64(wbFf2 + 2 * WF, hidden, cur, curb, TOK, 512, 2048, ff3_b2, cur, ffa3, 0);

    // 5. MHA1: fused QKV projection (Q pre-scaled), N=1536
    {
        PtrsB b;
        b.p[0] = b.p[1] = wbMha + 0 * WS;
        b.p[2] = b.p[3] = wbMha + 1 * WS;
        b.p[4] = b.p[5] = wbMha + 2 * WS;
        PtrsD d = {}; d.p[0] = bufQ; d.p[1] = bufK; d.p[2] = bufVt;
        gemm(b, d, curb, nullptr, TOK, 1536, 512, nullptr, nullptr, nullptr, 0, 3, 4, 1);
    }
    hipLaunchKernelGGL((attn6<0>), dim3(Nn / 64, Hh, Bb), tb, 0, stream,
                       bufQ, bufK, bufVt, nullptr, nullptr, nullptr, bufHA);
    g64(wbComb + 0 * WS, bufHA, cur, curb, TOK, 512, 512, comb_b, cur, alpha1, 0);
    gemm(uni(wbFf1 + 0 * WF), d1(hidden), curb, nullptr, TOK, 2048, 512, ff1_b1, nullptr, nullptr, 1, 0, 0, 0);
    g64(wbFf2 + 0 * WF, hidden, cur, curb, TOK, 512, 2048, ff1_b2, cur, ffa1, 0);

    // 6. MHA2: fused projection with split Q (Wq2p/Wq2d), N=1536
    {
        PtrsB b;
        b.p[0] = wbMha + 3 * WS; b.p[1] = wbMha + 4 * WS;
        b.p[2] = b.p[3] = wbMha + 5 * WS;
        b.p[4] = b.p[5] = wbMha + 6 * WS;
        PtrsD d = {}; d.p[0] = bufQ; d.p[1] = bufK; d.p[2] = bufVt;
        gemm(b, d, curb, nullptr, TOK, 1536, 512, nullptr, nullptr, nullptr, 0, 3, 4, 1);
    }
    hipLaunchKernelGGL((attn6<0>), dim3(Nn / 64, Hh, Bb), tb, 0, stream,
                       bufQ, bufK, bufVt, nullptr, nullptr, nullptr, bufHA);
    g64(wbComb + 1 * WS, bufHA, cur, curb, TOK, 512, 512, comb2_b, cur, alpha2, 0);
    gemm(uni(wbFf1 + 1 * WF), d1(hidden), curb, nullptr, TOK, 2048, 512, ff2_b1, nullptr, nullptr, 1, 0, 0, 0);
    g64(wbFf2 + 1 * WF, hidden, cur, nullptr, TOK, 512, 2048, ff2_b2, cur, ffa2, 0);
}

// Round 10
// 514.363 us; speedup vs baseline: 9.7920x; 1.0282x over previous
//
#include <hip/hip_runtime.h>
#include <math.h>

#define Hh 8
#define Bb 16
#define Nn 512
#define Dd 512
#define VDd 64
#define NPICKk 256
#define NORMF 0.125f

typedef unsigned short ushortT;
typedef __bf16 bf16x8 __attribute__((ext_vector_type(8)));
typedef float f32x4 __attribute__((ext_vector_type(4)));

struct PtrsB { const ushortT* p[12]; };
struct PtrsD { ushortT* p[6]; };
struct Ptrs9 { const float* p[9]; };
struct Ptrs10 { const float* p[10]; };
struct Ptrs6 { const float* p[6]; };

__device__ inline ushortT f2bf(float f) {
    union { float f; unsigned int u; } v; v.f = f;
    unsigned int r = v.u + 0x7FFFu + ((v.u >> 16) & 1u);
    return (ushortT)(r >> 16);
}
__device__ inline float bf2f(ushortT u) {
    union { unsigned int u; float f; } v; v.u = ((unsigned int)u) << 16;
    return v.f;
}
__device__ inline void gload16(const void* gptr, void* ldsptr) {
    auto g = reinterpret_cast<const __attribute__((address_space(1))) unsigned int*>(
        reinterpret_cast<uintptr_t>(gptr));
    auto l = reinterpret_cast<__attribute__((address_space(3))) unsigned int*>(
        reinterpret_cast<uintptr_t>(ldsptr));
    __builtin_amdgcn_global_load_lds(g, l, 16, 0, 0);
}

#define LIX(r, g) (((r) << 6) + ((((g) ^ ((r) & 7))) << 3))

// ---------- fp32 -> bf16 elementwise ----------
__global__ __launch_bounds__(256) void castx(const float* __restrict__ in,
                                             ushortT* __restrict__ out) {
    int i = blockIdx.x * 256 + threadIdx.x;
    float4 v = *(const float4*)&in[(size_t)i * 4];
    ushort4 o; o.x = f2bf(v.x); o.y = f2bf(v.y); o.z = f2bf(v.z); o.w = f2bf(v.w);
    *(ushort4*)&out[(size_t)i * 4] = o;
}

// ---------- transpose+cast body ----------
__device__ inline void tbody(const float* __restrict__ in, ushortT* __restrict__ out,
                             int in_ld, int out_ld, int r0, int c0) {
    __shared__ float T[64][65];
    int tr = threadIdx.x >> 4, tc4 = (threadIdx.x & 15) * 4;
#pragma unroll
    for (int p = 0; p < 4; ++p) {
        float4 v = *(const float4*)&in[(size_t)(r0 + tr + p * 16) * in_ld + c0 + tc4];
        T[tr + p * 16][tc4 + 0] = v.x; T[tr + p * 16][tc4 + 1] = v.y;
        T[tr + p * 16][tc4 + 2] = v.z; T[tr + p * 16][tc4 + 3] = v.w;
    }
    __syncthreads();
#pragma unroll
    for (int p = 0; p < 4; ++p) {
        int orow = c0 + tr + p * 16;
        int ocol = r0 + tc4;
        ushort4 o;
        o.x = f2bf(T[tc4 + 0][tr + p * 16]);
        o.y = f2bf(T[tc4 + 1][tr + p * 16]);
        o.z = f2bf(T[tc4 + 2][tr + p * 16]);
        o.w = f2bf(T[tc4 + 3][tr + p * 16]);
        *(ushort4*)&out[(size_t)orow * out_ld + ocol] = o;
    }
}

__global__ __launch_bounds__(256) void thead(Ptrs9 s, ushortT* __restrict__ dst) {
    int w = blockIdx.z >> 3, h = blockIdx.z & 7;
    tbody(s.p[w] + (size_t)h * 512 * 64,
          dst + (size_t)w * 262144 + (size_t)h * 64 * 512,
          64, 512, blockIdx.y * 64, 0);
}
__global__ __launch_bounds__(256) void tsq(Ptrs10 s, ushortT* __restrict__ dst) {
    tbody(s.p[blockIdx.z], dst + (size_t)blockIdx.z * 262144,
          512, 512, blockIdx.y * 64, blockIdx.x * 64);
}
__global__ __launch_bounds__(256) void tff(Ptrs6 s, ushortT* __restrict__ dst) {
    int z = blockIdx.z;
    if (z < 3) { if (blockIdx.y >= 8 || blockIdx.x >= 32) return; }
    else       { if (blockIdx.y >= 32 || blockIdx.x >= 8) return; }
    int in_ld = (z < 3) ? 2048 : 512;
    int out_ld = (z < 3) ? 512 : 2048;
    tbody(s.p[z], dst + (size_t)z * 1048576, in_ld, out_ld,
          blockIdx.y * 64, blockIdx.x * 64);
}

// ---------- 128x128 bf16 MFMA GEMM (routed / standard epilogues) ----------
__global__ __launch_bounds__(256) void gemm_bf(
    PtrsB Bp, PtrsD Db, const ushortT* __restrict__ A, float* __restrict__ outF,
    int M, int N, int K, const float* __restrict__ bias,
    const float* __restrict__ res, const float* __restrict__ alpha,
    int do_relu, int nroute, int vtmask, int scmask)
{
    __shared__ __align__(16) ushortT As[128 * 64];
    __shared__ __align__(16) ushortT Bs[128 * 64];
    const int tid = threadIdx.x;
    const int wid = tid >> 6, lane = tid & 63;
    const int wm = wid >> 1, wn = wid & 1;
    const int l15 = lane & 15, l4 = lane >> 4;

    int bid = blockIdx.y * gridDim.x + blockIdx.x;
    int nwg = gridDim.x * gridDim.y;
    int q = nwg >> 3;
    int swz = (bid & 7) * q + (bid >> 3);
    int bx = swz % gridDim.x, by = swz / gridDim.x;

    const int r0 = by * 128, c0 = bx * 128;
    const int half = ((r0 & (Nn - 1)) >= NPICKk) ? 1 : 0;
    const ushortT* Bt = Bp.p[((c0 >> 9) << 1) | half];
    const int cB = nroute ? (c0 & 511) : c0;

    const ushortT* aSrc[4];
    const ushortT* bSrc[4];
    char* ldsA[4];
    char* ldsB[4];
#pragma unroll
    for (int i = 0; i < 4; ++i) {
        int off = wid * 4096 + i * 1024 + lane * 16;
        int row = off >> 7;
        int sg = ((off >> 4) & 7) ^ (row & 7);
        aSrc[i] = A + (size_t)(r0 + row) * K + sg * 8;
        bSrc[i] = Bt + (size_t)(cB + row) * K + sg * 8;
        ldsA[i] = (char*)As + off;
        ldsB[i] = (char*)Bs + off;
    }

    f32x4 acc[4][4] = {};

    for (int kt = 0; kt < K; kt += 64) {
        __syncthreads();
#pragma unroll
        for (int i = 0; i < 4; ++i) {
            gload16(aSrc[i] + kt, ldsA[i]);
            gload16(bSrc[i] + kt, ldsB[i]);
        }
        asm volatile("s_waitcnt vmcnt(0)" ::: "memory");
        __syncthreads();
#pragma unroll
        for (int kk = 0; kk < 2; ++kk) {
            int g0 = kk * 4 + l4;
            bf16x8 af[4], bfv[4];
#pragma unroll
            for (int mi = 0; mi < 4; ++mi)
                af[mi] = *(const bf16x8*)&As[LIX(wm * 64 + mi * 16 + l15, g0)];
#pragma unroll
            for (int ni = 0; ni < 4; ++ni)
                bfv[ni] = *(const bf16x8*)&Bs[LIX(wn * 64 + ni * 16 + l15, g0)];
#pragma unroll
            for (int mi = 0; mi < 4; ++mi)
#pragma unroll
                for (int ni = 0; ni < 4; ++ni)
                    acc[mi][ni] = __builtin_amdgcn_mfma_f32_16x16x32_bf16(
                        bfv[ni], af[mi], acc[mi][ni], 0, 0, 0);   // C^T fragment
        }
    }

    if (nroute) {
#pragma unroll
        for (int mi = 0; mi < 4; ++mi) {
            int row = r0 + wm * 64 + mi * 16 + l15;
#pragma unroll
            for (int ni = 0; ni < 4; ++ni) {
                int col = c0 + wn * 64 + ni * 16 + l4 * 4;
                int range = col >> 9, cc = col & 511;
                ushortT* d = Db.p[range];
                f32x4 a = acc[mi][ni];
                if ((scmask >> range) & 1) {
                    a[0] *= NORMF; a[1] *= NORMF; a[2] *= NORMF; a[3] *= NORMF;
                }
                if ((vtmask >> range) & 1) {
                    size_t vb = ((size_t)(row >> 9) * Hh + (cc >> 6)) * 64 + (cc & 63);
                    int tok = row & 511;
#pragma unroll
                    for (int r = 0; r < 4; ++r)
                        d[((vb + r) << 9) + tok] = f2bf(a[r]);
                } else {
                    ushort4 o;
                    o.x = f2bf(a[0]); o.y = f2bf(a[1]);
                    o.z = f2bf(a[2]); o.w = f2bf(a[3]);
                    *(ushort4*)&d[((size_t)row << 9) + cc] = o;
                }
            }
        }
    } else {
        const float alp = alpha ? alpha[0] : 1.0f;
        ushortT* outB = Db.p[0];
#pragma unroll
        for (int mi = 0; mi < 4; ++mi) {
            int row = r0 + wm * 64 + mi * 16 + l15;
#pragma unroll
            for (int ni = 0; ni < 4; ++ni) {
                int colb = c0 + wn * 64 + ni * 16 + l4 * 4;
                f32x4 a = acc[mi][ni];
                if (bias) {
                    float4 b4 = *(const float4*)&bias[colb];
                    a[0] += b4.x; a[1] += b4.y; a[2] += b4.z; a[3] += b4.w;
                }
                if (do_relu) {
#pragma unroll
                    for (int r = 0; r < 4; ++r) a[r] = fmaxf(a[r], 0.f);
                }
#pragma unroll
                for (int r = 0; r < 4; ++r) a[r] *= alp;
                size_t idx = (size_t)row * N + colb;
                if (res) {
                    float4 r4 = *(const float4*)&res[idx];
                    a[0] += r4.x; a[1] += r4.y; a[2] += r4.z; a[3] += r4.w;
                }
                if (outF)
                    *(float4*)&outF[idx] = make_float4(a[0], a[1], a[2], a[3]);
                if (outB) {
                    ushort4 o;
                    o.x = f2bf(a[0]); o.y = f2bf(a[1]);
                    o.z = f2bf(a[2]); o.w = f2bf(a[3]);
                    *(ushort4*)&outB[idx] = o;
                }
            }
        }
    }
}

// ---------- 64x128 bf16 MFMA GEMM; residual can be f32 (resf) or bf16 (resb) ----------
__global__ __launch_bounds__(256) void gemm64(
    const ushortT* __restrict__ Bw, const ushortT* __restrict__ A,
    float* __restrict__ outF, ushortT* __restrict__ outB,
    int M, int N, int K, const float* __restrict__ bias,
    const float* __restrict__ resf, const ushortT* __restrict__ resb,
    const float* __restrict__ alpha, int do_relu)
{
    __shared__ __align__(16) ushortT As[64 * 64];    // 8 KB
    __shared__ __align__(16) ushortT Bs[128 * 64];   // 16 KB
    const int tid = threadIdx.x;
    const int wid = tid >> 6, lane = tid & 63;
    const int wm = wid >> 1, wn = wid & 1;
    const int l15 = lane & 15, l4 = lane >> 4;

    int bid = blockIdx.y * gridDim.x + blockIdx.x;
    int nwg = gridDim.x * gridDim.y;
    int q = nwg >> 3;
    int swz = (bid & 7) * q + (bid >> 3);
    int bx = swz % gridDim.x, by = swz / gridDim.x;
    const int r0 = by * 64, c0 = bx * 128;

    const ushortT* aSrc[2];
    char* ldsA[2];
#pragma unroll
    for (int i = 0; i < 2; ++i) {
        int off = wid * 2048 + i * 1024 + lane * 16;
        int row = off >> 7;
        int sg = ((off >> 4) & 7) ^ (row & 7);
        aSrc[i] = A + (size_t)(r0 + row) * K + sg * 8;
        ldsA[i] = (char*)As + off;
    }
    const ushortT* bSrc[4];
    char* ldsB[4];
#pragma unroll
    for (int i = 0; i < 4; ++i) {
        int off = wid * 4096 + i * 1024 + lane * 16;
        int row = off >> 7;
        int sg = ((off >> 4) & 7) ^ (row & 7);
        bSrc[i] = Bw + (size_t)(c0 + row) * K + sg * 8;
        ldsB[i] = (char*)Bs + off;
    }

    f32x4 acc[2][4] = {};

    for (int kt = 0; kt < K; kt += 64) {
        __syncthreads();
#pragma unroll
        for (int i = 0; i < 2; ++i) gload16(aSrc[i] + kt, ldsA[i]);
#pragma unroll
        for (int i = 0; i < 4; ++i) gload16(bSrc[i] + kt, ldsB[i]);
        asm volatile("s_waitcnt vmcnt(0)" ::: "memory");
        __syncthreads();
#pragma unroll
        for (int kk = 0; kk < 2; ++kk) {
            int g0 = kk * 4 + l4;
            bf16x8 af[2], bfv[4];
#pragma unroll
            for (int mi = 0; mi < 2; ++mi)
                af[mi] = *(const bf16x8*)&As[LIX(wm * 32 + mi * 16 + l15, g0)];
#pragma unroll
            for (int ni = 0; ni < 4; ++ni)
                bfv[ni] = *(const bf16x8*)&Bs[LIX(wn * 64 + ni * 16 + l15, g0)];
#pragma unroll
            for (int mi = 0; mi < 2; ++mi)
#pragma unroll
                for (int ni = 0; ni < 4; ++ni)
                    acc[mi][ni] = __builtin_amdgcn_mfma_f32_16x16x32_bf16(
                        bfv[ni], af[mi], acc[mi][ni], 0, 0, 0);
        }
    }

    const float alp = alpha ? alpha[0] : 1.0f;
#pragma unroll
    for (int mi = 0; mi < 2; ++mi) {
        int row = r0 + wm * 32 + mi * 16 + l15;
#pragma unroll
        for (int ni = 0; ni < 4; ++ni) {
            int colb = c0 + wn * 64 + ni * 16 + l4 * 4;
            f32x4 a = acc[mi][ni];
            if (bias) {
                float4 b4 = *(const float4*)&bias[colb];
                a[0] += b4.x; a[1] += b4.y; a[2] += b4.z; a[3] += b4.w;
            }
            if (do_relu) {
#pragma unroll
                for (int r = 0; r < 4; ++r) a[r] = fmaxf(a[r], 0.f);
            }
#pragma unroll
            for (int r = 0; r < 4; ++r) a[r] *= alp;
            size_t idx = (size_t)row * N + colb;
            if (resf) {
                float4 r4 = *(const float4*)&resf[idx];
                a[0] += r4.x; a[1] += r4.y; a[2] += r4.z; a[3] += r4.w;
            }
            if (resb) {
                ushort4 r4 = *(const ushort4*)&resb[idx];
                a[0] += bf2f(r4.x); a[1] += bf2f(r4.y);
                a[2] += bf2f(r4.z); a[3] += bf2f(r4.w);
            }
            if (outF)
                *(float4*)&outF[idx] = make_float4(a[0], a[1], a[2], a[3]);
            if (outB) {
                ushort4 o;
                o.x = f2bf(a[0]); o.y = f2bf(a[1]);
                o.z = f2bf(a[2]); o.w = f2bf(a[3]);
                *(ushort4*)&outB[idx] = o;
            }
        }
    }
}

// ---------- HA diagonal scores (QD pre-scaled by NORM) ----------
__global__ __launch_bounds__(256) void diag_dot_bb(const ushortT* __restrict__ QD,
                                                   const ushortT* __restrict__ K,
                                                   float* __restrict__ Sdg) {
    int i = blockIdx.x * 256 + threadIdx.x;
    int h = i & 7, n = (i >> 3) & 511, b = i >> 12;
    int dix = (n < NPICKk) ? n + NPICKk : n - NPICKk;
    const ushortT* q = QD + (((size_t)(b * Nn + n) * Hh + h) << 6);
    const ushortT* k = K + (((size_t)(b * Nn + dix) * Hh + h) << 6);
    float s = 0.f;
#pragma unroll
    for (int d = 0; d < 64; d += 4) {
        ushort4 a = *(const ushort4*)(q + d);
        ushort4 c = *(const ushort4*)(k + d);
        s += bf2f(a.x) * bf2f(c.x) + bf2f(a.y) * bf2f(c.y)
           + bf2f(a.z) * bf2f(c.z) + bf2f(a.w) * bf2f(c.w);
    }
    Sdg[i] = s;
}

// ---------- MFMA flash attention: per-wave P buffer, 2 barriers/tile ----------
template <int HA>
__global__ __launch_bounds__(256) void attn7(
    const ushortT* __restrict__ Qm, const ushortT* __restrict__ Km,
    const ushortT* __restrict__ Vtm, const ushortT* __restrict__ QAm,
    const ushortT* __restrict__ QBm, const float* __restrict__ Sdg,
    ushortT* __restrict__ Out)
{
    __shared__ __align__(16) ushortT Qs[64 * 64];            // 8 KB
    __shared__ __align__(16) ushortT Ks[64 * 64];            // 8 KB
    __shared__ __align__(16) ushortT Vs[64 * 64];            // 8 KB
    __shared__ __align__(16) ushortT Pw[4][16 * 64];         // 8 KB, wave-private strips
    __shared__ __align__(16) ushortT Qxs[HA ? 64 * 64 : 8];  // 8 KB (HA)
    __shared__ float sdl[64];

    const int tid = threadIdx.x, wid = tid >> 6, lane = tid & 63;
    const int l15 = lane & 15, l4 = lane >> 4;
    const int b = blockIdx.z, h = blockIdx.y, n0 = blockIdx.x * 64;
    const int bh = b * Hh + h;

    // stage Q (+QA), pre-swizzled global source; Q pre-scaled by NORM upstream
#pragma unroll
    for (int i = 0; i < 2; ++i) {
        int off = wid * 2048 + i * 1024 + lane * 16;
        int row = off >> 7, sg = ((off >> 4) & 7) ^ (row & 7);
        size_t gidx = (((size_t)(b * Nn + n0 + row) * Hh + h) << 6) + sg * 8;
        gload16(Qm + gidx, (char*)Qs + off);
        if (HA) gload16(QAm + gidx, (char*)Qxs + off);
    }
    if (HA && tid < 64) sdl[tid] = Sdg[((size_t)(b * Nn + n0 + tid)) * Hh + h];
    const int td = (n0 < NPICKk) ? ((n0 + NPICKk) >> 6) : ((n0 - NPICKk) >> 6);

    const ushortT* kSrc[2]; char* kDst[2];
    const ushortT* vSrc[2]; char* vDst[2];
#pragma unroll
    for (int i = 0; i < 2; ++i) {
        int off = wid * 2048 + i * 1024 + lane * 16;
        int row = off >> 7, sg = ((off >> 4) & 7) ^ (row & 7);
        kSrc[i] = Km + (((size_t)(b * Nn + row) * Hh + h) << 6) + sg * 8;
        kDst[i] = (char*)Ks + off;
        vSrc[i] = Vtm + (((size_t)(bh * 64 + row)) << 9) + sg * 8;
        vDst[i] = (char*)Vs + off;
    }

    float M[4], L[4];
    f32x4 Oa[4] = {};
#pragma unroll
    for (int r = 0; r < 4; ++r) { M[r] = -INFINITY; L[r] = 0.f; }

    for (int t = 0; t < 8; ++t) {
        __syncthreads();   // all reads of Ks/Vs (and Qxs at t==4) from prior iter done
#pragma unroll
        for (int i = 0; i < 2; ++i) {
            gload16(kSrc[i] + (size_t)t * (64 * Hh * VDd), kDst[i]);
            gload16(vSrc[i] + t * 64, vDst[i]);
        }
        if (HA && t == 4) {
#pragma unroll
            for (int i = 0; i < 2; ++i) {
                int off = wid * 2048 + i * 1024 + lane * 16;
                int row = off >> 7, sg = ((off >> 4) & 7) ^ (row & 7);
                gload16(QBm + (((size_t)(b * Nn + n0 + row) * Hh + h) << 6) + sg * 8,
                        (char*)Qxs + off);
            }
        }
        asm volatile("s_waitcnt vmcnt(0)" ::: "memory");
        __syncthreads();   // staged data visible

        // ---- S = Q K^T via MFMA ----
        __builtin_amdgcn_s_setprio(1);
        f32x4 s1[4] = {}, sX[4] = {};
#pragma unroll
        for (int kk = 0; kk < 2; ++kk) {
            int g0 = kk * 4 + l4;
            bf16x8 aq = *(const bf16x8*)&Qs[LIX(wid * 16 + l15, g0)];
            bf16x8 ax;
            if (HA) ax = *(const bf16x8*)&Qxs[LIX(wid * 16 + l15, g0)];
#pragma unroll
            for (int ni = 0; ni < 4; ++ni) {
                bf16x8 bk = *(const bf16x8*)&Ks[LIX(ni * 16 + l15, g0)];
                s1[ni] = __builtin_amdgcn_mfma_f32_16x16x32_bf16(aq, bk, s1[ni], 0, 0, 0);
                if (HA)
                    sX[ni] = __builtin_amdgcn_mfma_f32_16x16x32_bf16(ax, bk, sX[ni], 0, 0, 0);
            }
        }
        __builtin_amdgcn_s_setprio(0);

        const bool dt = HA && (t == td);

        // ---- online softmax ----
#pragma unroll
        for (int r = 0; r < 4; ++r) {
            int rw = wid * 16 + l4 * 4 + r;
            float m = s1[0][r];
#pragma unroll
            for (int ni = 1; ni < 4; ++ni) m = fmaxf(m, s1[ni][r]);
            if (HA) {
#pragma unroll
                for (int ni = 0; ni < 4; ++ni) m = fmaxf(m, sX[ni][r]);
            }
            if (dt) m = fmaxf(m, sdl[rw]);
#pragma unroll
            for (int o = 8; o >= 1; o >>= 1) m = fmaxf(m, __shfl_xor(m, o, 16));
            float mn = fmaxf(M[r], m);
            float sc = __expf(M[r] - mn);
            M[r] = mn; L[r] *= sc;
#pragma unroll
            for (int ni = 0; ni < 4; ++ni) Oa[ni][r] *= sc;
            float rs = 0.f;
#pragma unroll
            for (int ni = 0; ni < 4; ++ni) {
                float p = __expf(s1[ni][r] - mn);
                if (HA) p += __expf(sX[ni][r] - mn);
                if (dt && ni == wid && l15 == l4 * 4 + r) p += __expf(sdl[rw] - mn);
                s1[ni][r] = p;
                rs += p;
            }
#pragma unroll
            for (int o = 8; o >= 1; o >>= 1) rs += __shfl_xor(rs, o, 16);
            L[r] += rs;
        }

        // ---- write P into this wave's private strip (NO barrier needed) ----
#pragma unroll
        for (int ni = 0; ni < 4; ++ni)
#pragma unroll
            for (int r = 0; r < 4; ++r) {
                int prow = l4 * 4 + r;           // 0..15 within strip
                int col = ni * 16 + l15;
                Pw[wid][(prow << 6) + ((((col >> 3) ^ (prow & 7))) << 3) + (col & 7)] =
                    f2bf(s1[ni][r]);
            }

        // ---- O += P @ V (P strip is wave-private; lgkmcnt orders write->read) ----
        __builtin_amdgcn_s_setprio(1);
#pragma unroll
        for (int kk = 0; kk < 2; ++kk) {
            int g0 = kk * 4 + l4;
            bf16x8 ap = *(const bf16x8*)&Pw[wid][LIX(l15, g0)];
#pragma unroll
            for (int ni = 0; ni < 4; ++ni) {
                bf16x8 bv = *(const bf16x8*)&Vs[LIX(ni * 16 + l15, g0)];
                Oa[ni] = __builtin_amdgcn_mfma_f32_16x16x32_bf16(ap, bv, Oa[ni], 0, 0, 0);
            }
        }
        __builtin_amdgcn_s_setprio(0);
    }

#pragma unroll
    for (int r = 0; r < 4; ++r) {
        float inv = 1.0f / L[r];
        size_t obase = (((size_t)(b * Nn + n0 + wid * 16 + l4 * 4 + r) * Hh + h) << 6);
#pragma unroll
        for (int ni = 0; ni < 4; ++ni)
            Out[obase + ni * 16 + l15] = f2bf(Oa[ni][r] * inv);
    }
}

extern "C" void kernel_launch(void* const* d_in, const int* in_sizes, int n_in,
                              void* d_out, int out_size, void* d_ws, size_t ws_size,
                              hipStream_t stream)
{
    const float* x = (const float*)d_in[0];

    int dictOrder = (in_sizes[18] != 512);
    const float* comb_w  = (const float*)d_in[17];
    const float* comb2_w = (const float*)d_in[dictOrder ? 18 : 19];
    const float* comb3_w = (const float*)d_in[dictOrder ? 19 : 21];
    const float* comb_b  = (const float*)d_in[dictOrder ? 20 : 18];
    const float* comb2_b = (const float*)d_in[dictOrder ? 21 : 20];
    const float* comb3_b = (const float*)d_in[22];
    const float* alpha1 = (const float*)d_in[23];
    const float* alpha2 = (const float*)d_in[24];
    const float* alpha3 = (const float*)d_in[25];
    const float* ff1_w1 = (const float*)d_in[26];
    const float* ff1_b1 = (const float*)d_in[27];
    const float* ff1_w2 = (const float*)d_in[28];
    const float* ff1_b2 = (const float*)d_in[29];
    const float* ffa1   = (const float*)d_in[30];
    const float* ff2_w1 = (const float*)d_in[31];
    const float* ff2_b1 = (const float*)d_in[32];
    const float* ff2_w2 = (const float*)d_in[33];
    const float* ff2_b2 = (const float*)d_in[34];
    const float* ffa2   = (const float*)d_in[35];
    const float* ff3_w1 = (const float*)d_in[36];
    const float* ff3_b1 = (const float*)d_in[37];
    const float* ff3_w2 = (const float*)d_in[38];
    const float* ff3_b2 = (const float*)d_in[39];
    const float* ffa3   = (const float*)d_in[40];

    // ---- workspace layout (bytes) ----
    char* W = (char*)d_ws;
    ushortT* wbHead = (ushortT*)(W + 0);
    ushortT* wbMha  = (ushortT*)(W + 4718592);
    ushortT* wbComb = (ushortT*)(W + 8388608);
    ushortT* wbFf1  = (ushortT*)(W + 9961472);
    ushortT* wbFf2  = (ushortT*)(W + 16252928);
    ushortT* xbf    = (ushortT*)(W + 22544384);
    float*   Sd     = (float*)  (W + 30932992);
    ushortT* bufQ   = (ushortT*)(W + 31195136);
    ushortT* bufK   = (ushortT*)(W + 39583744);
    ushortT* bufVt  = (ushortT*)(W + 47972352);
    ushortT* bufQA  = (ushortT*)(W + 56360960);
    ushortT* bufQB  = (ushortT*)(W + 64749568);
    ushortT* bufQD  = (ushortT*)(W + 73138176);
    ushortT* hidden = (ushortT*)(W + 81526784);
    ushortT* curb   = (ushortT*)(W + 115081216);
    ushortT* bufHA  = xbf;
    float*   cur    = (float*)d_out;

    dim3 tb(256);
    const int TOK = Bb * Nn;  // 8192
    const size_t WS = 512 * 512;
    const size_t WF = 2048 * 512;

    // 1. casts / transposes (batched)
    hipLaunchKernelGGL(castx, dim3(TOK * 512 / 1024), tb, 0, stream, x, xbf);
    {
        Ptrs9 s; for (int i = 0; i < 9; ++i) s.p[i] = (const float*)d_in[1 + i];
        hipLaunchKernelGGL(thead, dim3(1, 8, 72), tb, 0, stream, s, wbHead);
    }
    {
        Ptrs10 s;
        for (int i = 0; i < 7; ++i) s.p[i] = (const float*)d_in[10 + i];
        s.p[7] = comb_w; s.p[8] = comb2_w; s.p[9] = comb3_w;
        hipLaunchKernelGGL(tsq, dim3(8, 8, 10), tb, 0, stream, s, wbMha);
    }
    {
        Ptrs6 s;
        s.p[0] = ff1_w1; s.p[1] = ff2_w1; s.p[2] = ff3_w1;
        s.p[3] = ff1_w2; s.p[4] = ff2_w2; s.p[5] = ff3_w2;
        hipLaunchKernelGGL(tff, dim3(32, 32, 6), tb, 0, stream, s, wbFf1);
    }

    auto gemm = [&](PtrsB Bp, PtrsD Db, const ushortT* A, float* oF,
                    int M, int Ncc, int Kc, const float* bias, const float* res,
                    const float* alp, int relu, int nroute, int vtmask, int scmask) {
        hipLaunchKernelGGL(gemm_bf, dim3(Ncc / 128, M / 128), tb, 0, stream,
                           Bp, Db, A, oF, M, Ncc, Kc, bias, res, alp, relu, nroute,
                           vtmask, scmask);
    };
    auto g64 = [&](const ushortT* Bw, const ushortT* A, float* oF, ushortT* oB,
                   int M, int Ncc, int Kc, const float* bias, const float* resf,
                   const ushortT* resb, const float* alp, int relu) {
        hipLaunchKernelGGL(gemm64, dim3(Ncc / 128, M / 64), tb, 0, stream,
                           Bw, A, oF, oB, M, Ncc, Kc, bias, resf, resb, alp, relu);
    };
    auto uni = [&](const ushortT* w) { PtrsB b; for (int i = 0; i < 12; ++i) b.p[i] = w; return b; };
    auto d1 = [&](ushortT* d) { PtrsD dd = {}; dd.p[0] = d; return dd; };

    // 2. HA projections: ONE fused GEMM, N=3072 (Q/QA/QB/QD pre-scaled, scmask=57)
    {
        PtrsB b;
        b.p[0] = b.p[1] = wbHead + 0 * WS;
        b.p[2] = b.p[3] = wbHead + 1 * WS;
        b.p[4] = b.p[5] = wbHead + 2 * WS;
        b.p[6] = wbHead + 4 * WS; b.p[7] = wbHead + 8 * WS;
        b.p[8] = wbHead + 5 * WS; b.p[9] = wbHead + 7 * WS;
        b.p[10] = wbHead + 3 * WS; b.p[11] = wbHead + 6 * WS;
        PtrsD d; d.p[0] = bufQ; d.p[1] = bufK; d.p[2] = bufVt;
        d.p[3] = bufQA; d.p[4] = bufQB; d.p[5] = bufQD;
        gemm(b, d, xbf, nullptr, TOK, 3072, 512, nullptr, nullptr, nullptr, 0, 6, 4, 57);
    }

    // 3. HA attention
    hipLaunchKernelGGL(diag_dot_bb, dim3(Bb * Nn * Hh / 256), tb, 0, stream, bufQD, bufK, Sd);
    hipLaunchKernelGGL((attn7<1>), dim3(Nn / 64, Hh, Bb), tb, 0, stream,
                       bufQ, bufK, bufVt, bufQA, bufQB, Sd, bufHA);

    // 4. comb3 + FF3 (bf16 residual stream from here on; no f32 writes)
    g64(wbComb + 2 * WS, bufHA, nullptr, curb, TOK, 512, 512, comb3_b, x, nullptr, alpha3, 0);
    gemm(uni(wbFf1 + 2 * WF), d1(hidden), curb, nullptr, TOK, 2048, 512, ff3_b1, nullptr, nullptr, 1, 0, 0, 0);
    g64(wbFf2 + 2 * WF, hidden, nullptr, curb, TOK, 512, 2048, ff3_b2, nullptr, curb, ffa3, 0);

    // 5. MHA1
    {
        PtrsB b;
        b.p[0] = b.p[1] = wbMha + 0 * WS;
        b.p[2] = b.p[3] = wbMha + 1 * WS;
        b.p[4] = b.p[5] = wbMha + 2 * WS;
        PtrsD d = {}; d.p[0] = bufQ; d.p[1] = bufK; d.p[2] = bufVt;
        gemm(b, d, curb, nullptr, TOK, 1536, 512, nullptr, nullptr, nullptr, 0, 3, 4, 1);
    }
    hipLaunchKernelGGL((attn7<0>), dim3(Nn / 64, Hh, Bb), tb, 0, stream,
                       bufQ, bufK, bufVt, nullptr, nullptr, nullptr, bufHA);
    g64(wbComb + 0 * WS, bufHA, nullptr, curb, TOK, 512, 512, comb_b, nullptr, curb, alpha1, 0);
    gemm(uni(wbFf1 + 0 * WF), d1(hidden), curb, nullptr, TOK, 2048, 512, ff1_b1, nullptr, nullptr, 1, 0, 0, 0);
    g64(wbFf2 + 0 * WF, hidden, nullptr, curb, TOK, 512, 2048, ff1_b2, nullptr, curb, ffa1, 0);

    // 6. MHA2
    {
        PtrsB b;
        b.p[0] = wbMha + 3 * WS; b.p[1] = wbMha + 4 * WS;
        b.p[2] = b.p[3] = wbMha + 5 * WS;
        b.p[4] = b.p[5] = wbMha + 6 * WS;
        PtrsD d = {}; d.p[0] = bufQ; d.p[1] = bufK; d.p[2] = bufVt;
        gemm(b, d, curb, nullptr, TOK, 1536, 512, nullptr, nullptr, nullptr, 0, 3, 4, 1);
    }
    hipLaunchKernelGGL((attn7<0>), dim3(Nn / 64, Hh, Bb), tb, 0, stream,
                       bufQ, bufK, bufVt, nullptr, nullptr, nullptr, bufHA);
    g64(wbComb + 1 * WS, bufHA, nullptr, curb, TOK, 512, 512, comb2_b, nullptr, curb, alpha2, 0);
    gemm(uni(wbFf1 + 1 * WF), d1(hidden), curb, nullptr, TOK, 2048, 512, ff2_b1, nullptr, nullptr, 1, 0, 0, 0);
    // final: write f32 d_out
    g64(wbFf2 + 1 * WF, hidden, cur, nullptr, TOK, 512, 2048, ff2_b2, nullptr, curb, ffa2, 0);
}

// Round 11
// 511.462 us; speedup vs baseline: 9.8476x; 1.0057x over previous
//
#include <hip/hip_runtime.h>
#include <math.h>

#define Hh 8
#define Bb 16
#define Nn 512
#define Dd 512
#define VDd 64
#define NPICKk 256
#define NORMF 0.125f

typedef unsigned short ushortT;
typedef __bf16 bf16x8 __attribute__((ext_vector_type(8)));
typedef float f32x4 __attribute__((ext_vector_type(4)));

struct PtrsB { const ushortT* p[12]; };
struct PtrsD { ushortT* p[6]; };
struct Ptrs9 { const float* p[9]; };
struct Ptrs10 { const float* p[10]; };
struct Ptrs6 { const float* p[6]; };

__device__ inline ushortT f2bf(float f) {
    __bf16 h = (__bf16)f;                    // native v_cvt (RTNE), 1 instr
    union { __bf16 h; ushortT u; } v; v.h = h;
    return v.u;
}
__device__ inline float bf2f(ushortT u) {
    union { unsigned int u; float f; } v; v.u = ((unsigned int)u) << 16;
    return v.f;
}
__device__ inline void gload16(const void* gptr, void* ldsptr) {
    auto g = reinterpret_cast<const __attribute__((address_space(1))) unsigned int*>(
        reinterpret_cast<uintptr_t>(gptr));
    auto l = reinterpret_cast<__attribute__((address_space(3))) unsigned int*>(
        reinterpret_cast<uintptr_t>(ldsptr));
    __builtin_amdgcn_global_load_lds(g, l, 16, 0, 0);
}

#define LIX(r, g) (((r) << 6) + ((((g) ^ ((r) & 7))) << 3))

// ---------- fp32 -> bf16 elementwise ----------
__global__ __launch_bounds__(256) void castx(const float* __restrict__ in,
                                             ushortT* __restrict__ out) {
    int i = blockIdx.x * 256 + threadIdx.x;
    float4 v = *(const float4*)&in[(size_t)i * 4];
    ushort4 o; o.x = f2bf(v.x); o.y = f2bf(v.y); o.z = f2bf(v.z); o.w = f2bf(v.w);
    *(ushort4*)&out[(size_t)i * 4] = o;
}

// ---------- transpose+cast body ----------
__device__ inline void tbody(const float* __restrict__ in, ushortT* __restrict__ out,
                             int in_ld, int out_ld, int r0, int c0) {
    __shared__ float T[64][65];
    int tr = threadIdx.x >> 4, tc4 = (threadIdx.x & 15) * 4;
#pragma unroll
    for (int p = 0; p < 4; ++p) {
        float4 v = *(const float4*)&in[(size_t)(r0 + tr + p * 16) * in_ld + c0 + tc4];
        T[tr + p * 16][tc4 + 0] = v.x; T[tr + p * 16][tc4 + 1] = v.y;
        T[tr + p * 16][tc4 + 2] = v.z; T[tr + p * 16][tc4 + 3] = v.w;
    }
    __syncthreads();
#pragma unroll
    for (int p = 0; p < 4; ++p) {
        int orow = c0 + tr + p * 16;
        int ocol = r0 + tc4;
        ushort4 o;
        o.x = f2bf(T[tc4 + 0][tr + p * 16]);
        o.y = f2bf(T[tc4 + 1][tr + p * 16]);
        o.z = f2bf(T[tc4 + 2][tr + p * 16]);
        o.w = f2bf(T[tc4 + 3][tr + p * 16]);
        *(ushort4*)&out[(size_t)orow * out_ld + ocol] = o;
    }
}

__global__ __launch_bounds__(256) void thead(Ptrs9 s, ushortT* __restrict__ dst) {
    int w = blockIdx.z >> 3, h = blockIdx.z & 7;
    tbody(s.p[w] + (size_t)h * 512 * 64,
          dst + (size_t)w * 262144 + (size_t)h * 64 * 512,
          64, 512, blockIdx.y * 64, 0);
}
__global__ __launch_bounds__(256) void tsq(Ptrs10 s, ushortT* __restrict__ dst) {
    tbody(s.p[blockIdx.z], dst + (size_t)blockIdx.z * 262144,
          512, 512, blockIdx.y * 64, blockIdx.x * 64);
}
__global__ __launch_bounds__(256) void tff(Ptrs6 s, ushortT* __restrict__ dst) {
    int z = blockIdx.z;
    if (z < 3) { if (blockIdx.y >= 8 || blockIdx.x >= 32) return; }
    else       { if (blockIdx.y >= 32 || blockIdx.x >= 8) return; }
    int in_ld = (z < 3) ? 2048 : 512;
    int out_ld = (z < 3) ? 512 : 2048;
    tbody(s.p[z], dst + (size_t)z * 1048576, in_ld, out_ld,
          blockIdx.y * 64, blockIdx.x * 64);
}

// ---------- 128x128 bf16 MFMA GEMM (routed / standard epilogues) ----------
__global__ __launch_bounds__(256) void gemm_bf(
    PtrsB Bp, PtrsD Db, const ushortT* __restrict__ A, float* __restrict__ outF,
    int M, int N, int K, const float* __restrict__ bias,
    const float* __restrict__ res, const float* __restrict__ alpha,
    int do_relu, int nroute, int vtmask, int scmask)
{
    __shared__ __align__(16) ushortT As[128 * 64];
    __shared__ __align__(16) ushortT Bs[128 * 64];
    const int tid = threadIdx.x;
    const int wid = tid >> 6, lane = tid & 63;
    const int wm = wid >> 1, wn = wid & 1;
    const int l15 = lane & 15, l4 = lane >> 4;

    int bid = blockIdx.y * gridDim.x + blockIdx.x;
    int nwg = gridDim.x * gridDim.y;
    int q = nwg >> 3;
    int swz = (bid & 7) * q + (bid >> 3);
    int bx = swz % gridDim.x, by = swz / gridDim.x;

    const int r0 = by * 128, c0 = bx * 128;
    const int half = ((r0 & (Nn - 1)) >= NPICKk) ? 1 : 0;
    const ushortT* Bt = Bp.p[((c0 >> 9) << 1) | half];
    const int cB = nroute ? (c0 & 511) : c0;

    const ushortT* aSrc[4];
    const ushortT* bSrc[4];
    char* ldsA[4];
    char* ldsB[4];
#pragma unroll
    for (int i = 0; i < 4; ++i) {
        int off = wid * 4096 + i * 1024 + lane * 16;
        int row = off >> 7;
        int sg = ((off >> 4) & 7) ^ (row & 7);
        aSrc[i] = A + (size_t)(r0 + row) * K + sg * 8;
        bSrc[i] = Bt + (size_t)(cB + row) * K + sg * 8;
        ldsA[i] = (char*)As + off;
        ldsB[i] = (char*)Bs + off;
    }

    f32x4 acc[4][4] = {};

    for (int kt = 0; kt < K; kt += 64) {
        __syncthreads();
#pragma unroll
        for (int i = 0; i < 4; ++i) {
            gload16(aSrc[i] + kt, ldsA[i]);
            gload16(bSrc[i] + kt, ldsB[i]);
        }
        asm volatile("s_waitcnt vmcnt(0)" ::: "memory");
        __syncthreads();
#pragma unroll
        for (int kk = 0; kk < 2; ++kk) {
            int g0 = kk * 4 + l4;
            bf16x8 af[4], bfv[4];
#pragma unroll
            for (int mi = 0; mi < 4; ++mi)
                af[mi] = *(const bf16x8*)&As[LIX(wm * 64 + mi * 16 + l15, g0)];
#pragma unroll
            for (int ni = 0; ni < 4; ++ni)
                bfv[ni] = *(const bf16x8*)&Bs[LIX(wn * 64 + ni * 16 + l15, g0)];
#pragma unroll
            for (int mi = 0; mi < 4; ++mi)
#pragma unroll
                for (int ni = 0; ni < 4; ++ni)
                    acc[mi][ni] = __builtin_amdgcn_mfma_f32_16x16x32_bf16(
                        bfv[ni], af[mi], acc[mi][ni], 0, 0, 0);   // C^T fragment
        }
    }

    if (nroute) {
#pragma unroll
        for (int mi = 0; mi < 4; ++mi) {
            int row = r0 + wm * 64 + mi * 16 + l15;
#pragma unroll
            for (int ni = 0; ni < 4; ++ni) {
                int col = c0 + wn * 64 + ni * 16 + l4 * 4;
                int range = col >> 9, cc = col & 511;
                ushortT* d = Db.p[range];
                f32x4 a = acc[mi][ni];
                if ((scmask >> range) & 1) {
                    a[0] *= NORMF; a[1] *= NORMF; a[2] *= NORMF; a[3] *= NORMF;
                }
                if ((vtmask >> range) & 1) {
                    size_t vb = ((size_t)(row >> 9) * Hh + (cc >> 6)) * 64 + (cc & 63);
                    int tok = row & 511;
#pragma unroll
                    for (int r = 0; r < 4; ++r)
                        d[((vb + r) << 9) + tok] = f2bf(a[r]);
                } else {
                    ushort4 o;
                    o.x = f2bf(a[0]); o.y = f2bf(a[1]);
                    o.z = f2bf(a[2]); o.w = f2bf(a[3]);
                    *(ushort4*)&d[((size_t)row << 9) + cc] = o;
                }
            }
        }
    } else {
        const float alp = alpha ? alpha[0] : 1.0f;
        ushortT* outB = Db.p[0];
#pragma unroll
        for (int mi = 0; mi < 4; ++mi) {
            int row = r0 + wm * 64 + mi * 16 + l15;
#pragma unroll
            for (int ni = 0; ni < 4; ++ni) {
                int colb = c0 + wn * 64 + ni * 16 + l4 * 4;
                f32x4 a = acc[mi][ni];
                if (bias) {
                    float4 b4 = *(const float4*)&bias[colb];
                    a[0] += b4.x; a[1] += b4.y; a[2] += b4.z; a[3] += b4.w;
                }
                if (do_relu) {
#pragma unroll
                    for (int r = 0; r < 4; ++r) a[r] = fmaxf(a[r], 0.f);
                }
#pragma unroll
                for (int r = 0; r < 4; ++r) a[r] *= alp;
                size_t idx = (size_t)row * N + colb;
                if (res) {
                    float4 r4 = *(const float4*)&res[idx];
                    a[0] += r4.x; a[1] += r4.y; a[2] += r4.z; a[3] += r4.w;
                }
                if (outF)
                    *(float4*)&outF[idx] = make_float4(a[0], a[1], a[2], a[3]);
                if (outB) {
                    ushort4 o;
                    o.x = f2bf(a[0]); o.y = f2bf(a[1]);
                    o.z = f2bf(a[2]); o.w = f2bf(a[3]);
                    *(ushort4*)&outB[idx] = o;
                }
            }
        }
    }
}

// ---------- 64x128 bf16 MFMA GEMM; residual f32 (resf) or bf16 (resb) ----------
__global__ __launch_bounds__(256) void gemm64(
    const ushortT* __restrict__ Bw, const ushortT* __restrict__ A,
    float* __restrict__ outF, ushortT* __restrict__ outB,
    int M, int N, int K, const float* __restrict__ bias,
    const float* __restrict__ resf, const ushortT* __restrict__ resb,
    const float* __restrict__ alpha, int do_relu)
{
    __shared__ __align__(16) ushortT As[64 * 64];    // 8 KB
    __shared__ __align__(16) ushortT Bs[128 * 64];   // 16 KB
    const int tid = threadIdx.x;
    const int wid = tid >> 6, lane = tid & 63;
    const int wm = wid >> 1, wn = wid & 1;
    const int l15 = lane & 15, l4 = lane >> 4;

    int bid = blockIdx.y * gridDim.x + blockIdx.x;
    int nwg = gridDim.x * gridDim.y;
    int q = nwg >> 3;
    int swz = (bid & 7) * q + (bid >> 3);
    int bx = swz % gridDim.x, by = swz / gridDim.x;
    const int r0 = by * 64, c0 = bx * 128;

    const ushortT* aSrc[2];
    char* ldsA[2];
#pragma unroll
    for (int i = 0; i < 2; ++i) {
        int off = wid * 2048 + i * 1024 + lane * 16;
        int row = off >> 7;
        int sg = ((off >> 4) & 7) ^ (row & 7);
        aSrc[i] = A + (size_t)(r0 + row) * K + sg * 8;
        ldsA[i] = (char*)As + off;
    }
    const ushortT* bSrc[4];
    char* ldsB[4];
#pragma unroll
    for (int i = 0; i < 4; ++i) {
        int off = wid * 4096 + i * 1024 + lane * 16;
        int row = off >> 7;
        int sg = ((off >> 4) & 7) ^ (row & 7);
        bSrc[i] = Bw + (size_t)(c0 + row) * K + sg * 8;
        ldsB[i] = (char*)Bs + off;
    }

    f32x4 acc[2][4] = {};

    for (int kt = 0; kt < K; kt += 64) {
        __syncthreads();
#pragma unroll
        for (int i = 0; i < 2; ++i) gload16(aSrc[i] + kt, ldsA[i]);
#pragma unroll
        for (int i = 0; i < 4; ++i) gload16(bSrc[i] + kt, ldsB[i]);
        asm volatile("s_waitcnt vmcnt(0)" ::: "memory");
        __syncthreads();
#pragma unroll
        for (int kk = 0; kk < 2; ++kk) {
            int g0 = kk * 4 + l4;
            bf16x8 af[2], bfv[4];
#pragma unroll
            for (int mi = 0; mi < 2; ++mi)
                af[mi] = *(const bf16x8*)&As[LIX(wm * 32 + mi * 16 + l15, g0)];
#pragma unroll
            for (int ni = 0; ni < 4; ++ni)
                bfv[ni] = *(const bf16x8*)&Bs[LIX(wn * 64 + ni * 16 + l15, g0)];
#pragma unroll
            for (int mi = 0; mi < 2; ++mi)
#pragma unroll
                for (int ni = 0; ni < 4; ++ni)
                    acc[mi][ni] = __builtin_amdgcn_mfma_f32_16x16x32_bf16(
                        bfv[ni], af[mi], acc[mi][ni], 0, 0, 0);
        }
    }

    const float alp = alpha ? alpha[0] : 1.0f;
#pragma unroll
    for (int mi = 0; mi < 2; ++mi) {
        int row = r0 + wm * 32 + mi * 16 + l15;
#pragma unroll
        for (int ni = 0; ni < 4; ++ni) {
            int colb = c0 + wn * 64 + ni * 16 + l4 * 4;
            f32x4 a = acc[mi][ni];
            if (bias) {
                float4 b4 = *(const float4*)&bias[colb];
                a[0] += b4.x; a[1] += b4.y; a[2] += b4.z; a[3] += b4.w;
            }
            if (do_relu) {
#pragma unroll
                for (int r = 0; r < 4; ++r) a[r] = fmaxf(a[r], 0.f);
            }
#pragma unroll
            for (int r = 0; r < 4; ++r) a[r] *= alp;
            size_t idx = (size_t)row * N + colb;
            if (resf) {
                float4 r4 = *(const float4*)&resf[idx];
                a[0] += r4.x; a[1] += r4.y; a[2] += r4.z; a[3] += r4.w;
            }
            if (resb) {
                ushort4 r4 = *(const ushort4*)&resb[idx];
                a[0] += bf2f(r4.x); a[1] += bf2f(r4.y);
                a[2] += bf2f(r4.z); a[3] += bf2f(r4.w);
            }
            if (outF)
                *(float4*)&outF[idx] = make_float4(a[0], a[1], a[2], a[3]);
            if (outB) {
                ushort4 o;
                o.x = f2bf(a[0]); o.y = f2bf(a[1]);
                o.z = f2bf(a[2]); o.w = f2bf(a[3]);
                *(ushort4*)&outB[idx] = o;
            }
        }
    }
}

// ---------- HA diagonal scores (QD pre-scaled by NORM) ----------
__global__ __launch_bounds__(256) void diag_dot_bb(const ushortT* __restrict__ QD,
                                                   const ushortT* __restrict__ K,
                                                   float* __restrict__ Sdg) {
    int i = blockIdx.x * 256 + threadIdx.x;
    int h = i & 7, n = (i >> 3) & 511, b = i >> 12;
    int dix = (n < NPICKk) ? n + NPICKk : n - NPICKk;
    const ushortT* q = QD + (((size_t)(b * Nn + n) * Hh + h) << 6);
    const ushortT* k = K + (((size_t)(b * Nn + dix) * Hh + h) << 6);
    float s = 0.f;
#pragma unroll
    for (int d = 0; d < 64; d += 4) {
        ushort4 a = *(const ushort4*)(q + d);
        ushort4 c = *(const ushort4*)(k + d);
        s += bf2f(a.x) * bf2f(c.x) + bf2f(a.y) * bf2f(c.y)
           + bf2f(a.z) * bf2f(c.z) + bf2f(a.w) * bf2f(c.w);
    }
    Sdg[i] = s;
}

// ---------- MFMA flash attention: Q/QA/QB in REGISTERS, LDS only K/V/P ----------
template <int HA>
__global__ __launch_bounds__(256) void attn8(
    const ushortT* __restrict__ Qm, const ushortT* __restrict__ Km,
    const ushortT* __restrict__ Vtm, const ushortT* __restrict__ QAm,
    const ushortT* __restrict__ QBm, const float* __restrict__ Sdg,
    ushortT* __restrict__ Out)
{
    __shared__ __align__(16) ushortT Ks[64 * 64];            // 8 KB
    __shared__ __align__(16) ushortT Vs[64 * 64];            // 8 KB
    __shared__ __align__(16) ushortT Pw[4][16 * 64];         // 8 KB, wave-private
    __shared__ float sdl[64];

    const int tid = threadIdx.x, wid = tid >> 6, lane = tid & 63;
    const int l15 = lane & 15, l4 = lane >> 4;
    const int b = blockIdx.z, h = blockIdx.y, n0 = blockIdx.x * 64;
    const int bh = b * Hh + h;

    // Q/QA/QB fragments direct to registers (rows are wave-private; no LDS)
    const size_t qrow = (((size_t)(b * Nn + n0 + wid * 16 + l15) * Hh + h) << 6);
    bf16x8 qf[2], xaf[2], xbf[2];
#pragma unroll
    for (int kk = 0; kk < 2; ++kk) {
        int g0 = kk * 4 + l4;
        qf[kk] = *(const bf16x8*)&Qm[qrow + g0 * 8];
        if (HA) {
            xaf[kk] = *(const bf16x8*)&QAm[qrow + g0 * 8];
            xbf[kk] = *(const bf16x8*)&QBm[qrow + g0 * 8];
        }
    }
    if (HA && tid < 64) sdl[tid] = Sdg[((size_t)(b * Nn + n0 + tid)) * Hh + h];
    const int td = (n0 < NPICKk) ? ((n0 + NPICKk) >> 6) : ((n0 - NPICKk) >> 6);

    const ushortT* kSrc[2]; char* kDst[2];
    const ushortT* vSrc[2]; char* vDst[2];
#pragma unroll
    for (int i = 0; i < 2; ++i) {
        int off = wid * 2048 + i * 1024 + lane * 16;
        int row = off >> 7, sg = ((off >> 4) & 7) ^ (row & 7);
        kSrc[i] = Km + (((size_t)(b * Nn + row) * Hh + h) << 6) + sg * 8;
        kDst[i] = (char*)Ks + off;
        vSrc[i] = Vtm + (((size_t)(bh * 64 + row)) << 9) + sg * 8;
        vDst[i] = (char*)Vs + off;
    }

    float M[4], L[4];
    f32x4 Oa[4] = {};
#pragma unroll
    for (int r = 0; r < 4; ++r) { M[r] = -INFINITY; L[r] = 0.f; }

    for (int t = 0; t < 8; ++t) {
        __syncthreads();   // prior-iter reads of Ks/Vs done
#pragma unroll
        for (int i = 0; i < 2; ++i) {
            gload16(kSrc[i] + (size_t)t * (64 * Hh * VDd), kDst[i]);
            gload16(vSrc[i] + t * 64, vDst[i]);
        }
        asm volatile("s_waitcnt vmcnt(0)" ::: "memory");
        __syncthreads();   // staged data visible

        // ---- S = Q K^T via MFMA (Q in regs) ----
        __builtin_amdgcn_s_setprio(1);
        f32x4 s1[4] = {}, sX[4] = {};
#pragma unroll
        for (int kk = 0; kk < 2; ++kk) {
            int g0 = kk * 4 + l4;
            bf16x8 aq = qf[kk];
            bf16x8 ax;
            if (HA) ax = (t >= 4) ? xbf[kk] : xaf[kk];
#pragma unroll
            for (int ni = 0; ni < 4; ++ni) {
                bf16x8 bk = *(const bf16x8*)&Ks[LIX(ni * 16 + l15, g0)];
                s1[ni] = __builtin_amdgcn_mfma_f32_16x16x32_bf16(aq, bk, s1[ni], 0, 0, 0);
                if (HA)
                    sX[ni] = __builtin_amdgcn_mfma_f32_16x16x32_bf16(ax, bk, sX[ni], 0, 0, 0);
            }
        }
        __builtin_amdgcn_s_setprio(0);

        const bool dt = HA && (t == td);

        // ---- online softmax ----
#pragma unroll
        for (int r = 0; r < 4; ++r) {
            int rw = wid * 16 + l4 * 4 + r;
            float m = s1[0][r];
#pragma unroll
            for (int ni = 1; ni < 4; ++ni) m = fmaxf(m, s1[ni][r]);
            if (HA) {
#pragma unroll
                for (int ni = 0; ni < 4; ++ni) m = fmaxf(m, sX[ni][r]);
            }
            if (dt) m = fmaxf(m, sdl[rw]);
#pragma unroll
            for (int o = 8; o >= 1; o >>= 1) m = fmaxf(m, __shfl_xor(m, o, 16));
            float mn = fmaxf(M[r], m);
            float sc = __expf(M[r] - mn);
            M[r] = mn; L[r] *= sc;
#pragma unroll
            for (int ni = 0; ni < 4; ++ni) Oa[ni][r] *= sc;
            float rs = 0.f;
#pragma unroll
            for (int ni = 0; ni < 4; ++ni) {
                float p = __expf(s1[ni][r] - mn);
                if (HA) p += __expf(sX[ni][r] - mn);
                if (dt && ni == wid && l15 == l4 * 4 + r) p += __expf(sdl[rw] - mn);
                s1[ni][r] = p;
                rs += p;
            }
#pragma unroll
            for (int o = 8; o >= 1; o >>= 1) rs += __shfl_xor(rs, o, 16);
            L[r] += rs;
        }

        // ---- write P into this wave's private strip (no barrier) ----
#pragma unroll
        for (int ni = 0; ni < 4; ++ni)
#pragma unroll
            for (int r = 0; r < 4; ++r) {
                int prow = l4 * 4 + r;
                int col = ni * 16 + l15;
                Pw[wid][(prow << 6) + ((((col >> 3) ^ (prow & 7))) << 3) + (col & 7)] =
                    f2bf(s1[ni][r]);
            }

        // ---- O += P @ V ----
        __builtin_amdgcn_s_setprio(1);
#pragma unroll
        for (int kk = 0; kk < 2; ++kk) {
            int g0 = kk * 4 + l4;
            bf16x8 ap = *(const bf16x8*)&Pw[wid][LIX(l15, g0)];
#pragma unroll
            for (int ni = 0; ni < 4; ++ni) {
                bf16x8 bv = *(const bf16x8*)&Vs[LIX(ni * 16 + l15, g0)];
                Oa[ni] = __builtin_amdgcn_mfma_f32_16x16x32_bf16(ap, bv, Oa[ni], 0, 0, 0);
            }
        }
        __builtin_amdgcn_s_setprio(0);
    }

#pragma unroll
    for (int r = 0; r < 4; ++r) {
        float inv = 1.0f / L[r];
        size_t obase = (((size_t)(b * Nn + n0 + wid * 16 + l4 * 4 + r) * Hh + h) << 6);
#pragma unroll
        for (int ni = 0; ni < 4; ++ni)
            Out[obase + ni * 16 + l15] = f2bf(Oa[ni][r] * inv);
    }
}

extern "C" void kernel_launch(void* const* d_in, const int* in_sizes, int n_in,
                              void* d_out, int out_size, void* d_ws, size_t ws_size,
                              hipStream_t stream)
{
    const float* x = (const float*)d_in[0];

    int dictOrder = (in_sizes[18] != 512);
    const float* comb_w  = (const float*)d_in[17];
    const float* comb2_w = (const float*)d_in[dictOrder ? 18 : 19];
    const float* comb3_w = (const float*)d_in[dictOrder ? 19 : 21];
    const float* comb_b  = (const float*)d_in[dictOrder ? 20 : 18];
    const float* comb2_b = (const float*)d_in[dictOrder ? 21 : 20];
    const float* comb3_b = (const float*)d_in[22];
    const float* alpha1 = (const float*)d_in[23];
    const float* alpha2 = (const float*)d_in[24];
    const float* alpha3 = (const float*)d_in[25];
    const float* ff1_w1 = (const float*)d_in[26];
    const float* ff1_b1 = (const float*)d_in[27];
    const float* ff1_w2 = (const float*)d_in[28];
    const float* ff1_b2 = (const float*)d_in[29];
    const float* ffa1   = (const float*)d_in[30];
    const float* ff2_w1 = (const float*)d_in[31];
    const float* ff2_b1 = (const float*)d_in[32];
    const float* ff2_w2 = (const float*)d_in[33];
    const float* ff2_b2 = (const float*)d_in[34];
    const float* ffa2   = (const float*)d_in[35];
    const float* ff3_w1 = (const float*)d_in[36];
    const float* ff3_b1 = (const float*)d_in[37];
    const float* ff3_w2 = (const float*)d_in[38];
    const float* ff3_b2 = (const float*)d_in[39];
    const float* ffa3   = (const float*)d_in[40];

    // ---- workspace layout (bytes) ----
    char* W = (char*)d_ws;
    ushortT* wbHead = (ushortT*)(W + 0);
    ushortT* wbMha  = (ushortT*)(W + 4718592);
    ushortT* wbComb = (ushortT*)(W + 8388608);
    ushortT* wbFf1  = (ushortT*)(W + 9961472);
    ushortT* wbFf2  = (ushortT*)(W + 16252928);
    ushortT* xbf    = (ushortT*)(W + 22544384);
    float*   Sd     = (float*)  (W + 30932992);
    ushortT* bufQ   = (ushortT*)(W + 31195136);
    ushortT* bufK   = (ushortT*)(W + 39583744);
    ushortT* bufVt  = (ushortT*)(W + 47972352);
    ushortT* bufQA  = (ushortT*)(W + 56360960);
    ushortT* bufQB  = (ushortT*)(W + 64749568);
    ushortT* bufQD  = (ushortT*)(W + 73138176);
    ushortT* hidden = (ushortT*)(W + 81526784);
    ushortT* curb   = (ushortT*)(W + 115081216);
    ushortT* bufHA  = xbf;
    float*   cur    = (float*)d_out;

    dim3 tb(256);
    const int TOK = Bb * Nn;  // 8192
    const size_t WS = 512 * 512;
    const size_t WF = 2048 * 512;

    // 1. casts / transposes (batched)
    hipLaunchKernelGGL(castx, dim3(TOK * 512 / 1024), tb, 0, stream, x, xbf);
    {
        Ptrs9 s; for (int i = 0; i < 9; ++i) s.p[i] = (const float*)d_in[1 + i];
        hipLaunchKernelGGL(thead, dim3(1, 8, 72), tb, 0, stream, s, wbHead);
    }
    {
        Ptrs10 s;
        for (int i = 0; i < 7; ++i) s.p[i] = (const float*)d_in[10 + i];
        s.p[7] = comb_w; s.p[8] = comb2_w; s.p[9] = comb3_w;
        hipLaunchKernelGGL(tsq, dim3(8, 8, 10), tb, 0, stream, s, wbMha);
    }
    {
        Ptrs6 s;
        s.p[0] = ff1_w1; s.p[1] = ff2_w1; s.p[2] = ff3_w1;
        s.p[3] = ff1_w2; s.p[4] = ff2_w2; s.p[5] = ff3_w2;
        hipLaunchKernelGGL(tff, dim3(32, 32, 6), tb, 0, stream, s, wbFf1);
    }

    auto gemm = [&](PtrsB Bp, PtrsD Db, const ushortT* A, float* oF,
                    int M, int Ncc, int Kc, const float* bias, const float* res,
                    const float* alp, int relu, int nroute, int vtmask, int scmask) {
        hipLaunchKernelGGL(gemm_bf, dim3(Ncc / 128, M / 128), tb, 0, stream,
                           Bp, Db, A, oF, M, Ncc, Kc, bias, res, alp, relu, nroute,
                           vtmask, scmask);
    };
    auto g64 = [&](const ushortT* Bw, const ushortT* A, float* oF, ushortT* oB,
                   int M, int Ncc, int Kc, const float* bias, const float* resf,
                   const ushortT* resb, const float* alp, int relu) {
        hipLaunchKernelGGL(gemm64, dim3(Ncc / 128, M / 64), tb, 0, stream,
                           Bw, A, oF, oB, M, Ncc, Kc, bias, resf, resb, alp, relu);
    };
    auto uni = [&](const ushortT* w) { PtrsB b; for (int i = 0; i < 12; ++i) b.p[i] = w; return b; };
    auto d1 = [&](ushortT* d) { PtrsD dd = {}; dd.p[0] = d; return dd; };

    // 2. HA projections: ONE fused GEMM, N=3072 (Q/QA/QB/QD pre-scaled, scmask=57)
    {
        PtrsB b;
        b.p[0] = b.p[1] = wbHead + 0 * WS;
        b.p[2] = b.p[3] = wbHead + 1 * WS;
        b.p[4] = b.p[5] = wbHead + 2 * WS;
        b.p[6] = wbHead + 4 * WS; b.p[7] = wbHead + 8 * WS;
        b.p[8] = wbHead + 5 * WS; b.p[9] = wbHead + 7 * WS;
        b.p[10] = wbHead + 3 * WS; b.p[11] = wbHead + 6 * WS;
        PtrsD d; d.p[0] = bufQ; d.p[1] = bufK; d.p[2] = bufVt;
        d.p[3] = bufQA; d.p[4] = bufQB; d.p[5] = bufQD;
        gemm(b, d, xbf, nullptr, TOK, 3072, 512, nullptr, nullptr, nullptr, 0, 6, 4, 57);
    }

    // 3. HA attention
    hipLaunchKernelGGL(diag_dot_bb, dim3(Bb * Nn * Hh / 256), tb, 0, stream, bufQD, bufK, Sd);
    hipLaunchKernelGGL((attn8<1>), dim3(Nn / 64, Hh, Bb), tb, 0, stream,
                       bufQ, bufK, bufVt, bufQA, bufQB, Sd, bufHA);

    // 4. comb3 + FF3 (bf16 residual stream)
    g64(wbComb + 2 * WS, bufHA, nullptr, curb, TOK, 512, 512, comb3_b, x, nullptr, alpha3, 0);
    gemm(uni(wbFf1 + 2 * WF), d1(hidden), curb, nullptr, TOK, 2048, 512, ff3_b1, nullptr, nullptr, 1, 0, 0, 0);
    g64(wbFf2 + 2 * WF, hidden, nullptr, curb, TOK, 512, 2048, ff3_b2, nullptr, curb, ffa3, 0);

    // 5. MHA1
    {
        PtrsB b;
        b.p[0] = b.p[1] = wbMha + 0 * WS;
        b.p[2] = b.p[3] = wbMha + 1 * WS;
        b.p[4] = b.p[5] = wbMha + 2 * WS;
        PtrsD d = {}; d.p[0] = bufQ; d.p[1] = bufK; d.p[2] = bufVt;
        gemm(b, d, curb, nullptr, TOK, 1536, 512, nullptr, nullptr, nullptr, 0, 3, 4, 1);
    }
    hipLaunchKernelGGL((attn8<0>), dim3(Nn / 64, Hh, Bb), tb, 0, stream,
                       bufQ, bufK, bufVt, nullptr, nullptr, nullptr, bufHA);
    g64(wbComb + 0 * WS, bufHA, nullptr, curb, TOK, 512, 512, comb_b, nullptr, curb, alpha1, 0);
    gemm(uni(wbFf1 + 0 * WF), d1(hidden), curb, nullptr, TOK, 2048, 512, ff1_b1, nullptr, nullptr, 1, 0, 0, 0);
    g64(wbFf2 + 0 * WF, hidden, nullptr, curb, TOK, 512, 2048, ff1_b2, nullptr, curb, ffa1, 0);

    // 6. MHA2
    {
        PtrsB b;
        b.p[0] = wbMha + 3 * WS; b.p[1] = wbMha + 4 * WS;
        b.p[2] = b.p[3] = wbMha + 5 * WS;
        b.p[4] = b.p[5] = wbMha + 6 * WS;
        PtrsD d = {}; d.p[0] = bufQ; d.p[1] = bufK; d.p[2] = bufVt;
        gemm(b, d, curb, nullptr, TOK, 1536, 512, nullptr, nullptr, nullptr, 0, 3, 4, 1);
    }
    hipLaunchKernelGGL((attn8<0>), dim3(Nn / 64, Hh, Bb), tb, 0, stream,
                       bufQ, bufK, bufVt, nullptr, nullptr, nullptr, bufHA);
    g64(wbComb + 1 * WS, bufHA, nullptr, curb, TOK, 512, 512, comb2_b, nullptr, curb, alpha2, 0);
    gemm(uni(wbFf1 + 1 * WF), d1(hidden), curb, nullptr, TOK, 2048, 512, ff2_b1, nullptr, nullptr, 1, 0, 0, 0);
    // final: write f32 d_out
    g64(wbFf2 + 1 * WF, hidden, cur, nullptr, TOK, 512, 2048, ff2_b2, nullptr, curb, ffa2, 0);
}

// Round 12
// 502.396 us; speedup vs baseline: 10.0253x; 1.0180x over previous
//
#include <hip/hip_runtime.h>
#include <math.h>

#define Hh 8
#define Bb 16
#define Nn 512
#define Dd 512
#define VDd 64
#define NPICKk 256
#define NORMF 0.125f
#define SCL2 0.1803368801f   /* NORMF * log2(e) */

typedef unsigned short ushortT;
typedef __bf16 bf16x8 __attribute__((ext_vector_type(8)));
typedef float f32x4 __attribute__((ext_vector_type(4)));

struct PtrsB { const ushortT* p[12]; };
struct PtrsD { ushortT* p[6]; };
struct Ptrs9 { const float* p[9]; };
struct Ptrs10 { const float* p[10]; };
struct Ptrs6 { const float* p[6]; };

__device__ inline ushortT f2bf(float f) {
    __bf16 h = (__bf16)f;
    union { __bf16 h; ushortT u; } v; v.h = h;
    return v.u;
}
__device__ inline float bf2f(ushortT u) {
    union { unsigned int u; float f; } v; v.u = ((unsigned int)u) << 16;
    return v.f;
}
__device__ inline float exp2fast(float x) {
#if __has_builtin(__builtin_amdgcn_exp2f)
    return __builtin_amdgcn_exp2f(x);
#else
    return exp2f(x);
#endif
}
__device__ inline void gload16(const void* gptr, void* ldsptr) {
    auto g = reinterpret_cast<const __attribute__((address_space(1))) unsigned int*>(
        reinterpret_cast<uintptr_t>(gptr));
    auto l = reinterpret_cast<__attribute__((address_space(3))) unsigned int*>(
        reinterpret_cast<uintptr_t>(ldsptr));
    __builtin_amdgcn_global_load_lds(g, l, 16, 0, 0);
}

#define LIX(r, g) (((r) << 6) + ((((g) ^ ((r) & 7))) << 3))

// ---------- fp32 -> bf16 elementwise ----------
__global__ __launch_bounds__(256) void castx(const float* __restrict__ in,
                                             ushortT* __restrict__ out) {
    int i = blockIdx.x * 256 + threadIdx.x;
    float4 v = *(const float4*)&in[(size_t)i * 4];
    ushort4 o; o.x = f2bf(v.x); o.y = f2bf(v.y); o.z = f2bf(v.z); o.w = f2bf(v.w);
    *(ushort4*)&out[(size_t)i * 4] = o;
}

// ---------- transpose+cast body ----------
__device__ inline void tbody(const float* __restrict__ in, ushortT* __restrict__ out,
                             int in_ld, int out_ld, int r0, int c0) {
    __shared__ float T[64][65];
    int tr = threadIdx.x >> 4, tc4 = (threadIdx.x & 15) * 4;
#pragma unroll
    for (int p = 0; p < 4; ++p) {
        float4 v = *(const float4*)&in[(size_t)(r0 + tr + p * 16) * in_ld + c0 + tc4];
        T[tr + p * 16][tc4 + 0] = v.x; T[tr + p * 16][tc4 + 1] = v.y;
        T[tr + p * 16][tc4 + 2] = v.z; T[tr + p * 16][tc4 + 3] = v.w;
    }
    __syncthreads();
#pragma unroll
    for (int p = 0; p < 4; ++p) {
        int orow = c0 + tr + p * 16;
        int ocol = r0 + tc4;
        ushort4 o;
        o.x = f2bf(T[tc4 + 0][tr + p * 16]);
        o.y = f2bf(T[tc4 + 1][tr + p * 16]);
        o.z = f2bf(T[tc4 + 2][tr + p * 16]);
        o.w = f2bf(T[tc4 + 3][tr + p * 16]);
        *(ushort4*)&out[(size_t)orow * out_ld + ocol] = o;
    }
}

__global__ __launch_bounds__(256) void thead(Ptrs9 s, ushortT* __restrict__ dst) {
    int w = blockIdx.z >> 3, h = blockIdx.z & 7;
    tbody(s.p[w] + (size_t)h * 512 * 64,
          dst + (size_t)w * 262144 + (size_t)h * 64 * 512,
          64, 512, blockIdx.y * 64, 0);
}
__global__ __launch_bounds__(256) void tsq(Ptrs10 s, ushortT* __restrict__ dst) {
    tbody(s.p[blockIdx.z], dst + (size_t)blockIdx.z * 262144,
          512, 512, blockIdx.y * 64, blockIdx.x * 64);
}
__global__ __launch_bounds__(256) void tff(Ptrs6 s, ushortT* __restrict__ dst) {
    int z = blockIdx.z;
    if (z < 3) { if (blockIdx.y >= 8 || blockIdx.x >= 32) return; }
    else       { if (blockIdx.y >= 32 || blockIdx.x >= 8) return; }
    int in_ld = (z < 3) ? 2048 : 512;
    int out_ld = (z < 3) ? 512 : 2048;
    tbody(s.p[z], dst + (size_t)z * 1048576, in_ld, out_ld,
          blockIdx.y * 64, blockIdx.x * 64);
}

// ---------- 128x128 bf16 MFMA GEMM (routed / standard epilogues) ----------
__global__ __launch_bounds__(256) void gemm_bf(
    PtrsB Bp, PtrsD Db, const ushortT* __restrict__ A, float* __restrict__ outF,
    int M, int N, int K, const float* __restrict__ bias,
    const float* __restrict__ res, const float* __restrict__ alpha,
    int do_relu, int nroute, int vtmask, int scmask)
{
    __shared__ __align__(16) ushortT As[128 * 64];
    __shared__ __align__(16) ushortT Bs[128 * 64];
    const int tid = threadIdx.x;
    const int wid = tid >> 6, lane = tid & 63;
    const int wm = wid >> 1, wn = wid & 1;
    const int l15 = lane & 15, l4 = lane >> 4;

    int bid = blockIdx.y * gridDim.x + blockIdx.x;
    int nwg = gridDim.x * gridDim.y;
    int q = nwg >> 3;
    int swz = (bid & 7) * q + (bid >> 3);
    int bx = swz % gridDim.x, by = swz / gridDim.x;

    const int r0 = by * 128, c0 = bx * 128;
    const int half = ((r0 & (Nn - 1)) >= NPICKk) ? 1 : 0;
    const ushortT* Bt = Bp.p[((c0 >> 9) << 1) | half];
    const int cB = nroute ? (c0 & 511) : c0;

    const ushortT* aSrc[4];
    const ushortT* bSrc[4];
    char* ldsA[4];
    char* ldsB[4];
#pragma unroll
    for (int i = 0; i < 4; ++i) {
        int off = wid * 4096 + i * 1024 + lane * 16;
        int row = off >> 7;
        int sg = ((off >> 4) & 7) ^ (row & 7);
        aSrc[i] = A + (size_t)(r0 + row) * K + sg * 8;
        bSrc[i] = Bt + (size_t)(cB + row) * K + sg * 8;
        ldsA[i] = (char*)As + off;
        ldsB[i] = (char*)Bs + off;
    }

    f32x4 acc[4][4] = {};

    for (int kt = 0; kt < K; kt += 64) {
        __syncthreads();
#pragma unroll
        for (int i = 0; i < 4; ++i) {
            gload16(aSrc[i] + kt, ldsA[i]);
            gload16(bSrc[i] + kt, ldsB[i]);
        }
        asm volatile("s_waitcnt vmcnt(0)" ::: "memory");
        __syncthreads();
#pragma unroll
        for (int kk = 0; kk < 2; ++kk) {
            int g0 = kk * 4 + l4;
            bf16x8 af[4], bfv[4];
#pragma unroll
            for (int mi = 0; mi < 4; ++mi)
                af[mi] = *(const bf16x8*)&As[LIX(wm * 64 + mi * 16 + l15, g0)];
#pragma unroll
            for (int ni = 0; ni < 4; ++ni)
                bfv[ni] = *(const bf16x8*)&Bs[LIX(wn * 64 + ni * 16 + l15, g0)];
#pragma unroll
            for (int mi = 0; mi < 4; ++mi)
#pragma unroll
                for (int ni = 0; ni < 4; ++ni)
                    acc[mi][ni] = __builtin_amdgcn_mfma_f32_16x16x32_bf16(
                        bfv[ni], af[mi], acc[mi][ni], 0, 0, 0);   // C^T fragment
        }
    }

    if (nroute) {
#pragma unroll
        for (int mi = 0; mi < 4; ++mi) {
            int row = r0 + wm * 64 + mi * 16 + l15;
#pragma unroll
            for (int ni = 0; ni < 4; ++ni) {
                int col = c0 + wn * 64 + ni * 16 + l4 * 4;
                int range = col >> 9, cc = col & 511;
                ushortT* d = Db.p[range];
                f32x4 a = acc[mi][ni];
                if ((scmask >> range) & 1) {
                    a[0] *= SCL2; a[1] *= SCL2; a[2] *= SCL2; a[3] *= SCL2;
                }
                if ((vtmask >> range) & 1) {
                    size_t vb = ((size_t)(row >> 9) * Hh + (cc >> 6)) * 64 + (cc & 63);
                    int tok = row & 511;
#pragma unroll
                    for (int r = 0; r < 4; ++r)
                        d[((vb + r) << 9) + tok] = f2bf(a[r]);
                } else {
                    ushort4 o;
                    o.x = f2bf(a[0]); o.y = f2bf(a[1]);
                    o.z = f2bf(a[2]); o.w = f2bf(a[3]);
                    *(ushort4*)&d[((size_t)row << 9) + cc] = o;
                }
            }
        }
    } else {
        const float alp = alpha ? alpha[0] : 1.0f;
        ushortT* outB = Db.p[0];
#pragma unroll
        for (int mi = 0; mi < 4; ++mi) {
            int row = r0 + wm * 64 + mi * 16 + l15;
#pragma unroll
            for (int ni = 0; ni < 4; ++ni) {
                int colb = c0 + wn * 64 + ni * 16 + l4 * 4;
                f32x4 a = acc[mi][ni];
                if (bias) {
                    float4 b4 = *(const float4*)&bias[colb];
                    a[0] += b4.x; a[1] += b4.y; a[2] += b4.z; a[3] += b4.w;
                }
                if (do_relu) {
#pragma unroll
                    for (int r = 0; r < 4; ++r) a[r] = fmaxf(a[r], 0.f);
                }
#pragma unroll
                for (int r = 0; r < 4; ++r) a[r] *= alp;
                size_t idx = (size_t)row * N + colb;
                if (res) {
                    float4 r4 = *(const float4*)&res[idx];
                    a[0] += r4.x; a[1] += r4.y; a[2] += r4.z; a[3] += r4.w;
                }
                if (outF)
                    *(float4*)&outF[idx] = make_float4(a[0], a[1], a[2], a[3]);
                if (outB) {
                    ushort4 o;
                    o.x = f2bf(a[0]); o.y = f2bf(a[1]);
                    o.z = f2bf(a[2]); o.w = f2bf(a[3]);
                    *(ushort4*)&outB[idx] = o;
                }
            }
        }
    }
}

// ---------- 64x128 bf16 MFMA GEMM; residual f32 (resf) or bf16 (resb) ----------
__global__ __launch_bounds__(256) void gemm64(
    const ushortT* __restrict__ Bw, const ushortT* __restrict__ A,
    float* __restrict__ outF, ushortT* __restrict__ outB,
    int M, int N, int K, const float* __restrict__ bias,
    const float* __restrict__ resf, const ushortT* __restrict__ resb,
    const float* __restrict__ alpha, int do_relu)
{
    __shared__ __align__(16) ushortT As[64 * 64];
    __shared__ __align__(16) ushortT Bs[128 * 64];
    const int tid = threadIdx.x;
    const int wid = tid >> 6, lane = tid & 63;
    const int wm = wid >> 1, wn = wid & 1;
    const int l15 = lane & 15, l4 = lane >> 4;

    int bid = blockIdx.y * gridDim.x + blockIdx.x;
    int nwg = gridDim.x * gridDim.y;
    int q = nwg >> 3;
    int swz = (bid & 7) * q + (bid >> 3);
    int bx = swz % gridDim.x, by = swz / gridDim.x;
    const int r0 = by * 64, c0 = bx * 128;

    const ushortT* aSrc[2];
    char* ldsA[2];
#pragma unroll
    for (int i = 0; i < 2; ++i) {
        int off = wid * 2048 + i * 1024 + lane * 16;
        int row = off >> 7;
        int sg = ((off >> 4) & 7) ^ (row & 7);
        aSrc[i] = A + (size_t)(r0 + row) * K + sg * 8;
        ldsA[i] = (char*)As + off;
    }
    const ushortT* bSrc[4];
    char* ldsB[4];
#pragma unroll
    for (int i = 0; i < 4; ++i) {
        int off = wid * 4096 + i * 1024 + lane * 16;
        int row = off >> 7;
        int sg = ((off >> 4) & 7) ^ (row & 7);
        bSrc[i] = Bw + (size_t)(c0 + row) * K + sg * 8;
        ldsB[i] = (char*)Bs + off;
    }

    f32x4 acc[2][4] = {};

    for (int kt = 0; kt < K; kt += 64) {
        __syncthreads();
#pragma unroll
        for (int i = 0; i < 2; ++i) gload16(aSrc[i] + kt, ldsA[i]);
#pragma unroll
        for (int i = 0; i < 4; ++i) gload16(bSrc[i] + kt, ldsB[i]);
        asm volatile("s_waitcnt vmcnt(0)" ::: "memory");
        __syncthreads();
#pragma unroll
        for (int kk = 0; kk < 2; ++kk) {
            int g0 = kk * 4 + l4;
            bf16x8 af[2], bfv[4];
#pragma unroll
            for (int mi = 0; mi < 2; ++mi)
                af[mi] = *(const bf16x8*)&As[LIX(wm * 32 + mi * 16 + l15, g0)];
#pragma unroll
            for (int ni = 0; ni < 4; ++ni)
                bfv[ni] = *(const bf16x8*)&Bs[LIX(wn * 64 + ni * 16 + l15, g0)];
#pragma unroll
            for (int mi = 0; mi < 2; ++mi)
#pragma unroll
                for (int ni = 0; ni < 4; ++ni)
                    acc[mi][ni] = __builtin_amdgcn_mfma_f32_16x16x32_bf16(
                        bfv[ni], af[mi], acc[mi][ni], 0, 0, 0);
        }
    }

    const float alp = alpha ? alpha[0] : 1.0f;
#pragma unroll
    for (int mi = 0; mi < 2; ++mi) {
        int row = r0 + wm * 32 + mi * 16 + l15;
#pragma unroll
        for (int ni = 0; ni < 4; ++ni) {
            int colb = c0 + wn * 64 + ni * 16 + l4 * 4;
            f32x4 a = acc[mi][ni];
            if (bias) {
                float4 b4 = *(const float4*)&bias[colb];
                a[0] += b4.x; a[1] += b4.y; a[2] += b4.z; a[3] += b4.w;
            }
            if (do_relu) {
#pragma unroll
                for (int r = 0; r < 4; ++r) a[r] = fmaxf(a[r], 0.f);
            }
#pragma unroll
            for (int r = 0; r < 4; ++r) a[r] *= alp;
            size_t idx = (size_t)row * N + colb;
            if (resf) {
                float4 r4 = *(const float4*)&resf[idx];
                a[0] += r4.x; a[1] += r4.y; a[2] += r4.z; a[3] += r4.w;
            }
            if (resb) {
                ushort4 r4 = *(const ushort4*)&resb[idx];
                a[0] += bf2f(r4.x); a[1] += bf2f(r4.y);
                a[2] += bf2f(r4.z); a[3] += bf2f(r4.w);
            }
            if (outF)
                *(float4*)&outF[idx] = make_float4(a[0], a[1], a[2], a[3]);
            if (outB) {
                ushort4 o;
                o.x = f2bf(a[0]); o.y = f2bf(a[1]);
                o.z = f2bf(a[2]); o.w = f2bf(a[3]);
                *(ushort4*)&outB[idx] = o;
            }
        }
    }
}

// ---------- HA diagonal scores (QD pre-scaled by NORM*log2e) ----------
__global__ __launch_bounds__(256) void diag_dot_bb(const ushortT* __restrict__ QD,
                                                   const ushortT* __restrict__ K,
                                                   float* __restrict__ Sdg) {
    int i = blockIdx.x * 256 + threadIdx.x;
    int h = i & 7, n = (i >> 3) & 511, b = i >> 12;
    int dix = (n < NPICKk) ? n + NPICKk : n - NPICKk;
    const ushortT* q = QD + (((size_t)(b * Nn + n) * Hh + h) << 6);
    const ushortT* k = K + (((size_t)(b * Nn + dix) * Hh + h) << 6);
    float s = 0.f;
#pragma unroll
    for (int d = 0; d < 64; d += 4) {
        ushort4 a = *(const ushort4*)(q + d);
        ushort4 c = *(const ushort4*)(k + d);
        s += bf2f(a.x) * bf2f(c.x) + bf2f(a.y) * bf2f(c.y)
           + bf2f(a.z) * bf2f(c.z) + bf2f(a.w) * bf2f(c.w);
    }
    Sdg[i] = s;
}

// ---------- MFMA flash attention: regs Q, exp2 domain, defer-max, XCD remap ----------
template <int HA>
__global__ __launch_bounds__(256) void attn9(
    const ushortT* __restrict__ Qm, const ushortT* __restrict__ Km,
    const ushortT* __restrict__ Vtm, const ushortT* __restrict__ QAm,
    const ushortT* __restrict__ QBm, const float* __restrict__ Sdg,
    ushortT* __restrict__ Out)
{
    __shared__ __align__(16) ushortT Ks[64 * 64];
    __shared__ __align__(16) ushortT Vs[64 * 64];
    __shared__ __align__(16) ushortT Pw[4][16 * 64];
    __shared__ float sdl[64];

    const int tid = threadIdx.x, wid = tid >> 6, lane = tid & 63;
    const int l15 = lane & 15, l4 = lane >> 4;

    // XCD-bijective remap: blocks sharing (b,h) get ids congruent mod 8 -> same XCD L2
    const int p = blockIdx.x + (blockIdx.y << 3) + (blockIdx.z << 6);
    const int n0 = (((p >> 3) & 7)) << 6;
    const int g8 = (p & 7) | ((p >> 6) << 3);   // 0..127
    const int h = g8 & 7, b = g8 >> 3;
    const int bh = b * Hh + h;

    // Q/QA/QB fragments direct to registers (rows wave-private)
    const size_t qrow = (((size_t)(b * Nn + n0 + wid * 16 + l15) * Hh + h) << 6);
    bf16x8 qf[2], xaf[2], xbf[2];
#pragma unroll
    for (int kk = 0; kk < 2; ++kk) {
        int g0 = kk * 4 + l4;
        qf[kk] = *(const bf16x8*)&Qm[qrow + g0 * 8];
        if (HA) {
            xaf[kk] = *(const bf16x8*)&QAm[qrow + g0 * 8];
            xbf[kk] = *(const bf16x8*)&QBm[qrow + g0 * 8];
        }
    }
    if (HA && tid < 64) sdl[tid] = Sdg[((size_t)(b * Nn + n0 + tid)) * Hh + h];
    const int td = (n0 < NPICKk) ? ((n0 + NPICKk) >> 6) : ((n0 - NPICKk) >> 6);

    const ushortT* kSrc[2]; char* kDst[2];
    const ushortT* vSrc[2]; char* vDst[2];
#pragma unroll
    for (int i = 0; i < 2; ++i) {
        int off = wid * 2048 + i * 1024 + lane * 16;
        int row = off >> 7, sg = ((off >> 4) & 7) ^ (row & 7);
        kSrc[i] = Km + (((size_t)(b * Nn + row) * Hh + h) << 6) + sg * 8;
        kDst[i] = (char*)Ks + off;
        vSrc[i] = Vtm + (((size_t)(bh * 64 + row)) << 9) + sg * 8;
        vDst[i] = (char*)Vs + off;
    }

    float M[4], L[4];
    f32x4 Oa[4] = {};
#pragma unroll
    for (int r = 0; r < 4; ++r) { M[r] = -INFINITY; L[r] = 0.f; }

    for (int t = 0; t < 8; ++t) {
        __syncthreads();
#pragma unroll
        for (int i = 0; i < 2; ++i) {
            gload16(kSrc[i] + (size_t)t * (64 * Hh * VDd), kDst[i]);
            gload16(vSrc[i] + t * 64, vDst[i]);
        }
        asm volatile("s_waitcnt vmcnt(0)" ::: "memory");
        __syncthreads();

        // ---- S = Q K^T (log2 domain: Q pre-scaled by NORM*log2e) ----
        __builtin_amdgcn_s_setprio(1);
        f32x4 s1[4] = {}, sX[4] = {};
#pragma unroll
        for (int kk = 0; kk < 2; ++kk) {
            bf16x8 aq = qf[kk];
            bf16x8 ax;
            if (HA) ax = (t >= 4) ? xbf[kk] : xaf[kk];
#pragma unroll
            for (int ni = 0; ni < 4; ++ni) {
                bf16x8 bk = *(const bf16x8*)&Ks[LIX(ni * 16 + l15, kk * 4 + l4)];
                s1[ni] = __builtin_amdgcn_mfma_f32_16x16x32_bf16(aq, bk, s1[ni], 0, 0, 0);
                if (HA)
                    sX[ni] = __builtin_amdgcn_mfma_f32_16x16x32_bf16(ax, bk, sX[ni], 0, 0, 0);
            }
        }
        __builtin_amdgcn_s_setprio(0);

        const bool dt = HA && (t == td);

        // ---- row maxes + wave-uniform defer-max check (T13, THR=8 in log2) ----
        float mrow[4];
        bool need = false;
#pragma unroll
        for (int r = 0; r < 4; ++r) {
            int rw = wid * 16 + l4 * 4 + r;
            float m = s1[0][r];
#pragma unroll
            for (int ni = 1; ni < 4; ++ni) m = fmaxf(m, s1[ni][r]);
            if (HA) {
#pragma unroll
                for (int ni = 0; ni < 4; ++ni) m = fmaxf(m, sX[ni][r]);
            }
            if (dt) m = fmaxf(m, sdl[rw]);
#pragma unroll
            for (int o = 8; o >= 1; o >>= 1) m = fmaxf(m, __shfl_xor(m, o, 16));
            mrow[r] = m;
            need = need || (m > M[r] + 8.f);
        }
        if (__any(need)) {
#pragma unroll
            for (int r = 0; r < 4; ++r) {
                float mn = fmaxf(M[r], mrow[r]);
                float sc = exp2fast(M[r] - mn);
                M[r] = mn; L[r] *= sc;
#pragma unroll
                for (int ni = 0; ni < 4; ++ni) Oa[ni][r] *= sc;
            }
        }

        // ---- P = exp2(S - M), row sums ----
#pragma unroll
        for (int r = 0; r < 4; ++r) {
            int rw = wid * 16 + l4 * 4 + r;
            float rs = 0.f;
#pragma unroll
            for (int ni = 0; ni < 4; ++ni) {
                float pv = exp2fast(s1[ni][r] - M[r]);
                if (HA) pv += exp2fast(sX[ni][r] - M[r]);
                if (dt && ni == wid && l15 == l4 * 4 + r) pv += exp2fast(sdl[rw] - M[r]);
                s1[ni][r] = pv;
                rs += pv;
            }
#pragma unroll
            for (int o = 8; o >= 1; o >>= 1) rs += __shfl_xor(rs, o, 16);
            L[r] += rs;
        }

        // ---- write P into wave-private strip (no barrier) ----
#pragma unroll
        for (int ni = 0; ni < 4; ++ni)
#pragma unroll
            for (int r = 0; r < 4; ++r) {
                int prow = l4 * 4 + r;
                int col = ni * 16 + l15;
                Pw[wid][(prow << 6) + ((((col >> 3) ^ (prow & 7))) << 3) + (col & 7)] =
                    f2bf(s1[ni][r]);
            }

        // ---- O += P @ V ----
        __builtin_amdgcn_s_setprio(1);
#pragma unroll
        for (int kk = 0; kk < 2; ++kk) {
            int g0 = kk * 4 + l4;
            bf16x8 ap = *(const bf16x8*)&Pw[wid][LIX(l15, g0)];
#pragma unroll
            for (int ni = 0; ni < 4; ++ni) {
                bf16x8 bv = *(const bf16x8*)&Vs[LIX(ni * 16 + l15, g0)];
                Oa[ni] = __builtin_amdgcn_mfma_f32_16x16x32_bf16(ap, bv, Oa[ni], 0, 0, 0);
            }
        }
        __builtin_amdgcn_s_setprio(0);
    }

#pragma unroll
    for (int r = 0; r < 4; ++r) {
        float inv = 1.0f / L[r];
        size_t obase = (((size_t)(b * Nn + n0 + wid * 16 + l4 * 4 + r) * Hh + h) << 6);
#pragma unroll
        for (int ni = 0; ni < 4; ++ni)
            Out[obase + ni * 16 + l15] = f2bf(Oa[ni][r] * inv);
    }
}

extern "C" void kernel_launch(void* const* d_in, const int* in_sizes, int n_in,
                              void* d_out, int out_size, void* d_ws, size_t ws_size,
                              hipStream_t stream)
{
    const float* x = (const float*)d_in[0];

    int dictOrder = (in_sizes[18] != 512);
    const float* comb_w  = (const float*)d_in[17];
    const float* comb2_w = (const float*)d_in[dictOrder ? 18 : 19];
    const float* comb3_w = (const float*)d_in[dictOrder ? 19 : 21];
    const float* comb_b  = (const float*)d_in[dictOrder ? 20 : 18];
    const float* comb2_b = (const float*)d_in[dictOrder ? 21 : 20];
    const float* comb3_b = (const float*)d_in[22];
    const float* alpha1 = (const float*)d_in[23];
    const float* alpha2 = (const float*)d_in[24];
    const float* alpha3 = (const float*)d_in[25];
    const float* ff1_w1 = (const float*)d_in[26];
    const float* ff1_b1 = (const float*)d_in[27];
    const float* ff1_w2 = (const float*)d_in[28];
    const float* ff1_b2 = (const float*)d_in[29];
    const float* ffa1   = (const float*)d_in[30];
    const float* ff2_w1 = (const float*)d_in[31];
    const float* ff2_b1 = (const float*)d_in[32];
    const float* ff2_w2 = (const float*)d_in[33];
    const float* ff2_b2 = (const float*)d_in[34];
    const float* ffa2   = (const float*)d_in[35];
    const float* ff3_w1 = (const float*)d_in[36];
    const float* ff3_b1 = (const float*)d_in[37];
    const float* ff3_w2 = (const float*)d_in[38];
    const float* ff3_b2 = (const float*)d_in[39];
    const float* ffa3   = (const float*)d_in[40];

    // ---- workspace layout (bytes) ----
    char* W = (char*)d_ws;
    ushortT* wbHead = (ushortT*)(W + 0);
    ushortT* wbMha  = (ushortT*)(W + 4718592);
    ushortT* wbComb = (ushortT*)(W + 8388608);
    ushortT* wbFf1  = (ushortT*)(W + 9961472);
    ushortT* wbFf2  = (ushortT*)(W + 16252928);
    ushortT* xbf    = (ushortT*)(W + 22544384);
    float*   Sd     = (float*)  (W + 30932992);
    ushortT* bufQ   = (ushortT*)(W + 31195136);
    ushortT* bufK   = (ushortT*)(W + 39583744);
    ushortT* bufVt  = (ushortT*)(W + 47972352);
    ushortT* bufQA  = (ushortT*)(W + 56360960);
    ushortT* bufQB  = (ushortT*)(W + 64749568);
    ushortT* bufQD  = (ushortT*)(W + 73138176);
    ushortT* hidden = (ushortT*)(W + 81526784);
    ushortT* curb   = (ushortT*)(W + 115081216);
    ushortT* bufHA  = xbf;
    float*   cur    = (float*)d_out;

    dim3 tb(256);
    const int TOK = Bb * Nn;  // 8192
    const size_t WS = 512 * 512;
    const size_t WF = 2048 * 512;

    // 1. casts / transposes (batched)
    hipLaunchKernelGGL(castx, dim3(TOK * 512 / 1024), tb, 0, stream, x, xbf);
    {
        Ptrs9 s; for (int i = 0; i < 9; ++i) s.p[i] = (const float*)d_in[1 + i];
        hipLaunchKernelGGL(thead, dim3(1, 8, 72), tb, 0, stream, s, wbHead);
    }
    {
        Ptrs10 s;
        for (int i = 0; i < 7; ++i) s.p[i] = (const float*)d_in[10 + i];
        s.p[7] = comb_w; s.p[8] = comb2_w; s.p[9] = comb3_w;
        hipLaunchKernelGGL(tsq, dim3(8, 8, 10), tb, 0, stream, s, wbMha);
    }
    {
        Ptrs6 s;
        s.p[0] = ff1_w1; s.p[1] = ff2_w1; s.p[2] = ff3_w1;
        s.p[3] = ff1_w2; s.p[4] = ff2_w2; s.p[5] = ff3_w2;
        hipLaunchKernelGGL(tff, dim3(32, 32, 6), tb, 0, stream, s, wbFf1);
    }

    auto gemm = [&](PtrsB Bp, PtrsD Db, const ushortT* A, float* oF,
                    int M, int Ncc, int Kc, const float* bias, const float* res,
                    const float* alp, int relu, int nroute, int vtmask, int scmask) {
        hipLaunchKernelGGL(gemm_bf, dim3(Ncc / 128, M / 128), tb, 0, stream,
                           Bp, Db, A, oF, M, Ncc, Kc, bias, res, alp, relu, nroute,
                           vtmask, scmask);
    };
    auto g64 = [&](const ushortT* Bw, const ushortT* A, float* oF, ushortT* oB,
                   int M, int Ncc, int Kc, const float* bias, const float* resf,
                   const ushortT* resb, const float* alp, int relu) {
        hipLaunchKernelGGL(gemm64, dim3(Ncc / 128, M / 64), tb, 0, stream,
                           Bw, A, oF, oB, M, Ncc, Kc, bias, resf, resb, alp, relu);
    };
    auto uni = [&](const ushortT* w) { PtrsB b; for (int i = 0; i < 12; ++i) b.p[i] = w; return b; };
    auto d1 = [&](ushortT* d) { PtrsD dd = {}; dd.p[0] = d; return dd; };

    // 2. HA projections: ONE fused GEMM, N=3072 (Q/QA/QB/QD pre-scaled, scmask=57)
    {
        PtrsB b;
        b.p[0] = b.p[1] = wbHead + 0 * WS;
        b.p[2] = b.p[3] = wbHead + 1 * WS;
        b.p[4] = b.p[5] = wbHead + 2 * WS;
        b.p[6] = wbHead + 4 * WS; b.p[7] = wbHead + 8 * WS;
        b.p[8] = wbHead + 5 * WS; b.p[9] = wbHead + 7 * WS;
        b.p[10] = wbHead + 3 * WS; b.p[11] = wbHead + 6 * WS;
        PtrsD d; d.p[0] = bufQ; d.p[1] = bufK; d.p[2] = bufVt;
        d.p[3] = bufQA; d.p[4] = bufQB; d.p[5] = bufQD;
        gemm(b, d, xbf, nullptr, TOK, 3072, 512, nullptr, nullptr, nullptr, 0, 6, 4, 57);
    }

    // 3. HA attention
    hipLaunchKernelGGL(diag_dot_bb, dim3(Bb * Nn * Hh / 256), tb, 0, stream, bufQD, bufK, Sd);
    hipLaunchKernelGGL((attn9<1>), dim3(Nn / 64, Hh, Bb), tb, 0, stream,
                       bufQ, bufK, bufVt, bufQA, bufQB, Sd, bufHA);

    // 4. comb3 + FF3 (bf16 residual stream)
    g64(wbComb + 2 * WS, bufHA, nullptr, curb, TOK, 512, 512, comb3_b, x, nullptr, alpha3, 0);
    gemm(uni(wbFf1 + 2 * WF), d1(hidden), curb, nullptr, TOK, 2048, 512, ff3_b1, nullptr, nullptr, 1, 0, 0, 0);
    g64(wbFf2 + 2 * WF, hidden, nullptr, curb, TOK, 512, 2048, ff3_b2, nullptr, curb, ffa3, 0);

    // 5. MHA1
    {
        PtrsB b;
        b.p[0] = b.p[1] = wbMha + 0 * WS;
        b.p[2] = b.p[3] = wbMha + 1 * WS;
        b.p[4] = b.p[5] = wbMha + 2 * WS;
        PtrsD d = {}; d.p[0] = bufQ; d.p[1] = bufK; d.p[2] = bufVt;
        gemm(b, d, curb, nullptr, TOK, 1536, 512, nullptr, nullptr, nullptr, 0, 3, 4, 1);
    }
    hipLaunchKernelGGL((attn9<0>), dim3(Nn / 64, Hh, Bb), tb, 0, stream,
                       bufQ, bufK, bufVt, nullptr, nullptr, nullptr, bufHA);
    g64(wbComb + 0 * WS, bufHA, nullptr, curb, TOK, 512, 512, comb_b, nullptr, curb, alpha1, 0);
    gemm(uni(wbFf1 + 0 * WF), d1(hidden), curb, nullptr, TOK, 2048, 512, ff1_b1, nullptr, nullptr, 1, 0, 0, 0);
    g64(wbFf2 + 0 * WF, hidden, nullptr, curb, TOK, 512, 2048, ff1_b2, nullptr, curb, ffa1, 0);

    // 6. MHA2
    {
        PtrsB b;
        b.p[0] = wbMha + 3 * WS; b.p[1] = wbMha + 4 * WS;
        b.p[2] = b.p[3] = wbMha + 5 * WS;
        b.p[4] = b.p[5] = wbMha + 6 * WS;
        PtrsD d = {}; d.p[0] = bufQ; d.p[1] = bufK; d.p[2] = bufVt;
        gemm(b, d, curb, nullptr, TOK, 1536, 512, nullptr, nullptr, nullptr, 0, 3, 4, 1);
    }
    hipLaunchKernelGGL((attn9<0>), dim3(Nn / 64, Hh, Bb), tb, 0, stream,
                       bufQ, bufK, bufVt, nullptr, nullptr, nullptr, bufHA);
    g64(wbComb + 1 * WS, bufHA, nullptr, curb, TOK, 512, 512, comb2_b, nullptr, curb, alpha2, 0);
    gemm(uni(wbFf1 + 1 * WF), d1(hidden), curb, nullptr, TOK, 2048, 512, ff2_b1, nullptr, nullptr, 1, 0, 0, 0);
    // final: write f32 d_out
    g64(wbFf2 + 1 * WF, hidden, cur, nullptr, TOK, 512, 2048, ff2_b2, nullptr, curb, ffa2, 0);
}

// Round 13
// 474.881 us; speedup vs baseline: 10.6062x; 1.0579x over previous
//
#include <hip/hip_runtime.h>
#include <math.h>

#define Hh 8
#define Bb 16
#define Nn 512
#define Dd 512
#define VDd 64
#define NPICKk 256
#define NORMF 0.125f
#define SCL2 0.1803368801f   /* NORMF * log2(e) */

typedef unsigned short ushortT;
typedef __bf16 bf16x8 __attribute__((ext_vector_type(8)));
typedef float f32x4 __attribute__((ext_vector_type(4)));

struct PtrsB { const ushortT* p[12]; };
struct PtrsD { ushortT* p[6]; };
struct Ptrs9 { const float* p[9]; };
struct Ptrs10 { const float* p[10]; };
struct Ptrs6 { const float* p[6]; };

__device__ inline ushortT f2bf(float f) {
    __bf16 h = (__bf16)f;
    union { __bf16 h; ushortT u; } v; v.h = h;
    return v.u;
}
__device__ inline float bf2f(ushortT u) {
    union { unsigned int u; float f; } v; v.u = ((unsigned int)u) << 16;
    return v.f;
}
__device__ inline float exp2fast(float x) {
#if __has_builtin(__builtin_amdgcn_exp2f)
    return __builtin_amdgcn_exp2f(x);
#else
    return exp2f(x);
#endif
}
__device__ inline void gload16(const void* gptr, void* ldsptr) {
    auto g = reinterpret_cast<const __attribute__((address_space(1))) unsigned int*>(
        reinterpret_cast<uintptr_t>(gptr));
    auto l = reinterpret_cast<__attribute__((address_space(3))) unsigned int*>(
        reinterpret_cast<uintptr_t>(ldsptr));
    __builtin_amdgcn_global_load_lds(g, l, 16, 0, 0);
}

#define LIX(r, g) (((r) << 6) + ((((g) ^ ((r) & 7))) << 3))

// ---------- fp32 -> bf16 elementwise ----------
__global__ __launch_bounds__(256) void castx(const float* __restrict__ in,
                                             ushortT* __restrict__ out) {
    int i = blockIdx.x * 256 + threadIdx.x;
    float4 v = *(const float4*)&in[(size_t)i * 4];
    ushort4 o; o.x = f2bf(v.x); o.y = f2bf(v.y); o.z = f2bf(v.z); o.w = f2bf(v.w);
    *(ushort4*)&out[(size_t)i * 4] = o;
}

// ---------- transpose+cast body ----------
__device__ inline void tbody(const float* __restrict__ in, ushortT* __restrict__ out,
                             int in_ld, int out_ld, int r0, int c0) {
    __shared__ float T[64][65];
    int tr = threadIdx.x >> 4, tc4 = (threadIdx.x & 15) * 4;
#pragma unroll
    for (int p = 0; p < 4; ++p) {
        float4 v = *(const float4*)&in[(size_t)(r0 + tr + p * 16) * in_ld + c0 + tc4];
        T[tr + p * 16][tc4 + 0] = v.x; T[tr + p * 16][tc4 + 1] = v.y;
        T[tr + p * 16][tc4 + 2] = v.z; T[tr + p * 16][tc4 + 3] = v.w;
    }
    __syncthreads();
#pragma unroll
    for (int p = 0; p < 4; ++p) {
        int orow = c0 + tr + p * 16;
        int ocol = r0 + tc4;
        ushort4 o;
        o.x = f2bf(T[tc4 + 0][tr + p * 16]);
        o.y = f2bf(T[tc4 + 1][tr + p * 16]);
        o.z = f2bf(T[tc4 + 2][tr + p * 16]);
        o.w = f2bf(T[tc4 + 3][tr + p * 16]);
        *(ushort4*)&out[(size_t)orow * out_ld + ocol] = o;
    }
}

__global__ __launch_bounds__(256) void thead(Ptrs9 s, ushortT* __restrict__ dst) {
    int w = blockIdx.z >> 3, h = blockIdx.z & 7;
    tbody(s.p[w] + (size_t)h * 512 * 64,
          dst + (size_t)w * 262144 + (size_t)h * 64 * 512,
          64, 512, blockIdx.y * 64, 0);
}
__global__ __launch_bounds__(256) void tsq(Ptrs10 s, ushortT* __restrict__ dst) {
    tbody(s.p[blockIdx.z], dst + (size_t)blockIdx.z * 262144,
          512, 512, blockIdx.y * 64, blockIdx.x * 64);
}
__global__ __launch_bounds__(256) void tff(Ptrs6 s, ushortT* __restrict__ dst) {
    int z = blockIdx.z;
    if (z < 3) { if (blockIdx.y >= 8 || blockIdx.x >= 32) return; }
    else       { if (blockIdx.y >= 32 || blockIdx.x >= 8) return; }
    int in_ld = (z < 3) ? 2048 : 512;
    int out_ld = (z < 3) ? 512 : 2048;
    tbody(s.p[z], dst + (size_t)z * 1048576, in_ld, out_ld,
          blockIdx.y * 64, blockIdx.x * 64);
}

// ---------- 128x128 bf16 MFMA GEMM (routed / standard epilogues) ----------
__global__ __launch_bounds__(256) void gemm_bf(
    PtrsB Bp, PtrsD Db, const ushortT* __restrict__ A, float* __restrict__ outF,
    int M, int N, int K, const float* __restrict__ bias,
    const float* __restrict__ res, const float* __restrict__ alpha,
    int do_relu, int nroute, int vtmask, int scmask)
{
    __shared__ __align__(16) ushortT As[128 * 64];
    __shared__ __align__(16) ushortT Bs[128 * 64];
    const int tid = threadIdx.x;
    const int wid = tid >> 6, lane = tid & 63;
    const int wm = wid >> 1, wn = wid & 1;
    const int l15 = lane & 15, l4 = lane >> 4;

    int bid = blockIdx.y * gridDim.x + blockIdx.x;
    int nwg = gridDim.x * gridDim.y;
    int q = nwg >> 3;
    int swz = (bid & 7) * q + (bid >> 3);
    int bx = swz % gridDim.x, by = swz / gridDim.x;

    const int r0 = by * 128, c0 = bx * 128;
    const int half = ((r0 & (Nn - 1)) >= NPICKk) ? 1 : 0;
    const ushortT* Bt = Bp.p[((c0 >> 9) << 1) | half];
    const int cB = nroute ? (c0 & 511) : c0;

    const ushortT* aSrc[4];
    const ushortT* bSrc[4];
    char* ldsA[4];
    char* ldsB[4];
#pragma unroll
    for (int i = 0; i < 4; ++i) {
        int off = wid * 4096 + i * 1024 + lane * 16;
        int row = off >> 7;
        int sg = ((off >> 4) & 7) ^ (row & 7);
        aSrc[i] = A + (size_t)(r0 + row) * K + sg * 8;
        bSrc[i] = Bt + (size_t)(cB + row) * K + sg * 8;
        ldsA[i] = (char*)As + off;
        ldsB[i] = (char*)Bs + off;
    }

    f32x4 acc[4][4] = {};

    for (int kt = 0; kt < K; kt += 64) {
        __syncthreads();
#pragma unroll
        for (int i = 0; i < 4; ++i) {
            gload16(aSrc[i] + kt, ldsA[i]);
            gload16(bSrc[i] + kt, ldsB[i]);
        }
        asm volatile("s_waitcnt vmcnt(0)" ::: "memory");
        __syncthreads();
#pragma unroll
        for (int kk = 0; kk < 2; ++kk) {
            int g0 = kk * 4 + l4;
            bf16x8 af[4], bfv[4];
#pragma unroll
            for (int mi = 0; mi < 4; ++mi)
                af[mi] = *(const bf16x8*)&As[LIX(wm * 64 + mi * 16 + l15, g0)];
#pragma unroll
            for (int ni = 0; ni < 4; ++ni)
                bfv[ni] = *(const bf16x8*)&Bs[LIX(wn * 64 + ni * 16 + l15, g0)];
#pragma unroll
            for (int mi = 0; mi < 4; ++mi)
#pragma unroll
                for (int ni = 0; ni < 4; ++ni)
                    acc[mi][ni] = __builtin_amdgcn_mfma_f32_16x16x32_bf16(
                        bfv[ni], af[mi], acc[mi][ni], 0, 0, 0);   // C^T fragment
        }
    }

    if (nroute) {
#pragma unroll
        for (int mi = 0; mi < 4; ++mi) {
            int row = r0 + wm * 64 + mi * 16 + l15;
#pragma unroll
            for (int ni = 0; ni < 4; ++ni) {
                int col = c0 + wn * 64 + ni * 16 + l4 * 4;
                int range = col >> 9, cc = col & 511;
                ushortT* d = Db.p[range];
                f32x4 a = acc[mi][ni];
                if ((scmask >> range) & 1) {
                    a[0] *= SCL2; a[1] *= SCL2; a[2] *= SCL2; a[3] *= SCL2;
                }
                if ((vtmask >> range) & 1) {
                    size_t vb = ((size_t)(row >> 9) * Hh + (cc >> 6)) * 64 + (cc & 63);
                    int tok = row & 511;
#pragma unroll
                    for (int r = 0; r < 4; ++r)
                        d[((vb + r) << 9) + tok] = f2bf(a[r]);
                } else {
                    ushort4 o;
                    o.x = f2bf(a[0]); o.y = f2bf(a[1]);
                    o.z = f2bf(a[2]); o.w = f2bf(a[3]);
                    *(ushort4*)&d[((size_t)row << 9) + cc] = o;
                }
            }
        }
    } else {
        const float alp = alpha ? alpha[0] : 1.0f;
        ushortT* outB = Db.p[0];
#pragma unroll
        for (int mi = 0; mi < 4; ++mi) {
            int row = r0 + wm * 64 + mi * 16 + l15;
#pragma unroll
            for (int ni = 0; ni < 4; ++ni) {
                int colb = c0 + wn * 64 + ni * 16 + l4 * 4;
                f32x4 a = acc[mi][ni];
                if (bias) {
                    float4 b4 = *(const float4*)&bias[colb];
                    a[0] += b4.x; a[1] += b4.y; a[2] += b4.z; a[3] += b4.w;
                }
                if (do_relu) {
#pragma unroll
                    for (int r = 0; r < 4; ++r) a[r] = fmaxf(a[r], 0.f);
                }
#pragma unroll
                for (int r = 0; r < 4; ++r) a[r] *= alp;
                size_t idx = (size_t)row * N + colb;
                if (res) {
                    float4 r4 = *(const float4*)&res[idx];
                    a[0] += r4.x; a[1] += r4.y; a[2] += r4.z; a[3] += r4.w;
                }
                if (outF)
                    *(float4*)&outF[idx] = make_float4(a[0], a[1], a[2], a[3]);
                if (outB) {
                    ushort4 o;
                    o.x = f2bf(a[0]); o.y = f2bf(a[1]);
                    o.z = f2bf(a[2]); o.w = f2bf(a[3]);
                    *(ushort4*)&outB[idx] = o;
                }
            }
        }
    }
}

// ---------- 64x128 bf16 MFMA GEMM; residual f32 (resf) or bf16 (resb) ----------
__global__ __launch_bounds__(256) void gemm64(
    const ushortT* __restrict__ Bw, const ushortT* __restrict__ A,
    float* __restrict__ outF, ushortT* __restrict__ outB,
    int M, int N, int K, const float* __restrict__ bias,
    const float* __restrict__ resf, const ushortT* __restrict__ resb,
    const float* __restrict__ alpha, int do_relu)
{
    __shared__ __align__(16) ushortT As[64 * 64];
    __shared__ __align__(16) ushortT Bs[128 * 64];
    const int tid = threadIdx.x;
    const int wid = tid >> 6, lane = tid & 63;
    const int wm = wid >> 1, wn = wid & 1;
    const int l15 = lane & 15, l4 = lane >> 4;

    int bid = blockIdx.y * gridDim.x + blockIdx.x;
    int nwg = gridDim.x * gridDim.y;
    int q = nwg >> 3;
    int swz = (bid & 7) * q + (bid >> 3);
    int bx = swz % gridDim.x, by = swz / gridDim.x;
    const int r0 = by * 64, c0 = bx * 128;

    const ushortT* aSrc[2];
    char* ldsA[2];
#pragma unroll
    for (int i = 0; i < 2; ++i) {
        int off = wid * 2048 + i * 1024 + lane * 16;
        int row = off >> 7;
        int sg = ((off >> 4) & 7) ^ (row & 7);
        aSrc[i] = A + (size_t)(r0 + row) * K + sg * 8;
        ldsA[i] = (char*)As + off;
    }
    const ushortT* bSrc[4];
    char* ldsB[4];
#pragma unroll
    for (int i = 0; i < 4; ++i) {
        int off = wid * 4096 + i * 1024 + lane * 16;
        int row = off >> 7;
        int sg = ((off >> 4) & 7) ^ (row & 7);
        bSrc[i] = Bw + (size_t)(c0 + row) * K + sg * 8;
        ldsB[i] = (char*)Bs + off;
    }

    f32x4 acc[2][4] = {};

    for (int kt = 0; kt < K; kt += 64) {
        __syncthreads();
#pragma unroll
        for (int i = 0; i < 2; ++i) gload16(aSrc[i] + kt, ldsA[i]);
#pragma unroll
        for (int i = 0; i < 4; ++i) gload16(bSrc[i] + kt, ldsB[i]);
        asm volatile("s_waitcnt vmcnt(0)" ::: "memory");
        __syncthreads();
#pragma unroll
        for (int kk = 0; kk < 2; ++kk) {
            int g0 = kk * 4 + l4;
            bf16x8 af[2], bfv[4];
#pragma unroll
            for (int mi = 0; mi < 2; ++mi)
                af[mi] = *(const bf16x8*)&As[LIX(wm * 32 + mi * 16 + l15, g0)];
#pragma unroll
            for (int ni = 0; ni < 4; ++ni)
                bfv[ni] = *(const bf16x8*)&Bs[LIX(wn * 64 + ni * 16 + l15, g0)];
#pragma unroll
            for (int mi = 0; mi < 2; ++mi)
#pragma unroll
                for (int ni = 0; ni < 4; ++ni)
                    acc[mi][ni] = __builtin_amdgcn_mfma_f32_16x16x32_bf16(
                        bfv[ni], af[mi], acc[mi][ni], 0, 0, 0);
        }
    }

    const float alp = alpha ? alpha[0] : 1.0f;
#pragma unroll
    for (int mi = 0; mi < 2; ++mi) {
        int row = r0 + wm * 32 + mi * 16 + l15;
#pragma unroll
        for (int ni = 0; ni < 4; ++ni) {
            int colb = c0 + wn * 64 + ni * 16 + l4 * 4;
            f32x4 a = acc[mi][ni];
            if (bias) {
                float4 b4 = *(const float4*)&bias[colb];
                a[0] += b4.x; a[1] += b4.y; a[2] += b4.z; a[3] += b4.w;
            }
            if (do_relu) {
#pragma unroll
                for (int r = 0; r < 4; ++r) a[r] = fmaxf(a[r], 0.f);
            }
#pragma unroll
            for (int r = 0; r < 4; ++r) a[r] *= alp;
            size_t idx = (size_t)row * N + colb;
            if (resf) {
                float4 r4 = *(const float4*)&resf[idx];
                a[0] += r4.x; a[1] += r4.y; a[2] += r4.z; a[3] += r4.w;
            }
            if (resb) {
                ushort4 r4 = *(const ushort4*)&resb[idx];
                a[0] += bf2f(r4.x); a[1] += bf2f(r4.y);
                a[2] += bf2f(r4.z); a[3] += bf2f(r4.w);
            }
            if (outF)
                *(float4*)&outF[idx] = make_float4(a[0], a[1], a[2], a[3]);
            if (outB) {
                ushort4 o;
                o.x = f2bf(a[0]); o.y = f2bf(a[1]);
                o.z = f2bf(a[2]); o.w = f2bf(a[3]);
                *(ushort4*)&outB[idx] = o;
            }
        }
    }
}

// ---------- HA diagonal scores (QD pre-scaled by NORM*log2e) ----------
__global__ __launch_bounds__(256) void diag_dot_bb(const ushortT* __restrict__ QD,
                                                   const ushortT* __restrict__ K,
                                                   float* __restrict__ Sdg) {
    int i = blockIdx.x * 256 + threadIdx.x;
    int h = i & 7, n = (i >> 3) & 511, b = i >> 12;
    int dix = (n < NPICKk) ? n + NPICKk : n - NPICKk;
    const ushortT* q = QD + (((size_t)(b * Nn + n) * Hh + h) << 6);
    const ushortT* k = K + (((size_t)(b * Nn + dix) * Hh + h) << 6);
    float s = 0.f;
#pragma unroll
    for (int d = 0; d < 64; d += 4) {
        ushort4 a = *(const ushort4*)(q + d);
        ushort4 c = *(const ushort4*)(k + d);
        s += bf2f(a.x) * bf2f(c.x) + bf2f(a.y) * bf2f(c.y)
           + bf2f(a.z) * bf2f(c.z) + bf2f(a.w) * bf2f(c.w);
    }
    Sdg[i] = s;
}

// ---------- flash attention: T14 reg-staged double-buffered K/V, lazy max, deferred L ----------
template <int HA>
__global__ __launch_bounds__(256) void attn10(
    const ushortT* __restrict__ Qm, const ushortT* __restrict__ Km,
    const ushortT* __restrict__ Vtm, const ushortT* __restrict__ QAm,
    const ushortT* __restrict__ QBm, const float* __restrict__ Sdg,
    ushortT* __restrict__ Out)
{
    __shared__ __align__(16) ushortT Ks[64 * 64];
    __shared__ __align__(16) ushortT Vs[64 * 64];
    __shared__ __align__(16) ushortT Pw[4][16 * 64];
    __shared__ float sdl[64];

    const int tid = threadIdx.x, wid = tid >> 6, lane = tid & 63;
    const int l15 = lane & 15, l4 = lane >> 4;

    // XCD-bijective remap: blocks sharing (b,h) -> same XCD L2
    const int p = blockIdx.x + (blockIdx.y << 3) + (blockIdx.z << 6);
    const int n0 = (((p >> 3) & 7)) << 6;
    const int g8 = (p & 7) | ((p >> 6) << 3);
    const int h = g8 & 7, b = g8 >> 3;
    const int bh = b * Hh + h;

    // Q/QA/QB fragments direct to registers
    const size_t qrow = (((size_t)(b * Nn + n0 + wid * 16 + l15) * Hh + h) << 6);
    bf16x8 qf[2], xaf[2], xbf[2];
#pragma unroll
    for (int kk = 0; kk < 2; ++kk) {
        int g0 = kk * 4 + l4;
        qf[kk] = *(const bf16x8*)&Qm[qrow + g0 * 8];
        if (HA) {
            xaf[kk] = *(const bf16x8*)&QAm[qrow + g0 * 8];
            xbf[kk] = *(const bf16x8*)&QBm[qrow + g0 * 8];
        }
    }
    if (HA && tid < 64) sdl[tid] = Sdg[((size_t)(b * Nn + n0 + tid)) * Hh + h];
    const int td = (n0 < NPICKk) ? ((n0 + NPICKk) >> 6) : ((n0 - NPICKk) >> 6);

    const ushortT* kSrc[2]; ushortT* kDst[2];
    const ushortT* vSrc[2]; ushortT* vDst[2];
#pragma unroll
    for (int i = 0; i < 2; ++i) {
        int off = wid * 2048 + i * 1024 + lane * 16;
        int row = off >> 7, sg = ((off >> 4) & 7) ^ (row & 7);
        kSrc[i] = Km + (((size_t)(b * Nn + row) * Hh + h) << 6) + sg * 8;
        kDst[i] = (ushortT*)((char*)Ks + off);
        vSrc[i] = Vtm + (((size_t)(bh * 64 + row)) << 9) + sg * 8;
        vDst[i] = (ushortT*)((char*)Vs + off);
    }

    float M[4], Lp[4];
    f32x4 Oa[4] = {};
#pragma unroll
    for (int r = 0; r < 4; ++r) { M[r] = -INFINITY; Lp[r] = 0.f; }

    // prologue: tile 0 into regs
    bf16x8 krbuf[2][2], vrbuf[2][2];
#pragma unroll
    for (int i = 0; i < 2; ++i) {
        krbuf[0][i] = *(const bf16x8*)kSrc[i];
        vrbuf[0][i] = *(const bf16x8*)vSrc[i];
    }

#pragma unroll
    for (int t = 0; t < 8; ++t) {
        const int cur = t & 1, nxt = cur ^ 1;
        __builtin_amdgcn_s_barrier();   // all waves done reading Ks/Vs (prev tile)
#pragma unroll
        for (int i = 0; i < 2; ++i) {
            *(bf16x8*)kDst[i] = krbuf[cur][i];
            *(bf16x8*)vDst[i] = vrbuf[cur][i];
        }
        if (t < 7) {   // prefetch t+1 (stays in flight across this tile's compute)
#pragma unroll
            for (int i = 0; i < 2; ++i) {
                krbuf[nxt][i] = *(const bf16x8*)(kSrc[i] + (size_t)(t + 1) * (64 * Hh * VDd));
                vrbuf[nxt][i] = *(const bf16x8*)(vSrc[i] + (t + 1) * 64);
            }
        }
        asm volatile("s_waitcnt lgkmcnt(0)" ::: "memory");  // own ds_writes done
        __builtin_amdgcn_s_barrier();                        // all writes visible
        __builtin_amdgcn_sched_barrier(0);

        // ---- S = Q K^T ----
        __builtin_amdgcn_s_setprio(1);
        f32x4 s1[4] = {}, sX[4] = {};
#pragma unroll
        for (int kk = 0; kk < 2; ++kk) {
            bf16x8 aq = qf[kk];
            bf16x8 ax;
            if (HA) ax = (t >= 4) ? xbf[kk] : xaf[kk];
#pragma unroll
            for (int ni = 0; ni < 4; ++ni) {
                bf16x8 bk = *(const bf16x8*)&Ks[LIX(ni * 16 + l15, kk * 4 + l4)];
                s1[ni] = __builtin_amdgcn_mfma_f32_16x16x32_bf16(aq, bk, s1[ni], 0, 0, 0);
                if (HA)
                    sX[ni] = __builtin_amdgcn_mfma_f32_16x16x32_bf16(ax, bk, sX[ni], 0, 0, 0);
            }
        }
        __builtin_amdgcn_s_setprio(0);

        const bool dt = HA && (t == td);

        // ---- lazy max: lane-local maxes; full reduce+rescale only on growth ----
        float mloc[4];
        bool grow = false;
#pragma unroll
        for (int r = 0; r < 4; ++r) {
            int rw = wid * 16 + l4 * 4 + r;
            float m = s1[0][r];
#pragma unroll
            for (int ni = 1; ni < 4; ++ni) m = fmaxf(m, s1[ni][r]);
            if (HA) {
#pragma unroll
                for (int ni = 0; ni < 4; ++ni) m = fmaxf(m, sX[ni][r]);
            }
            if (dt && l15 == l4 * 4 + r) m = fmaxf(m, sdl[rw]);
            mloc[r] = m;
            grow = grow || (m > M[r] + 8.f);
        }
        if (__any(grow)) {
#pragma unroll
            for (int r = 0; r < 4; ++r) {
                float m = mloc[r];
#pragma unroll
                for (int o = 8; o >= 1; o >>= 1) m = fmaxf(m, __shfl_xor(m, o, 16));
                float mn = fmaxf(M[r], m);
                float sc = exp2fast(M[r] - mn);
                M[r] = mn; Lp[r] *= sc;
#pragma unroll
                for (int ni = 0; ni < 4; ++ni) Oa[ni][r] *= sc;
            }
        }

        // ---- P = exp2(S - M); per-lane partial L (deferred reduce) ----
#pragma unroll
        for (int r = 0; r < 4; ++r) {
            int rw = wid * 16 + l4 * 4 + r;
            float rs = 0.f;
#pragma unroll
            for (int ni = 0; ni < 4; ++ni) {
                float pv = exp2fast(s1[ni][r] - M[r]);
                if (HA) pv += exp2fast(sX[ni][r] - M[r]);
                if (dt && ni == wid && l15 == l4 * 4 + r) pv += exp2fast(sdl[rw] - M[r]);
                s1[ni][r] = pv;
                rs += pv;
            }
            Lp[r] += rs;
        }

        // ---- write P into wave-private strip (no barrier) ----
#pragma unroll
        for (int ni = 0; ni < 4; ++ni)
#pragma unroll
            for (int r = 0; r < 4; ++r) {
                int prow = l4 * 4 + r;
                int col = ni * 16 + l15;
                Pw[wid][(prow << 6) + ((((col >> 3) ^ (prow & 7))) << 3) + (col & 7)] =
                    f2bf(s1[ni][r]);
            }

        // ---- O += P @ V ----
        __builtin_amdgcn_s_setprio(1);
#pragma unroll
        for (int kk = 0; kk < 2; ++kk) {
            int g0 = kk * 4 + l4;
            bf16x8 ap = *(const bf16x8*)&Pw[wid][LIX(l15, g0)];
#pragma unroll
            for (int ni = 0; ni < 4; ++ni) {
                bf16x8 bv = *(const bf16x8*)&Vs[LIX(ni * 16 + l15, g0)];
                Oa[ni] = __builtin_amdgcn_mfma_f32_16x16x32_bf16(ap, bv, Oa[ni], 0, 0, 0);
            }
        }
        __builtin_amdgcn_s_setprio(0);
    }

#pragma unroll
    for (int r = 0; r < 4; ++r) {
        float l = Lp[r];
#pragma unroll
        for (int o = 8; o >= 1; o >>= 1) l += __shfl_xor(l, o, 16);
        float inv = 1.0f / l;
        size_t obase = (((size_t)(b * Nn + n0 + wid * 16 + l4 * 4 + r) * Hh + h) << 6);
#pragma unroll
        for (int ni = 0; ni < 4; ++ni)
            Out[obase + ni * 16 + l15] = f2bf(Oa[ni][r] * inv);
    }
}

extern "C" void kernel_launch(void* const* d_in, const int* in_sizes, int n_in,
                              void* d_out, int out_size, void* d_ws, size_t ws_size,
                              hipStream_t stream)
{
    const float* x = (const float*)d_in[0];

    int dictOrder = (in_sizes[18] != 512);
    const float* comb_w  = (const float*)d_in[17];
    const float* comb2_w = (const float*)d_in[dictOrder ? 18 : 19];
    const float* comb3_w = (const float*)d_in[dictOrder ? 19 : 21];
    const float* comb_b  = (const float*)d_in[dictOrder ? 20 : 18];
    const float* comb2_b = (const float*)d_in[dictOrder ? 21 : 20];
    const float* comb3_b = (const float*)d_in[22];
    const float* alpha1 = (const float*)d_in[23];
    const float* alpha2 = (const float*)d_in[24];
    const float* alpha3 = (const float*)d_in[25];
    const float* ff1_w1 = (const float*)d_in[26];
    const float* ff1_b1 = (const float*)d_in[27];
    const float* ff1_w2 = (const float*)d_in[28];
    const float* ff1_b2 = (const float*)d_in[29];
    const float* ffa1   = (const float*)d_in[30];
    const float* ff2_w1 = (const float*)d_in[31];
    const float* ff2_b1 = (const float*)d_in[32];
    const float* ff2_w2 = (const float*)d_in[33];
    const float* ff2_b2 = (const float*)d_in[34];
    const float* ffa2   = (const float*)d_in[35];
    const float* ff3_w1 = (const float*)d_in[36];
    const float* ff3_b1 = (const float*)d_in[37];
    const float* ff3_w2 = (const float*)d_in[38];
    const float* ff3_b2 = (const float*)d_in[39];
    const float* ffa3   = (const float*)d_in[40];

    // ---- workspace layout (bytes) ----
    char* W = (char*)d_ws;
    ushortT* wbHead = (ushortT*)(W + 0);
    ushortT* wbMha  = (ushortT*)(W + 4718592);
    ushortT* wbComb = (ushortT*)(W + 8388608);
    ushortT* wbFf1  = (ushortT*)(W + 9961472);
    ushortT* wbFf2  = (ushortT*)(W + 16252928);
    ushortT* xbf    = (ushortT*)(W + 22544384);
    float*   Sd     = (float*)  (W + 30932992);
    ushortT* bufQ   = (ushortT*)(W + 31195136);
    ushortT* bufK   = (ushortT*)(W + 39583744);
    ushortT* bufVt  = (ushortT*)(W + 47972352);
    ushortT* bufQA  = (ushortT*)(W + 56360960);
    ushortT* bufQB  = (ushortT*)(W + 64749568);
    ushortT* bufQD  = (ushortT*)(W + 73138176);
    ushortT* hidden = (ushortT*)(W + 81526784);
    ushortT* curb   = (ushortT*)(W + 115081216);
    ushortT* bufHA  = xbf;
    float*   cur    = (float*)d_out;

    dim3 tb(256);
    const int TOK = Bb * Nn;  // 8192
    const size_t WS = 512 * 512;
    const size_t WF = 2048 * 512;

    // 1. casts / transposes (batched)
    hipLaunchKernelGGL(castx, dim3(TOK * 512 / 1024), tb, 0, stream, x, xbf);
    {
        Ptrs9 s; for (int i = 0; i < 9; ++i) s.p[i] = (const float*)d_in[1 + i];
        hipLaunchKernelGGL(thead, dim3(1, 8, 72), tb, 0, stream, s, wbHead);
    }
    {
        Ptrs10 s;
        for (int i = 0; i < 7; ++i) s.p[i] = (const float*)d_in[10 + i];
        s.p[7] = comb_w; s.p[8] = comb2_w; s.p[9] = comb3_w;
        hipLaunchKernelGGL(tsq, dim3(8, 8, 10), tb, 0, stream, s, wbMha);
    }
    {
        Ptrs6 s;
        s.p[0] = ff1_w1; s.p[1] = ff2_w1; s.p[2] = ff3_w1;
        s.p[3] = ff1_w2; s.p[4] = ff2_w2; s.p[5] = ff3_w2;
        hipLaunchKernelGGL(tff, dim3(32, 32, 6), tb, 0, stream, s, wbFf1);
    }

    auto gemm = [&](PtrsB Bp, PtrsD Db, const ushortT* A, float* oF,
                    int M, int Ncc, int Kc, const float* bias, const float* res,
                    const float* alp, int relu, int nroute, int vtmask, int scmask) {
        hipLaunchKernelGGL(gemm_bf, dim3(Ncc / 128, M / 128), tb, 0, stream,
                           Bp, Db, A, oF, M, Ncc, Kc, bias, res, alp, relu, nroute,
                           vtmask, scmask);
    };
    auto g64 = [&](const ushortT* Bw, const ushortT* A, float* oF, ushortT* oB,
                   int M, int Ncc, int Kc, const float* bias, const float* resf,
                   const ushortT* resb, const float* alp, int relu) {
        hipLaunchKernelGGL(gemm64, dim3(Ncc / 128, M / 64), tb, 0, stream,
                           Bw, A, oF, oB, M, Ncc, Kc, bias, resf, resb, alp, relu);
    };
    auto uni = [&](const ushortT* w) { PtrsB b; for (int i = 0; i < 12; ++i) b.p[i] = w; return b; };
    auto d1 = [&](ushortT* d) { PtrsD dd = {}; dd.p[0] = d; return dd; };

    // 2. HA projections: ONE fused GEMM, N=3072 (Q/QA/QB/QD pre-scaled, scmask=57)
    {
        PtrsB b;
        b.p[0] = b.p[1] = wbHead + 0 * WS;
        b.p[2] = b.p[3] = wbHead + 1 * WS;
        b.p[4] = b.p[5] = wbHead + 2 * WS;
        b.p[6] = wbHead + 4 * WS; b.p[7] = wbHead + 8 * WS;
        b.p[8] = wbHead + 5 * WS; b.p[9] = wbHead + 7 * WS;
        b.p[10] = wbHead + 3 * WS; b.p[11] = wbHead + 6 * WS;
        PtrsD d; d.p[0] = bufQ; d.p[1] = bufK; d.p[2] = bufVt;
        d.p[3] = bufQA; d.p[4] = bufQB; d.p[5] = bufQD;
        gemm(b, d, xbf, nullptr, TOK, 3072, 512, nullptr, nullptr, nullptr, 0, 6, 4, 57);
    }

    // 3. HA attention
    hipLaunchKernelGGL(diag_dot_bb, dim3(Bb * Nn * Hh / 256), tb, 0, stream, bufQD, bufK, Sd);
    hipLaunchKernelGGL((attn10<1>), dim3(Nn / 64, Hh, Bb), tb, 0, stream,
                       bufQ, bufK, bufVt, bufQA, bufQB, Sd, bufHA);

    // 4. comb3 + FF3 (bf16 residual stream)
    g64(wbComb + 2 * WS, bufHA, nullptr, curb, TOK, 512, 512, comb3_b, x, nullptr, alpha3, 0);
    gemm(uni(wbFf1 + 2 * WF), d1(hidden), curb, nullptr, TOK, 2048, 512, ff3_b1, nullptr, nullptr, 1, 0, 0, 0);
    g64(wbFf2 + 2 * WF, hidden, nullptr, curb, TOK, 512, 2048, ff3_b2, nullptr, curb, ffa3, 0);

    // 5. MHA1
    {
        PtrsB b;
        b.p[0] = b.p[1] = wbMha + 0 * WS;
        b.p[2] = b.p[3] = wbMha + 1 * WS;
        b.p[4] = b.p[5] = wbMha + 2 * WS;
        PtrsD d = {}; d.p[0] = bufQ; d.p[1] = bufK; d.p[2] = bufVt;
        gemm(b, d, curb, nullptr, TOK, 1536, 512, nullptr, nullptr, nullptr, 0, 3, 4, 1);
    }
    hipLaunchKernelGGL((attn10<0>), dim3(Nn / 64, Hh, Bb), tb, 0, stream,
                       bufQ, bufK, bufVt, nullptr, nullptr, nullptr, bufHA);
    g64(wbComb + 0 * WS, bufHA, nullptr, curb, TOK, 512, 512, comb_b, nullptr, curb, alpha1, 0);
    gemm(uni(wbFf1 + 0 * WF), d1(hidden), curb, nullptr, TOK, 2048, 512, ff1_b1, nullptr, nullptr, 1, 0, 0, 0);
    g64(wbFf2 + 0 * WF, hidden, nullptr, curb, TOK, 512, 2048, ff1_b2, nullptr, curb, ffa1, 0);

    // 6. MHA2
    {
        PtrsB b;
        b.p[0] = wbMha + 3 * WS; b.p[1] = wbMha + 4 * WS;
        b.p[2] = b.p[3] = wbMha + 5 * WS;
        b.p[4] = b.p[5] = wbMha + 6 * WS;
        PtrsD d = {}; d.p[0] = bufQ; d.p[1] = bufK; d.p[2] = bufVt;
        gemm(b, d, curb, nullptr, TOK, 1536, 512, nullptr, nullptr, nullptr, 0, 3, 4, 1);
    }
    hipLaunchKernelGGL((attn10<0>), dim3(Nn / 64, Hh, Bb), tb, 0, stream,
                       bufQ, bufK, bufVt, nullptr, nullptr, nullptr, bufHA);
    g64(wbComb + 1 * WS, bufHA, nullptr, curb, TOK, 512, 512, comb2_b, nullptr, curb, alpha2, 0);
    gemm(uni(wbFf1 + 1 * WF), d1(hidden), curb, nullptr, TOK, 2048, 512, ff2_b1, nullptr, nullptr, 1, 0, 0, 0);
    // final: write f32 d_out
    g64(wbFf2 + 1 * WF, hidden, cur, nullptr, TOK, 512, 2048, ff2_b2, nullptr, curb, ffa2, 0);
}

// Round 14
// 460.642 us; speedup vs baseline: 10.9340x; 1.0309x over previous
//
#include <hip/hip_runtime.h>
#include <math.h>

#define Hh 8
#define Bb 16
#define Nn 512
#define Dd 512
#define VDd 64
#define NPICKk 256
#define NORMF 0.125f
#define SCL2 0.1803368801f   /* NORMF * log2(e) */

typedef unsigned short ushortT;
typedef __bf16 bf16x8 __attribute__((ext_vector_type(8)));
typedef float f32x4 __attribute__((ext_vector_type(4)));

struct PtrsB { const ushortT* p[12]; };
struct PtrsD { ushortT* p[6]; };
struct Ptrs9 { const float* p[9]; };
struct Ptrs10 { const float* p[10]; };
struct Ptrs6 { const float* p[6]; };

__device__ inline ushortT f2bf(float f) {
    __bf16 h = (__bf16)f;
    union { __bf16 h; ushortT u; } v; v.h = h;
    return v.u;
}
__device__ inline float bf2f(ushortT u) {
    union { unsigned int u; float f; } v; v.u = ((unsigned int)u) << 16;
    return v.f;
}
__device__ inline float exp2fast(float x) {
#if __has_builtin(__builtin_amdgcn_exp2f)
    return __builtin_amdgcn_exp2f(x);
#else
    return exp2f(x);
#endif
}
__device__ inline void gload16(const void* gptr, void* ldsptr) {
    auto g = reinterpret_cast<const __attribute__((address_space(1))) unsigned int*>(
        reinterpret_cast<uintptr_t>(gptr));
    auto l = reinterpret_cast<__attribute__((address_space(3))) unsigned int*>(
        reinterpret_cast<uintptr_t>(ldsptr));
    __builtin_amdgcn_global_load_lds(g, l, 16, 0, 0);
}

#define LIX(r, g) (((r) << 6) + ((((g) ^ ((r) & 7))) << 3))

// ---------- fp32 -> bf16 elementwise ----------
__global__ __launch_bounds__(256) void castx(const float* __restrict__ in,
                                             ushortT* __restrict__ out) {
    int i = blockIdx.x * 256 + threadIdx.x;
    float4 v = *(const float4*)&in[(size_t)i * 4];
    ushort4 o; o.x = f2bf(v.x); o.y = f2bf(v.y); o.z = f2bf(v.z); o.w = f2bf(v.w);
    *(ushort4*)&out[(size_t)i * 4] = o;
}

// ---------- transpose+cast body ----------
__device__ inline void tbody(const float* __restrict__ in, ushortT* __restrict__ out,
                             int in_ld, int out_ld, int r0, int c0) {
    __shared__ float T[64][65];
    int tr = threadIdx.x >> 4, tc4 = (threadIdx.x & 15) * 4;
#pragma unroll
    for (int p = 0; p < 4; ++p) {
        float4 v = *(const float4*)&in[(size_t)(r0 + tr + p * 16) * in_ld + c0 + tc4];
        T[tr + p * 16][tc4 + 0] = v.x; T[tr + p * 16][tc4 + 1] = v.y;
        T[tr + p * 16][tc4 + 2] = v.z; T[tr + p * 16][tc4 + 3] = v.w;
    }
    __syncthreads();
#pragma unroll
    for (int p = 0; p < 4; ++p) {
        int orow = c0 + tr + p * 16;
        int ocol = r0 + tc4;
        ushort4 o;
        o.x = f2bf(T[tc4 + 0][tr + p * 16]);
        o.y = f2bf(T[tc4 + 1][tr + p * 16]);
        o.z = f2bf(T[tc4 + 2][tr + p * 16]);
        o.w = f2bf(T[tc4 + 3][tr + p * 16]);
        *(ushort4*)&out[(size_t)orow * out_ld + ocol] = o;
    }
}

__global__ __launch_bounds__(256) void thead(Ptrs9 s, ushortT* __restrict__ dst) {
    int w = blockIdx.z >> 3, h = blockIdx.z & 7;
    tbody(s.p[w] + (size_t)h * 512 * 64,
          dst + (size_t)w * 262144 + (size_t)h * 64 * 512,
          64, 512, blockIdx.y * 64, 0);
}
__global__ __launch_bounds__(256) void tsq(Ptrs10 s, ushortT* __restrict__ dst) {
    tbody(s.p[blockIdx.z], dst + (size_t)blockIdx.z * 262144,
          512, 512, blockIdx.y * 64, blockIdx.x * 64);
}
__global__ __launch_bounds__(256) void tff(Ptrs6 s, ushortT* __restrict__ dst) {
    int z = blockIdx.z;
    if (z < 3) { if (blockIdx.y >= 8 || blockIdx.x >= 32) return; }
    else       { if (blockIdx.y >= 32 || blockIdx.x >= 8) return; }
    int in_ld = (z < 3) ? 2048 : 512;
    int out_ld = (z < 3) ? 512 : 2048;
    tbody(s.p[z], dst + (size_t)z * 1048576, in_ld, out_ld,
          blockIdx.y * 64, blockIdx.x * 64);
}

// ---------- 128x128 bf16 MFMA GEMM, T4 counted-vmcnt LDS double-buffer ----------
__global__ __launch_bounds__(256) void gemm_bf(
    PtrsB Bp, PtrsD Db, const ushortT* __restrict__ A, float* __restrict__ outF,
    int M, int N, int K, const float* __restrict__ bias,
    const float* __restrict__ res, const float* __restrict__ alpha,
    int do_relu, int nroute, int vtmask, int scmask)
{
    __shared__ __align__(16) ushortT As[2][128 * 64];   // 32 KB
    __shared__ __align__(16) ushortT Bs[2][128 * 64];   // 32 KB
    const int tid = threadIdx.x;
    const int wid = tid >> 6, lane = tid & 63;
    const int wm = wid >> 1, wn = wid & 1;
    const int l15 = lane & 15, l4 = lane >> 4;

    int bid = blockIdx.y * gridDim.x + blockIdx.x;
    int nwg = gridDim.x * gridDim.y;
    int q = nwg >> 3;
    int swz = (bid & 7) * q + (bid >> 3);
    int bx = swz % gridDim.x, by = swz / gridDim.x;

    const int r0 = by * 128, c0 = bx * 128;
    const int half = ((r0 & (Nn - 1)) >= NPICKk) ? 1 : 0;
    const ushortT* Bt = Bp.p[((c0 >> 9) << 1) | half];
    const int cB = nroute ? (c0 & 511) : c0;

    const ushortT* aSrc[4];
    const ushortT* bSrc[4];
    int offv[4];
#pragma unroll
    for (int i = 0; i < 4; ++i) {
        int off = wid * 4096 + i * 1024 + lane * 16;
        int row = off >> 7;
        int sg = ((off >> 4) & 7) ^ (row & 7);
        aSrc[i] = A + (size_t)(r0 + row) * K + sg * 8;
        bSrc[i] = Bt + (size_t)(cB + row) * K + sg * 8;
        offv[i] = off;
    }

    const int nkt = K >> 6;
    // prologue: issue tiles 0 and 1 (16 loads outstanding)
#pragma unroll
    for (int i = 0; i < 4; ++i) {
        gload16(aSrc[i], (char*)As[0] + offv[i]);
        gload16(bSrc[i], (char*)Bs[0] + offv[i]);
    }
#pragma unroll
    for (int i = 0; i < 4; ++i) {
        gload16(aSrc[i] + 64, (char*)As[1] + offv[i]);
        gload16(bSrc[i] + 64, (char*)Bs[1] + offv[i]);
    }

    f32x4 acc[4][4] = {};

    for (int t = 0; t < nkt; ++t) {
        const int cur = t & 1;
        if (t == nkt - 1) asm volatile("s_waitcnt vmcnt(0)" ::: "memory");
        else              asm volatile("s_waitcnt vmcnt(8)" ::: "memory");
        __builtin_amdgcn_s_barrier();          // all waves: buf[cur] fully staged
        __builtin_amdgcn_sched_barrier(0);
        const ushortT* Ac = As[cur];
        const ushortT* Bc = Bs[cur];
#pragma unroll
        for (int kk = 0; kk < 2; ++kk) {
            int g0 = kk * 4 + l4;
            bf16x8 af[4], bfv[4];
#pragma unroll
            for (int mi = 0; mi < 4; ++mi)
                af[mi] = *(const bf16x8*)&Ac[LIX(wm * 64 + mi * 16 + l15, g0)];
#pragma unroll
            for (int ni = 0; ni < 4; ++ni)
                bfv[ni] = *(const bf16x8*)&Bc[LIX(wn * 64 + ni * 16 + l15, g0)];
#pragma unroll
            for (int mi = 0; mi < 4; ++mi)
#pragma unroll
                for (int ni = 0; ni < 4; ++ni)
                    acc[mi][ni] = __builtin_amdgcn_mfma_f32_16x16x32_bf16(
                        bfv[ni], af[mi], acc[mi][ni], 0, 0, 0);   // C^T fragment
        }
        __builtin_amdgcn_s_barrier();          // all waves done reading buf[cur]
        asm volatile("" ::: "memory");
        if (t + 2 < nkt) {                     // refill buf[cur] with tile t+2
            int kt2 = (t + 2) << 6;
#pragma unroll
            for (int i = 0; i < 4; ++i) {
                gload16(aSrc[i] + kt2, (char*)As[cur] + offv[i]);
                gload16(bSrc[i] + kt2, (char*)Bs[cur] + offv[i]);
            }
        }
    }

    if (nroute) {
#pragma unroll
        for (int mi = 0; mi < 4; ++mi) {
            int row = r0 + wm * 64 + mi * 16 + l15;
#pragma unroll
            for (int ni = 0; ni < 4; ++ni) {
                int col = c0 + wn * 64 + ni * 16 + l4 * 4;
                int range = col >> 9, cc = col & 511;
                ushortT* d = Db.p[range];
                f32x4 a = acc[mi][ni];
                if ((scmask >> range) & 1) {
                    a[0] *= SCL2; a[1] *= SCL2; a[2] *= SCL2; a[3] *= SCL2;
                }
                if ((vtmask >> range) & 1) {
                    size_t vb = ((size_t)(row >> 9) * Hh + (cc >> 6)) * 64 + (cc & 63);
                    int tok = row & 511;
#pragma unroll
                    for (int r = 0; r < 4; ++r)
                        d[((vb + r) << 9) + tok] = f2bf(a[r]);
                } else {
                    ushort4 o;
                    o.x = f2bf(a[0]); o.y = f2bf(a[1]);
                    o.z = f2bf(a[2]); o.w = f2bf(a[3]);
                    *(ushort4*)&d[((size_t)row << 9) + cc] = o;
                }
            }
        }
    } else {
        const float alp = alpha ? alpha[0] : 1.0f;
        ushortT* outB = Db.p[0];
#pragma unroll
        for (int mi = 0; mi < 4; ++mi) {
            int row = r0 + wm * 64 + mi * 16 + l15;
#pragma unroll
            for (int ni = 0; ni < 4; ++ni) {
                int colb = c0 + wn * 64 + ni * 16 + l4 * 4;
                f32x4 a = acc[mi][ni];
                if (bias) {
                    float4 b4 = *(const float4*)&bias[colb];
                    a[0] += b4.x; a[1] += b4.y; a[2] += b4.z; a[3] += b4.w;
                }
                if (do_relu) {
#pragma unroll
                    for (int r = 0; r < 4; ++r) a[r] = fmaxf(a[r], 0.f);
                }
#pragma unroll
                for (int r = 0; r < 4; ++r) a[r] *= alp;
                size_t idx = (size_t)row * N + colb;
                if (res) {
                    float4 r4 = *(const float4*)&res[idx];
                    a[0] += r4.x; a[1] += r4.y; a[2] += r4.z; a[3] += r4.w;
                }
                if (outF)
                    *(float4*)&outF[idx] = make_float4(a[0], a[1], a[2], a[3]);
                if (outB) {
                    ushort4 o;
                    o.x = f2bf(a[0]); o.y = f2bf(a[1]);
                    o.z = f2bf(a[2]); o.w = f2bf(a[3]);
                    *(ushort4*)&outB[idx] = o;
                }
            }
        }
    }
}

// ---------- 64x128 bf16 MFMA GEMM; residual f32 (resf) or bf16 (resb) ----------
__global__ __launch_bounds__(256) void gemm64(
    const ushortT* __restrict__ Bw, const ushortT* __restrict__ A,
    float* __restrict__ outF, ushortT* __restrict__ outB,
    int M, int N, int K, const float* __restrict__ bias,
    const float* __restrict__ resf, const ushortT* __restrict__ resb,
    const float* __restrict__ alpha, int do_relu)
{
    __shared__ __align__(16) ushortT As[64 * 64];
    __shared__ __align__(16) ushortT Bs[128 * 64];
    const int tid = threadIdx.x;
    const int wid = tid >> 6, lane = tid & 63;
    const int wm = wid >> 1, wn = wid & 1;
    const int l15 = lane & 15, l4 = lane >> 4;

    int bid = blockIdx.y * gridDim.x + blockIdx.x;
    int nwg = gridDim.x * gridDim.y;
    int q = nwg >> 3;
    int swz = (bid & 7) * q + (bid >> 3);
    int bx = swz % gridDim.x, by = swz / gridDim.x;
    const int r0 = by * 64, c0 = bx * 128;

    const ushortT* aSrc[2];
    char* ldsA[2];
#pragma unroll
    for (int i = 0; i < 2; ++i) {
        int off = wid * 2048 + i * 1024 + lane * 16;
        int row = off >> 7;
        int sg = ((off >> 4) & 7) ^ (row & 7);
        aSrc[i] = A + (size_t)(r0 + row) * K + sg * 8;
        ldsA[i] = (char*)As + off;
    }
    const ushortT* bSrc[4];
    char* ldsB[4];
#pragma unroll
    for (int i = 0; i < 4; ++i) {
        int off = wid * 4096 + i * 1024 + lane * 16;
        int row = off >> 7;
        int sg = ((off >> 4) & 7) ^ (row & 7);
        bSrc[i] = Bw + (size_t)(c0 + row) * K + sg * 8;
        ldsB[i] = (char*)Bs + off;
    }

    f32x4 acc[2][4] = {};

    for (int kt = 0; kt < K; kt += 64) {
        __syncthreads();
#pragma unroll
        for (int i = 0; i < 2; ++i) gload16(aSrc[i] + kt, ldsA[i]);
#pragma unroll
        for (int i = 0; i < 4; ++i) gload16(bSrc[i] + kt, ldsB[i]);
        asm volatile("s_waitcnt vmcnt(0)" ::: "memory");
        __syncthreads();
#pragma unroll
        for (int kk = 0; kk < 2; ++kk) {
            int g0 = kk * 4 + l4;
            bf16x8 af[2], bfv[4];
#pragma unroll
            for (int mi = 0; mi < 2; ++mi)
                af[mi] = *(const bf16x8*)&As[LIX(wm * 32 + mi * 16 + l15, g0)];
#pragma unroll
            for (int ni = 0; ni < 4; ++ni)
                bfv[ni] = *(const bf16x8*)&Bs[LIX(wn * 64 + ni * 16 + l15, g0)];
#pragma unroll
            for (int mi = 0; mi < 2; ++mi)
#pragma unroll
                for (int ni = 0; ni < 4; ++ni)
                    acc[mi][ni] = __builtin_amdgcn_mfma_f32_16x16x32_bf16(
                        bfv[ni], af[mi], acc[mi][ni], 0, 0, 0);
        }
    }

    const float alp = alpha ? alpha[0] : 1.0f;
#pragma unroll
    for (int mi = 0; mi < 2; ++mi) {
        int row = r0 + wm * 32 + mi * 16 + l15;
#pragma unroll
        for (int ni = 0; ni < 4; ++ni) {
            int colb = c0 + wn * 64 + ni * 16 + l4 * 4;
            f32x4 a = acc[mi][ni];
            if (bias) {
                float4 b4 = *(const float4*)&bias[colb];
                a[0] += b4.x; a[1] += b4.y; a[2] += b4.z; a[3] += b4.w;
            }
            if (do_relu) {
#pragma unroll
                for (int r = 0; r < 4; ++r) a[r] = fmaxf(a[r], 0.f);
            }
#pragma unroll
            for (int r = 0; r < 4; ++r) a[r] *= alp;
            size_t idx = (size_t)row * N + colb;
            if (resf) {
                float4 r4 = *(const float4*)&resf[idx];
                a[0] += r4.x; a[1] += r4.y; a[2] += r4.z; a[3] += r4.w;
            }
            if (resb) {
                ushort4 r4 = *(const ushort4*)&resb[idx];
                a[0] += bf2f(r4.x); a[1] += bf2f(r4.y);
                a[2] += bf2f(r4.z); a[3] += bf2f(r4.w);
            }
            if (outF)
                *(float4*)&outF[idx] = make_float4(a[0], a[1], a[2], a[3]);
            if (outB) {
                ushort4 o;
                o.x = f2bf(a[0]); o.y = f2bf(a[1]);
                o.z = f2bf(a[2]); o.w = f2bf(a[3]);
                *(ushort4*)&outB[idx] = o;
            }
        }
    }
}

// ---------- HA diagonal scores (QD pre-scaled by NORM*log2e) ----------
__global__ __launch_bounds__(256) void diag_dot_bb(const ushortT* __restrict__ QD,
                                                   const ushortT* __restrict__ K,
                                                   float* __restrict__ Sdg) {
    int i = blockIdx.x * 256 + threadIdx.x;
    int h = i & 7, n = (i >> 3) & 511, b = i >> 12;
    int dix = (n < NPICKk) ? n + NPICKk : n - NPICKk;
    const ushortT* q = QD + (((size_t)(b * Nn + n) * Hh + h) << 6);
    const ushortT* k = K + (((size_t)(b * Nn + dix) * Hh + h) << 6);
    float s = 0.f;
#pragma unroll
    for (int d = 0; d < 64; d += 4) {
        ushort4 a = *(const ushort4*)(q + d);
        ushort4 c = *(const ushort4*)(k + d);
        s += bf2f(a.x) * bf2f(c.x) + bf2f(a.y) * bf2f(c.y)
           + bf2f(a.z) * bf2f(c.z) + bf2f(a.w) * bf2f(c.w);
    }
    Sdg[i] = s;
}

// ---------- flash attention: T14 reg-staged double-buffered K/V, lazy max, deferred L ----------
template <int HA>
__global__ __launch_bounds__(256) void attn10(
    const ushortT* __restrict__ Qm, const ushortT* __restrict__ Km,
    const ushortT* __restrict__ Vtm, const ushortT* __restrict__ QAm,
    const ushortT* __restrict__ QBm, const float* __restrict__ Sdg,
    ushortT* __restrict__ Out)
{
    __shared__ __align__(16) ushortT Ks[64 * 64];
    __shared__ __align__(16) ushortT Vs[64 * 64];
    __shared__ __align__(16) ushortT Pw[4][16 * 64];
    __shared__ float sdl[64];

    const int tid = threadIdx.x, wid = tid >> 6, lane = tid & 63;
    const int l15 = lane & 15, l4 = lane >> 4;

    // XCD-bijective remap: blocks sharing (b,h) -> same XCD L2
    const int p = blockIdx.x + (blockIdx.y << 3) + (blockIdx.z << 6);
    const int n0 = (((p >> 3) & 7)) << 6;
    const int g8 = (p & 7) | ((p >> 6) << 3);
    const int h = g8 & 7, b = g8 >> 3;
    const int bh = b * Hh + h;

    // Q/QA/QB fragments direct to registers
    const size_t qrow = (((size_t)(b * Nn + n0 + wid * 16 + l15) * Hh + h) << 6);
    bf16x8 qf[2], xaf[2], xbf[2];
#pragma unroll
    for (int kk = 0; kk < 2; ++kk) {
        int g0 = kk * 4 + l4;
        qf[kk] = *(const bf16x8*)&Qm[qrow + g0 * 8];
        if (HA) {
            xaf[kk] = *(const bf16x8*)&QAm[qrow + g0 * 8];
            xbf[kk] = *(const bf16x8*)&QBm[qrow + g0 * 8];
        }
    }
    if (HA && tid < 64) sdl[tid] = Sdg[((size_t)(b * Nn + n0 + tid)) * Hh + h];
    const int td = (n0 < NPICKk) ? ((n0 + NPICKk) >> 6) : ((n0 - NPICKk) >> 6);

    const ushortT* kSrc[2]; ushortT* kDst[2];
    const ushortT* vSrc[2]; ushortT* vDst[2];
#pragma unroll
    for (int i = 0; i < 2; ++i) {
        int off = wid * 2048 + i * 1024 + lane * 16;
        int row = off >> 7, sg = ((off >> 4) & 7) ^ (row & 7);
        kSrc[i] = Km + (((size_t)(b * Nn + row) * Hh + h) << 6) + sg * 8;
        kDst[i] = (ushortT*)((char*)Ks + off);
        vSrc[i] = Vtm + (((size_t)(bh * 64 + row)) << 9) + sg * 8;
        vDst[i] = (ushortT*)((char*)Vs + off);
    }

    float M[4], Lp[4];
    f32x4 Oa[4] = {};
#pragma unroll
    for (int r = 0; r < 4; ++r) { M[r] = -INFINITY; Lp[r] = 0.f; }

    // prologue: tile 0 into regs
    bf16x8 krbuf[2][2], vrbuf[2][2];
#pragma unroll
    for (int i = 0; i < 2; ++i) {
        krbuf[0][i] = *(const bf16x8*)kSrc[i];
        vrbuf[0][i] = *(const bf16x8*)vSrc[i];
    }

#pragma unroll
    for (int t = 0; t < 8; ++t) {
        const int cur = t & 1, nxt = cur ^ 1;
        __builtin_amdgcn_s_barrier();   // all waves done reading Ks/Vs (prev tile)
#pragma unroll
        for (int i = 0; i < 2; ++i) {
            *(bf16x8*)kDst[i] = krbuf[cur][i];
            *(bf16x8*)vDst[i] = vrbuf[cur][i];
        }
        if (t < 7) {   // prefetch t+1 (stays in flight across this tile's compute)
#pragma unroll
            for (int i = 0; i < 2; ++i) {
                krbuf[nxt][i] = *(const bf16x8*)(kSrc[i] + (size_t)(t + 1) * (64 * Hh * VDd));
                vrbuf[nxt][i] = *(const bf16x8*)(vSrc[i] + (t + 1) * 64);
            }
        }
        asm volatile("s_waitcnt lgkmcnt(0)" ::: "memory");  // own ds_writes done
        __builtin_amdgcn_s_barrier();                        // all writes visible
        __builtin_amdgcn_sched_barrier(0);

        // ---- S = Q K^T ----
        __builtin_amdgcn_s_setprio(1);
        f32x4 s1[4] = {}, sX[4] = {};
#pragma unroll
        for (int kk = 0; kk < 2; ++kk) {
            bf16x8 aq = qf[kk];
            bf16x8 ax;
            if (HA) ax = (t >= 4) ? xbf[kk] : xaf[kk];
#pragma unroll
            for (int ni = 0; ni < 4; ++ni) {
                bf16x8 bk = *(const bf16x8*)&Ks[LIX(ni * 16 + l15, kk * 4 + l4)];
                s1[ni] = __builtin_amdgcn_mfma_f32_16x16x32_bf16(aq, bk, s1[ni], 0, 0, 0);
                if (HA)
                    sX[ni] = __builtin_amdgcn_mfma_f32_16x16x32_bf16(ax, bk, sX[ni], 0, 0, 0);
            }
        }
        __builtin_amdgcn_s_setprio(0);

        const bool dt = HA && (t == td);

        // ---- lazy max: lane-local maxes; full reduce+rescale only on growth ----
        float mloc[4];
        bool grow = false;
#pragma unroll
        for (int r = 0; r < 4; ++r) {
            int rw = wid * 16 + l4 * 4 + r;
            float m = s1[0][r];
#pragma unroll
            for (int ni = 1; ni < 4; ++ni) m = fmaxf(m, s1[ni][r]);
            if (HA) {
#pragma unroll
                for (int ni = 0; ni < 4; ++ni) m = fmaxf(m, sX[ni][r]);
            }
            if (dt && l15 == l4 * 4 + r) m = fmaxf(m, sdl[rw]);
            mloc[r] = m;
            grow = grow || (m > M[r] + 8.f);
        }
        if (__any(grow)) {
#pragma unroll
            for (int r = 0; r < 4; ++r) {
                float m = mloc[r];
#pragma unroll
                for (int o = 8; o >= 1; o >>= 1) m = fmaxf(m, __shfl_xor(m, o, 16));
                float mn = fmaxf(M[r], m);
                float sc = exp2fast(M[r] - mn);
                M[r] = mn; Lp[r] *= sc;
#pragma unroll
                for (int ni = 0; ni < 4; ++ni) Oa[ni][r] *= sc;
            }
        }

        // ---- P = exp2(S - M); per-lane partial L (deferred reduce) ----
#pragma unroll
        for (int r = 0; r < 4; ++r) {
            int rw = wid * 16 + l4 * 4 + r;
            float rs = 0.f;
#pragma unroll
            for (int ni = 0; ni < 4; ++ni) {
                float pv = exp2fast(s1[ni][r] - M[r]);
                if (HA) pv += exp2fast(sX[ni][r] - M[r]);
                if (dt && ni == wid && l15 == l4 * 4 + r) pv += exp2fast(sdl[rw] - M[r]);
                s1[ni][r] = pv;
                rs += pv;
            }
            Lp[r] += rs;
        }

        // ---- write P into wave-private strip (no barrier) ----
#pragma unroll
        for (int ni = 0; ni < 4; ++ni)
#pragma unroll
            for (int r = 0; r < 4; ++r) {
                int prow = l4 * 4 + r;
                int col = ni * 16 + l15;
                Pw[wid][(prow << 6) + ((((col >> 3) ^ (prow & 7))) << 3) + (col & 7)] =
                    f2bf(s1[ni][r]);
            }

        // ---- O += P @ V ----
        __builtin_amdgcn_s_setprio(1);
#pragma unroll
        for (int kk = 0; kk < 2; ++kk) {
            int g0 = kk * 4 + l4;
            bf16x8 ap = *(const bf16x8*)&Pw[wid][LIX(l15, g0)];
#pragma unroll
            for (int ni = 0; ni < 4; ++ni) {
                bf16x8 bv = *(const bf16x8*)&Vs[LIX(ni * 16 + l15, g0)];
                Oa[ni] = __builtin_amdgcn_mfma_f32_16x16x32_bf16(ap, bv, Oa[ni], 0, 0, 0);
            }
        }
        __builtin_amdgcn_s_setprio(0);
    }

#pragma unroll
    for (int r = 0; r < 4; ++r) {
        float l = Lp[r];
#pragma unroll
        for (int o = 8; o >= 1; o >>= 1) l += __shfl_xor(l, o, 16);
        float inv = 1.0f / l;
        size_t obase = (((size_t)(b * Nn + n0 + wid * 16 + l4 * 4 + r) * Hh + h) << 6);
#pragma unroll
        for (int ni = 0; ni < 4; ++ni)
            Out[obase + ni * 16 + l15] = f2bf(Oa[ni][r] * inv);
    }
}

extern "C" void kernel_launch(void* const* d_in, const int* in_sizes, int n_in,
                              void* d_out, int out_size, void* d_ws, size_t ws_size,
                              hipStream_t stream)
{
    const float* x = (const float*)d_in[0];

    int dictOrder = (in_sizes[18] != 512);
    const float* comb_w  = (const float*)d_in[17];
    const float* comb2_w = (const float*)d_in[dictOrder ? 18 : 19];
    const float* comb3_w = (const float*)d_in[dictOrder ? 19 : 21];
    const float* comb_b  = (const float*)d_in[dictOrder ? 20 : 18];
    const float* comb2_b = (const float*)d_in[dictOrder ? 21 : 20];
    const float* comb3_b = (const float*)d_in[22];
    const float* alpha1 = (const float*)d_in[23];
    const float* alpha2 = (const float*)d_in[24];
    const float* alpha3 = (const float*)d_in[25];
    const float* ff1_w1 = (const float*)d_in[26];
    const float* ff1_b1 = (const float*)d_in[27];
    const float* ff1_w2 = (const float*)d_in[28];
    const float* ff1_b2 = (const float*)d_in[29];
    const float* ffa1   = (const float*)d_in[30];
    const float* ff2_w1 = (const float*)d_in[31];
    const float* ff2_b1 = (const float*)d_in[32];
    const float* ff2_w2 = (const float*)d_in[33];
    const float* ff2_b2 = (const float*)d_in[34];
    const float* ffa2   = (const float*)d_in[35];
    const float* ff3_w1 = (const float*)d_in[36];
    const float* ff3_b1 = (const float*)d_in[37];
    const float* ff3_w2 = (const float*)d_in[38];
    const float* ff3_b2 = (const float*)d_in[39];
    const float* ffa3   = (const float*)d_in[40];

    // ---- workspace layout (bytes) ----
    char* W = (char*)d_ws;
    ushortT* wbHead = (ushortT*)(W + 0);
    ushortT* wbMha  = (ushortT*)(W + 4718592);
    ushortT* wbComb = (ushortT*)(W + 8388608);
    ushortT* wbFf1  = (ushortT*)(W + 9961472);
    ushortT* wbFf2  = (ushortT*)(W + 16252928);
    ushortT* xbf    = (ushortT*)(W + 22544384);
    float*   Sd     = (float*)  (W + 30932992);
    ushortT* bufQ   = (ushortT*)(W + 31195136);
    ushortT* bufK   = (ushortT*)(W + 39583744);
    ushortT* bufVt  = (ushortT*)(W + 47972352);
    ushortT* bufQA  = (ushortT*)(W + 56360960);
    ushortT* bufQB  = (ushortT*)(W + 64749568);
    ushortT* bufQD  = (ushortT*)(W + 73138176);
    ushortT* hidden = (ushortT*)(W + 81526784);
    ushortT* curb   = (ushortT*)(W + 115081216);
    ushortT* bufHA  = xbf;
    float*   cur    = (float*)d_out;

    dim3 tb(256);
    const int TOK = Bb * Nn;  // 8192
    const size_t WS = 512 * 512;
    const size_t WF = 2048 * 512;

    // 1. casts / transposes (batched)
    hipLaunchKernelGGL(castx, dim3(TOK * 512 / 1024), tb, 0, stream, x, xbf);
    {
        Ptrs9 s; for (int i = 0; i < 9; ++i) s.p[i] = (const float*)d_in[1 + i];
        hipLaunchKernelGGL(thead, dim3(1, 8, 72), tb, 0, stream, s, wbHead);
    }
    {
        Ptrs10 s;
        for (int i = 0; i < 7; ++i) s.p[i] = (const float*)d_in[10 + i];
        s.p[7] = comb_w; s.p[8] = comb2_w; s.p[9] = comb3_w;
        hipLaunchKernelGGL(tsq, dim3(8, 8, 10), tb, 0, stream, s, wbMha);
    }
    {
        Ptrs6 s;
        s.p[0] = ff1_w1; s.p[1] = ff2_w1; s.p[2] = ff3_w1;
        s.p[3] = ff1_w2; s.p[4] = ff2_w2; s.p[5] = ff3_w2;
        hipLaunchKernelGGL(tff, dim3(32, 32, 6), tb, 0, stream, s, wbFf1);
    }

    auto gemm = [&](PtrsB Bp, PtrsD Db, const ushortT* A, float* oF,
                    int M, int Ncc, int Kc, const float* bias, const float* res,
                    const float* alp, int relu, int nroute, int vtmask, int scmask) {
        hipLaunchKernelGGL(gemm_bf, dim3(Ncc / 128, M / 128), tb, 0, stream,
                           Bp, Db, A, oF, M, Ncc, Kc, bias, res, alp, relu, nroute,
                           vtmask, scmask);
    };
    auto g64 = [&](const ushortT* Bw, const ushortT* A, float* oF, ushortT* oB,
                   int M, int Ncc, int Kc, const float* bias, const float* resf,
                   const ushortT* resb, const float* alp, int relu) {
        hipLaunchKernelGGL(gemm64, dim3(Ncc / 128, M / 64), tb, 0, stream,
                           Bw, A, oF, oB, M, Ncc, Kc, bias, resf, resb, alp, relu);
    };
    auto uni = [&](const ushortT* w) { PtrsB b; for (int i = 0; i < 12; ++i) b.p[i] = w; return b; };
    auto d1 = [&](ushortT* d) { PtrsD dd = {}; dd.p[0] = d; return dd; };

    // 2. HA projections: ONE fused GEMM, N=3072 (Q/QA/QB/QD pre-scaled, scmask=57)
    {
        PtrsB b;
        b.p[0] = b.p[1] = wbHead + 0 * WS;
        b.p[2] = b.p[3] = wbHead + 1 * WS;
        b.p[4] = b.p[5] = wbHead + 2 * WS;
        b.p[6] = wbHead + 4 * WS; b.p[7] = wbHead + 8 * WS;
        b.p[8] = wbHead + 5 * WS; b.p[9] = wbHead + 7 * WS;
        b.p[10] = wbHead + 3 * WS; b.p[11] = wbHead + 6 * WS;
        PtrsD d; d.p[0] = bufQ; d.p[1] = bufK; d.p[2] = bufVt;
        d.p[3] = bufQA; d.p[4] = bufQB; d.p[5] = bufQD;
        gemm(b, d, xbf, nullptr, TOK, 3072, 512, nullptr, nullptr, nullptr, 0, 6, 4, 57);
    }

    // 3. HA attention
    hipLaunchKernelGGL(diag_dot_bb, dim3(Bb * Nn * Hh / 256), tb, 0, stream, bufQD, bufK, Sd);
    hipLaunchKernelGGL((attn10<1>), dim3(Nn / 64, Hh, Bb), tb, 0, stream,
                       bufQ, bufK, bufVt, bufQA, bufQB, Sd, bufHA);

    // 4. comb3 + FF3 (bf16 residual stream)
    g64(wbComb + 2 * WS, bufHA, nullptr, curb, TOK, 512, 512, comb3_b, x, nullptr, alpha3, 0);
    gemm(uni(wbFf1 + 2 * WF), d1(hidden), curb, nullptr, TOK, 2048, 512, ff3_b1, nullptr, nullptr, 1, 0, 0, 0);
    g64(wbFf2 + 2 * WF, hidden, nullptr, curb, TOK, 512, 2048, ff3_b2, nullptr, curb, ffa3, 0);

    // 5. MHA1
    {
        PtrsB b;
        b.p[0] = b.p[1] = wbMha + 0 * WS;
        b.p[2] = b.p[3] = wbMha + 1 * WS;
        b.p[4] = b.p[5] = wbMha + 2 * WS;
        PtrsD d = {}; d.p[0] = bufQ; d.p[1] = bufK; d.p[2] = bufVt;
        gemm(b, d, curb, nullptr, TOK, 1536, 512, nullptr, nullptr, nullptr, 0, 3, 4, 1);
    }
    hipLaunchKernelGGL((attn10<0>), dim3(Nn / 64, Hh, Bb), tb, 0, stream,
                       bufQ, bufK, bufVt, nullptr, nullptr, nullptr, bufHA);
    g64(wbComb + 0 * WS, bufHA, nullptr, curb, TOK, 512, 512, comb_b, nullptr, curb, alpha1, 0);
    gemm(uni(wbFf1 + 0 * WF), d1(hidden), curb, nullptr, TOK, 2048, 512, ff1_b1, nullptr, nullptr, 1, 0, 0, 0);
    g64(wbFf2 + 0 * WF, hidden, nullptr, curb, TOK, 512, 2048, ff1_b2, nullptr, curb, ffa1, 0);

    // 6. MHA2
    {
        PtrsB b;
        b.p[0] = wbMha + 3 * WS; b.p[1] = wbMha + 4 * WS;
        b.p[2] = b.p[3] = wbMha + 5 * WS;
        b.p[4] = b.p[5] = wbMha + 6 * WS;
        PtrsD d = {}; d.p[0] = bufQ; d.p[1] = bufK; d.p[2] = bufVt;
        gemm(b, d, curb, nullptr, TOK, 1536, 512, nullptr, nullptr, nullptr, 0, 3, 4, 1);
    }
    hipLaunchKernelGGL((attn10<0>), dim3(Nn / 64, Hh, Bb), tb, 0, stream,
                       bufQ, bufK, bufVt, nullptr, nullptr, nullptr, bufHA);
    g64(wbComb + 1 * WS, bufHA, nullptr, curb, TOK, 512, 512, comb2_b, nullptr, curb, alpha2, 0);
    gemm(uni(wbFf1 + 1 * WF), d1(hidden), curb, nullptr, TOK, 2048, 512, ff2_b1, nullptr, nullptr, 1, 0, 0, 0);
    // final: write f32 d_out
    g64(wbFf2 + 1 * WF, hidden, cur, nullptr, TOK, 512, 2048, ff2_b2, nullptr, curb, ffa2, 0);
}

// Round 15
// 426.741 us; speedup vs baseline: 11.8026x; 1.0794x over previous
//
#include <hip/hip_runtime.h>
#include <math.h>

#define Hh 8
#define Bb 16
#define Nn 512
#define Dd 512
#define VDd 64
#define NPICKk 256
#define NORMF 0.125f
#define SCL2 0.1803368801f   /* NORMF * log2(e) */

typedef unsigned short ushortT;
typedef __bf16 bf16x8 __attribute__((ext_vector_type(8)));
typedef float f32x4 __attribute__((ext_vector_type(4)));

struct PtrsB { const ushortT* p[12]; };
struct PtrsD { ushortT* p[6]; };
struct Ptrs9 { const float* p[9]; };
struct Ptrs10 { const float* p[10]; };
struct Ptrs6 { const float* p[6]; };

__device__ inline ushortT f2bf(float f) {
    __bf16 h = (__bf16)f;
    union { __bf16 h; ushortT u; } v; v.h = h;
    return v.u;
}
__device__ inline float bf2f(ushortT u) {
    union { unsigned int u; float f; } v; v.u = ((unsigned int)u) << 16;
    return v.f;
}
__device__ inline float exp2fast(float x) {
#if __has_builtin(__builtin_amdgcn_exp2f)
    return __builtin_amdgcn_exp2f(x);
#else
    return exp2f(x);
#endif
}
__device__ inline void gload16(const void* gptr, void* ldsptr) {
    auto g = reinterpret_cast<const __attribute__((address_space(1))) unsigned int*>(
        reinterpret_cast<uintptr_t>(gptr));
    auto l = reinterpret_cast<__attribute__((address_space(3))) unsigned int*>(
        reinterpret_cast<uintptr_t>(ldsptr));
    __builtin_amdgcn_global_load_lds(g, l, 16, 0, 0);
}

#define LIX(r, g) (((r) << 6) + ((((g) ^ ((r) & 7))) << 3))

// ---------- fp32 -> bf16 elementwise ----------
__global__ __launch_bounds__(256) void castx(const float* __restrict__ in,
                                             ushortT* __restrict__ out) {
    int i = blockIdx.x * 256 + threadIdx.x;
    float4 v = *(const float4*)&in[(size_t)i * 4];
    ushort4 o; o.x = f2bf(v.x); o.y = f2bf(v.y); o.z = f2bf(v.z); o.w = f2bf(v.w);
    *(ushort4*)&out[(size_t)i * 4] = o;
}

// ---------- transpose+cast body ----------
__device__ inline void tbody(const float* __restrict__ in, ushortT* __restrict__ out,
                             int in_ld, int out_ld, int r0, int c0) {
    __shared__ float T[64][65];
    int tr = threadIdx.x >> 4, tc4 = (threadIdx.x & 15) * 4;
#pragma unroll
    for (int p = 0; p < 4; ++p) {
        float4 v = *(const float4*)&in[(size_t)(r0 + tr + p * 16) * in_ld + c0 + tc4];
        T[tr + p * 16][tc4 + 0] = v.x; T[tr + p * 16][tc4 + 1] = v.y;
        T[tr + p * 16][tc4 + 2] = v.z; T[tr + p * 16][tc4 + 3] = v.w;
    }
    __syncthreads();
#pragma unroll
    for (int p = 0; p < 4; ++p) {
        int orow = c0 + tr + p * 16;
        int ocol = r0 + tc4;
        ushort4 o;
        o.x = f2bf(T[tc4 + 0][tr + p * 16]);
        o.y = f2bf(T[tc4 + 1][tr + p * 16]);
        o.z = f2bf(T[tc4 + 2][tr + p * 16]);
        o.w = f2bf(T[tc4 + 3][tr + p * 16]);
        *(ushort4*)&out[(size_t)orow * out_ld + ocol] = o;
    }
}

__global__ __launch_bounds__(256) void thead(Ptrs9 s, ushortT* __restrict__ dst) {
    int w = blockIdx.z >> 3, h = blockIdx.z & 7;
    tbody(s.p[w] + (size_t)h * 512 * 64,
          dst + (size_t)w * 262144 + (size_t)h * 64 * 512,
          64, 512, blockIdx.y * 64, 0);
}
__global__ __launch_bounds__(256) void tsq(Ptrs10 s, ushortT* __restrict__ dst) {
    tbody(s.p[blockIdx.z], dst + (size_t)blockIdx.z * 262144,
          512, 512, blockIdx.y * 64, blockIdx.x * 64);
}
__global__ __launch_bounds__(256) void tff(Ptrs6 s, ushortT* __restrict__ dst) {
    int z = blockIdx.z;
    if (z < 3) { if (blockIdx.y >= 8 || blockIdx.x >= 32) return; }
    else       { if (blockIdx.y >= 32 || blockIdx.x >= 8) return; }
    int in_ld = (z < 3) ? 2048 : 512;
    int out_ld = (z < 3) ? 512 : 2048;
    tbody(s.p[z], dst + (size_t)z * 1048576, in_ld, out_ld,
          blockIdx.y * 64, blockIdx.x * 64);
}

// ---------- 128x128 bf16 MFMA GEMM, T4 counted-vmcnt double-buffer + T5 ----------
__global__ __launch_bounds__(256) void gemm_bf(
    PtrsB Bp, PtrsD Db, const ushortT* __restrict__ A, float* __restrict__ outF,
    int M, int N, int K, const float* __restrict__ bias,
    const float* __restrict__ res, const float* __restrict__ alpha,
    int do_relu, int nroute, int vtmask, int scmask)
{
    __shared__ __align__(16) ushortT As[2][128 * 64];
    __shared__ __align__(16) ushortT Bs[2][128 * 64];
    const int tid = threadIdx.x;
    const int wid = tid >> 6, lane = tid & 63;
    const int wm = wid >> 1, wn = wid & 1;
    const int l15 = lane & 15, l4 = lane >> 4;

    int bid = blockIdx.y * gridDim.x + blockIdx.x;
    int nwg = gridDim.x * gridDim.y;
    int q = nwg >> 3;
    int swz = (bid & 7) * q + (bid >> 3);
    int bx = swz % gridDim.x, by = swz / gridDim.x;

    const int r0 = by * 128, c0 = bx * 128;
    const int half = ((r0 & (Nn - 1)) >= NPICKk) ? 1 : 0;
    const ushortT* Bt = Bp.p[((c0 >> 9) << 1) | half];
    const int cB = nroute ? (c0 & 511) : c0;

    const ushortT* aSrc[4];
    const ushortT* bSrc[4];
    int offv[4];
#pragma unroll
    for (int i = 0; i < 4; ++i) {
        int off = wid * 4096 + i * 1024 + lane * 16;
        int row = off >> 7;
        int sg = ((off >> 4) & 7) ^ (row & 7);
        aSrc[i] = A + (size_t)(r0 + row) * K + sg * 8;
        bSrc[i] = Bt + (size_t)(cB + row) * K + sg * 8;
        offv[i] = off;
    }

    const int nkt = K >> 6;
#pragma unroll
    for (int i = 0; i < 4; ++i) {
        gload16(aSrc[i], (char*)As[0] + offv[i]);
        gload16(bSrc[i], (char*)Bs[0] + offv[i]);
    }
#pragma unroll
    for (int i = 0; i < 4; ++i) {
        gload16(aSrc[i] + 64, (char*)As[1] + offv[i]);
        gload16(bSrc[i] + 64, (char*)Bs[1] + offv[i]);
    }

    f32x4 acc[4][4] = {};

    for (int t = 0; t < nkt; ++t) {
        const int cur = t & 1;
        if (t == nkt - 1) asm volatile("s_waitcnt vmcnt(0)" ::: "memory");
        else              asm volatile("s_waitcnt vmcnt(8)" ::: "memory");
        __builtin_amdgcn_s_barrier();
        __builtin_amdgcn_sched_barrier(0);
        const ushortT* Ac = As[cur];
        const ushortT* Bc = Bs[cur];
        __builtin_amdgcn_s_setprio(1);
#pragma unroll
        for (int kk = 0; kk < 2; ++kk) {
            int g0 = kk * 4 + l4;
            bf16x8 af[4], bfv[4];
#pragma unroll
            for (int mi = 0; mi < 4; ++mi)
                af[mi] = *(const bf16x8*)&Ac[LIX(wm * 64 + mi * 16 + l15, g0)];
#pragma unroll
            for (int ni = 0; ni < 4; ++ni)
                bfv[ni] = *(const bf16x8*)&Bc[LIX(wn * 64 + ni * 16 + l15, g0)];
#pragma unroll
            for (int mi = 0; mi < 4; ++mi)
#pragma unroll
                for (int ni = 0; ni < 4; ++ni)
                    acc[mi][ni] = __builtin_amdgcn_mfma_f32_16x16x32_bf16(
                        bfv[ni], af[mi], acc[mi][ni], 0, 0, 0);   // C^T fragment
        }
        __builtin_amdgcn_s_setprio(0);
        __builtin_amdgcn_s_barrier();
        asm volatile("" ::: "memory");
        if (t + 2 < nkt) {
            int kt2 = (t + 2) << 6;
#pragma unroll
            for (int i = 0; i < 4; ++i) {
                gload16(aSrc[i] + kt2, (char*)As[cur] + offv[i]);
                gload16(bSrc[i] + kt2, (char*)Bs[cur] + offv[i]);
            }
        }
    }

    if (nroute) {
#pragma unroll
        for (int mi = 0; mi < 4; ++mi) {
            int row = r0 + wm * 64 + mi * 16 + l15;
#pragma unroll
            for (int ni = 0; ni < 4; ++ni) {
                int col = c0 + wn * 64 + ni * 16 + l4 * 4;
                int range = col >> 9, cc = col & 511;
                ushortT* d = Db.p[range];
                f32x4 a = acc[mi][ni];
                if ((scmask >> range) & 1) {
                    a[0] *= SCL2; a[1] *= SCL2; a[2] *= SCL2; a[3] *= SCL2;
                }
                if ((vtmask >> range) & 1) {
                    size_t vb = ((size_t)(row >> 9) * Hh + (cc >> 6)) * 64 + (cc & 63);
                    int tok = row & 511;
#pragma unroll
                    for (int r = 0; r < 4; ++r)
                        d[((vb + r) << 9) + tok] = f2bf(a[r]);
                } else {
                    ushort4 o;
                    o.x = f2bf(a[0]); o.y = f2bf(a[1]);
                    o.z = f2bf(a[2]); o.w = f2bf(a[3]);
                    *(ushort4*)&d[((size_t)row << 9) + cc] = o;
                }
            }
        }
    } else {
        const float alp = alpha ? alpha[0] : 1.0f;
        ushortT* outB = Db.p[0];
#pragma unroll
        for (int mi = 0; mi < 4; ++mi) {
            int row = r0 + wm * 64 + mi * 16 + l15;
#pragma unroll
            for (int ni = 0; ni < 4; ++ni) {
                int colb = c0 + wn * 64 + ni * 16 + l4 * 4;
                f32x4 a = acc[mi][ni];
                if (bias) {
                    float4 b4 = *(const float4*)&bias[colb];
                    a[0] += b4.x; a[1] += b4.y; a[2] += b4.z; a[3] += b4.w;
                }
                if (do_relu) {
#pragma unroll
                    for (int r = 0; r < 4; ++r) a[r] = fmaxf(a[r], 0.f);
                }
#pragma unroll
                for (int r = 0; r < 4; ++r) a[r] *= alp;
                size_t idx = (size_t)row * N + colb;
                if (res) {
                    float4 r4 = *(const float4*)&res[idx];
                    a[0] += r4.x; a[1] += r4.y; a[2] += r4.z; a[3] += r4.w;
                }
                if (outF)
                    *(float4*)&outF[idx] = make_float4(a[0], a[1], a[2], a[3]);
                if (outB) {
                    ushort4 o;
                    o.x = f2bf(a[0]); o.y = f2bf(a[1]);
                    o.z = f2bf(a[2]); o.w = f2bf(a[3]);
                    *(ushort4*)&outB[idx] = o;
                }
            }
        }
    }
}

// ---------- 64x128 bf16 MFMA GEMM, T4 double-buffer + T5; res f32/bf16 ----------
__global__ __launch_bounds__(256) void gemm64(
    const ushortT* __restrict__ Bw, const ushortT* __restrict__ A,
    float* __restrict__ outF, ushortT* __restrict__ outB,
    int M, int N, int K, const float* __restrict__ bias,
    const float* __restrict__ resf, const ushortT* __restrict__ resb,
    const float* __restrict__ alpha, int do_relu)
{
    __shared__ __align__(16) ushortT As[2][64 * 64];    // 16 KB
    __shared__ __align__(16) ushortT Bs[2][128 * 64];   // 32 KB
    const int tid = threadIdx.x;
    const int wid = tid >> 6, lane = tid & 63;
    const int wm = wid >> 1, wn = wid & 1;
    const int l15 = lane & 15, l4 = lane >> 4;

    int bid = blockIdx.y * gridDim.x + blockIdx.x;
    int nwg = gridDim.x * gridDim.y;
    int q = nwg >> 3;
    int swz = (bid & 7) * q + (bid >> 3);
    int bx = swz % gridDim.x, by = swz / gridDim.x;
    const int r0 = by * 64, c0 = bx * 128;

    const ushortT* aSrc[2];
    int offA[2];
#pragma unroll
    for (int i = 0; i < 2; ++i) {
        int off = wid * 2048 + i * 1024 + lane * 16;
        int row = off >> 7;
        int sg = ((off >> 4) & 7) ^ (row & 7);
        aSrc[i] = A + (size_t)(r0 + row) * K + sg * 8;
        offA[i] = off;
    }
    const ushortT* bSrc[4];
    int offB[4];
#pragma unroll
    for (int i = 0; i < 4; ++i) {
        int off = wid * 4096 + i * 1024 + lane * 16;
        int row = off >> 7;
        int sg = ((off >> 4) & 7) ^ (row & 7);
        bSrc[i] = Bw + (size_t)(c0 + row) * K + sg * 8;
        offB[i] = off;
    }

    const int nkt = K >> 6;
    // prologue: tiles 0 and 1 (12 loads outstanding)
#pragma unroll
    for (int i = 0; i < 2; ++i) gload16(aSrc[i], (char*)As[0] + offA[i]);
#pragma unroll
    for (int i = 0; i < 4; ++i) gload16(bSrc[i], (char*)Bs[0] + offB[i]);
#pragma unroll
    for (int i = 0; i < 2; ++i) gload16(aSrc[i] + 64, (char*)As[1] + offA[i]);
#pragma unroll
    for (int i = 0; i < 4; ++i) gload16(bSrc[i] + 64, (char*)Bs[1] + offB[i]);

    f32x4 acc[2][4] = {};

    for (int t = 0; t < nkt; ++t) {
        const int cur = t & 1;
        if (t == nkt - 1) asm volatile("s_waitcnt vmcnt(0)" ::: "memory");
        else              asm volatile("s_waitcnt vmcnt(6)" ::: "memory");
        __builtin_amdgcn_s_barrier();
        __builtin_amdgcn_sched_barrier(0);
        const ushortT* Ac = As[cur];
        const ushortT* Bc = Bs[cur];
        __builtin_amdgcn_s_setprio(1);
#pragma unroll
        for (int kk = 0; kk < 2; ++kk) {
            int g0 = kk * 4 + l4;
            bf16x8 af[2], bfv[4];
#pragma unroll
            for (int mi = 0; mi < 2; ++mi)
                af[mi] = *(const bf16x8*)&Ac[LIX(wm * 32 + mi * 16 + l15, g0)];
#pragma unroll
            for (int ni = 0; ni < 4; ++ni)
                bfv[ni] = *(const bf16x8*)&Bc[LIX(wn * 64 + ni * 16 + l15, g0)];
#pragma unroll
            for (int mi = 0; mi < 2; ++mi)
#pragma unroll
                for (int ni = 0; ni < 4; ++ni)
                    acc[mi][ni] = __builtin_amdgcn_mfma_f32_16x16x32_bf16(
                        bfv[ni], af[mi], acc[mi][ni], 0, 0, 0);
        }
        __builtin_amdgcn_s_setprio(0);
        __builtin_amdgcn_s_barrier();
        asm volatile("" ::: "memory");
        if (t + 2 < nkt) {
            int kt2 = (t + 2) << 6;
#pragma unroll
            for (int i = 0; i < 2; ++i) gload16(aSrc[i] + kt2, (char*)As[cur] + offA[i]);
#pragma unroll
            for (int i = 0; i < 4; ++i) gload16(bSrc[i] + kt2, (char*)Bs[cur] + offB[i]);
        }
    }

    const float alp = alpha ? alpha[0] : 1.0f;
#pragma unroll
    for (int mi = 0; mi < 2; ++mi) {
        int row = r0 + wm * 32 + mi * 16 + l15;
#pragma unroll
        for (int ni = 0; ni < 4; ++ni) {
            int colb = c0 + wn * 64 + ni * 16 + l4 * 4;
            f32x4 a = acc[mi][ni];
            if (bias) {
                float4 b4 = *(const float4*)&bias[colb];
                a[0] += b4.x; a[1] += b4.y; a[2] += b4.z; a[3] += b4.w;
            }
            if (do_relu) {
#pragma unroll
                for (int r = 0; r < 4; ++r) a[r] = fmaxf(a[r], 0.f);
            }
#pragma unroll
            for (int r = 0; r < 4; ++r) a[r] *= alp;
            size_t idx = (size_t)row * N + colb;
            if (resf) {
                float4 r4 = *(const float4*)&resf[idx];
                a[0] += r4.x; a[1] += r4.y; a[2] += r4.z; a[3] += r4.w;
            }
            if (resb) {
                ushort4 r4 = *(const ushort4*)&resb[idx];
                a[0] += bf2f(r4.x); a[1] += bf2f(r4.y);
                a[2] += bf2f(r4.z); a[3] += bf2f(r4.w);
            }
            if (outF)
                *(float4*)&outF[idx] = make_float4(a[0], a[1], a[2], a[3]);
            if (outB) {
                ushort4 o;
                o.x = f2bf(a[0]); o.y = f2bf(a[1]);
                o.z = f2bf(a[2]); o.w = f2bf(a[3]);
                *(ushort4*)&outB[idx] = o;
            }
        }
    }
}

// ---------- HA diagonal scores (QD pre-scaled by NORM*log2e) ----------
__global__ __launch_bounds__(256) void diag_dot_bb(const ushortT* __restrict__ QD,
                                                   const ushortT* __restrict__ K,
                                                   float* __restrict__ Sdg) {
    int i = blockIdx.x * 256 + threadIdx.x;
    int h = i & 7, n = (i >> 3) & 511, b = i >> 12;
    int dix = (n < NPICKk) ? n + NPICKk : n - NPICKk;
    const ushortT* q = QD + (((size_t)(b * Nn + n) * Hh + h) << 6);
    const ushortT* k = K + (((size_t)(b * Nn + dix) * Hh + h) << 6);
    float s = 0.f;
#pragma unroll
    for (int d = 0; d < 64; d += 4) {
        ushort4 a = *(const ushort4*)(q + d);
        ushort4 c = *(const ushort4*)(k + d);
        s += bf2f(a.x) * bf2f(c.x) + bf2f(a.y) * bf2f(c.y)
           + bf2f(a.z) * bf2f(c.z) + bf2f(a.w) * bf2f(c.w);
    }
    Sdg[i] = s;
}

// ---------- flash attention: T14 reg-staged double-buffered K/V, lazy max, deferred L ----------
template <int HA>
__global__ __launch_bounds__(256) void attn10(
    const ushortT* __restrict__ Qm, const ushortT* __restrict__ Km,
    const ushortT* __restrict__ Vtm, const ushortT* __restrict__ QAm,
    const ushortT* __restrict__ QBm, const float* __restrict__ Sdg,
    ushortT* __restrict__ Out)
{
    __shared__ __align__(16) ushortT Ks[64 * 64];
    __shared__ __align__(16) ushortT Vs[64 * 64];
    __shared__ __align__(16) ushortT Pw[4][16 * 64];
    __shared__ float sdl[64];

    const int tid = threadIdx.x, wid = tid >> 6, lane = tid & 63;
    const int l15 = lane & 15, l4 = lane >> 4;

    const int p = blockIdx.x + (blockIdx.y << 3) + (blockIdx.z << 6);
    const int n0 = (((p >> 3) & 7)) << 6;
    const int g8 = (p & 7) | ((p >> 6) << 3);
    const int h = g8 & 7, b = g8 >> 3;
    const int bh = b * Hh + h;

    const size_t qrow = (((size_t)(b * Nn + n0 + wid * 16 + l15) * Hh + h) << 6);
    bf16x8 qf[2], xaf[2], xbf[2];
#pragma unroll
    for (int kk = 0; kk < 2; ++kk) {
        int g0 = kk * 4 + l4;
        qf[kk] = *(const bf16x8*)&Qm[qrow + g0 * 8];
        if (HA) {
            xaf[kk] = *(const bf16x8*)&QAm[qrow + g0 * 8];
            xbf[kk] = *(const bf16x8*)&QBm[qrow + g0 * 8];
        }
    }
    if (HA && tid < 64) sdl[tid] = Sdg[((size_t)(b * Nn + n0 + tid)) * Hh + h];
    const int td = (n0 < NPICKk) ? ((n0 + NPICKk) >> 6) : ((n0 - NPICKk) >> 6);

    const ushortT* kSrc[2]; ushortT* kDst[2];
    const ushortT* vSrc[2]; ushortT* vDst[2];
#pragma unroll
    for (int i = 0; i < 2; ++i) {
        int off = wid * 2048 + i * 1024 + lane * 16;
        int row = off >> 7, sg = ((off >> 4) & 7) ^ (row & 7);
        kSrc[i] = Km + (((size_t)(b * Nn + row) * Hh + h) << 6) + sg * 8;
        kDst[i] = (ushortT*)((char*)Ks + off);
        vSrc[i] = Vtm + (((size_t)(bh * 64 + row)) << 9) + sg * 8;
        vDst[i] = (ushortT*)((char*)Vs + off);
    }

    float M[4], Lp[4];
    f32x4 Oa[4] = {};
#pragma unroll
    for (int r = 0; r < 4; ++r) { M[r] = -INFINITY; Lp[r] = 0.f; }

    bf16x8 krbuf[2][2], vrbuf[2][2];
#pragma unroll
    for (int i = 0; i < 2; ++i) {
        krbuf[0][i] = *(const bf16x8*)kSrc[i];
        vrbuf[0][i] = *(const bf16x8*)vSrc[i];
    }

#pragma unroll
    for (int t = 0; t < 8; ++t) {
        const int cur = t & 1, nxt = cur ^ 1;
        __builtin_amdgcn_s_barrier();
#pragma unroll
        for (int i = 0; i < 2; ++i) {
            *(bf16x8*)kDst[i] = krbuf[cur][i];
            *(bf16x8*)vDst[i] = vrbuf[cur][i];
        }
        if (t < 7) {
#pragma unroll
            for (int i = 0; i < 2; ++i) {
                krbuf[nxt][i] = *(const bf16x8*)(kSrc[i] + (size_t)(t + 1) * (64 * Hh * VDd));
                vrbuf[nxt][i] = *(const bf16x8*)(vSrc[i] + (t + 1) * 64);
            }
        }
        asm volatile("s_waitcnt lgkmcnt(0)" ::: "memory");
        __builtin_amdgcn_s_barrier();
        __builtin_amdgcn_sched_barrier(0);

        __builtin_amdgcn_s_setprio(1);
        f32x4 s1[4] = {}, sX[4] = {};
#pragma unroll
        for (int kk = 0; kk < 2; ++kk) {
            bf16x8 aq = qf[kk];
            bf16x8 ax;
            if (HA) ax = (t >= 4) ? xbf[kk] : xaf[kk];
#pragma unroll
            for (int ni = 0; ni < 4; ++ni) {
                bf16x8 bk = *(const bf16x8*)&Ks[LIX(ni * 16 + l15, kk * 4 + l4)];
                s1[ni] = __builtin_amdgcn_mfma_f32_16x16x32_bf16(aq, bk, s1[ni], 0, 0, 0);
                if (HA)
                    sX[ni] = __builtin_amdgcn_mfma_f32_16x16x32_bf16(ax, bk, sX[ni], 0, 0, 0);
            }
        }
        __builtin_amdgcn_s_setprio(0);

        const bool dt = HA && (t == td);

        float mloc[4];
        bool grow = false;
#pragma unroll
        for (int r = 0; r < 4; ++r) {
            int rw = wid * 16 + l4 * 4 + r;
            float m = s1[0][r];
#pragma unroll
            for (int ni = 1; ni < 4; ++ni) m = fmaxf(m, s1[ni][r]);
            if (HA) {
#pragma unroll
                for (int ni = 0; ni < 4; ++ni) m = fmaxf(m, sX[ni][r]);
            }
            if (dt && l15 == l4 * 4 + r) m = fmaxf(m, sdl[rw]);
            mloc[r] = m;
            grow = grow || (m > M[r] + 8.f);
        }
        if (__any(grow)) {
#pragma unroll
            for (int r = 0; r < 4; ++r) {
                float m = mloc[r];
#pragma unroll
                for (int o = 8; o >= 1; o >>= 1) m = fmaxf(m, __shfl_xor(m, o, 16));
                float mn = fmaxf(M[r], m);
                float sc = exp2fast(M[r] - mn);
                M[r] = mn; Lp[r] *= sc;
#pragma unroll
                for (int ni = 0; ni < 4; ++ni) Oa[ni][r] *= sc;
            }
        }

#pragma unroll
        for (int r = 0; r < 4; ++r) {
            int rw = wid * 16 + l4 * 4 + r;
            float rs = 0.f;
#pragma unroll
            for (int ni = 0; ni < 4; ++ni) {
                float pv = exp2fast(s1[ni][r] - M[r]);
                if (HA) pv += exp2fast(sX[ni][r] - M[r]);
                if (dt && ni == wid && l15 == l4 * 4 + r) pv += exp2fast(sdl[rw] - M[r]);
                s1[ni][r] = pv;
                rs += pv;
            }
            Lp[r] += rs;
        }

#pragma unroll
        for (int ni = 0; ni < 4; ++ni)
#pragma unroll
            for (int r = 0; r < 4; ++r) {
                int prow = l4 * 4 + r;
                int col = ni * 16 + l15;
                Pw[wid][(prow << 6) + ((((col >> 3) ^ (prow & 7))) << 3) + (col & 7)] =
                    f2bf(s1[ni][r]);
            }

        __builtin_amdgcn_s_setprio(1);
#pragma unroll
        for (int kk = 0; kk < 2; ++kk) {
            int g0 = kk * 4 + l4;
            bf16x8 ap = *(const bf16x8*)&Pw[wid][LIX(l15, g0)];
#pragma unroll
            for (int ni = 0; ni < 4; ++ni) {
                bf16x8 bv = *(const bf16x8*)&Vs[LIX(ni * 16 + l15, g0)];
                Oa[ni] = __builtin_amdgcn_mfma_f32_16x16x32_bf16(ap, bv, Oa[ni], 0, 0, 0);
            }
        }
        __builtin_amdgcn_s_setprio(0);
    }

#pragma unroll
    for (int r = 0; r < 4; ++r) {
        float l = Lp[r];
#pragma unroll
        for (int o = 8; o >= 1; o >>= 1) l += __shfl_xor(l, o, 16);
        float inv = 1.0f / l;
        size_t obase = (((size_t)(b * Nn + n0 + wid * 16 + l4 * 4 + r) * Hh + h) << 6);
#pragma unroll
        for (int ni = 0; ni < 4; ++ni)
            Out[obase + ni * 16 + l15] = f2bf(Oa[ni][r] * inv);
    }
}

extern "C" void kernel_launch(void* const* d_in, const int* in_sizes, int n_in,
                              void* d_out, int out_size, void* d_ws, size_t ws_size,
                              hipStream_t stream)
{
    const float* x = (const float*)d_in[0];

    int dictOrder = (in_sizes[18] != 512);
    const float* comb_w  = (const float*)d_in[17];
    const float* comb2_w = (const float*)d_in[dictOrder ? 18 : 19];
    const float* comb3_w = (const float*)d_in[dictOrder ? 19 : 21];
    const float* comb_b  = (const float*)d_in[dictOrder ? 20 : 18];
    const float* comb2_b = (const float*)d_in[dictOrder ? 21 : 20];
    const float* comb3_b = (const float*)d_in[22];
    const float* alpha1 = (const float*)d_in[23];
    const float* alpha2 = (const float*)d_in[24];
    const float* alpha3 = (const float*)d_in[25];
    const float* ff1_w1 = (const float*)d_in[26];
    const float* ff1_b1 = (const float*)d_in[27];
    const float* ff1_w2 = (const float*)d_in[28];
    const float* ff1_b2 = (const float*)d_in[29];
    const float* ffa1   = (const float*)d_in[30];
    const float* ff2_w1 = (const float*)d_in[31];
    const float* ff2_b1 = (const float*)d_in[32];
    const float* ff2_w2 = (const float*)d_in[33];
    const float* ff2_b2 = (const float*)d_in[34];
    const float* ffa2   = (const float*)d_in[35];
    const float* ff3_w1 = (const float*)d_in[36];
    const float* ff3_b1 = (const float*)d_in[37];
    const float* ff3_w2 = (const float*)d_in[38];
    const float* ff3_b2 = (const float*)d_in[39];
    const float* ffa3   = (const float*)d_in[40];

    // ---- workspace layout (bytes) ----
    char* W = (char*)d_ws;
    ushortT* wbHead = (ushortT*)(W + 0);
    ushortT* wbMha  = (ushortT*)(W + 4718592);
    ushortT* wbComb = (ushortT*)(W + 8388608);
    ushortT* wbFf1  = (ushortT*)(W + 9961472);
    ushortT* wbFf2  = (ushortT*)(W + 16252928);
    ushortT* xbf    = (ushortT*)(W + 22544384);
    float*   Sd     = (float*)  (W + 30932992);
    ushortT* bufQ   = (ushortT*)(W + 31195136);
    ushortT* bufK   = (ushortT*)(W + 39583744);
    ushortT* bufVt  = (ushortT*)(W + 47972352);
    ushortT* bufQA  = (ushortT*)(W + 56360960);
    ushortT* bufQB  = (ushortT*)(W + 64749568);
    ushortT* bufQD  = (ushortT*)(W + 73138176);
    ushortT* hidden = (ushortT*)(W + 81526784);
    ushortT* curb   = (ushortT*)(W + 115081216);
    ushortT* bufHA  = xbf;
    float*   cur    = (float*)d_out;

    dim3 tb(256);
    const int TOK = Bb * Nn;  // 8192
    const size_t WS = 512 * 512;
    const size_t WF = 2048 * 512;

    // 1. casts / transposes (batched)
    hipLaunchKernelGGL(castx, dim3(TOK * 512 / 1024), tb, 0, stream, x, xbf);
    {
        Ptrs9 s; for (int i = 0; i < 9; ++i) s.p[i] = (const float*)d_in[1 + i];
        hipLaunchKernelGGL(thead, dim3(1, 8, 72), tb, 0, stream, s, wbHead);
    }
    {
        Ptrs10 s;
        for (int i = 0; i < 7; ++i) s.p[i] = (const float*)d_in[10 + i];
        s.p[7] = comb_w; s.p[8] = comb2_w; s.p[9] = comb3_w;
        hipLaunchKernelGGL(tsq, dim3(8, 8, 10), tb, 0, stream, s, wbMha);
    }
    {
        Ptrs6 s;
        s.p[0] = ff1_w1; s.p[1] = ff2_w1; s.p[2] = ff3_w1;
        s.p[3] = ff1_w2; s.p[4] = ff2_w2; s.p[5] = ff3_w2;
        hipLaunchKernelGGL(tff, dim3(32, 32, 6), tb, 0, stream, s, wbFf1);
    }

    auto gemm = [&](PtrsB Bp, PtrsD Db, const ushortT* A, float* oF,
                    int M, int Ncc, int Kc, const float* bias, const float* res,
                    const float* alp, int relu, int nroute, int vtmask, int scmask) {
        hipLaunchKernelGGL(gemm_bf, dim3(Ncc / 128, M / 128), tb, 0, stream,
                           Bp, Db, A, oF, M, Ncc, Kc, bias, res, alp, relu, nroute,
                           vtmask, scmask);
    };
    auto g64 = [&](const ushortT* Bw, const ushortT* A, float* oF, ushortT* oB,
                   int M, int Ncc, int Kc, const float* bias, const float* resf,
                   const ushortT* resb, const float* alp, int relu) {
        hipLaunchKernelGGL(gemm64, dim3(Ncc / 128, M / 64), tb, 0, stream,
                           Bw, A, oF, oB, M, Ncc, Kc, bias, resf, resb, alp, relu);
    };
    auto uni = [&](const ushortT* w) { PtrsB b; for (int i = 0; i < 12; ++i) b.p[i] = w; return b; };
    auto d1 = [&](ushortT* d) { PtrsD dd = {}; dd.p[0] = d; return dd; };

    // 2. HA projections: ONE fused GEMM, N=3072 (Q/QA/QB/QD pre-scaled, scmask=57)
    {
        PtrsB b;
        b.p[0] = b.p[1] = wbHead + 0 * WS;
        b.p[2] = b.p[3] = wbHead + 1 * WS;
        b.p[4] = b.p[5] = wbHead + 2 * WS;
        b.p[6] = wbHead + 4 * WS; b.p[7] = wbHead + 8 * WS;
        b.p[8] = wbHead + 5 * WS; b.p[9] = wbHead + 7 * WS;
        b.p[10] = wbHead + 3 * WS; b.p[11] = wbHead + 6 * WS;
        PtrsD d; d.p[0] = bufQ; d.p[1] = bufK; d.p[2] = bufVt;
        d.p[3] = bufQA; d.p[4] = bufQB; d.p[5] = bufQD;
        gemm(b, d, xbf, nullptr, TOK, 3072, 512, nullptr, nullptr, nullptr, 0, 6, 4, 57);
    }

    // 3. HA attention
    hipLaunchKernelGGL(diag_dot_bb, dim3(Bb * Nn * Hh / 256), tb, 0, stream, bufQD, bufK, Sd);
    hipLaunchKernelGGL((attn10<1>), dim3(Nn / 64, Hh, Bb), tb, 0, stream,
                       bufQ, bufK, bufVt, bufQA, bufQB, Sd, bufHA);

    // 4. comb3 + FF3 (bf16 residual stream)
    g64(wbComb + 2 * WS, bufHA, nullptr, curb, TOK, 512, 512, comb3_b, x, nullptr, alpha3, 0);
    gemm(uni(wbFf1 + 2 * WF), d1(hidden), curb, nullptr, TOK, 2048, 512, ff3_b1, nullptr, nullptr, 1, 0, 0, 0);
    g64(wbFf2 + 2 * WF, hidden, nullptr, curb, TOK, 512, 2048, ff3_b2, nullptr, curb, ffa3, 0);

    // 5. MHA1
    {
        PtrsB b;
        b.p[0] = b.p[1] = wbMha + 0 * WS;
        b.p[2] = b.p[3] = wbMha + 1 * WS;
        b.p[4] = b.p[5] = wbMha + 2 * WS;
        PtrsD d = {}; d.p[0] = bufQ; d.p[1] = bufK; d.p[2] = bufVt;
        gemm(b, d, curb, nullptr, TOK, 1536, 512, nullptr, nullptr, nullptr, 0, 3, 4, 1);
    }
    hipLaunchKernelGGL((attn10<0>), dim3(Nn / 64, Hh, Bb), tb, 0, stream,
                       bufQ, bufK, bufVt, nullptr, nullptr, nullptr, bufHA);
    g64(wbComb + 0 * WS, bufHA, nullptr, curb, TOK, 512, 512, comb_b, nullptr, curb, alpha1, 0);
    gemm(uni(wbFf1 + 0 * WF), d1(hidden), curb, nullptr, TOK, 2048, 512, ff1_b1, nullptr, nullptr, 1, 0, 0, 0);
    g64(wbFf2 + 0 * WF, hidden, nullptr, curb, TOK, 512, 2048, ff1_b2, nullptr, curb, ffa1, 0);

    // 6. MHA2
    {
        PtrsB b;
        b.p[0] = wbMha + 3 * WS; b.p[1] = wbMha + 4 * WS;
        b.p[2] = b.p[3] = wbMha + 5 * WS;
        b.p[4] = b.p[5] = wbMha + 6 * WS;
        PtrsD d = {}; d.p[0] = bufQ; d.p[1] = bufK; d.p[2] = bufVt;
        gemm(b, d, curb, nullptr, TOK, 1536, 512, nullptr, nullptr, nullptr, 0, 3, 4, 1);
    }
    hipLaunchKernelGGL((attn10<0>), dim3(Nn / 64, Hh, Bb), tb, 0, stream,
                       bufQ, bufK, bufVt, nullptr, nullptr, nullptr, bufHA);
    g64(wbComb + 1 * WS, bufHA, nullptr, curb, TOK, 512, 512, comb2_b, nullptr, curb, alpha2, 0);
    gemm(uni(wbFf1 + 1 * WF), d1(hidden), curb, nullptr, TOK, 2048, 512, ff2_b1, nullptr, nullptr, 1, 0, 0, 0);
    // final: write f32 d_out
    g64(wbFf2 + 1 * WF, hidden, cur, nullptr, TOK, 512, 2048, ff2_b2, nullptr, curb, ffa2, 0);
}